// Round 1
// baseline (2876.007 us; speedup 1.0000x reference)
//
#include <hip/hip_runtime.h>
#include <math.h>

// Problem constants
#define NA   4096
#define NPA  8192
#define NT   4096
#define E_AP 80000
#define E_PA 80000
#define E_TP 160000

__device__ __forceinline__ unsigned fenc(float f){
  unsigned u = __float_as_uint(f);
  return (u & 0x80000000u) ? ~u : (u | 0x80000000u);
}
__device__ __forceinline__ float fdec(unsigned u){
  return (u & 0x80000000u) ? __uint_as_float(u & 0x7fffffffu) : __uint_as_float(~u);
}

// ---------------------------------------------------------------- GEMM
// C[M,N] = act(A[M,K]@B[K,N] + bias + addmat + (accumulate? C : 0))
// row-major, leading dims; z-batch via element offsets (per-head GAT GEMM).
template<int ACT>
__global__ __launch_bounds__(256) void gemm_k(
    const float* __restrict__ A, const float* __restrict__ B, float* __restrict__ C,
    const float* __restrict__ bias, const float* __restrict__ addmat,
    int M, int N, int K, int lda, int ldb, int ldc,
    int aOffZ, int bOffZ, int cOffZ, int accumulate)
{
  A += (size_t)blockIdx.z * aOffZ;
  B += (size_t)blockIdx.z * bOffZ;
  C += (size_t)blockIdx.z * cOffZ;
  __shared__ float As[16][68];
  __shared__ float Bs[16][68];
  int bm = blockIdx.x * 64, bn = blockIdx.y * 64;
  int tid = threadIdx.x;
  int tr = tid >> 4, tc = tid & 15;
  float acc[4][4] = {{0.f}};
  for (int k0 = 0; k0 < K; k0 += 16) {
#pragma unroll
    for (int i = 0; i < 4; ++i) {
      int idx = tid + i * 256;          // 0..1023
      int r  = idx >> 4, kk = idx & 15; // A: 16 contiguous k per row
      int gr = bm + r, gk = k0 + kk;
      As[kk][r] = (gr < M && gk < K) ? A[(size_t)gr * lda + gk] : 0.f;
      int c  = idx & 63, k2 = idx >> 6; // B: 64 contiguous cols
      int gc = bn + c, gk2 = k0 + k2;
      Bs[k2][c] = (gk2 < K && gc < N) ? B[(size_t)gk2 * ldb + gc] : 0.f;
    }
    __syncthreads();
#pragma unroll
    for (int kk = 0; kk < 16; ++kk) {
      float a0[4], b0[4];
#pragma unroll
      for (int i = 0; i < 4; ++i) a0[i] = As[kk][tr * 4 + i];
#pragma unroll
      for (int j = 0; j < 4; ++j) b0[j] = Bs[kk][tc * 4 + j];
#pragma unroll
      for (int i = 0; i < 4; ++i)
#pragma unroll
        for (int j = 0; j < 4; ++j) acc[i][j] = fmaf(a0[i], b0[j], acc[i][j]);
    }
    __syncthreads();
  }
#pragma unroll
  for (int i = 0; i < 4; ++i) {
    int r = bm + tr * 4 + i;
    if (r >= M) continue;
#pragma unroll
    for (int j = 0; j < 4; ++j) {
      int c = bn + tc * 4 + j;
      if (c >= N) continue;
      float v = acc[i][j];
      if (bias)   v += bias[c];
      if (addmat) v += addmat[(size_t)r * ldc + c];
      if (accumulate) v += C[(size_t)r * ldc + c];
      if (ACT == 1) v = fmaxf(v, 0.f);
      C[(size_t)r * ldc + c] = v;
    }
  }
}

// ---------------------------------------------------------------- GAT pieces
// Ps[k,h] = sum_c W[k, h*128+c]*as[h,c];  Pd likewise with ad.
__global__ void gat_proj_k(const float* __restrict__ W, const float* __restrict__ as_,
                           const float* __restrict__ ad_, float* __restrict__ Ps,
                           float* __restrict__ Pd){
  int t = blockIdx.x * blockDim.x + threadIdx.x;
  if (t >= 128 * 8) return;
  int k = t >> 3, h = t & 7;
  const float* wr = W + (size_t)k * 1024 + h * 128;
  const float* a1 = as_ + h * 128;
  const float* a2 = ad_ + h * 128;
  float s1 = 0.f, s2 = 0.f;
  for (int c = 0; c < 128; ++c){ float wv = wr[c]; s1 = fmaf(wv, a1[c], s1); s2 = fmaf(wv, a2[c], s2); }
  Ps[k * 8 + h] = s1;
  Pd[k * 8 + h] = s2;
}

__global__ void hist_k(const int* __restrict__ dst, int* __restrict__ cnt, int E){
  int i = blockIdx.x * blockDim.x + threadIdx.x;
  if (i < E) atomicAdd(&cnt[dst[i]], 1);
}

__global__ void exscan_k(const int* __restrict__ in, int* __restrict__ out, int n){
  __shared__ int buf[256];
  __shared__ int carry;
  if (threadIdx.x == 0) carry = 0;
  __syncthreads();
  for (int base = 0; base < n; base += 256){
    int i = base + threadIdx.x;
    int v = (i < n) ? in[i] : 0;
    buf[threadIdx.x] = v;
    __syncthreads();
    for (int o2 = 1; o2 < 256; o2 <<= 1){
      int tval = (threadIdx.x >= o2) ? buf[threadIdx.x - o2] : 0;
      __syncthreads();
      buf[threadIdx.x] += tval;
      __syncthreads();
    }
    if (i < n) out[i] = carry + buf[threadIdx.x] - v;
    int total = buf[255];
    __syncthreads();
    if (threadIdx.x == 0) carry += total;
    __syncthreads();
  }
}

__global__ void scatter_k(const int* __restrict__ dst, const int* __restrict__ off,
                          int* __restrict__ cur, int* __restrict__ eidx, int E){
  int i = blockIdx.x * blockDim.x + threadIdx.x;
  if (i >= E) return;
  int d = dst[i];
  int p = atomicAdd(&cur[d], 1);
  eidx[off[d] + p] = i;
}

// per-(edge,head): e = leakyrelu(ss[src]+sd[dst]); store; atomic max encode
__global__ void edgeA_k(const int* __restrict__ src, const int* __restrict__ dst,
                        const float* __restrict__ ss, const float* __restrict__ sd,
                        float* __restrict__ tmp, unsigned* __restrict__ mEnc, int E, int H){
  int i = blockIdx.x * blockDim.x + threadIdx.x;
  if (i >= E * H) return;
  int e = i / H, h = i - e * H;
  float v = ss[src[e] * H + h] + sd[dst[e] * H + h];
  v = v > 0.f ? v : 0.2f * v;
  tmp[i] = v;
  atomicMax(mEnc + dst[e] * H + h, fenc(v));
}

// w = exp(e - m[dst]);  den[dst] += w
__global__ void edgeB_k(const int* __restrict__ dst, float* __restrict__ w,
                        const unsigned* __restrict__ mEnc, float* __restrict__ den, int E, int H){
  int i = blockIdx.x * blockDim.x + threadIdx.x;
  if (i >= E * H) return;
  int e = i / H, h = i - e * H;
  float m = fdec(mEnc[dst[e] * H + h]);
  float ww = __expf(w[i] - m);
  w[i] = ww;
  atomicAdd(den + dst[e] * H + h, ww);
}

// x-space aggregation, H=8: agg[d,h,c] = (sum_e w[e,h]*x[src_e,c]) / (den[d,h]+1e-16)
__global__ __launch_bounds__(256) void gat_agg8_k(
    const int* __restrict__ eidx, const int* __restrict__ off, const int* __restrict__ cnt,
    const int* __restrict__ src, const float* __restrict__ x,
    const float* __restrict__ w, const float* __restrict__ den, float* __restrict__ agg){
  int d = blockIdx.x;
  int t = threadIdx.x;
  int c = t & 127, hb = (t >> 7) << 2;  // two thread-groups: heads 0..3 / 4..7
  float a0 = 0.f, a1 = 0.f, a2 = 0.f, a3 = 0.f;
  int base = off[d], n = cnt[d];
  for (int k = 0; k < n; ++k){
    int e = eidx[base + k];
    int s = src[e];
    float xv = x[(size_t)s * 128 + c];
    const float* we = w + (size_t)e * 8 + hb;
    a0 = fmaf(we[0], xv, a0); a1 = fmaf(we[1], xv, a1);
    a2 = fmaf(we[2], xv, a2); a3 = fmaf(we[3], xv, a3);
  }
  const float* dd = den + (size_t)d * 8 + hb;
  float* o = agg + (size_t)d * 1024 + c;
  o[(hb + 0) * 128] = a0 / (dd[0] + 1e-16f);
  o[(hb + 1) * 128] = a1 / (dd[1] + 1e-16f);
  o[(hb + 2) * 128] = a2 / (dd[2] + 1e-16f);
  o[(hb + 3) * 128] = a3 / (dd[3] + 1e-16f);
}

// transform-first aggregation, H=1, C=128 (gat2): out = sum w*hs[src]/(den+eps) + b
__global__ void gat_agg1_k(const int* __restrict__ eidx, const int* __restrict__ off,
                           const int* __restrict__ cnt, const int* __restrict__ src,
                           const float* __restrict__ hs, const float* __restrict__ w,
                           const float* __restrict__ den, const float* __restrict__ bias,
                           float* __restrict__ out){
  int d = blockIdx.x;
  int c = threadIdx.x; // 128
  float a = 0.f;
  int base = off[d], n = cnt[d];
  for (int k = 0; k < n; ++k){
    int e = eidx[base + k];
    a = fmaf(w[e], hs[(size_t)src[e] * 128 + c], a);
  }
  out[(size_t)d * 128 + c] = a / (den[d] + 1e-16f) + bias[c];
}

__global__ void rowdot_k(const float* __restrict__ X, const float* __restrict__ v,
                         float* __restrict__ out, int C){
  int r = blockIdx.x;
  int t = threadIdx.x; // 64
  float s = 0.f;
  for (int c = t; c < C; c += 64) s = fmaf(X[(size_t)r * C + c], v[c], s);
#pragma unroll
  for (int o = 32; o; o >>= 1) s += __shfl_down(s, o);
  if (t == 0) out[r] = s;
}

__global__ void bias2_relu_k(float* __restrict__ x, const float* __restrict__ b0,
                             const float* __restrict__ b1, int total, int cols){
  int i = blockIdx.x * blockDim.x + threadIdx.x;
  if (i >= total) return;
  int c = i % cols;
  float v = x[i] + b0[c];
  if (b1) v += b1[c];
  x[i] = fmaxf(v, 0.f);
}

// ---------------------------------------------------------------- PE loss
__global__ __launch_bounds__(256) void loss_k(const float* __restrict__ peQ,
    const float* __restrict__ peK, const float* __restrict__ A4, float* __restrict__ lossAcc)
{
  __shared__ float Qs[16][68];
  __shared__ float Ks[16][68];
  int br = blockIdx.x * 64, bc = blockIdx.y * 64;
  int tid = threadIdx.x, tr = tid >> 4, tc = tid & 15;
  float acc[4][4] = {{0.f}};
  for (int k0 = 0; k0 < 128; k0 += 16){
#pragma unroll
    for (int i = 0; i < 4; ++i){
      int idx = tid + i * 256;
      int r = idx >> 4, kk = idx & 15;
      Qs[kk][r] = peQ[(size_t)(br + r) * 128 + k0 + kk];
      Ks[kk][r] = peK[(size_t)(bc + r) * 128 + k0 + kk];
    }
    __syncthreads();
#pragma unroll
    for (int kk = 0; kk < 16; ++kk){
      float a0[4], b0[4];
#pragma unroll
      for (int i = 0; i < 4; ++i) a0[i] = Qs[kk][tr * 4 + i];
#pragma unroll
      for (int j = 0; j < 4; ++j) b0[j] = Ks[kk][tc * 4 + j];
#pragma unroll
      for (int i = 0; i < 4; ++i)
#pragma unroll
        for (int j = 0; j < 4; ++j) acc[i][j] = fmaf(a0[i], b0[j], acc[i][j]);
    }
    __syncthreads();
  }
  float err = 0.f;
#pragma unroll
  for (int i = 0; i < 4; ++i){
    int r = br + tr * 4 + i;
    float s0 = 1.f / (1.f + __expf(-acc[i][0]));
    float s1 = 1.f / (1.f + __expf(-acc[i][1]));
    float s2 = 1.f / (1.f + __expf(-acc[i][2]));
    float s3 = 1.f / (1.f + __expf(-acc[i][3]));
    size_t rowoff = (size_t)r * 4096 + bc + tc * 4;
#pragma unroll
    for (int q = 0; q < 4; ++q){
      const float4 av = *(const float4*)(A4 + (size_t)q * 16777216 + rowoff);
      float d0 = s0 - av.x, d1 = s1 - av.y, d2 = s2 - av.z, d3 = s3 - av.w;
      err += d0 * d0 + d1 * d1 + d2 * d2 + d3 * d3;
    }
  }
  __shared__ float red[256];
  red[tid] = err;
  __syncthreads();
  for (int o = 128; o; o >>= 1){
    if (tid < o) red[tid] += red[tid + o];
    __syncthreads();
  }
  if (tid == 0) atomicAdd(lossAcc, red[0]);
}

__global__ void finalize_loss_k(const float* __restrict__ acc, float* __restrict__ out){
  out[0] = acc[0] * (1.0f / 67108864.0f); // /(4*4096*4096)
}

__global__ void db_k(const int* __restrict__ deg, float* __restrict__ dbv){
  int i = blockIdx.x * blockDim.x + threadIdx.x;
  if (i >= NA) return;
  dbv[i] = logf(fmaxf((float)deg[i], 1.f));
}

// ---------------------------------------------------------------- transformer
// flash attention, heads=8, dh=16, with per-key bias db[m]; one wave / 64 q-rows
__global__ __launch_bounds__(64) void attn_k(const float* __restrict__ Q,
    const float* __restrict__ K, const float* __restrict__ V,
    const float* __restrict__ dbv, float* __restrict__ O)
{
  int h = blockIdx.y;
  int t = threadIdx.x;
  int r = blockIdx.x * 64 + t;
  __shared__ float Kt[64][20];
  __shared__ float Vt[64][20];
  __shared__ float dbs[64];
  __shared__ float sbuf[64][68];
  float q[16];
#pragma unroll
  for (int j = 0; j < 16; ++j) q[j] = Q[(size_t)r * 128 + h * 16 + j] * 0.25f;
  float m = -1e30f, l = 0.f;
  float acc[16];
#pragma unroll
  for (int j = 0; j < 16; ++j) acc[j] = 0.f;
  for (int kb = 0; kb < 4096; kb += 64){
    int kr = kb + t;
#pragma unroll
    for (int j = 0; j < 16; ++j){
      Kt[t][j] = K[(size_t)kr * 128 + h * 16 + j];
      Vt[t][j] = V[(size_t)kr * 128 + h * 16 + j];
    }
    dbs[t] = dbv[kr];
    __syncthreads();
    float tmax = -1e30f;
#pragma unroll 4
    for (int k = 0; k < 64; ++k){
      float s = dbs[k];
#pragma unroll
      for (int j = 0; j < 16; ++j) s = fmaf(q[j], Kt[k][j], s);
      sbuf[t][k] = s;
      tmax = fmaxf(tmax, s);
    }
    float mn = fmaxf(m, tmax);
    float scale = __expf(m - mn);
    l *= scale;
#pragma unroll
    for (int j = 0; j < 16; ++j) acc[j] *= scale;
#pragma unroll 2
    for (int k = 0; k < 64; ++k){
      float p = __expf(sbuf[t][k] - mn);
      l += p;
#pragma unroll
      for (int j = 0; j < 16; ++j) acc[j] = fmaf(p, Vt[k][j], acc[j]);
    }
    m = mn;
    __syncthreads();
  }
  float invl = 1.f / l;
#pragma unroll
  for (int j = 0; j < 16; ++j) O[(size_t)r * 128 + h * 16 + j] = acc[j] * invl;
}

// layernorm over rows of 128 (biased var), out = (x-mean)*rsqrt(var+1e-5)*g + b
__global__ __launch_bounds__(64) void ln_k(const float* __restrict__ in,
    const float* __restrict__ g, const float* __restrict__ b, float* __restrict__ out){
  int r = blockIdx.x;
  int t = threadIdx.x;
  float v0 = in[(size_t)r * 128 + t], v1 = in[(size_t)r * 128 + 64 + t];
  float s = v0 + v1;
#pragma unroll
  for (int o = 32; o; o >>= 1) s += __shfl_down(s, o);
  float mean = __shfl(s, 0) * (1.f / 128.f);
  float d0 = v0 - mean, d1 = v1 - mean;
  float qv = d0 * d0 + d1 * d1;
#pragma unroll
  for (int o = 32; o; o >>= 1) qv += __shfl_down(qv, o);
  float var = __shfl(qv, 0) * (1.f / 128.f);
  float inv = rsqrtf(var + 1e-5f);
  out[(size_t)r * 128 + t]      = d0 * inv * g[t] + b[t];
  out[(size_t)r * 128 + 64 + t] = d1 * inv * g[64 + t] + b[64 + t];
}

__global__ void concat3_k(const float* __restrict__ a, const float* __restrict__ b,
                          const float* __restrict__ c, float* __restrict__ out, int rows){
  int i = blockIdx.x * blockDim.x + threadIdx.x;
  int total = rows * 384;
  if (i >= total) return;
  int r = i / 384, col = i - r * 384;
  float v = (col < 128) ? a[(size_t)r * 128 + col]
          : (col < 256) ? b[(size_t)r * 128 + col - 128]
                        : c[(size_t)r * 128 + col - 256];
  out[i] = v;
}

__global__ void softmax4_k(const float* __restrict__ logits, float* __restrict__ out){
  int r = blockIdx.x * blockDim.x + threadIdx.x;
  if (r >= NA) return;
  const float* l = logits + (size_t)r * 4;
  float m = fmaxf(fmaxf(l[0], l[1]), fmaxf(l[2], l[3]));
  float e0 = __expf(l[0] - m), e1 = __expf(l[1] - m), e2 = __expf(l[2] - m), e3 = __expf(l[3] - m);
  float inv = 1.f / (e0 + e1 + e2 + e3);
  out[(size_t)r * 4 + 0] = e0 * inv;
  out[(size_t)r * 4 + 1] = e1 * inv;
  out[(size_t)r * 4 + 2] = e2 * inv;
  out[(size_t)r * 4 + 3] = e3 * inv;
}

__global__ void setval_k(float* p, float v){ p[0] = v; }

// ---------------------------------------------------------------- host
extern "C" void kernel_launch(void* const* d_in, const int* in_sizes, int n_in,
                              void* d_out, int out_size, void* d_ws, size_t ws_size,
                              hipStream_t stream)
{
  (void)in_sizes; (void)n_in; (void)out_size;
  const float* x_author = (const float*)d_in[0];
  const float* x_paper  = (const float*)d_in[1];
  const float* x_term   = (const float*)d_in[2];
  const int* ap_src = (const int*)d_in[3];
  const int* ap_dst = (const int*)d_in[4];
  const int* pa_src = (const int*)d_in[5];
  const int* pa_dst = (const int*)d_in[6];
  const int* tp_src = (const int*)d_in[9];
  const int* tp_dst = (const int*)d_in[10];
  const float* original_A = (const float*)d_in[11];
  const int* deg = (const int*)d_in[12];
  const float* t1_W = (const float*)d_in[13]; const float* t1_b = (const float*)d_in[14];
  const float* t2_W = (const float*)d_in[15]; const float* t2_b = (const float*)d_in[16];
  const float* t3_W = (const float*)d_in[17]; const float* t3_b = (const float*)d_in[18];
  const float* gat1_W  = (const float*)d_in[19];
  const float* gat1_as = (const float*)d_in[20];
  const float* gat1_ad = (const float*)d_in[21];
  const float* gat1_b  = (const float*)d_in[22];
  const float* gat2_W  = (const float*)d_in[23];
  const float* gat2_as = (const float*)d_in[24];
  const float* gat2_ad = (const float*)d_in[25];
  const float* gat2_b  = (const float*)d_in[26];
  const float* pe_embed = (const float*)d_in[27];
  const float* peWQ = (const float*)d_in[28];
  const float* peWK = (const float*)d_in[29];
  const float* gt_Wq = (const float*)d_in[30]; const float* gt_bq = (const float*)d_in[31];
  const float* gt_Wk = (const float*)d_in[32]; const float* gt_bk = (const float*)d_in[33];
  const float* gt_Wv = (const float*)d_in[34]; const float* gt_bv = (const float*)d_in[35];
  const float* gt_Wo = (const float*)d_in[36]; const float* gt_bo = (const float*)d_in[37];
  const float* gt_g1 = (const float*)d_in[38]; const float* gt_be1 = (const float*)d_in[39];
  const float* gt_Wf1 = (const float*)d_in[40]; const float* gt_bf1 = (const float*)d_in[41];
  const float* gt_Wf2 = (const float*)d_in[42]; const float* gt_bf2 = (const float*)d_in[43];
  const float* gt_g2 = (const float*)d_in[44]; const float* gt_be2 = (const float*)d_in[45];
  const float* cat_W = (const float*)d_in[46]; const float* cat_b = (const float*)d_in[47];
  const float* mlp_W1 = (const float*)d_in[48]; const float* mlp_b1 = (const float*)d_in[49];
  const float* mlp_W2 = (const float*)d_in[50]; const float* mlp_b2 = (const float*)d_in[51];
  float* out = (float*)d_out;

  // ---- workspace layout (~135 MB total) ----
  char* base = (char*)d_ws;
  size_t off = 0;
  auto alloc = [&](size_t nbytes) -> void* {
    void* p = base + off;
    off += (nbytes + 255) & ~(size_t)255;
    return p;
  };
  float* xa   = (float*)alloc((size_t)NA * 128 * 4);
  float* xp   = (float*)alloc((size_t)NPA * 128 * 4);
  float* xt   = (float*)alloc((size_t)NT * 128 * 4);
  float* accP = (float*)alloc((size_t)NPA * 1024 * 4);
  float* accA = (float*)alloc((size_t)NA * 1024 * 4);
  float* agg  = (float*)alloc((size_t)NPA * 1024 * 4);
  float* wbuf = (float*)alloc((size_t)E_TP * 8 * 4);
  float* ssrc = (float*)alloc((size_t)NPA * 8 * 4);
  float* sdst = (float*)alloc((size_t)NPA * 8 * 4);
  float* Ps   = (float*)alloc(1024 * 4);
  float* Pd   = (float*)alloc(1024 * 4);
  unsigned* mEnc = (unsigned*)alloc((size_t)NPA * 8 * 4);
  float* den  = (float*)alloc((size_t)NPA * 8 * 4);
  float* hs2  = (float*)alloc((size_t)NPA * 128 * 4);
  float* hd2  = (float*)alloc((size_t)NA * 128 * 4);
  float* s2s  = (float*)alloc((size_t)NPA * 4);
  float* s2d  = (float*)alloc((size_t)NA * 4);
  float* w2   = (float*)alloc((size_t)E_PA * 4);
  unsigned* m2Enc = (unsigned*)alloc((size_t)NA * 4);
  float* den2 = (float*)alloc((size_t)NA * 4);
  float* hA2  = (float*)alloc((size_t)NA * 128 * 4);
  float* peQ  = (float*)alloc((size_t)NA * 128 * 4);
  float* peK  = (float*)alloc((size_t)NA * 128 * 4);
  float* dbv  = (float*)alloc((size_t)NA * 4);
  float* lossAcc = (float*)alloc(256);
  float* Qb   = (float*)alloc((size_t)NA * 128 * 4);
  float* Kb   = (float*)alloc((size_t)NA * 128 * 4);
  float* Vb   = (float*)alloc((size_t)NA * 128 * 4);
  float* Ob   = (float*)alloc((size_t)NA * 128 * 4);
  float* res1 = (float*)alloc((size_t)NA * 128 * 4);
  float* x1b  = (float*)alloc((size_t)NA * 128 * 4);
  float* f1   = (float*)alloc((size_t)NA * 256 * 4);
  float* ffres= (float*)alloc((size_t)NA * 128 * 4);
  float* outs1= (float*)alloc((size_t)NA * 128 * 4);
  float* outs2= (float*)alloc((size_t)NA * 128 * 4);
  float* catb = (float*)alloc((size_t)NA * 384 * 4);
  float* l1   = (float*)alloc((size_t)NA * 256 * 4);
  float* logits = (float*)alloc((size_t)NA * 4 * 4);
  int* cnt  = (int*)alloc((size_t)NPA * 4);
  int* offb = (int*)alloc((size_t)NPA * 4);
  int* cur  = (int*)alloc((size_t)NPA * 4);
  int* eidx = (int*)alloc((size_t)E_TP * 4);
  int* cntpa  = (int*)alloc((size_t)NA * 4);
  int* offpa  = (int*)alloc((size_t)NA * 4);
  int* curpa  = (int*)alloc((size_t)NA * 4);
  int* eidxpa = (int*)alloc((size_t)E_PA * 4);

  if (off > ws_size){
    setval_k<<<1, 1, 0, stream>>>(out, -12345.0f); // ws too small sentinel
    return;
  }

  auto gemm = [&](const float* A, const float* B, float* C, const float* bias,
                  const float* addmat, int M, int N, int K, int lda, int ldb, int ldc,
                  int relu, int Z = 1, int aOffZ = 0, int bOffZ = 0, int cOffZ = 0,
                  int accum = 0){
    dim3 g((M + 63) / 64, (N + 63) / 64, Z);
    if (relu) gemm_k<1><<<g, 256, 0, stream>>>(A, B, C, bias, addmat, M, N, K, lda, ldb, ldc, aOffZ, bOffZ, cOffZ, accum);
    else      gemm_k<0><<<g, 256, 0, stream>>>(A, B, C, bias, addmat, M, N, K, lda, ldb, ldc, aOffZ, bOffZ, cOffZ, accum);
  };

  auto build_csr = [&](const int* edst, int E, int Ndst, int* cnt_, int* off_, int* cur_, int* eidx_){
    hipMemsetAsync(cnt_, 0, (size_t)Ndst * 4, stream);
    hipMemsetAsync(cur_, 0, (size_t)Ndst * 4, stream);
    hist_k<<<(E + 255) / 256, 256, 0, stream>>>(edst, cnt_, E);
    exscan_k<<<1, 256, 0, stream>>>(cnt_, off_, Ndst);
    scatter_k<<<(E + 255) / 256, 256, 0, stream>>>(edst, off_, cur_, eidx_, E);
  };

  // GAT layer-1 one edge type: scores -> edge softmax -> x-space agg -> per-head GEMM (+= accOut)
  auto gat1_type = [&](const float* xsrc, int Nsrc, const float* xdst, int Ndst,
                       const int* esrc, const int* edst, int E,
                       const float* W, const float* as_, const float* ad_,
                       const int* eidx_, const int* off_, const int* cnt_, float* accOut){
    gat_proj_k<<<4, 256, 0, stream>>>(W, as_, ad_, Ps, Pd);
    gemm(xsrc, Ps, ssrc, nullptr, nullptr, Nsrc, 8, 128, 128, 8, 8, 0);
    gemm(xdst, Pd, sdst, nullptr, nullptr, Ndst, 8, 128, 128, 8, 8, 0);
    hipMemsetAsync(mEnc, 0, (size_t)Ndst * 8 * 4, stream);
    hipMemsetAsync(den,  0, (size_t)Ndst * 8 * 4, stream);
    int EH = E * 8;
    edgeA_k<<<(EH + 255) / 256, 256, 0, stream>>>(esrc, edst, ssrc, sdst, wbuf, mEnc, E, 8);
    edgeB_k<<<(EH + 255) / 256, 256, 0, stream>>>(edst, wbuf, mEnc, den, E, 8);
    gat_agg8_k<<<Ndst, 256, 0, stream>>>(eidx_, off_, cnt_, esrc, xsrc, wbuf, den, agg);
    gemm(agg, W, accOut, nullptr, nullptr, Ndst, 128, 128, 1024, 1024, 1024, 0, 8, 128, 128, 128, 1);
  };

  // ---- stage 0: node feature MLPs ----
  gemm(x_author, t1_W, xa, t1_b, nullptr, NA, 128, 334, 334, 128, 128, 1);
  gemm(x_paper,  t2_W, xp, t2_b, nullptr, NPA, 128, 512, 512, 128, 128, 1);
  gemm(x_term,   t3_W, xt, t3_b, nullptr, NT, 128, 128, 128, 128, 128, 1);

  hipMemsetAsync(accP, 0, (size_t)NPA * 1024 * 4, stream);
  hipMemsetAsync(accA, 0, (size_t)NA * 1024 * 4, stream);

  // ---- GAT layer 1 ----
  build_csr(ap_dst, E_AP, NPA, cnt, offb, cur, eidx);
  gat1_type(xa, NA, xp, NPA, ap_src, ap_dst, E_AP,
            gat1_W + 0 * 131072, gat1_as + 0 * 1024, gat1_ad + 0 * 1024, eidx, offb, cnt, accP);
  build_csr(tp_dst, E_TP, NPA, cnt, offb, cur, eidx);
  gat1_type(xt, NT, xp, NPA, tp_src, tp_dst, E_TP,
            gat1_W + 3 * 131072, gat1_as + 3 * 1024, gat1_ad + 3 * 1024, eidx, offb, cnt, accP);
  build_csr(pa_dst, E_PA, NA, cntpa, offpa, curpa, eidxpa);
  gat1_type(xp, NPA, xa, NA, pa_src, pa_dst, E_PA,
            gat1_W + 1 * 131072, gat1_as + 1 * 1024, gat1_ad + 1 * 1024, eidxpa, offpa, cntpa, accA);
  bias2_relu_k<<<((NPA * 1024) + 255) / 256, 256, 0, stream>>>(accP, gat1_b, gat1_b + 3 * 1024, NPA * 1024, 1024);
  bias2_relu_k<<<((NA * 1024) + 255) / 256, 256, 0, stream>>>(accA, gat1_b + 1024, nullptr, NA * 1024, 1024);
  // accP == h_p1, accA == h_a1

  // ---- GAT layer 2 (type pa, heads=1, out=128) ----
  gemm(accP, gat2_W + 131072, hs2, nullptr, nullptr, NPA, 128, 1024, 1024, 128, 128, 0);
  gemm(accA, gat2_W + 131072, hd2, nullptr, nullptr, NA, 128, 1024, 1024, 128, 128, 0);
  rowdot_k<<<NPA, 64, 0, stream>>>(hs2, gat2_as + 128, s2s, 128);
  rowdot_k<<<NA, 64, 0, stream>>>(hd2, gat2_ad + 128, s2d, 128);
  hipMemsetAsync(m2Enc, 0, (size_t)NA * 4, stream);
  hipMemsetAsync(den2, 0, (size_t)NA * 4, stream);
  edgeA_k<<<(E_PA + 255) / 256, 256, 0, stream>>>(pa_src, pa_dst, s2s, s2d, w2, m2Enc, E_PA, 1);
  edgeB_k<<<(E_PA + 255) / 256, 256, 0, stream>>>(pa_dst, w2, m2Enc, den2, E_PA, 1);
  gat_agg1_k<<<NA, 128, 0, stream>>>(eidxpa, offpa, cntpa, pa_src, hs2, w2, den2, gat2_b + 128, hA2);

  // ---- positional encodings + reconstruction loss ----
  gemm(pe_embed, peWQ, peQ, nullptr, nullptr, NA, 128, 128, 128, 128, 128, 0);
  gemm(pe_embed, peWK, peK, nullptr, nullptr, NA, 128, 128, 128, 128, 128, 0);
  db_k<<<16, 256, 0, stream>>>(deg, dbv);
  hipMemsetAsync(lossAcc, 0, 256, stream);
  loss_k<<<dim3(64, 64), 256, 0, stream>>>(peQ, peK, original_A, lossAcc);
  finalize_loss_k<<<1, 1, 0, stream>>>(lossAcc, out);

  // ---- graph transformer (2 layers) ----
  const float* x = hA2;
  float* louts[2] = { outs1, outs2 };
  for (int i = 0; i < 2; ++i){
    const float* Wq = gt_Wq + i * 16384; const float* bq = gt_bq + i * 128;
    const float* Wk = gt_Wk + i * 16384; const float* bk = gt_bk + i * 128;
    const float* Wv = gt_Wv + i * 16384; const float* bv = gt_bv + i * 128;
    const float* Wo = gt_Wo + i * 16384; const float* bo = gt_bo + i * 128;
    const float* Wf1 = gt_Wf1 + i * 32768; const float* bf1 = gt_bf1 + i * 256;
    const float* Wf2 = gt_Wf2 + i * 32768; const float* bf2 = gt_bf2 + i * 128;
    gemm(x, Wq, Qb, bq, peQ, NA, 128, 128, 128, 128, 128, 0);
    gemm(x, Wk, Kb, bk, peK, NA, 128, 128, 128, 128, 128, 0);
    gemm(x, Wv, Vb, bv, nullptr, NA, 128, 128, 128, 128, 128, 0);
    attn_k<<<dim3(NA / 64, 8), 64, 0, stream>>>(Qb, Kb, Vb, dbv, Ob);
    gemm(Ob, Wo, res1, bo, x, NA, 128, 128, 128, 128, 128, 0);
    ln_k<<<NA, 64, 0, stream>>>(res1, gt_g1 + i * 128, gt_be1 + i * 128, x1b);
    gemm(x1b, Wf1, f1, bf1, nullptr, NA, 256, 128, 128, 256, 256, 1);
    gemm(f1, Wf2, ffres, bf2, x1b, NA, 128, 256, 256, 128, 128, 0);
    ln_k<<<NA, 64, 0, stream>>>(ffres, gt_g2 + i * 128, gt_be2 + i * 128, louts[i]);
    x = louts[i];
  }

  // ---- head ----
  concat3_k<<<((NA * 384) + 255) / 256, 256, 0, stream>>>(hA2, outs1, outs2, catb, NA);
  float* xgt = out + 1 + NA * 4;
  gemm(catb, cat_W, xgt, cat_b, nullptr, NA, 128, 384, 384, 128, 128, 1);
  gemm(xgt, mlp_W1, l1, mlp_b1, nullptr, NA, 256, 128, 128, 256, 256, 1);
  gemm(l1, mlp_W2, logits, mlp_b2, nullptr, NA, 4, 256, 256, 4, 4, 0);
  softmax4_k<<<(NA + 255) / 256, 256, 0, stream>>>(logits, out + 1);
}

// Round 2
// 2275.746 us; speedup vs baseline: 1.2638x; 1.2638x over previous
//
#include <hip/hip_runtime.h>
#include <math.h>

// Problem constants
#define NA   4096
#define NPA  8192
#define NT   4096
#define E_AP 80000
#define E_PA 80000
#define E_TP 160000
#define ASPLIT 16

__device__ __forceinline__ unsigned fenc(float f){
  unsigned u = __float_as_uint(f);
  return (u & 0x80000000u) ? ~u : (u | 0x80000000u);
}
__device__ __forceinline__ float fdec(unsigned u){
  return (u & 0x80000000u) ? __uint_as_float(u & 0x7fffffffu) : __uint_as_float(~u);
}

// ---------------------------------------------------------------- GEMM
// C[M,N] = act(A[M,K]@B[K,N] + bias + addmat + (accumulate? C : 0))
// row-major, leading dims; z-batch via element offsets (per-head GAT GEMM).
template<int ACT>
__global__ __launch_bounds__(256) void gemm_k(
    const float* __restrict__ A, const float* __restrict__ B, float* __restrict__ C,
    const float* __restrict__ bias, const float* __restrict__ addmat,
    int M, int N, int K, int lda, int ldb, int ldc,
    int aOffZ, int bOffZ, int cOffZ, int accumulate)
{
  A += (size_t)blockIdx.z * aOffZ;
  B += (size_t)blockIdx.z * bOffZ;
  C += (size_t)blockIdx.z * cOffZ;
  __shared__ float As[16][68];
  __shared__ float Bs[16][68];
  int bm = blockIdx.x * 64, bn = blockIdx.y * 64;
  int tid = threadIdx.x;
  int tr = tid >> 4, tc = tid & 15;
  float acc[4][4] = {{0.f}};
  for (int k0 = 0; k0 < K; k0 += 16) {
#pragma unroll
    for (int i = 0; i < 4; ++i) {
      int idx = tid + i * 256;          // 0..1023
      int r  = idx >> 4, kk = idx & 15; // A: 16 contiguous k per row
      int gr = bm + r, gk = k0 + kk;
      As[kk][r] = (gr < M && gk < K) ? A[(size_t)gr * lda + gk] : 0.f;
      int c  = idx & 63, k2 = idx >> 6; // B: 64 contiguous cols
      int gc = bn + c, gk2 = k0 + k2;
      Bs[k2][c] = (gk2 < K && gc < N) ? B[(size_t)gk2 * ldb + gc] : 0.f;
    }
    __syncthreads();
#pragma unroll
    for (int kk = 0; kk < 16; ++kk) {
      float a0[4], b0[4];
#pragma unroll
      for (int i = 0; i < 4; ++i) a0[i] = As[kk][tr * 4 + i];
#pragma unroll
      for (int j = 0; j < 4; ++j) b0[j] = Bs[kk][tc * 4 + j];
#pragma unroll
      for (int i = 0; i < 4; ++i)
#pragma unroll
        for (int j = 0; j < 4; ++j) acc[i][j] = fmaf(a0[i], b0[j], acc[i][j]);
    }
    __syncthreads();
  }
#pragma unroll
  for (int i = 0; i < 4; ++i) {
    int r = bm + tr * 4 + i;
    if (r >= M) continue;
#pragma unroll
    for (int j = 0; j < 4; ++j) {
      int c = bn + tc * 4 + j;
      if (c >= N) continue;
      float v = acc[i][j];
      if (bias)   v += bias[c];
      if (addmat) v += addmat[(size_t)r * ldc + c];
      if (accumulate) v += C[(size_t)r * ldc + c];
      if (ACT == 1) v = fmaxf(v, 0.f);
      C[(size_t)r * ldc + c] = v;
    }
  }
}

// ---------------------------------------------------------------- GAT pieces
// Ps[k,h] = sum_c W[k, h*128+c]*as[h,c];  Pd likewise with ad.
__global__ void gat_proj_k(const float* __restrict__ W, const float* __restrict__ as_,
                           const float* __restrict__ ad_, float* __restrict__ Ps,
                           float* __restrict__ Pd){
  int t = blockIdx.x * blockDim.x + threadIdx.x;
  if (t >= 128 * 8) return;
  int k = t >> 3, h = t & 7;
  const float* wr = W + (size_t)k * 1024 + h * 128;
  const float* a1 = as_ + h * 128;
  const float* a2 = ad_ + h * 128;
  float s1 = 0.f, s2 = 0.f;
  for (int c = 0; c < 128; ++c){ float wv = wr[c]; s1 = fmaf(wv, a1[c], s1); s2 = fmaf(wv, a2[c], s2); }
  Ps[k * 8 + h] = s1;
  Pd[k * 8 + h] = s2;
}

__global__ void hist_k(const int* __restrict__ dst, int* __restrict__ cnt, int E){
  int i = blockIdx.x * blockDim.x + threadIdx.x;
  if (i < E) atomicAdd(&cnt[dst[i]], 1);
}

__global__ void exscan_k(const int* __restrict__ in, int* __restrict__ out, int n){
  __shared__ int buf[256];
  __shared__ int carry;
  if (threadIdx.x == 0) carry = 0;
  __syncthreads();
  for (int base = 0; base < n; base += 256){
    int i = base + threadIdx.x;
    int v = (i < n) ? in[i] : 0;
    buf[threadIdx.x] = v;
    __syncthreads();
    for (int o2 = 1; o2 < 256; o2 <<= 1){
      int tval = (threadIdx.x >= o2) ? buf[threadIdx.x - o2] : 0;
      __syncthreads();
      buf[threadIdx.x] += tval;
      __syncthreads();
    }
    if (i < n) out[i] = carry + buf[threadIdx.x] - v;
    int total = buf[255];
    __syncthreads();
    if (threadIdx.x == 0) carry += total;
    __syncthreads();
  }
}

__global__ void scatter_k(const int* __restrict__ dst, const int* __restrict__ off,
                          int* __restrict__ cur, int* __restrict__ eidx, int E){
  int i = blockIdx.x * blockDim.x + threadIdx.x;
  if (i >= E) return;
  int d = dst[i];
  int p = atomicAdd(&cur[d], 1);
  eidx[off[d] + p] = i;
}

// per-(edge,head): e = leakyrelu(ss[src]+sd[dst]); store; atomic max encode
__global__ void edgeA_k(const int* __restrict__ src, const int* __restrict__ dst,
                        const float* __restrict__ ss, const float* __restrict__ sd,
                        float* __restrict__ tmp, unsigned* __restrict__ mEnc, int E, int H){
  int i = blockIdx.x * blockDim.x + threadIdx.x;
  if (i >= E * H) return;
  int e = i / H, h = i - e * H;
  float v = ss[src[e] * H + h] + sd[dst[e] * H + h];
  v = v > 0.f ? v : 0.2f * v;
  tmp[i] = v;
  atomicMax(mEnc + dst[e] * H + h, fenc(v));
}

// w = exp(e - m[dst]);  den[dst] += w
__global__ void edgeB_k(const int* __restrict__ dst, float* __restrict__ w,
                        const unsigned* __restrict__ mEnc, float* __restrict__ den, int E, int H){
  int i = blockIdx.x * blockDim.x + threadIdx.x;
  if (i >= E * H) return;
  int e = i / H, h = i - e * H;
  float m = fdec(mEnc[dst[e] * H + h]);
  float ww = __expf(w[i] - m);
  w[i] = ww;
  atomicAdd(den + dst[e] * H + h, ww);
}

// x-space aggregation, H=8: agg[d,h,c] = (sum_e w[e,h]*x[src_e,c]) / (den[d,h]+1e-16)
__global__ __launch_bounds__(256) void gat_agg8_k(
    const int* __restrict__ eidx, const int* __restrict__ off, const int* __restrict__ cnt,
    const int* __restrict__ src, const float* __restrict__ x,
    const float* __restrict__ w, const float* __restrict__ den, float* __restrict__ agg){
  int d = blockIdx.x;
  int t = threadIdx.x;
  int c = t & 127, hb = (t >> 7) << 2;  // two thread-groups: heads 0..3 / 4..7
  float a0 = 0.f, a1 = 0.f, a2 = 0.f, a3 = 0.f;
  int base = off[d], n = cnt[d];
  for (int k = 0; k < n; ++k){
    int e = eidx[base + k];
    int s = src[e];
    float xv = x[(size_t)s * 128 + c];
    const float* we = w + (size_t)e * 8 + hb;
    a0 = fmaf(we[0], xv, a0); a1 = fmaf(we[1], xv, a1);
    a2 = fmaf(we[2], xv, a2); a3 = fmaf(we[3], xv, a3);
  }
  const float* dd = den + (size_t)d * 8 + hb;
  float* o = agg + (size_t)d * 1024 + c;
  o[(hb + 0) * 128] = a0 / (dd[0] + 1e-16f);
  o[(hb + 1) * 128] = a1 / (dd[1] + 1e-16f);
  o[(hb + 2) * 128] = a2 / (dd[2] + 1e-16f);
  o[(hb + 3) * 128] = a3 / (dd[3] + 1e-16f);
}

// transform-first aggregation, H=1, C=128 (gat2): out = sum w*hs[src]/(den+eps) + b
__global__ void gat_agg1_k(const int* __restrict__ eidx, const int* __restrict__ off,
                           const int* __restrict__ cnt, const int* __restrict__ src,
                           const float* __restrict__ hs, const float* __restrict__ w,
                           const float* __restrict__ den, const float* __restrict__ bias,
                           float* __restrict__ out){
  int d = blockIdx.x;
  int c = threadIdx.x; // 128
  float a = 0.f;
  int base = off[d], n = cnt[d];
  for (int k = 0; k < n; ++k){
    int e = eidx[base + k];
    a = fmaf(w[e], hs[(size_t)src[e] * 128 + c], a);
  }
  out[(size_t)d * 128 + c] = a / (den[d] + 1e-16f) + bias[c];
}

__global__ void rowdot_k(const float* __restrict__ X, const float* __restrict__ v,
                         float* __restrict__ out, int C){
  int r = blockIdx.x;
  int t = threadIdx.x; // 64
  float s = 0.f;
  for (int c = t; c < C; c += 64) s = fmaf(X[(size_t)r * C + c], v[c], s);
#pragma unroll
  for (int o = 32; o; o >>= 1) s += __shfl_down(s, o);
  if (t == 0) out[r] = s;
}

__global__ void bias2_relu_k(float* __restrict__ x, const float* __restrict__ b0,
                             const float* __restrict__ b1, int total, int cols){
  int i = blockIdx.x * blockDim.x + threadIdx.x;
  if (i >= total) return;
  int c = i % cols;
  float v = x[i] + b0[c];
  if (b1) v += b1[c];
  x[i] = fmaxf(v, 0.f);
}

// ---------------------------------------------------------------- PE loss
__global__ __launch_bounds__(256) void loss_k(const float* __restrict__ peQ,
    const float* __restrict__ peK, const float* __restrict__ A4, float* __restrict__ lossAcc)
{
  __shared__ float Qs[16][68];
  __shared__ float Ks[16][68];
  int br = blockIdx.x * 64, bc = blockIdx.y * 64;
  int tid = threadIdx.x, tr = tid >> 4, tc = tid & 15;
  float acc[4][4] = {{0.f}};
  for (int k0 = 0; k0 < 128; k0 += 16){
#pragma unroll
    for (int i = 0; i < 4; ++i){
      int idx = tid + i * 256;
      int r = idx >> 4, kk = idx & 15;
      Qs[kk][r] = peQ[(size_t)(br + r) * 128 + k0 + kk];
      Ks[kk][r] = peK[(size_t)(bc + r) * 128 + k0 + kk];
    }
    __syncthreads();
#pragma unroll
    for (int kk = 0; kk < 16; ++kk){
      float a0[4], b0[4];
#pragma unroll
      for (int i = 0; i < 4; ++i) a0[i] = Qs[kk][tr * 4 + i];
#pragma unroll
      for (int j = 0; j < 4; ++j) b0[j] = Ks[kk][tc * 4 + j];
#pragma unroll
      for (int i = 0; i < 4; ++i)
#pragma unroll
        for (int j = 0; j < 4; ++j) acc[i][j] = fmaf(a0[i], b0[j], acc[i][j]);
    }
    __syncthreads();
  }
  float err = 0.f;
#pragma unroll
  for (int i = 0; i < 4; ++i){
    int r = br + tr * 4 + i;
    float s0 = 1.f / (1.f + __expf(-acc[i][0]));
    float s1 = 1.f / (1.f + __expf(-acc[i][1]));
    float s2 = 1.f / (1.f + __expf(-acc[i][2]));
    float s3 = 1.f / (1.f + __expf(-acc[i][3]));
    size_t rowoff = (size_t)r * 4096 + bc + tc * 4;
#pragma unroll
    for (int q = 0; q < 4; ++q){
      const float4 av = *(const float4*)(A4 + (size_t)q * 16777216 + rowoff);
      float d0 = s0 - av.x, d1 = s1 - av.y, d2 = s2 - av.z, d3 = s3 - av.w;
      err += d0 * d0 + d1 * d1 + d2 * d2 + d3 * d3;
    }
  }
  __shared__ float red[256];
  red[tid] = err;
  __syncthreads();
  for (int o = 128; o; o >>= 1){
    if (tid < o) red[tid] += red[tid + o];
    __syncthreads();
  }
  if (tid == 0) atomicAdd(lossAcc, red[0]);
}

__global__ void finalize_loss_k(const float* __restrict__ acc, float* __restrict__ out){
  out[0] = acc[0] * (1.0f / 67108864.0f); // /(4*4096*4096)
}

__global__ void db_k(const int* __restrict__ deg, float* __restrict__ dbv){
  int i = blockIdx.x * blockDim.x + threadIdx.x;
  if (i >= NA) return;
  dbv[i] = logf(fmaxf((float)deg[i], 1.f));
}

// ---------------------------------------------------------------- transformer
// Split-K flash attention, heads=8, dh=16, per-key bias db[m].
// grid (NA/512, 8, ASPLIT), block 256; each thread owns 2 q-rows (r, r+256).
// Partials (acc[16], m, l) per (split, head, row) -> combine kernel.
__global__ __launch_bounds__(256) void attn_part_k(
    const float* __restrict__ Q, const float* __restrict__ K, const float* __restrict__ V,
    const float* __restrict__ dbv, float* __restrict__ part)
{
  int h = blockIdx.y, sp = blockIdx.z;
  int tid = threadIdx.x;
  int r0 = blockIdx.x * 512 + tid;
  int r1 = r0 + 256;
  __shared__ float Kt[16][16];
  __shared__ float Vt[16][16];
  __shared__ float dbs[16];
  float q0[16], q1[16];
  {
    const float4* a = (const float4*)(Q + (size_t)r0 * 128 + h * 16);
    const float4* b = (const float4*)(Q + (size_t)r1 * 128 + h * 16);
#pragma unroll
    for (int i = 0; i < 4; ++i){
      float4 va = a[i], vb = b[i];
      q0[i*4+0] = va.x * 0.25f; q0[i*4+1] = va.y * 0.25f;
      q0[i*4+2] = va.z * 0.25f; q0[i*4+3] = va.w * 0.25f;
      q1[i*4+0] = vb.x * 0.25f; q1[i*4+1] = vb.y * 0.25f;
      q1[i*4+2] = vb.z * 0.25f; q1[i*4+3] = vb.w * 0.25f;
    }
  }
  float m0 = -1e30f, m1 = -1e30f, l0 = 0.f, l1 = 0.f;
  float acc0[16], acc1[16];
#pragma unroll
  for (int j = 0; j < 16; ++j){ acc0[j] = 0.f; acc1[j] = 0.f; }

  int kend = sp * 256 + 256;
  for (int kb = sp * 256; kb < kend; kb += 16){
    __syncthreads();
    if (tid < 64){
      int row = tid >> 2, jo = (tid & 3) * 4;
      *(float4*)&Kt[row][jo] = *(const float4*)(K + (size_t)(kb + row) * 128 + h * 16 + jo);
    } else if (tid < 128){
      int u = tid - 64;
      int row = u >> 2, jo = (u & 3) * 4;
      *(float4*)&Vt[row][jo] = *(const float4*)(V + (size_t)(kb + row) * 128 + h * 16 + jo);
    }
    if (tid < 16) dbs[tid] = dbv[kb + tid];
    __syncthreads();
    float s0[16], s1[16];
    float tm0 = -1e30f, tm1 = -1e30f;
#pragma unroll
    for (int k = 0; k < 16; ++k){
      float a0 = dbs[k], a1 = dbs[k];
#pragma unroll
      for (int j = 0; j < 16; ++j){
        float kv = Kt[k][j];
        a0 = fmaf(q0[j], kv, a0);
        a1 = fmaf(q1[j], kv, a1);
      }
      s0[k] = a0; s1[k] = a1;
      tm0 = fmaxf(tm0, a0); tm1 = fmaxf(tm1, a1);
    }
    float mn0 = fmaxf(m0, tm0), mn1 = fmaxf(m1, tm1);
    float sc0 = __expf(m0 - mn0), sc1 = __expf(m1 - mn1);
    l0 *= sc0; l1 *= sc1;
#pragma unroll
    for (int j = 0; j < 16; ++j){ acc0[j] *= sc0; acc1[j] *= sc1; }
#pragma unroll
    for (int k = 0; k < 16; ++k){
      float p0 = __expf(s0[k] - mn0), p1 = __expf(s1[k] - mn1);
      l0 += p0; l1 += p1;
#pragma unroll
      for (int j = 0; j < 16; ++j){
        float vv = Vt[k][j];
        acc0[j] = fmaf(p0, vv, acc0[j]);
        acc1[j] = fmaf(p1, vv, acc1[j]);
      }
    }
    m0 = mn0; m1 = mn1;
  }
  float* pp0 = part + ((size_t)(sp * 8 + h) * NA + r0) * 18;
  float* pp1 = part + ((size_t)(sp * 8 + h) * NA + r1) * 18;
#pragma unroll
  for (int j = 0; j < 16; ++j){ pp0[j] = acc0[j]; pp1[j] = acc1[j]; }
  pp0[16] = m0; pp0[17] = l0;
  pp1[16] = m1; pp1[17] = l1;
}

// combine: thread t -> (r = t>>3, h = t&7); O writes coalesced across 8 heads/row
__global__ __launch_bounds__(256) void attn_comb_k(const float* __restrict__ part,
                                                   float* __restrict__ O){
  int t = blockIdx.x * 256 + threadIdx.x;
  int r = t >> 3, h = t & 7;
  float m = -1e30f;
#pragma unroll
  for (int sp = 0; sp < ASPLIT; ++sp)
    m = fmaxf(m, part[((size_t)(sp * 8 + h) * NA + r) * 18 + 16]);
  float l = 0.f, acc[16];
#pragma unroll
  for (int j = 0; j < 16; ++j) acc[j] = 0.f;
  for (int sp = 0; sp < ASPLIT; ++sp){
    const float* pp = part + ((size_t)(sp * 8 + h) * NA + r) * 18;
    float w = __expf(pp[16] - m);
    l += pp[17] * w;
#pragma unroll
    for (int j = 0; j < 16; ++j) acc[j] = fmaf(pp[j], w, acc[j]);
  }
  float inv = 1.f / l;
#pragma unroll
  for (int j = 0; j < 16; ++j) O[(size_t)r * 128 + h * 16 + j] = acc[j] * inv;
}

// layernorm over rows of 128 (biased var), out = (x-mean)*rsqrt(var+1e-5)*g + b
__global__ __launch_bounds__(64) void ln_k(const float* __restrict__ in,
    const float* __restrict__ g, const float* __restrict__ b, float* __restrict__ out){
  int r = blockIdx.x;
  int t = threadIdx.x;
  float v0 = in[(size_t)r * 128 + t], v1 = in[(size_t)r * 128 + 64 + t];
  float s = v0 + v1;
#pragma unroll
  for (int o = 32; o; o >>= 1) s += __shfl_down(s, o);
  float mean = __shfl(s, 0) * (1.f / 128.f);
  float d0 = v0 - mean, d1 = v1 - mean;
  float qv = d0 * d0 + d1 * d1;
#pragma unroll
  for (int o = 32; o; o >>= 1) qv += __shfl_down(qv, o);
  float var = __shfl(qv, 0) * (1.f / 128.f);
  float inv = rsqrtf(var + 1e-5f);
  out[(size_t)r * 128 + t]      = d0 * inv * g[t] + b[t];
  out[(size_t)r * 128 + 64 + t] = d1 * inv * g[64 + t] + b[64 + t];
}

__global__ void concat3_k(const float* __restrict__ a, const float* __restrict__ b,
                          const float* __restrict__ c, float* __restrict__ out, int rows){
  int i = blockIdx.x * blockDim.x + threadIdx.x;
  int total = rows * 384;
  if (i >= total) return;
  int r = i / 384, col = i - r * 384;
  float v = (col < 128) ? a[(size_t)r * 128 + col]
          : (col < 256) ? b[(size_t)r * 128 + col - 128]
                        : c[(size_t)r * 128 + col - 256];
  out[i] = v;
}

__global__ void softmax4_k(const float* __restrict__ logits, float* __restrict__ out){
  int r = blockIdx.x * blockDim.x + threadIdx.x;
  if (r >= NA) return;
  const float* l = logits + (size_t)r * 4;
  float m = fmaxf(fmaxf(l[0], l[1]), fmaxf(l[2], l[3]));
  float e0 = __expf(l[0] - m), e1 = __expf(l[1] - m), e2 = __expf(l[2] - m), e3 = __expf(l[3] - m);
  float inv = 1.f / (e0 + e1 + e2 + e3);
  out[(size_t)r * 4 + 0] = e0 * inv;
  out[(size_t)r * 4 + 1] = e1 * inv;
  out[(size_t)r * 4 + 2] = e2 * inv;
  out[(size_t)r * 4 + 3] = e3 * inv;
}

__global__ void setval_k(float* p, float v){ p[0] = v; }

// ---------------------------------------------------------------- host
extern "C" void kernel_launch(void* const* d_in, const int* in_sizes, int n_in,
                              void* d_out, int out_size, void* d_ws, size_t ws_size,
                              hipStream_t stream)
{
  (void)in_sizes; (void)n_in; (void)out_size;
  const float* x_author = (const float*)d_in[0];
  const float* x_paper  = (const float*)d_in[1];
  const float* x_term   = (const float*)d_in[2];
  const int* ap_src = (const int*)d_in[3];
  const int* ap_dst = (const int*)d_in[4];
  const int* pa_src = (const int*)d_in[5];
  const int* pa_dst = (const int*)d_in[6];
  const int* tp_src = (const int*)d_in[9];
  const int* tp_dst = (const int*)d_in[10];
  const float* original_A = (const float*)d_in[11];
  const int* deg = (const int*)d_in[12];
  const float* t1_W = (const float*)d_in[13]; const float* t1_b = (const float*)d_in[14];
  const float* t2_W = (const float*)d_in[15]; const float* t2_b = (const float*)d_in[16];
  const float* t3_W = (const float*)d_in[17]; const float* t3_b = (const float*)d_in[18];
  const float* gat1_W  = (const float*)d_in[19];
  const float* gat1_as = (const float*)d_in[20];
  const float* gat1_ad = (const float*)d_in[21];
  const float* gat1_b  = (const float*)d_in[22];
  const float* gat2_W  = (const float*)d_in[23];
  const float* gat2_as = (const float*)d_in[24];
  const float* gat2_ad = (const float*)d_in[25];
  const float* gat2_b  = (const float*)d_in[26];
  const float* pe_embed = (const float*)d_in[27];
  const float* peWQ = (const float*)d_in[28];
  const float* peWK = (const float*)d_in[29];
  const float* gt_Wq = (const float*)d_in[30]; const float* gt_bq = (const float*)d_in[31];
  const float* gt_Wk = (const float*)d_in[32]; const float* gt_bk = (const float*)d_in[33];
  const float* gt_Wv = (const float*)d_in[34]; const float* gt_bv = (const float*)d_in[35];
  const float* gt_Wo = (const float*)d_in[36]; const float* gt_bo = (const float*)d_in[37];
  const float* gt_g1 = (const float*)d_in[38]; const float* gt_be1 = (const float*)d_in[39];
  const float* gt_Wf1 = (const float*)d_in[40]; const float* gt_bf1 = (const float*)d_in[41];
  const float* gt_Wf2 = (const float*)d_in[42]; const float* gt_bf2 = (const float*)d_in[43];
  const float* gt_g2 = (const float*)d_in[44]; const float* gt_be2 = (const float*)d_in[45];
  const float* cat_W = (const float*)d_in[46]; const float* cat_b = (const float*)d_in[47];
  const float* mlp_W1 = (const float*)d_in[48]; const float* mlp_b1 = (const float*)d_in[49];
  const float* mlp_W2 = (const float*)d_in[50]; const float* mlp_b2 = (const float*)d_in[51];
  float* out = (float*)d_out;

  // ---- workspace layout ----
  char* base = (char*)d_ws;
  size_t off = 0;
  auto alloc = [&](size_t nbytes) -> void* {
    void* p = base + off;
    off += (nbytes + 255) & ~(size_t)255;
    return p;
  };
  float* xa   = (float*)alloc((size_t)NA * 128 * 4);
  float* xp   = (float*)alloc((size_t)NPA * 128 * 4);
  float* xt   = (float*)alloc((size_t)NT * 128 * 4);
  float* accP = (float*)alloc((size_t)NPA * 1024 * 4);   // also reused (w/ accA) as attn partials
  float* accA = (float*)alloc((size_t)NA * 1024 * 4);
  float* agg  = (float*)alloc((size_t)NPA * 1024 * 4);
  float* wbuf = (float*)alloc((size_t)E_TP * 8 * 4);
  float* ssrc = (float*)alloc((size_t)NPA * 8 * 4);
  float* sdst = (float*)alloc((size_t)NPA * 8 * 4);
  float* Ps   = (float*)alloc(1024 * 4);
  float* Pd   = (float*)alloc(1024 * 4);
  unsigned* mEnc = (unsigned*)alloc((size_t)NPA * 8 * 4);
  float* den  = (float*)alloc((size_t)NPA * 8 * 4);
  float* hs2  = (float*)alloc((size_t)NPA * 128 * 4);
  float* hd2  = (float*)alloc((size_t)NA * 128 * 4);
  float* s2s  = (float*)alloc((size_t)NPA * 4);
  float* s2d  = (float*)alloc((size_t)NA * 4);
  float* w2   = (float*)alloc((size_t)E_PA * 4);
  unsigned* m2Enc = (unsigned*)alloc((size_t)NA * 4);
  float* den2 = (float*)alloc((size_t)NA * 4);
  float* hA2  = (float*)alloc((size_t)NA * 128 * 4);
  float* peQ  = (float*)alloc((size_t)NA * 128 * 4);
  float* peK  = (float*)alloc((size_t)NA * 128 * 4);
  float* dbv  = (float*)alloc((size_t)NA * 4);
  float* lossAcc = (float*)alloc(256);
  float* Qb   = (float*)alloc((size_t)NA * 128 * 4);
  float* Kb   = (float*)alloc((size_t)NA * 128 * 4);
  float* Vb   = (float*)alloc((size_t)NA * 128 * 4);
  float* Ob   = (float*)alloc((size_t)NA * 128 * 4);
  float* res1 = (float*)alloc((size_t)NA * 128 * 4);
  float* x1b  = (float*)alloc((size_t)NA * 128 * 4);
  float* f1   = (float*)alloc((size_t)NA * 256 * 4);
  float* ffres= (float*)alloc((size_t)NA * 128 * 4);
  float* outs1= (float*)alloc((size_t)NA * 128 * 4);
  float* outs2= (float*)alloc((size_t)NA * 128 * 4);
  float* catb = (float*)alloc((size_t)NA * 384 * 4);
  float* l1   = (float*)alloc((size_t)NA * 256 * 4);
  float* logits = (float*)alloc((size_t)NA * 4 * 4);
  int* cnt  = (int*)alloc((size_t)NPA * 4);
  int* offb = (int*)alloc((size_t)NPA * 4);
  int* cur  = (int*)alloc((size_t)NPA * 4);
  int* eidx = (int*)alloc((size_t)E_TP * 4);
  int* cntpa  = (int*)alloc((size_t)NA * 4);
  int* offpa  = (int*)alloc((size_t)NA * 4);
  int* curpa  = (int*)alloc((size_t)NA * 4);
  int* eidxpa = (int*)alloc((size_t)E_PA * 4);

  // attention partials: ASPLIT*8*NA*18 floats = 37.75 MB; alias onto accP+accA
  // (48 MB contiguous, dead by the time the transformer runs).
  float* part = accP;

  if (off > ws_size){
    setval_k<<<1, 1, 0, stream>>>(out, -12345.0f); // ws too small sentinel
    return;
  }

  auto gemm = [&](const float* A, const float* B, float* C, const float* bias,
                  const float* addmat, int M, int N, int K, int lda, int ldb, int ldc,
                  int relu, int Z = 1, int aOffZ = 0, int bOffZ = 0, int cOffZ = 0,
                  int accum = 0){
    dim3 g((M + 63) / 64, (N + 63) / 64, Z);
    if (relu) gemm_k<1><<<g, 256, 0, stream>>>(A, B, C, bias, addmat, M, N, K, lda, ldb, ldc, aOffZ, bOffZ, cOffZ, accum);
    else      gemm_k<0><<<g, 256, 0, stream>>>(A, B, C, bias, addmat, M, N, K, lda, ldb, ldc, aOffZ, bOffZ, cOffZ, accum);
  };

  auto build_csr = [&](const int* edst, int E, int Ndst, int* cnt_, int* off_, int* cur_, int* eidx_){
    hipMemsetAsync(cnt_, 0, (size_t)Ndst * 4, stream);
    hipMemsetAsync(cur_, 0, (size_t)Ndst * 4, stream);
    hist_k<<<(E + 255) / 256, 256, 0, stream>>>(edst, cnt_, E);
    exscan_k<<<1, 256, 0, stream>>>(cnt_, off_, Ndst);
    scatter_k<<<(E + 255) / 256, 256, 0, stream>>>(edst, off_, cur_, eidx_, E);
  };

  // GAT layer-1 one edge type: scores -> edge softmax -> x-space agg -> per-head GEMM (+= accOut)
  auto gat1_type = [&](const float* xsrc, int Nsrc, const float* xdst, int Ndst,
                       const int* esrc, const int* edst, int E,
                       const float* W, const float* as_, const float* ad_,
                       const int* eidx_, const int* off_, const int* cnt_, float* accOut){
    gat_proj_k<<<4, 256, 0, stream>>>(W, as_, ad_, Ps, Pd);
    gemm(xsrc, Ps, ssrc, nullptr, nullptr, Nsrc, 8, 128, 128, 8, 8, 0);
    gemm(xdst, Pd, sdst, nullptr, nullptr, Ndst, 8, 128, 128, 8, 8, 0);
    hipMemsetAsync(mEnc, 0, (size_t)Ndst * 8 * 4, stream);
    hipMemsetAsync(den,  0, (size_t)Ndst * 8 * 4, stream);
    int EH = E * 8;
    edgeA_k<<<(EH + 255) / 256, 256, 0, stream>>>(esrc, edst, ssrc, sdst, wbuf, mEnc, E, 8);
    edgeB_k<<<(EH + 255) / 256, 256, 0, stream>>>(edst, wbuf, mEnc, den, E, 8);
    gat_agg8_k<<<Ndst, 256, 0, stream>>>(eidx_, off_, cnt_, esrc, xsrc, wbuf, den, agg);
    gemm(agg, W, accOut, nullptr, nullptr, Ndst, 128, 128, 1024, 1024, 1024, 0, 8, 128, 128, 128, 1);
  };

  // ---- stage 0: node feature MLPs ----
  gemm(x_author, t1_W, xa, t1_b, nullptr, NA, 128, 334, 334, 128, 128, 1);
  gemm(x_paper,  t2_W, xp, t2_b, nullptr, NPA, 128, 512, 512, 128, 128, 1);
  gemm(x_term,   t3_W, xt, t3_b, nullptr, NT, 128, 128, 128, 128, 128, 1);

  hipMemsetAsync(accP, 0, (size_t)NPA * 1024 * 4, stream);
  hipMemsetAsync(accA, 0, (size_t)NA * 1024 * 4, stream);

  // ---- GAT layer 1 ----
  build_csr(ap_dst, E_AP, NPA, cnt, offb, cur, eidx);
  gat1_type(xa, NA, xp, NPA, ap_src, ap_dst, E_AP,
            gat1_W + 0 * 131072, gat1_as + 0 * 1024, gat1_ad + 0 * 1024, eidx, offb, cnt, accP);
  build_csr(tp_dst, E_TP, NPA, cnt, offb, cur, eidx);
  gat1_type(xt, NT, xp, NPA, tp_src, tp_dst, E_TP,
            gat1_W + 3 * 131072, gat1_as + 3 * 1024, gat1_ad + 3 * 1024, eidx, offb, cnt, accP);
  build_csr(pa_dst, E_PA, NA, cntpa, offpa, curpa, eidxpa);
  gat1_type(xp, NPA, xa, NA, pa_src, pa_dst, E_PA,
            gat1_W + 1 * 131072, gat1_as + 1 * 1024, gat1_ad + 1 * 1024, eidxpa, offpa, cntpa, accA);
  bias2_relu_k<<<((NPA * 1024) + 255) / 256, 256, 0, stream>>>(accP, gat1_b, gat1_b + 3 * 1024, NPA * 1024, 1024);
  bias2_relu_k<<<((NA * 1024) + 255) / 256, 256, 0, stream>>>(accA, gat1_b + 1024, nullptr, NA * 1024, 1024);
  // accP == h_p1, accA == h_a1

  // ---- GAT layer 2 (type pa, heads=1, out=128) ----
  gemm(accP, gat2_W + 131072, hs2, nullptr, nullptr, NPA, 128, 1024, 1024, 128, 128, 0);
  gemm(accA, gat2_W + 131072, hd2, nullptr, nullptr, NA, 128, 1024, 1024, 128, 128, 0);
  rowdot_k<<<NPA, 64, 0, stream>>>(hs2, gat2_as + 128, s2s, 128);
  rowdot_k<<<NA, 64, 0, stream>>>(hd2, gat2_ad + 128, s2d, 128);
  hipMemsetAsync(m2Enc, 0, (size_t)NA * 4, stream);
  hipMemsetAsync(den2, 0, (size_t)NA * 4, stream);
  edgeA_k<<<(E_PA + 255) / 256, 256, 0, stream>>>(pa_src, pa_dst, s2s, s2d, w2, m2Enc, E_PA, 1);
  edgeB_k<<<(E_PA + 255) / 256, 256, 0, stream>>>(pa_dst, w2, m2Enc, den2, E_PA, 1);
  gat_agg1_k<<<NA, 128, 0, stream>>>(eidxpa, offpa, cntpa, pa_src, hs2, w2, den2, gat2_b + 128, hA2);

  // ---- positional encodings + reconstruction loss ----
  gemm(pe_embed, peWQ, peQ, nullptr, nullptr, NA, 128, 128, 128, 128, 128, 0);
  gemm(pe_embed, peWK, peK, nullptr, nullptr, NA, 128, 128, 128, 128, 128, 0);
  db_k<<<16, 256, 0, stream>>>(deg, dbv);
  hipMemsetAsync(lossAcc, 0, 256, stream);
  loss_k<<<dim3(64, 64), 256, 0, stream>>>(peQ, peK, original_A, lossAcc);
  finalize_loss_k<<<1, 1, 0, stream>>>(lossAcc, out);

  // ---- graph transformer (2 layers) ----
  const float* x = hA2;
  float* louts[2] = { outs1, outs2 };
  for (int i = 0; i < 2; ++i){
    const float* Wq = gt_Wq + i * 16384; const float* bq = gt_bq + i * 128;
    const float* Wk = gt_Wk + i * 16384; const float* bk = gt_bk + i * 128;
    const float* Wv = gt_Wv + i * 16384; const float* bv = gt_bv + i * 128;
    const float* Wo = gt_Wo + i * 16384; const float* bo = gt_bo + i * 128;
    const float* Wf1 = gt_Wf1 + i * 32768; const float* bf1 = gt_bf1 + i * 256;
    const float* Wf2 = gt_Wf2 + i * 32768; const float* bf2 = gt_bf2 + i * 128;
    gemm(x, Wq, Qb, bq, peQ, NA, 128, 128, 128, 128, 128, 0);
    gemm(x, Wk, Kb, bk, peK, NA, 128, 128, 128, 128, 128, 0);
    gemm(x, Wv, Vb, bv, nullptr, NA, 128, 128, 128, 128, 128, 0);
    attn_part_k<<<dim3(NA / 512, 8, ASPLIT), 256, 0, stream>>>(Qb, Kb, Vb, dbv, part);
    attn_comb_k<<<(NA * 8) / 256, 256, 0, stream>>>(part, Ob);
    gemm(Ob, Wo, res1, bo, x, NA, 128, 128, 128, 128, 128, 0);
    ln_k<<<NA, 64, 0, stream>>>(res1, gt_g1 + i * 128, gt_be1 + i * 128, x1b);
    gemm(x1b, Wf1, f1, bf1, nullptr, NA, 256, 128, 128, 256, 256, 1);
    gemm(f1, Wf2, ffres, bf2, x1b, NA, 128, 256, 256, 128, 128, 0);
    ln_k<<<NA, 64, 0, stream>>>(ffres, gt_g2 + i * 128, gt_be2 + i * 128, louts[i]);
    x = louts[i];
  }

  // ---- head ----
  concat3_k<<<((NA * 384) + 255) / 256, 256, 0, stream>>>(hA2, outs1, outs2, catb, NA);
  float* xgt = out + 1 + NA * 4;
  gemm(catb, cat_W, xgt, cat_b, nullptr, NA, 128, 384, 384, 128, 128, 1);
  gemm(xgt, mlp_W1, l1, mlp_b1, nullptr, NA, 256, 128, 128, 256, 256, 1);
  gemm(l1, mlp_W2, logits, mlp_b2, nullptr, NA, 4, 256, 256, 4, 4, 0);
  softmax4_k<<<(NA + 255) / 256, 256, 0, stream>>>(logits, out + 1);
}

// Round 3
// 1780.865 us; speedup vs baseline: 1.6149x; 1.2779x over previous
//
#include <hip/hip_runtime.h>
#include <math.h>

// Problem constants
#define NA   4096
#define NPA  8192
#define NT   4096
#define E_AP 80000
#define E_PA 80000
#define E_TP 160000
#define ASPLIT 16

typedef __attribute__((ext_vector_type(4))) float f32x4;
typedef __attribute__((ext_vector_type(8))) short s16x8;
typedef __attribute__((ext_vector_type(8))) unsigned short u16x8;

__device__ __forceinline__ unsigned fenc(float f){
  unsigned u = __float_as_uint(f);
  return (u & 0x80000000u) ? ~u : (u | 0x80000000u);
}
__device__ __forceinline__ float fdec(unsigned u){
  return (u & 0x80000000u) ? __uint_as_float(u & 0x7fffffffu) : __uint_as_float(~u);
}
__device__ __forceinline__ unsigned short f2bf(float f){
  unsigned u = __float_as_uint(f);
  unsigned r = u + 0x7fffu + ((u >> 16) & 1u);   // RNE
  return (unsigned short)(r >> 16);
}

// ---------------------------------------------------------------- f32 GEMM (small-N leftovers)
template<int ACT>
__global__ __launch_bounds__(256) void gemm_k(
    const float* __restrict__ A, const float* __restrict__ B, float* __restrict__ C,
    const float* __restrict__ bias, const float* __restrict__ addmat,
    int M, int N, int K, int lda, int ldb, int ldc,
    int aOffZ, int bOffZ, int cOffZ, int accumulate)
{
  A += (size_t)blockIdx.z * aOffZ;
  B += (size_t)blockIdx.z * bOffZ;
  C += (size_t)blockIdx.z * cOffZ;
  __shared__ float As[16][68];
  __shared__ float Bs[16][68];
  int bm = blockIdx.x * 64, bn = blockIdx.y * 64;
  int tid = threadIdx.x;
  int tr = tid >> 4, tc = tid & 15;
  float acc[4][4] = {{0.f}};
  for (int k0 = 0; k0 < K; k0 += 16) {
#pragma unroll
    for (int i = 0; i < 4; ++i) {
      int idx = tid + i * 256;
      int r  = idx >> 4, kk = idx & 15;
      int gr = bm + r, gk = k0 + kk;
      As[kk][r] = (gr < M && gk < K) ? A[(size_t)gr * lda + gk] : 0.f;
      int c  = idx & 63, k2 = idx >> 6;
      int gc = bn + c, gk2 = k0 + k2;
      Bs[k2][c] = (gk2 < K && gc < N) ? B[(size_t)gk2 * ldb + gc] : 0.f;
    }
    __syncthreads();
#pragma unroll
    for (int kk = 0; kk < 16; ++kk) {
      float a0[4], b0[4];
#pragma unroll
      for (int i = 0; i < 4; ++i) a0[i] = As[kk][tr * 4 + i];
#pragma unroll
      for (int j = 0; j < 4; ++j) b0[j] = Bs[kk][tc * 4 + j];
#pragma unroll
      for (int i = 0; i < 4; ++i)
#pragma unroll
        for (int j = 0; j < 4; ++j) acc[i][j] = fmaf(a0[i], b0[j], acc[i][j]);
    }
    __syncthreads();
  }
#pragma unroll
  for (int i = 0; i < 4; ++i) {
    int r = bm + tr * 4 + i;
    if (r >= M) continue;
#pragma unroll
    for (int j = 0; j < 4; ++j) {
      int c = bn + tc * 4 + j;
      if (c >= N) continue;
      float v = acc[i][j];
      if (bias)   v += bias[c];
      if (addmat) v += addmat[(size_t)r * ldc + c];
      if (accumulate) v += C[(size_t)r * ldc + c];
      if (ACT == 1) v = fmaxf(v, 0.f);
      C[(size_t)r * ldc + c] = v;
    }
  }
}

// ---------------------------------------------------------------- bf16 MFMA GEMM
// C[M,N] = act(A@B + bias + addmat + (accum? C:0)); A,B f32 in HBM, converted to
// bf16 while staging to LDS; f32 accumulate. Tile 64x128xBK32, 4 waves (2x2),
// each wave 32x64 = 2x4 fragments of 16x16. Requires M%64==0, N%128==0.
template<int ACT>
__global__ __launch_bounds__(256) void gemm_mfma_k(
    const float* __restrict__ A, const float* __restrict__ B, float* __restrict__ C,
    const float* __restrict__ bias, const float* __restrict__ addmat,
    int M, int N, int K, int lda, int ldb, int ldc,
    int aOffZ, int bOffZ, int cOffZ, int accumulate)
{
  A += (size_t)blockIdx.z * aOffZ;
  B += (size_t)blockIdx.z * bOffZ;
  C += (size_t)blockIdx.z * cOffZ;
  __shared__ __align__(16) unsigned short As[64][40];   // [m][k], pad 32->40
  __shared__ __align__(16) unsigned short Bs[128][40];  // [n][k]
  int bm = blockIdx.x * 64, bn = blockIdx.y * 128;
  int tid = threadIdx.x;
  int w = tid >> 6, lane = tid & 63, lg = lane >> 4, lid = lane & 15;
  int wm = (w & 1) * 32, wn = (w >> 1) * 64;
  f32x4 acc[2][4];
#pragma unroll
  for (int i = 0; i < 2; ++i)
#pragma unroll
    for (int j = 0; j < 4; ++j) acc[i][j] = (f32x4){0.f, 0.f, 0.f, 0.f};

  for (int k0 = 0; k0 < K; k0 += 32) {
    // stage A: thread t -> row t>>2, k-seg (t&3)*8
    {
      int r = tid >> 2, ks = (tid & 3) * 8;
      const float* ap = A + (size_t)(bm + r) * lda + k0 + ks;
      u16x8 v;
#pragma unroll
      for (int j = 0; j < 8; ++j) {
        int gk = k0 + ks + j;
        float fv = (gk < K) ? ap[j] : 0.f;
        v[j] = f2bf(fv);
      }
      *(u16x8*)&As[r][ks] = v;
    }
    // stage B transposed: thread t -> n = t>>1, k-seg (t&1)*16
    {
      int n = tid >> 1, ks = (tid & 1) * 16;
      unsigned short tmp[16];
#pragma unroll
      for (int j = 0; j < 16; ++j) {
        int gk = k0 + ks + j;
        float fv = (gk < K) ? B[(size_t)gk * ldb + bn + n] : 0.f;
        tmp[j] = f2bf(fv);
      }
      u16x8 v0, v1;
#pragma unroll
      for (int j = 0; j < 8; ++j) { v0[j] = tmp[j]; v1[j] = tmp[8 + j]; }
      *(u16x8*)&Bs[n][ks] = v0;
      *(u16x8*)&Bs[n][ks + 8] = v1;
    }
    __syncthreads();
    s16x8 a_frag[2], b_frag[4];
#pragma unroll
    for (int i = 0; i < 2; ++i) a_frag[i] = *(s16x8*)&As[wm + i * 16 + lid][lg * 8];
#pragma unroll
    for (int j = 0; j < 4; ++j) b_frag[j] = *(s16x8*)&Bs[wn + j * 16 + lid][lg * 8];
#pragma unroll
    for (int i = 0; i < 2; ++i)
#pragma unroll
      for (int j = 0; j < 4; ++j)
        acc[i][j] = __builtin_amdgcn_mfma_f32_16x16x32_bf16(a_frag[i], b_frag[j], acc[i][j], 0, 0, 0);
    __syncthreads();
  }
  // epilogue
#pragma unroll
  for (int i = 0; i < 2; ++i) {
#pragma unroll
    for (int j = 0; j < 4; ++j) {
      int c = bn + wn + j * 16 + lid;
#pragma unroll
      for (int rr = 0; rr < 4; ++rr) {
        int r = bm + wm + i * 16 + lg * 4 + rr;
        float v = acc[i][j][rr];
        if (bias)   v += bias[c];
        if (addmat) v += addmat[(size_t)r * ldc + c];
        if (accumulate) v += C[(size_t)r * ldc + c];
        if (ACT == 1) v = fmaxf(v, 0.f);
        C[(size_t)r * ldc + c] = v;
      }
    }
  }
}

// ---------------------------------------------------------------- GAT pieces
__global__ void gat_proj_k(const float* __restrict__ W, const float* __restrict__ as_,
                           const float* __restrict__ ad_, float* __restrict__ Ps,
                           float* __restrict__ Pd){
  int t = blockIdx.x * blockDim.x + threadIdx.x;
  if (t >= 128 * 8) return;
  int k = t >> 3, h = t & 7;
  const float* wr = W + (size_t)k * 1024 + h * 128;
  const float* a1 = as_ + h * 128;
  const float* a2 = ad_ + h * 128;
  float s1 = 0.f, s2 = 0.f;
  for (int c = 0; c < 128; ++c){ float wv = wr[c]; s1 = fmaf(wv, a1[c], s1); s2 = fmaf(wv, a2[c], s2); }
  Ps[k * 8 + h] = s1;
  Pd[k * 8 + h] = s2;
}

__global__ void hist_k(const int* __restrict__ dst, int* __restrict__ cnt, int E){
  int i = blockIdx.x * blockDim.x + threadIdx.x;
  if (i < E) atomicAdd(&cnt[dst[i]], 1);
}

__global__ void exscan_k(const int* __restrict__ in, int* __restrict__ out, int n){
  __shared__ int buf[256];
  __shared__ int carry;
  if (threadIdx.x == 0) carry = 0;
  __syncthreads();
  for (int base = 0; base < n; base += 256){
    int i = base + threadIdx.x;
    int v = (i < n) ? in[i] : 0;
    buf[threadIdx.x] = v;
    __syncthreads();
    for (int o2 = 1; o2 < 256; o2 <<= 1){
      int tval = (threadIdx.x >= o2) ? buf[threadIdx.x - o2] : 0;
      __syncthreads();
      buf[threadIdx.x] += tval;
      __syncthreads();
    }
    if (i < n) out[i] = carry + buf[threadIdx.x] - v;
    int total = buf[255];
    __syncthreads();
    if (threadIdx.x == 0) carry += total;
    __syncthreads();
  }
}

__global__ void scatter_k(const int* __restrict__ dst, const int* __restrict__ off,
                          int* __restrict__ cur, int* __restrict__ eidx, int E){
  int i = blockIdx.x * blockDim.x + threadIdx.x;
  if (i >= E) return;
  int d = dst[i];
  int p = atomicAdd(&cur[d], 1);
  eidx[off[d] + p] = i;
}

__global__ void edgeA_k(const int* __restrict__ src, const int* __restrict__ dst,
                        const float* __restrict__ ss, const float* __restrict__ sd,
                        float* __restrict__ tmp, unsigned* __restrict__ mEnc, int E, int H){
  int i = blockIdx.x * blockDim.x + threadIdx.x;
  if (i >= E * H) return;
  int e = i / H, h = i - e * H;
  float v = ss[src[e] * H + h] + sd[dst[e] * H + h];
  v = v > 0.f ? v : 0.2f * v;
  tmp[i] = v;
  atomicMax(mEnc + dst[e] * H + h, fenc(v));
}

__global__ void edgeB_k(const int* __restrict__ dst, float* __restrict__ w,
                        const unsigned* __restrict__ mEnc, float* __restrict__ den, int E, int H){
  int i = blockIdx.x * blockDim.x + threadIdx.x;
  if (i >= E * H) return;
  int e = i / H, h = i - e * H;
  float m = fdec(mEnc[dst[e] * H + h]);
  float ww = __expf(w[i] - m);
  w[i] = ww;
  atomicAdd(den + dst[e] * H + h, ww);
}

__global__ __launch_bounds__(256) void gat_agg8_k(
    const int* __restrict__ eidx, const int* __restrict__ off, const int* __restrict__ cnt,
    const int* __restrict__ src, const float* __restrict__ x,
    const float* __restrict__ w, const float* __restrict__ den, float* __restrict__ agg){
  int d = blockIdx.x;
  int t = threadIdx.x;
  int c = t & 127, hb = (t >> 7) << 2;
  float a0 = 0.f, a1 = 0.f, a2 = 0.f, a3 = 0.f;
  int base = off[d], n = cnt[d];
  for (int k = 0; k < n; ++k){
    int e = eidx[base + k];
    int s = src[e];
    float xv = x[(size_t)s * 128 + c];
    const float* we = w + (size_t)e * 8 + hb;
    a0 = fmaf(we[0], xv, a0); a1 = fmaf(we[1], xv, a1);
    a2 = fmaf(we[2], xv, a2); a3 = fmaf(we[3], xv, a3);
  }
  const float* dd = den + (size_t)d * 8 + hb;
  float* o = agg + (size_t)d * 1024 + c;
  o[(hb + 0) * 128] = a0 / (dd[0] + 1e-16f);
  o[(hb + 1) * 128] = a1 / (dd[1] + 1e-16f);
  o[(hb + 2) * 128] = a2 / (dd[2] + 1e-16f);
  o[(hb + 3) * 128] = a3 / (dd[3] + 1e-16f);
}

__global__ void gat_agg1_k(const int* __restrict__ eidx, const int* __restrict__ off,
                           const int* __restrict__ cnt, const int* __restrict__ src,
                           const float* __restrict__ hs, const float* __restrict__ w,
                           const float* __restrict__ den, const float* __restrict__ bias,
                           float* __restrict__ out){
  int d = blockIdx.x;
  int c = threadIdx.x; // 128
  float a = 0.f;
  int base = off[d], n = cnt[d];
  for (int k = 0; k < n; ++k){
    int e = eidx[base + k];
    a = fmaf(w[e], hs[(size_t)src[e] * 128 + c], a);
  }
  out[(size_t)d * 128 + c] = a / (den[d] + 1e-16f) + bias[c];
}

__global__ void rowdot_k(const float* __restrict__ X, const float* __restrict__ v,
                         float* __restrict__ out, int C){
  int r = blockIdx.x;
  int t = threadIdx.x; // 64
  float s = 0.f;
  for (int c = t; c < C; c += 64) s = fmaf(X[(size_t)r * C + c], v[c], s);
#pragma unroll
  for (int o = 32; o; o >>= 1) s += __shfl_down(s, o);
  if (t == 0) out[r] = s;
}

__global__ void bias2_relu_k(float* __restrict__ x, const float* __restrict__ b0,
                             const float* __restrict__ b1, int total, int cols){
  int i = blockIdx.x * blockDim.x + threadIdx.x;
  if (i >= total) return;
  int c = i % cols;
  float v = x[i] + b0[c];
  if (b1) v += b1[c];
  x[i] = fmaxf(v, 0.f);
}

// ---------------------------------------------------------------- PE loss (MFMA)
// S-tile 64x128 = peQ[br..][k] @ peK[bc..][k]^T via bf16 MFMA, then
// sigmoid + sq-err vs 4 adjacency planes, block-reduce, atomicAdd.
__global__ __launch_bounds__(256) void loss_mfma_k(const float* __restrict__ peQ,
    const float* __restrict__ peK, const float* __restrict__ A4, float* __restrict__ lossAcc)
{
  __shared__ __align__(16) unsigned short As[64][40];
  __shared__ __align__(16) unsigned short Bs[128][40];
  __shared__ float red[256];
  int br = blockIdx.x * 64, bc = blockIdx.y * 128;
  int tid = threadIdx.x;
  int w = tid >> 6, lane = tid & 63, lg = lane >> 4, lid = lane & 15;
  int wm = (w & 1) * 32, wn = (w >> 1) * 64;
  f32x4 acc[2][4];
#pragma unroll
  for (int i = 0; i < 2; ++i)
#pragma unroll
    for (int j = 0; j < 4; ++j) acc[i][j] = (f32x4){0.f, 0.f, 0.f, 0.f};

  for (int k0 = 0; k0 < 128; k0 += 32) {
    {
      int r = tid >> 2, ks = (tid & 3) * 8;
      const float* ap = peQ + (size_t)(br + r) * 128 + k0 + ks;
      u16x8 v;
#pragma unroll
      for (int j = 0; j < 8; ++j) v[j] = f2bf(ap[j]);
      *(u16x8*)&As[r][ks] = v;
    }
    {
      int n = tid >> 1, ks = (tid & 1) * 16;
      const float* bp = peK + (size_t)(bc + n) * 128 + k0 + ks;
      u16x8 v0, v1;
#pragma unroll
      for (int j = 0; j < 8; ++j) { v0[j] = f2bf(bp[j]); v1[j] = f2bf(bp[8 + j]); }
      *(u16x8*)&Bs[n][ks] = v0;
      *(u16x8*)&Bs[n][ks + 8] = v1;
    }
    __syncthreads();
    s16x8 a_frag[2], b_frag[4];
#pragma unroll
    for (int i = 0; i < 2; ++i) a_frag[i] = *(s16x8*)&As[wm + i * 16 + lid][lg * 8];
#pragma unroll
    for (int j = 0; j < 4; ++j) b_frag[j] = *(s16x8*)&Bs[wn + j * 16 + lid][lg * 8];
#pragma unroll
    for (int i = 0; i < 2; ++i)
#pragma unroll
      for (int j = 0; j < 4; ++j)
        acc[i][j] = __builtin_amdgcn_mfma_f32_16x16x32_bf16(a_frag[i], b_frag[j], acc[i][j], 0, 0, 0);
    __syncthreads();
  }
  float err = 0.f;
#pragma unroll
  for (int i = 0; i < 2; ++i) {
#pragma unroll
    for (int rr = 0; rr < 4; ++rr) {
      int r = br + wm + i * 16 + lg * 4 + rr;
#pragma unroll
      for (int j = 0; j < 4; ++j) {
        int c = bc + wn + j * 16 + lid;
        float s = 1.f / (1.f + __expf(-acc[i][j][rr]));
        size_t o = (size_t)r * 4096 + c;
#pragma unroll
        for (int q = 0; q < 4; ++q) {
          float d = s - A4[(size_t)q * 16777216 + o];
          err += d * d;
        }
      }
    }
  }
  red[tid] = err;
  __syncthreads();
  for (int o = 128; o; o >>= 1){
    if (tid < o) red[tid] += red[tid + o];
    __syncthreads();
  }
  if (tid == 0) atomicAdd(lossAcc, red[0]);
}

__global__ void finalize_loss_k(const float* __restrict__ acc, float* __restrict__ out){
  out[0] = acc[0] * (1.0f / 67108864.0f); // /(4*4096*4096)
}

__global__ void db_k(const int* __restrict__ deg, float* __restrict__ dbv){
  int i = blockIdx.x * blockDim.x + threadIdx.x;
  if (i >= NA) return;
  dbv[i] = logf(fmaxf((float)deg[i], 1.f));
}

// ---------------------------------------------------------------- transformer
__global__ __launch_bounds__(256) void attn_part_k(
    const float* __restrict__ Q, const float* __restrict__ K, const float* __restrict__ V,
    const float* __restrict__ dbv, float* __restrict__ part)
{
  int h = blockIdx.y, sp = blockIdx.z;
  int tid = threadIdx.x;
  int r0 = blockIdx.x * 512 + tid;
  int r1 = r0 + 256;
  __shared__ float Kt[16][16];
  __shared__ float Vt[16][16];
  __shared__ float dbs[16];
  float q0[16], q1[16];
  {
    const float4* a = (const float4*)(Q + (size_t)r0 * 128 + h * 16);
    const float4* b = (const float4*)(Q + (size_t)r1 * 128 + h * 16);
#pragma unroll
    for (int i = 0; i < 4; ++i){
      float4 va = a[i], vb = b[i];
      q0[i*4+0] = va.x * 0.25f; q0[i*4+1] = va.y * 0.25f;
      q0[i*4+2] = va.z * 0.25f; q0[i*4+3] = va.w * 0.25f;
      q1[i*4+0] = vb.x * 0.25f; q1[i*4+1] = vb.y * 0.25f;
      q1[i*4+2] = vb.z * 0.25f; q1[i*4+3] = vb.w * 0.25f;
    }
  }
  float m0 = -1e30f, m1 = -1e30f, l0 = 0.f, l1 = 0.f;
  float acc0[16], acc1[16];
#pragma unroll
  for (int j = 0; j < 16; ++j){ acc0[j] = 0.f; acc1[j] = 0.f; }

  int kend = sp * 256 + 256;
  for (int kb = sp * 256; kb < kend; kb += 16){
    __syncthreads();
    if (tid < 64){
      int row = tid >> 2, jo = (tid & 3) * 4;
      *(float4*)&Kt[row][jo] = *(const float4*)(K + (size_t)(kb + row) * 128 + h * 16 + jo);
    } else if (tid < 128){
      int u = tid - 64;
      int row = u >> 2, jo = (u & 3) * 4;
      *(float4*)&Vt[row][jo] = *(const float4*)(V + (size_t)(kb + row) * 128 + h * 16 + jo);
    }
    if (tid < 16) dbs[tid] = dbv[kb + tid];
    __syncthreads();
    float s0[16], s1[16];
    float tm0 = -1e30f, tm1 = -1e30f;
#pragma unroll
    for (int k = 0; k < 16; ++k){
      float a0 = dbs[k], a1 = dbs[k];
#pragma unroll
      for (int j = 0; j < 16; ++j){
        float kv = Kt[k][j];
        a0 = fmaf(q0[j], kv, a0);
        a1 = fmaf(q1[j], kv, a1);
      }
      s0[k] = a0; s1[k] = a1;
      tm0 = fmaxf(tm0, a0); tm1 = fmaxf(tm1, a1);
    }
    float mn0 = fmaxf(m0, tm0), mn1 = fmaxf(m1, tm1);
    float sc0 = __expf(m0 - mn0), sc1 = __expf(m1 - mn1);
    l0 *= sc0; l1 *= sc1;
#pragma unroll
    for (int j = 0; j < 16; ++j){ acc0[j] *= sc0; acc1[j] *= sc1; }
#pragma unroll
    for (int k = 0; k < 16; ++k){
      float p0 = __expf(s0[k] - mn0), p1 = __expf(s1[k] - mn1);
      l0 += p0; l1 += p1;
#pragma unroll
      for (int j = 0; j < 16; ++j){
        float vv = Vt[k][j];
        acc0[j] = fmaf(p0, vv, acc0[j]);
        acc1[j] = fmaf(p1, vv, acc1[j]);
      }
    }
    m0 = mn0; m1 = mn1;
  }
  float* pp0 = part + ((size_t)(sp * 8 + h) * NA + r0) * 18;
  float* pp1 = part + ((size_t)(sp * 8 + h) * NA + r1) * 18;
#pragma unroll
  for (int j = 0; j < 16; ++j){ pp0[j] = acc0[j]; pp1[j] = acc1[j]; }
  pp0[16] = m0; pp0[17] = l0;
  pp1[16] = m1; pp1[17] = l1;
}

__global__ __launch_bounds__(256) void attn_comb_k(const float* __restrict__ part,
                                                   float* __restrict__ O){
  int t = blockIdx.x * 256 + threadIdx.x;
  int r = t >> 3, h = t & 7;
  float m = -1e30f;
#pragma unroll
  for (int sp = 0; sp < ASPLIT; ++sp)
    m = fmaxf(m, part[((size_t)(sp * 8 + h) * NA + r) * 18 + 16]);
  float l = 0.f, acc[16];
#pragma unroll
  for (int j = 0; j < 16; ++j) acc[j] = 0.f;
  for (int sp = 0; sp < ASPLIT; ++sp){
    const float* pp = part + ((size_t)(sp * 8 + h) * NA + r) * 18;
    float w = __expf(pp[16] - m);
    l += pp[17] * w;
#pragma unroll
    for (int j = 0; j < 16; ++j) acc[j] = fmaf(pp[j], w, acc[j]);
  }
  float inv = 1.f / l;
#pragma unroll
  for (int j = 0; j < 16; ++j) O[(size_t)r * 128 + h * 16 + j] = acc[j] * inv;
}

__global__ __launch_bounds__(64) void ln_k(const float* __restrict__ in,
    const float* __restrict__ g, const float* __restrict__ b, float* __restrict__ out){
  int r = blockIdx.x;
  int t = threadIdx.x;
  float v0 = in[(size_t)r * 128 + t], v1 = in[(size_t)r * 128 + 64 + t];
  float s = v0 + v1;
#pragma unroll
  for (int o = 32; o; o >>= 1) s += __shfl_down(s, o);
  float mean = __shfl(s, 0) * (1.f / 128.f);
  float d0 = v0 - mean, d1 = v1 - mean;
  float qv = d0 * d0 + d1 * d1;
#pragma unroll
  for (int o = 32; o; o >>= 1) qv += __shfl_down(qv, o);
  float var = __shfl(qv, 0) * (1.f / 128.f);
  float inv = rsqrtf(var + 1e-5f);
  out[(size_t)r * 128 + t]      = d0 * inv * g[t] + b[t];
  out[(size_t)r * 128 + 64 + t] = d1 * inv * g[64 + t] + b[64 + t];
}

__global__ void concat3_k(const float* __restrict__ a, const float* __restrict__ b,
                          const float* __restrict__ c, float* __restrict__ out, int rows){
  int i = blockIdx.x * blockDim.x + threadIdx.x;
  int total = rows * 384;
  if (i >= total) return;
  int r = i / 384, col = i - r * 384;
  float v = (col < 128) ? a[(size_t)r * 128 + col]
          : (col < 256) ? b[(size_t)r * 128 + col - 128]
                        : c[(size_t)r * 128 + col - 256];
  out[i] = v;
}

__global__ void softmax4_k(const float* __restrict__ logits, float* __restrict__ out){
  int r = blockIdx.x * blockDim.x + threadIdx.x;
  if (r >= NA) return;
  const float* l = logits + (size_t)r * 4;
  float m = fmaxf(fmaxf(l[0], l[1]), fmaxf(l[2], l[3]));
  float e0 = __expf(l[0] - m), e1 = __expf(l[1] - m), e2 = __expf(l[2] - m), e3 = __expf(l[3] - m);
  float inv = 1.f / (e0 + e1 + e2 + e3);
  out[(size_t)r * 4 + 0] = e0 * inv;
  out[(size_t)r * 4 + 1] = e1 * inv;
  out[(size_t)r * 4 + 2] = e2 * inv;
  out[(size_t)r * 4 + 3] = e3 * inv;
}

__global__ void setval_k(float* p, float v){ p[0] = v; }

// ---------------------------------------------------------------- host
extern "C" void kernel_launch(void* const* d_in, const int* in_sizes, int n_in,
                              void* d_out, int out_size, void* d_ws, size_t ws_size,
                              hipStream_t stream)
{
  (void)in_sizes; (void)n_in; (void)out_size;
  const float* x_author = (const float*)d_in[0];
  const float* x_paper  = (const float*)d_in[1];
  const float* x_term   = (const float*)d_in[2];
  const int* ap_src = (const int*)d_in[3];
  const int* ap_dst = (const int*)d_in[4];
  const int* pa_src = (const int*)d_in[5];
  const int* pa_dst = (const int*)d_in[6];
  const int* tp_src = (const int*)d_in[9];
  const int* tp_dst = (const int*)d_in[10];
  const float* original_A = (const float*)d_in[11];
  const int* deg = (const int*)d_in[12];
  const float* t1_W = (const float*)d_in[13]; const float* t1_b = (const float*)d_in[14];
  const float* t2_W = (const float*)d_in[15]; const float* t2_b = (const float*)d_in[16];
  const float* t3_W = (const float*)d_in[17]; const float* t3_b = (const float*)d_in[18];
  const float* gat1_W  = (const float*)d_in[19];
  const float* gat1_as = (const float*)d_in[20];
  const float* gat1_ad = (const float*)d_in[21];
  const float* gat1_b  = (const float*)d_in[22];
  const float* gat2_W  = (const float*)d_in[23];
  const float* gat2_as = (const float*)d_in[24];
  const float* gat2_ad = (const float*)d_in[25];
  const float* gat2_b  = (const float*)d_in[26];
  const float* pe_embed = (const float*)d_in[27];
  const float* peWQ = (const float*)d_in[28];
  const float* peWK = (const float*)d_in[29];
  const float* gt_Wq = (const float*)d_in[30]; const float* gt_bq = (const float*)d_in[31];
  const float* gt_Wk = (const float*)d_in[32]; const float* gt_bk = (const float*)d_in[33];
  const float* gt_Wv = (const float*)d_in[34]; const float* gt_bv = (const float*)d_in[35];
  const float* gt_Wo = (const float*)d_in[36]; const float* gt_bo = (const float*)d_in[37];
  const float* gt_g1 = (const float*)d_in[38]; const float* gt_be1 = (const float*)d_in[39];
  const float* gt_Wf1 = (const float*)d_in[40]; const float* gt_bf1 = (const float*)d_in[41];
  const float* gt_Wf2 = (const float*)d_in[42]; const float* gt_bf2 = (const float*)d_in[43];
  const float* gt_g2 = (const float*)d_in[44]; const float* gt_be2 = (const float*)d_in[45];
  const float* cat_W = (const float*)d_in[46]; const float* cat_b = (const float*)d_in[47];
  const float* mlp_W1 = (const float*)d_in[48]; const float* mlp_b1 = (const float*)d_in[49];
  const float* mlp_W2 = (const float*)d_in[50]; const float* mlp_b2 = (const float*)d_in[51];
  float* out = (float*)d_out;

  // ---- workspace layout ----
  char* base = (char*)d_ws;
  size_t off = 0;
  auto alloc = [&](size_t nbytes) -> void* {
    void* p = base + off;
    off += (nbytes + 255) & ~(size_t)255;
    return p;
  };
  float* xa   = (float*)alloc((size_t)NA * 128 * 4);
  float* xp   = (float*)alloc((size_t)NPA * 128 * 4);
  float* xt   = (float*)alloc((size_t)NT * 128 * 4);
  float* accP = (float*)alloc((size_t)NPA * 1024 * 4);   // also reused (w/ accA) as attn partials
  float* accA = (float*)alloc((size_t)NA * 1024 * 4);
  float* agg  = (float*)alloc((size_t)NPA * 1024 * 4);
  float* wbuf = (float*)alloc((size_t)E_TP * 8 * 4);
  float* ssrc = (float*)alloc((size_t)NPA * 8 * 4);
  float* sdst = (float*)alloc((size_t)NPA * 8 * 4);
  float* Ps   = (float*)alloc(1024 * 4);
  float* Pd   = (float*)alloc(1024 * 4);
  unsigned* mEnc = (unsigned*)alloc((size_t)NPA * 8 * 4);
  float* den  = (float*)alloc((size_t)NPA * 8 * 4);
  float* hs2  = (float*)alloc((size_t)NPA * 128 * 4);
  float* hd2  = (float*)alloc((size_t)NA * 128 * 4);
  float* s2s  = (float*)alloc((size_t)NPA * 4);
  float* s2d  = (float*)alloc((size_t)NA * 4);
  float* w2   = (float*)alloc((size_t)E_PA * 4);
  unsigned* m2Enc = (unsigned*)alloc((size_t)NA * 4);
  float* den2 = (float*)alloc((size_t)NA * 4);
  float* hA2  = (float*)alloc((size_t)NA * 128 * 4);
  float* peQ  = (float*)alloc((size_t)NA * 128 * 4);
  float* peK  = (float*)alloc((size_t)NA * 128 * 4);
  float* dbv  = (float*)alloc((size_t)NA * 4);
  float* lossAcc = (float*)alloc(256);
  float* Qb   = (float*)alloc((size_t)NA * 128 * 4);
  float* Kb   = (float*)alloc((size_t)NA * 128 * 4);
  float* Vb   = (float*)alloc((size_t)NA * 128 * 4);
  float* Ob   = (float*)alloc((size_t)NA * 128 * 4);
  float* res1 = (float*)alloc((size_t)NA * 128 * 4);
  float* x1b  = (float*)alloc((size_t)NA * 128 * 4);
  float* f1   = (float*)alloc((size_t)NA * 256 * 4);
  float* ffres= (float*)alloc((size_t)NA * 128 * 4);
  float* outs1= (float*)alloc((size_t)NA * 128 * 4);
  float* outs2= (float*)alloc((size_t)NA * 128 * 4);
  float* catb = (float*)alloc((size_t)NA * 384 * 4);
  float* l1   = (float*)alloc((size_t)NA * 256 * 4);
  float* logits = (float*)alloc((size_t)NA * 4 * 4);
  int* cnt  = (int*)alloc((size_t)NPA * 4);
  int* offb = (int*)alloc((size_t)NPA * 4);
  int* cur  = (int*)alloc((size_t)NPA * 4);
  int* eidx = (int*)alloc((size_t)E_TP * 4);
  int* cntpa  = (int*)alloc((size_t)NA * 4);
  int* offpa  = (int*)alloc((size_t)NA * 4);
  int* curpa  = (int*)alloc((size_t)NA * 4);
  int* eidxpa = (int*)alloc((size_t)E_PA * 4);

  // attention partials alias onto accP/accA (dead by transformer time)
  float* part = accP;

  if (off > ws_size){
    setval_k<<<1, 1, 0, stream>>>(out, -12345.0f);
    return;
  }

  // f32 fallback GEMM (small N)
  auto gemm32 = [&](const float* A, const float* B, float* C, const float* bias,
                    const float* addmat, int M, int N, int K, int lda, int ldb, int ldc,
                    int relu){
    dim3 g((M + 63) / 64, (N + 63) / 64, 1);
    if (relu) gemm_k<1><<<g, 256, 0, stream>>>(A, B, C, bias, addmat, M, N, K, lda, ldb, ldc, 0, 0, 0, 0);
    else      gemm_k<0><<<g, 256, 0, stream>>>(A, B, C, bias, addmat, M, N, K, lda, ldb, ldc, 0, 0, 0, 0);
  };
  // bf16 MFMA GEMM: requires M%64==0, N%128==0
  auto gemm = [&](const float* A, const float* B, float* C, const float* bias,
                  const float* addmat, int M, int N, int K, int lda, int ldb, int ldc,
                  int relu, int Z = 1, int aOffZ = 0, int bOffZ = 0, int cOffZ = 0,
                  int accum = 0){
    dim3 g(M / 64, N / 128, Z);
    if (relu) gemm_mfma_k<1><<<g, 256, 0, stream>>>(A, B, C, bias, addmat, M, N, K, lda, ldb, ldc, aOffZ, bOffZ, cOffZ, accum);
    else      gemm_mfma_k<0><<<g, 256, 0, stream>>>(A, B, C, bias, addmat, M, N, K, lda, ldb, ldc, aOffZ, bOffZ, cOffZ, accum);
  };

  auto build_csr = [&](const int* edst, int E, int Ndst, int* cnt_, int* off_, int* cur_, int* eidx_){
    hipMemsetAsync(cnt_, 0, (size_t)Ndst * 4, stream);
    hipMemsetAsync(cur_, 0, (size_t)Ndst * 4, stream);
    hist_k<<<(E + 255) / 256, 256, 0, stream>>>(edst, cnt_, E);
    exscan_k<<<1, 256, 0, stream>>>(cnt_, off_, Ndst);
    scatter_k<<<(E + 255) / 256, 256, 0, stream>>>(edst, off_, cur_, eidx_, E);
  };

  auto gat1_type = [&](const float* xsrc, int Nsrc, const float* xdst, int Ndst,
                       const int* esrc, const int* edst, int E,
                       const float* W, const float* as_, const float* ad_,
                       const int* eidx_, const int* off_, const int* cnt_, float* accOut){
    gat_proj_k<<<4, 256, 0, stream>>>(W, as_, ad_, Ps, Pd);
    gemm32(xsrc, Ps, ssrc, nullptr, nullptr, Nsrc, 8, 128, 128, 8, 8, 0);
    gemm32(xdst, Pd, sdst, nullptr, nullptr, Ndst, 8, 128, 128, 8, 8, 0);
    hipMemsetAsync(mEnc, 0, (size_t)Ndst * 8 * 4, stream);
    hipMemsetAsync(den,  0, (size_t)Ndst * 8 * 4, stream);
    int EH = E * 8;
    edgeA_k<<<(EH + 255) / 256, 256, 0, stream>>>(esrc, edst, ssrc, sdst, wbuf, mEnc, E, 8);
    edgeB_k<<<(EH + 255) / 256, 256, 0, stream>>>(edst, wbuf, mEnc, den, E, 8);
    gat_agg8_k<<<Ndst, 256, 0, stream>>>(eidx_, off_, cnt_, esrc, xsrc, wbuf, den, agg);
    gemm(agg, W, accOut, nullptr, nullptr, Ndst, 128, 128, 1024, 1024, 1024, 0, 8, 128, 128, 128, 1);
  };

  // ---- stage 0: node feature MLPs ----
  gemm(x_author, t1_W, xa, t1_b, nullptr, NA, 128, 334, 334, 128, 128, 1);
  gemm(x_paper,  t2_W, xp, t2_b, nullptr, NPA, 128, 512, 512, 128, 128, 1);
  gemm(x_term,   t3_W, xt, t3_b, nullptr, NT, 128, 128, 128, 128, 128, 1);

  hipMemsetAsync(accP, 0, (size_t)NPA * 1024 * 4, stream);
  hipMemsetAsync(accA, 0, (size_t)NA * 1024 * 4, stream);

  // ---- GAT layer 1 ----
  build_csr(ap_dst, E_AP, NPA, cnt, offb, cur, eidx);
  gat1_type(xa, NA, xp, NPA, ap_src, ap_dst, E_AP,
            gat1_W + 0 * 131072, gat1_as + 0 * 1024, gat1_ad + 0 * 1024, eidx, offb, cnt, accP);
  build_csr(tp_dst, E_TP, NPA, cnt, offb, cur, eidx);
  gat1_type(xt, NT, xp, NPA, tp_src, tp_dst, E_TP,
            gat1_W + 3 * 131072, gat1_as + 3 * 1024, gat1_ad + 3 * 1024, eidx, offb, cnt, accP);
  build_csr(pa_dst, E_PA, NA, cntpa, offpa, curpa, eidxpa);
  gat1_type(xp, NPA, xa, NA, pa_src, pa_dst, E_PA,
            gat1_W + 1 * 131072, gat1_as + 1 * 1024, gat1_ad + 1 * 1024, eidxpa, offpa, cntpa, accA);
  bias2_relu_k<<<((NPA * 1024) + 255) / 256, 256, 0, stream>>>(accP, gat1_b, gat1_b + 3 * 1024, NPA * 1024, 1024);
  bias2_relu_k<<<((NA * 1024) + 255) / 256, 256, 0, stream>>>(accA, gat1_b + 1024, nullptr, NA * 1024, 1024);

  // ---- GAT layer 2 (type pa, heads=1, out=128) ----
  gemm(accP, gat2_W + 131072, hs2, nullptr, nullptr, NPA, 128, 1024, 1024, 128, 128, 0);
  gemm(accA, gat2_W + 131072, hd2, nullptr, nullptr, NA, 128, 1024, 1024, 128, 128, 0);
  rowdot_k<<<NPA, 64, 0, stream>>>(hs2, gat2_as + 128, s2s, 128);
  rowdot_k<<<NA, 64, 0, stream>>>(hd2, gat2_ad + 128, s2d, 128);
  hipMemsetAsync(m2Enc, 0, (size_t)NA * 4, stream);
  hipMemsetAsync(den2, 0, (size_t)NA * 4, stream);
  edgeA_k<<<(E_PA + 255) / 256, 256, 0, stream>>>(pa_src, pa_dst, s2s, s2d, w2, m2Enc, E_PA, 1);
  edgeB_k<<<(E_PA + 255) / 256, 256, 0, stream>>>(pa_dst, w2, m2Enc, den2, E_PA, 1);
  gat_agg1_k<<<NA, 128, 0, stream>>>(eidxpa, offpa, cntpa, pa_src, hs2, w2, den2, gat2_b + 128, hA2);

  // ---- positional encodings + reconstruction loss ----
  gemm(pe_embed, peWQ, peQ, nullptr, nullptr, NA, 128, 128, 128, 128, 128, 0);
  gemm(pe_embed, peWK, peK, nullptr, nullptr, NA, 128, 128, 128, 128, 128, 0);
  db_k<<<16, 256, 0, stream>>>(deg, dbv);
  hipMemsetAsync(lossAcc, 0, 256, stream);
  loss_mfma_k<<<dim3(64, 32), 256, 0, stream>>>(peQ, peK, original_A, lossAcc);
  finalize_loss_k<<<1, 1, 0, stream>>>(lossAcc, out);

  // ---- graph transformer (2 layers) ----
  const float* x = hA2;
  float* louts[2] = { outs1, outs2 };
  for (int i = 0; i < 2; ++i){
    const float* Wq = gt_Wq + i * 16384; const float* bq = gt_bq + i * 128;
    const float* Wk = gt_Wk + i * 16384; const float* bk = gt_bk + i * 128;
    const float* Wv = gt_Wv + i * 16384; const float* bv = gt_bv + i * 128;
    const float* Wo = gt_Wo + i * 16384; const float* bo = gt_bo + i * 128;
    const float* Wf1 = gt_Wf1 + i * 32768; const float* bf1 = gt_bf1 + i * 256;
    const float* Wf2 = gt_Wf2 + i * 32768; const float* bf2 = gt_bf2 + i * 128;
    gemm(x, Wq, Qb, bq, peQ, NA, 128, 128, 128, 128, 128, 0);
    gemm(x, Wk, Kb, bk, peK, NA, 128, 128, 128, 128, 128, 0);
    gemm(x, Wv, Vb, bv, nullptr, NA, 128, 128, 128, 128, 128, 0);
    attn_part_k<<<dim3(NA / 512, 8, ASPLIT), 256, 0, stream>>>(Qb, Kb, Vb, dbv, part);
    attn_comb_k<<<(NA * 8) / 256, 256, 0, stream>>>(part, Ob);
    gemm(Ob, Wo, res1, bo, x, NA, 128, 128, 128, 128, 128, 0);
    ln_k<<<NA, 64, 0, stream>>>(res1, gt_g1 + i * 128, gt_be1 + i * 128, x1b);
    gemm(x1b, Wf1, f1, bf1, nullptr, NA, 256, 128, 128, 256, 256, 1);
    gemm(f1, Wf2, ffres, bf2, x1b, NA, 128, 256, 256, 128, 128, 0);
    ln_k<<<NA, 64, 0, stream>>>(ffres, gt_g2 + i * 128, gt_be2 + i * 128, louts[i]);
    x = louts[i];
  }

  // ---- head ----
  concat3_k<<<((NA * 384) + 255) / 256, 256, 0, stream>>>(hA2, outs1, outs2, catb, NA);
  float* xgt = out + 1 + NA * 4;
  gemm(catb, cat_W, xgt, cat_b, nullptr, NA, 128, 384, 384, 128, 128, 1);
  gemm(xgt, mlp_W1, l1, mlp_b1, nullptr, NA, 256, 128, 128, 256, 256, 1);
  gemm32(l1, mlp_W2, logits, mlp_b2, nullptr, NA, 4, 256, 256, 4, 4, 0);
  softmax4_k<<<(NA + 255) / 256, 256, 0, stream>>>(logits, out + 1);
}

// Round 4
// 1477.176 us; speedup vs baseline: 1.9470x; 1.2056x over previous
//
#include <hip/hip_runtime.h>
#include <math.h>

// Problem constants
#define NA   4096
#define NPA  8192
#define NT   4096
#define E_AP 80000
#define E_PA 80000
#define E_TP 160000
#define ASPLIT 4   // attention key-splits (== KSPL)

typedef __attribute__((ext_vector_type(4))) float f32x4;
typedef __attribute__((ext_vector_type(8))) short s16x8;
typedef __attribute__((ext_vector_type(8))) unsigned short u16x8;

__device__ __forceinline__ unsigned fenc(float f){
  unsigned u = __float_as_uint(f);
  return (u & 0x80000000u) ? ~u : (u | 0x80000000u);
}
__device__ __forceinline__ float fdec(unsigned u){
  return (u & 0x80000000u) ? __uint_as_float(u & 0x7fffffffu) : __uint_as_float(~u);
}
__device__ __forceinline__ unsigned short f2bf(float f){
  unsigned u = __float_as_uint(f);
  unsigned r = u + 0x7fffu + ((u >> 16) & 1u);   // RNE
  return (unsigned short)(r >> 16);
}

// ---------------------------------------------------------------- f32 GEMM (small-N leftovers)
template<int ACT>
__global__ __launch_bounds__(256) void gemm_k(
    const float* __restrict__ A, const float* __restrict__ B, float* __restrict__ C,
    const float* __restrict__ bias, const float* __restrict__ addmat,
    int M, int N, int K, int lda, int ldb, int ldc,
    int aOffZ, int bOffZ, int cOffZ, int accumulate)
{
  A += (size_t)blockIdx.z * aOffZ;
  B += (size_t)blockIdx.z * bOffZ;
  C += (size_t)blockIdx.z * cOffZ;
  __shared__ float As[16][68];
  __shared__ float Bs[16][68];
  int bm = blockIdx.x * 64, bn = blockIdx.y * 64;
  int tid = threadIdx.x;
  int tr = tid >> 4, tc = tid & 15;
  float acc[4][4] = {{0.f}};
  for (int k0 = 0; k0 < K; k0 += 16) {
#pragma unroll
    for (int i = 0; i < 4; ++i) {
      int idx = tid + i * 256;
      int r  = idx >> 4, kk = idx & 15;
      int gr = bm + r, gk = k0 + kk;
      As[kk][r] = (gr < M && gk < K) ? A[(size_t)gr * lda + gk] : 0.f;
      int c  = idx & 63, k2 = idx >> 6;
      int gc = bn + c, gk2 = k0 + k2;
      Bs[k2][c] = (gk2 < K && gc < N) ? B[(size_t)gk2 * ldb + gc] : 0.f;
    }
    __syncthreads();
#pragma unroll
    for (int kk = 0; kk < 16; ++kk) {
      float a0[4], b0[4];
#pragma unroll
      for (int i = 0; i < 4; ++i) a0[i] = As[kk][tr * 4 + i];
#pragma unroll
      for (int j = 0; j < 4; ++j) b0[j] = Bs[kk][tc * 4 + j];
#pragma unroll
      for (int i = 0; i < 4; ++i)
#pragma unroll
        for (int j = 0; j < 4; ++j) acc[i][j] = fmaf(a0[i], b0[j], acc[i][j]);
    }
    __syncthreads();
  }
#pragma unroll
  for (int i = 0; i < 4; ++i) {
    int r = bm + tr * 4 + i;
    if (r >= M) continue;
#pragma unroll
    for (int j = 0; j < 4; ++j) {
      int c = bn + tc * 4 + j;
      if (c >= N) continue;
      float v = acc[i][j];
      if (bias)   v += bias[c];
      if (addmat) v += addmat[(size_t)r * ldc + c];
      if (accumulate) v += C[(size_t)r * ldc + c];
      if (ACT == 1) v = fmaxf(v, 0.f);
      C[(size_t)r * ldc + c] = v;
    }
  }
}

// ---------------------------------------------------------------- bf16 MFMA GEMM
// Tile 64x128xBK32, 4 waves (2x2), each wave 32x64 = 2x4 fragments of 16x16.
// Requires M%64==0, N%128==0.
template<int ACT>
__global__ __launch_bounds__(256) void gemm_mfma_k(
    const float* __restrict__ A, const float* __restrict__ B, float* __restrict__ C,
    const float* __restrict__ bias, const float* __restrict__ addmat,
    int M, int N, int K, int lda, int ldb, int ldc,
    int aOffZ, int bOffZ, int cOffZ, int accumulate)
{
  A += (size_t)blockIdx.z * aOffZ;
  B += (size_t)blockIdx.z * bOffZ;
  C += (size_t)blockIdx.z * cOffZ;
  __shared__ __align__(16) unsigned short As[64][40];
  __shared__ __align__(16) unsigned short Bs[128][40];
  int bm = blockIdx.x * 64, bn = blockIdx.y * 128;
  int tid = threadIdx.x;
  int w = tid >> 6, lane = tid & 63, lg = lane >> 4, lid = lane & 15;
  int wm = (w & 1) * 32, wn = (w >> 1) * 64;
  f32x4 acc[2][4];
#pragma unroll
  for (int i = 0; i < 2; ++i)
#pragma unroll
    for (int j = 0; j < 4; ++j) acc[i][j] = (f32x4){0.f, 0.f, 0.f, 0.f};

  for (int k0 = 0; k0 < K; k0 += 32) {
    {
      int r = tid >> 2, ks = (tid & 3) * 8;
      const float* ap = A + (size_t)(bm + r) * lda + k0 + ks;
      u16x8 v;
#pragma unroll
      for (int j = 0; j < 8; ++j) {
        int gk = k0 + ks + j;
        float fv = (gk < K) ? ap[j] : 0.f;
        v[j] = f2bf(fv);
      }
      *(u16x8*)&As[r][ks] = v;
    }
    {
      int n = tid >> 1, ks = (tid & 1) * 16;
      unsigned short tmp[16];
#pragma unroll
      for (int j = 0; j < 16; ++j) {
        int gk = k0 + ks + j;
        float fv = (gk < K) ? B[(size_t)gk * ldb + bn + n] : 0.f;
        tmp[j] = f2bf(fv);
      }
      u16x8 v0, v1;
#pragma unroll
      for (int j = 0; j < 8; ++j) { v0[j] = tmp[j]; v1[j] = tmp[8 + j]; }
      *(u16x8*)&Bs[n][ks] = v0;
      *(u16x8*)&Bs[n][ks + 8] = v1;
    }
    __syncthreads();
    s16x8 a_frag[2], b_frag[4];
#pragma unroll
    for (int i = 0; i < 2; ++i) a_frag[i] = *(s16x8*)&As[wm + i * 16 + lid][lg * 8];
#pragma unroll
    for (int j = 0; j < 4; ++j) b_frag[j] = *(s16x8*)&Bs[wn + j * 16 + lid][lg * 8];
#pragma unroll
    for (int i = 0; i < 2; ++i)
#pragma unroll
      for (int j = 0; j < 4; ++j)
        acc[i][j] = __builtin_amdgcn_mfma_f32_16x16x32_bf16(a_frag[i], b_frag[j], acc[i][j], 0, 0, 0);
    __syncthreads();
  }
#pragma unroll
  for (int i = 0; i < 2; ++i) {
#pragma unroll
    for (int j = 0; j < 4; ++j) {
      int c = bn + wn + j * 16 + lid;
#pragma unroll
      for (int rr = 0; rr < 4; ++rr) {
        int r = bm + wm + i * 16 + lg * 4 + rr;
        float v = acc[i][j][rr];
        if (bias)   v += bias[c];
        if (addmat) v += addmat[(size_t)r * ldc + c];
        if (accumulate) v += C[(size_t)r * ldc + c];
        if (ACT == 1) v = fmaxf(v, 0.f);
        C[(size_t)r * ldc + c] = v;
      }
    }
  }
}

// ---------------------------------------------------------------- GAT pieces
__global__ void gat_proj_k(const float* __restrict__ W, const float* __restrict__ as_,
                           const float* __restrict__ ad_, float* __restrict__ Ps,
                           float* __restrict__ Pd){
  int t = blockIdx.x * blockDim.x + threadIdx.x;
  if (t >= 128 * 8) return;
  int k = t >> 3, h = t & 7;
  const float* wr = W + (size_t)k * 1024 + h * 128;
  const float* a1 = as_ + h * 128;
  const float* a2 = ad_ + h * 128;
  float s1 = 0.f, s2 = 0.f;
  for (int c = 0; c < 128; ++c){ float wv = wr[c]; s1 = fmaf(wv, a1[c], s1); s2 = fmaf(wv, a2[c], s2); }
  Ps[k * 8 + h] = s1;
  Pd[k * 8 + h] = s2;
}

__global__ void hist_k(const int* __restrict__ dst, int* __restrict__ cnt, int E){
  int i = blockIdx.x * blockDim.x + threadIdx.x;
  if (i < E) atomicAdd(&cnt[dst[i]], 1);
}

// shuffle-based exclusive scan, 1 block, 2 barriers per 256-chunk
__global__ void exscan_k(const int* __restrict__ in, int* __restrict__ out, int n){
  __shared__ int wsum[4];
  __shared__ int carrySh;
  int t = threadIdx.x, w = t >> 6, lane = t & 63;
  if (t == 0) carrySh = 0;
  __syncthreads();
  for (int base = 0; base < n; base += 256){
    int carry = carrySh;
    int v = (base + t < n) ? in[base + t] : 0;
    int sc = v;
#pragma unroll
    for (int o2 = 1; o2 < 64; o2 <<= 1){
      int u = __shfl_up(sc, o2);
      if (lane >= o2) sc += u;
    }
    if (lane == 63) wsum[w] = sc;
    __syncthreads();
    int wadd = 0;
#pragma unroll
    for (int i = 0; i < 3; ++i) if (i < w) wadd += wsum[i];
    if (base + t < n) out[base + t] = carry + wadd + sc - v;
    if (t == 255) carrySh = carry + wadd + sc;
    __syncthreads();
  }
}

__global__ void scatter_k(const int* __restrict__ dst, const int* __restrict__ off,
                          int* __restrict__ cur, int* __restrict__ eidx, int E){
  int i = blockIdx.x * blockDim.x + threadIdx.x;
  if (i >= E) return;
  int d = dst[i];
  int p = atomicAdd(&cur[d], 1);
  eidx[off[d] + p] = i;
}

// per-(edge,head): e = leakyrelu(ss[src]+sd[dst]); store; atomic max encode
__global__ void edgeA_k(const int* __restrict__ src, const int* __restrict__ dst,
                        const float* __restrict__ ss, const float* __restrict__ sd,
                        float* __restrict__ tmp, unsigned* __restrict__ mEnc, int E, int H){
  int i = blockIdx.x * blockDim.x + threadIdx.x;
  if (i >= E * H) return;
  int e = i / H, h = i - e * H;
  float v = ss[src[e] * H + h] + sd[dst[e] * H + h];
  v = v > 0.f ? v : 0.2f * v;
  tmp[i] = v;
  atomicMax(mEnc + dst[e] * H + h, fenc(v));
}

// fused edge-softmax + x-space aggregation, H=8; one WAVE per dst node.
// agg[d,h,c] = (sum_e exp(tmp[e,h]-m[d,h]) * x[src_e,c]) / (sum_e exp(...) + eps)
__global__ __launch_bounds__(256) void gat_agg8f_k(
    const int* __restrict__ eidx, const int* __restrict__ off, const int* __restrict__ cnt,
    const int* __restrict__ src, const float* __restrict__ x,
    const float* __restrict__ tmp, const unsigned* __restrict__ mEnc,
    float* __restrict__ agg, int Ndst)
{
  int d = blockIdx.x * 4 + (threadIdx.x >> 6);
  if (d >= Ndst) return;
  int lane = threadIdx.x & 63;
  int hh = lane & 7;
  float mh = fdec(mEnc[(size_t)d * 8 + hh]);
  float acc0[8], acc1[8];
#pragma unroll
  for (int h2 = 0; h2 < 8; ++h2){ acc0[h2] = 0.f; acc1[h2] = 0.f; }
  float den = 0.f;
  int base = off[d], n = cnt[d];
  int e = (n > 0) ? eidx[base] : 0;
  int s = (n > 0) ? src[e] : 0;
  for (int k = 0; k < n; ++k){
    int en = 0, sn = 0;
    if (k + 1 < n){ en = eidx[base + k + 1]; sn = src[en]; }
    float wv_ = __expf(tmp[(size_t)e * 8 + hh] - mh);
    den += wv_;
    float xv0 = x[(size_t)s * 128 + lane];
    float xv1 = x[(size_t)s * 128 + 64 + lane];
#pragma unroll
    for (int h2 = 0; h2 < 8; ++h2){
      float wh = __shfl(wv_, h2);
      acc0[h2] = fmaf(wh, xv0, acc0[h2]);
      acc1[h2] = fmaf(wh, xv1, acc1[h2]);
    }
    e = en; s = sn;
  }
  float* o = agg + (size_t)d * 1024;
#pragma unroll
  for (int h2 = 0; h2 < 8; ++h2){
    float dh = __shfl(den, h2) + 1e-16f;
    o[h2 * 128 + lane] = acc0[h2] / dh;
    o[h2 * 128 + 64 + lane] = acc1[h2] / dh;
  }
}

// fused H=1 variant (gat2): out = sum w*hs[src]/(den+eps) + b; one wave per dst
__global__ __launch_bounds__(256) void gat_agg1f_k(
    const int* __restrict__ eidx, const int* __restrict__ off, const int* __restrict__ cnt,
    const int* __restrict__ src, const float* __restrict__ hs,
    const float* __restrict__ tmp, const unsigned* __restrict__ mEnc,
    const float* __restrict__ bias, float* __restrict__ outp, int Ndst)
{
  int d = blockIdx.x * 4 + (threadIdx.x >> 6);
  if (d >= Ndst) return;
  int lane = threadIdx.x & 63;
  float mh = fdec(mEnc[d]);
  float a0 = 0.f, a1 = 0.f, den = 0.f;
  int base = off[d], n = cnt[d];
  int e = (n > 0) ? eidx[base] : 0;
  int s = (n > 0) ? src[e] : 0;
  for (int k = 0; k < n; ++k){
    int en = 0, sn = 0;
    if (k + 1 < n){ en = eidx[base + k + 1]; sn = src[en]; }
    float w_ = __expf(tmp[e] - mh);
    den += w_;
    a0 = fmaf(w_, hs[(size_t)s * 128 + lane], a0);
    a1 = fmaf(w_, hs[(size_t)s * 128 + 64 + lane], a1);
    e = en; s = sn;
  }
  float inv = 1.f / (den + 1e-16f);
  outp[(size_t)d * 128 + lane]      = a0 * inv + bias[lane];
  outp[(size_t)d * 128 + 64 + lane] = a1 * inv + bias[64 + lane];
}

__global__ void rowdot_k(const float* __restrict__ X, const float* __restrict__ v,
                         float* __restrict__ out, int C){
  int r = blockIdx.x;
  int t = threadIdx.x; // 64
  float s = 0.f;
  for (int c = t; c < C; c += 64) s = fmaf(X[(size_t)r * C + c], v[c], s);
#pragma unroll
  for (int o = 32; o; o >>= 1) s += __shfl_down(s, o);
  if (t == 0) out[r] = s;
}

__global__ void addvec_k(const float* __restrict__ a, const float* __restrict__ b,
                         float* __restrict__ o, int n){
  int i = blockIdx.x * blockDim.x + threadIdx.x;
  if (i < n) o[i] = a[i] + b[i];
}

// ---------------------------------------------------------------- PE loss (MFMA)
__global__ __launch_bounds__(256) void loss_mfma_k(const float* __restrict__ peQ,
    const float* __restrict__ peK, const float* __restrict__ A4, float* __restrict__ lossAcc)
{
  __shared__ __align__(16) unsigned short As[64][40];
  __shared__ __align__(16) unsigned short Bs[128][40];
  __shared__ float red[256];
  int br = blockIdx.x * 64, bc = blockIdx.y * 128;
  int tid = threadIdx.x;
  int w = tid >> 6, lane = tid & 63, lg = lane >> 4, lid = lane & 15;
  int wm = (w & 1) * 32, wn = (w >> 1) * 64;
  f32x4 acc[2][4];
#pragma unroll
  for (int i = 0; i < 2; ++i)
#pragma unroll
    for (int j = 0; j < 4; ++j) acc[i][j] = (f32x4){0.f, 0.f, 0.f, 0.f};

  for (int k0 = 0; k0 < 128; k0 += 32) {
    {
      int r = tid >> 2, ks = (tid & 3) * 8;
      const float* ap = peQ + (size_t)(br + r) * 128 + k0 + ks;
      u16x8 v;
#pragma unroll
      for (int j = 0; j < 8; ++j) v[j] = f2bf(ap[j]);
      *(u16x8*)&As[r][ks] = v;
    }
    {
      int n = tid >> 1, ks = (tid & 1) * 16;
      const float* bp = peK + (size_t)(bc + n) * 128 + k0 + ks;
      u16x8 v0, v1;
#pragma unroll
      for (int j = 0; j < 8; ++j) { v0[j] = f2bf(bp[j]); v1[j] = f2bf(bp[8 + j]); }
      *(u16x8*)&Bs[n][ks] = v0;
      *(u16x8*)&Bs[n][ks + 8] = v1;
    }
    __syncthreads();
    s16x8 a_frag[2], b_frag[4];
#pragma unroll
    for (int i = 0; i < 2; ++i) a_frag[i] = *(s16x8*)&As[wm + i * 16 + lid][lg * 8];
#pragma unroll
    for (int j = 0; j < 4; ++j) b_frag[j] = *(s16x8*)&Bs[wn + j * 16 + lid][lg * 8];
#pragma unroll
    for (int i = 0; i < 2; ++i)
#pragma unroll
      for (int j = 0; j < 4; ++j)
        acc[i][j] = __builtin_amdgcn_mfma_f32_16x16x32_bf16(a_frag[i], b_frag[j], acc[i][j], 0, 0, 0);
    __syncthreads();
  }
  float err = 0.f;
#pragma unroll
  for (int i = 0; i < 2; ++i) {
#pragma unroll
    for (int rr = 0; rr < 4; ++rr) {
      int r = br + wm + i * 16 + lg * 4 + rr;
#pragma unroll
      for (int j = 0; j < 4; ++j) {
        int c = bc + wn + j * 16 + lid;
        float s = 1.f / (1.f + __expf(-acc[i][j][rr]));
        size_t o = (size_t)r * 4096 + c;
#pragma unroll
        for (int q = 0; q < 4; ++q) {
          float d = s - A4[(size_t)q * 16777216 + o];
          err += d * d;
        }
      }
    }
  }
  red[tid] = err;
  __syncthreads();
  for (int o = 128; o; o >>= 1){
    if (tid < o) red[tid] += red[tid + o];
    __syncthreads();
  }
  if (tid == 0) atomicAdd(lossAcc, red[0]);
}

__global__ void finalize_loss_k(const float* __restrict__ acc, float* __restrict__ out){
  out[0] = acc[0] * (1.0f / 67108864.0f); // /(4*4096*4096)
}

__global__ void db_k(const int* __restrict__ deg, float* __restrict__ dbv){
  int i = blockIdx.x * blockDim.x + threadIdx.x;
  if (i >= NA) return;
  dbv[i] = logf(fmaxf((float)deg[i], 1.f));
}

// ---------------------------------------------------------------- MFMA flash attention
// grid (NA/64, 8 heads, ASPLIT). 4 waves/block; wave w owns q-rows qbase+16w..+16.
// Swapped QK^T: S^T = mfma(A=K_frag, B=Q_frag) so C col = q = lane&15.
// P staged per-wave in LDS (bf16), PV = mfma(A=P, B=V^T) accumulating O[16q x 16d].
__global__ __launch_bounds__(256) void attn_mfma_k(
    const float* __restrict__ Q, const float* __restrict__ K, const float* __restrict__ V,
    const float* __restrict__ dbv, float* __restrict__ part)
{
  int h = blockIdx.y, sp = blockIdx.z;
  int qbase = blockIdx.x * 64;
  int tid = threadIdx.x;
  int w = tid >> 6, lane = tid & 63, lid = lane & 15, lg = lane >> 4;
  __shared__ __align__(16) unsigned short Vt[16][72];    // [d][key] bf16
  __shared__ __align__(16) unsigned short Pl[4][16][72]; // [wave][q-local][key] bf16
  __shared__ float dbs[64];

  // Q B-fragment (fixed for block): lane holds Q[(q)*128+h*16+8lg..+8]*0.25, lg<2
  s16x8 qf;
  if (lg < 2) {
    const float* qp = Q + (size_t)(qbase + 16 * w + lid) * 128 + h * 16 + 8 * lg;
    u16x8 v;
#pragma unroll
    for (int j = 0; j < 8; ++j) v[j] = f2bf(qp[j] * 0.25f);
    qf = (s16x8)v;
  } else {
    qf = (s16x8){0,0,0,0,0,0,0,0};
  }

  float m = -1e30f, l = 0.f;
  f32x4 o = {0.f, 0.f, 0.f, 0.f};

  int kb0 = sp * (4096 / ASPLIT);
  for (int kt = 0; kt < 4096 / ASPLIT; kt += 64) {
    int kb = kb0 + kt;
    __syncthreads();   // protect Vt from previous iteration's readers
    {
      int key = tid >> 2, ds_ = (tid & 3) * 4;
      const float* vp = V + (size_t)(kb + key) * 128 + h * 16 + ds_;
#pragma unroll
      for (int j = 0; j < 4; ++j) Vt[ds_ + j][key] = f2bf(vp[j]);
      if (tid < 64) dbs[tid] = dbv[kb + tid];
    }
    __syncthreads();

    // S^T per 16-key group: rows = keys (4lg+r), cols = q (lid)
    f32x4 s[4];
#pragma unroll
    for (int g = 0; g < 4; ++g) {
      s16x8 kf;
      if (lg < 2) {
        const float* kp = K + (size_t)(kb + 16 * g + lid) * 128 + h * 16 + 8 * lg;
        u16x8 v;
#pragma unroll
        for (int j = 0; j < 8; ++j) v[j] = f2bf(kp[j]);
        kf = (s16x8)v;
      } else kf = (s16x8){0,0,0,0,0,0,0,0};
      s[g] = __builtin_amdgcn_mfma_f32_16x16x32_bf16(kf, qf, (f32x4){0.f,0.f,0.f,0.f}, 0, 0, 0);
    }
#pragma unroll
    for (int g = 0; g < 4; ++g)
#pragma unroll
      for (int r = 0; r < 4; ++r) s[g][r] += dbs[16 * g + 4 * lg + r];

    // per-q (column) max over this lane's 16 keys, then across lg groups
    float tmax = -1e30f;
#pragma unroll
    for (int g = 0; g < 4; ++g)
#pragma unroll
      for (int r = 0; r < 4; ++r) tmax = fmaxf(tmax, s[g][r]);
    tmax = fmaxf(tmax, __shfl_xor(tmax, 16));
    tmax = fmaxf(tmax, __shfl_xor(tmax, 32));
    float mn = fmaxf(m, tmax);
    float scale = __expf(m - mn);
    float psum = 0.f;
    float p[4][4];
#pragma unroll
    for (int g = 0; g < 4; ++g)
#pragma unroll
      for (int r = 0; r < 4; ++r) { p[g][r] = __expf(s[g][r] - mn); psum += p[g][r]; }
    psum += __shfl_xor(psum, 16);
    psum += __shfl_xor(psum, 32);
    l = l * scale + psum;
    m = mn;

    // write P (bf16) to this wave's LDS rows: row=q(lid), col=key(16g+4lg+r)
#pragma unroll
    for (int g = 0; g < 4; ++g) {
#pragma unroll
      for (int rp = 0; rp < 4; rp += 2) {
        unsigned pack = (unsigned)f2bf(p[g][rp]) | ((unsigned)f2bf(p[g][rp + 1]) << 16);
        *(unsigned*)&Pl[w][lid][16 * g + 4 * lg + rp] = pack;
      }
    }
    // rescale O (rows q = 4lg+r; scale lives in lane lid==q)
#pragma unroll
    for (int r = 0; r < 4; ++r) o[r] *= __shfl(scale, 4 * lg + r);
    // PV: two K=32 contractions over the 64-key tile
#pragma unroll
    for (int kc = 0; kc < 2; ++kc) {
      s16x8 pa = *(s16x8*)&Pl[w][lid][32 * kc + 8 * lg];
      s16x8 vb = *(s16x8*)&Vt[lid][32 * kc + 8 * lg];
      o = __builtin_amdgcn_mfma_f32_16x16x32_bf16(pa, vb, o, 0, 0, 0);
    }
  }
  // partials: O C-layout col=d=lid, row q=4lg+r; m,l written by lg==0 lanes
  float* pb = part + ((size_t)(sp * 8 + h) * NA) * 18;
#pragma unroll
  for (int r = 0; r < 4; ++r) {
    int qq = qbase + 16 * w + 4 * lg + r;
    pb[(size_t)qq * 18 + lid] = o[r];
  }
  if (lg == 0) {
    int qq = qbase + 16 * w + lid;
    pb[(size_t)qq * 18 + 16] = m;
    pb[(size_t)qq * 18 + 17] = l;
  }
}

__global__ __launch_bounds__(256) void attn_comb_k(const float* __restrict__ part,
                                                   float* __restrict__ O){
  int t = blockIdx.x * 256 + threadIdx.x;
  int r = t >> 3, h = t & 7;
  float m = -1e30f;
#pragma unroll
  for (int sp = 0; sp < ASPLIT; ++sp)
    m = fmaxf(m, part[((size_t)(sp * 8 + h) * NA + r) * 18 + 16]);
  float l = 0.f, acc[16];
#pragma unroll
  for (int j = 0; j < 16; ++j) acc[j] = 0.f;
  for (int sp = 0; sp < ASPLIT; ++sp){
    const float* pp = part + ((size_t)(sp * 8 + h) * NA + r) * 18;
    float w = __expf(pp[16] - m);
    l += pp[17] * w;
#pragma unroll
    for (int j = 0; j < 16; ++j) acc[j] = fmaf(pp[j], w, acc[j]);
  }
  float inv = 1.f / l;
#pragma unroll
  for (int j = 0; j < 16; ++j) O[(size_t)r * 128 + h * 16 + j] = acc[j] * inv;
}

// layernorm over rows of 128
__global__ __launch_bounds__(64) void ln_k(const float* __restrict__ in,
    const float* __restrict__ g, const float* __restrict__ b, float* __restrict__ out){
  int r = blockIdx.x;
  int t = threadIdx.x;
  float v0 = in[(size_t)r * 128 + t], v1 = in[(size_t)r * 128 + 64 + t];
  float s = v0 + v1;
#pragma unroll
  for (int o = 32; o; o >>= 1) s += __shfl_down(s, o);
  float mean = __shfl(s, 0) * (1.f / 128.f);
  float d0 = v0 - mean, d1 = v1 - mean;
  float qv = d0 * d0 + d1 * d1;
#pragma unroll
  for (int o = 32; o; o >>= 1) qv += __shfl_down(qv, o);
  float var = __shfl(qv, 0) * (1.f / 128.f);
  float inv = rsqrtf(var + 1e-5f);
  out[(size_t)r * 128 + t]      = d0 * inv * g[t] + b[t];
  out[(size_t)r * 128 + 64 + t] = d1 * inv * g[64 + t] + b[64 + t];
}

__global__ void concat3_k(const float* __restrict__ a, const float* __restrict__ b,
                          const float* __restrict__ c, float* __restrict__ out, int rows){
  int i = blockIdx.x * blockDim.x + threadIdx.x;
  int total = rows * 384;
  if (i >= total) return;
  int r = i / 384, col = i - r * 384;
  float v = (col < 128) ? a[(size_t)r * 128 + col]
          : (col < 256) ? b[(size_t)r * 128 + col - 128]
                        : c[(size_t)r * 128 + col - 256];
  out[i] = v;
}

__global__ void softmax4_k(const float* __restrict__ logits, float* __restrict__ out){
  int r = blockIdx.x * blockDim.x + threadIdx.x;
  if (r >= NA) return;
  const float* l = logits + (size_t)r * 4;
  float m = fmaxf(fmaxf(l[0], l[1]), fmaxf(l[2], l[3]));
  float e0 = __expf(l[0] - m), e1 = __expf(l[1] - m), e2 = __expf(l[2] - m), e3 = __expf(l[3] - m);
  float inv = 1.f / (e0 + e1 + e2 + e3);
  out[(size_t)r * 4 + 0] = e0 * inv;
  out[(size_t)r * 4 + 1] = e1 * inv;
  out[(size_t)r * 4 + 2] = e2 * inv;
  out[(size_t)r * 4 + 3] = e3 * inv;
}

__global__ void setval_k(float* p, float v){ p[0] = v; }

// ---------------------------------------------------------------- host
extern "C" void kernel_launch(void* const* d_in, const int* in_sizes, int n_in,
                              void* d_out, int out_size, void* d_ws, size_t ws_size,
                              hipStream_t stream)
{
  (void)in_sizes; (void)n_in; (void)out_size;
  const float* x_author = (const float*)d_in[0];
  const float* x_paper  = (const float*)d_in[1];
  const float* x_term   = (const float*)d_in[2];
  const int* ap_src = (const int*)d_in[3];
  const int* ap_dst = (const int*)d_in[4];
  const int* pa_src = (const int*)d_in[5];
  const int* pa_dst = (const int*)d_in[6];
  const int* tp_src = (const int*)d_in[9];
  const int* tp_dst = (const int*)d_in[10];
  const float* original_A = (const float*)d_in[11];
  const int* deg = (const int*)d_in[12];
  const float* t1_W = (const float*)d_in[13]; const float* t1_b = (const float*)d_in[14];
  const float* t2_W = (const float*)d_in[15]; const float* t2_b = (const float*)d_in[16];
  const float* t3_W = (const float*)d_in[17]; const float* t3_b = (const float*)d_in[18];
  const float* gat1_W  = (const float*)d_in[19];
  const float* gat1_as = (const float*)d_in[20];
  const float* gat1_ad = (const float*)d_in[21];
  const float* gat1_b  = (const float*)d_in[22];
  const float* gat2_W  = (const float*)d_in[23];
  const float* gat2_as = (const float*)d_in[24];
  const float* gat2_ad = (const float*)d_in[25];
  const float* gat2_b  = (const float*)d_in[26];
  const float* pe_embed = (const float*)d_in[27];
  const float* peWQ = (const float*)d_in[28];
  const float* peWK = (const float*)d_in[29];
  const float* gt_Wq = (const float*)d_in[30]; const float* gt_bq = (const float*)d_in[31];
  const float* gt_Wk = (const float*)d_in[32]; const float* gt_bk = (const float*)d_in[33];
  const float* gt_Wv = (const float*)d_in[34]; const float* gt_bv = (const float*)d_in[35];
  const float* gt_Wo = (const float*)d_in[36]; const float* gt_bo = (const float*)d_in[37];
  const float* gt_g1 = (const float*)d_in[38]; const float* gt_be1 = (const float*)d_in[39];
  const float* gt_Wf1 = (const float*)d_in[40]; const float* gt_bf1 = (const float*)d_in[41];
  const float* gt_Wf2 = (const float*)d_in[42]; const float* gt_bf2 = (const float*)d_in[43];
  const float* gt_g2 = (const float*)d_in[44]; const float* gt_be2 = (const float*)d_in[45];
  const float* cat_W = (const float*)d_in[46]; const float* cat_b = (const float*)d_in[47];
  const float* mlp_W1 = (const float*)d_in[48]; const float* mlp_b1 = (const float*)d_in[49];
  const float* mlp_W2 = (const float*)d_in[50]; const float* mlp_b2 = (const float*)d_in[51];
  float* out = (float*)d_out;

  // ---- workspace layout ----
  char* base = (char*)d_ws;
  size_t off = 0;
  auto alloc = [&](size_t nbytes) -> void* {
    void* p = base + off;
    off += (nbytes + 255) & ~(size_t)255;
    return p;
  };
  float* xa   = (float*)alloc((size_t)NA * 128 * 4);
  float* xp   = (float*)alloc((size_t)NPA * 128 * 4);
  float* xt   = (float*)alloc((size_t)NT * 128 * 4);
  float* accP = (float*)alloc((size_t)NPA * 1024 * 4);   // reused as attn partials
  float* accA = (float*)alloc((size_t)NA * 1024 * 4);
  float* agg  = (float*)alloc((size_t)NPA * 1024 * 4);
  float* wbuf = (float*)alloc((size_t)E_TP * 8 * 4);
  float* ssrc = (float*)alloc((size_t)NPA * 8 * 4);
  float* sdst = (float*)alloc((size_t)NPA * 8 * 4);
  float* Ps   = (float*)alloc(1024 * 4);
  float* Pd   = (float*)alloc(1024 * 4);
  unsigned* mEnc = (unsigned*)alloc((size_t)NPA * 8 * 4);
  float* hs2  = (float*)alloc((size_t)NPA * 128 * 4);
  float* hd2  = (float*)alloc((size_t)NA * 128 * 4);
  float* s2s  = (float*)alloc((size_t)NPA * 4);
  float* s2d  = (float*)alloc((size_t)NA * 4);
  float* w2   = (float*)alloc((size_t)E_PA * 4);
  unsigned* m2Enc = (unsigned*)alloc((size_t)NA * 4);
  float* hA2  = (float*)alloc((size_t)NA * 128 * 4);
  float* peQ  = (float*)alloc((size_t)NA * 128 * 4);
  float* peK  = (float*)alloc((size_t)NA * 128 * 4);
  float* dbv  = (float*)alloc((size_t)NA * 4);
  float* lossAcc = (float*)alloc(256);
  float* bsum = (float*)alloc(1024 * 4);
  float* Qb   = (float*)alloc((size_t)NA * 128 * 4);
  float* Kb   = (float*)alloc((size_t)NA * 128 * 4);
  float* Vb   = (float*)alloc((size_t)NA * 128 * 4);
  float* Ob   = (float*)alloc((size_t)NA * 128 * 4);
  float* res1 = (float*)alloc((size_t)NA * 128 * 4);
  float* x1b  = (float*)alloc((size_t)NA * 128 * 4);
  float* f1   = (float*)alloc((size_t)NA * 256 * 4);
  float* ffres= (float*)alloc((size_t)NA * 128 * 4);
  float* outs1= (float*)alloc((size_t)NA * 128 * 4);
  float* outs2= (float*)alloc((size_t)NA * 128 * 4);
  float* catb = (float*)alloc((size_t)NA * 384 * 4);
  float* l1   = (float*)alloc((size_t)NA * 256 * 4);
  float* logits = (float*)alloc((size_t)NA * 4 * 4);
  int* cnt  = (int*)alloc((size_t)NPA * 4);
  int* offb = (int*)alloc((size_t)NPA * 4);
  int* cur  = (int*)alloc((size_t)NPA * 4);
  int* eidx = (int*)alloc((size_t)E_TP * 4);
  int* cntpa  = (int*)alloc((size_t)NA * 4);
  int* offpa  = (int*)alloc((size_t)NA * 4);
  int* curpa  = (int*)alloc((size_t)NA * 4);
  int* eidxpa = (int*)alloc((size_t)E_PA * 4);

  // attention partials: ASPLIT*8*NA*18 floats = 9.4 MB, aliased onto accP (dead by then)
  float* part = accP;

  if (off > ws_size){
    setval_k<<<1, 1, 0, stream>>>(out, -12345.0f);
    return;
  }

  auto gemm32 = [&](const float* A, const float* B, float* C, const float* bias,
                    const float* addmat, int M, int N, int K, int lda, int ldb, int ldc,
                    int relu){
    dim3 g((M + 63) / 64, (N + 63) / 64, 1);
    if (relu) gemm_k<1><<<g, 256, 0, stream>>>(A, B, C, bias, addmat, M, N, K, lda, ldb, ldc, 0, 0, 0, 0);
    else      gemm_k<0><<<g, 256, 0, stream>>>(A, B, C, bias, addmat, M, N, K, lda, ldb, ldc, 0, 0, 0, 0);
  };
  auto gemm = [&](const float* A, const float* B, float* C, const float* bias,
                  const float* addmat, int M, int N, int K, int lda, int ldb, int ldc,
                  int relu, int Z = 1, int aOffZ = 0, int bOffZ = 0, int cOffZ = 0,
                  int accum = 0){
    dim3 g(M / 64, N / 128, Z);
    if (relu) gemm_mfma_k<1><<<g, 256, 0, stream>>>(A, B, C, bias, addmat, M, N, K, lda, ldb, ldc, aOffZ, bOffZ, cOffZ, accum);
    else      gemm_mfma_k<0><<<g, 256, 0, stream>>>(A, B, C, bias, addmat, M, N, K, lda, ldb, ldc, aOffZ, bOffZ, cOffZ, accum);
  };

  auto build_csr = [&](const int* edst, int E, int Ndst, int* cnt_, int* off_, int* cur_, int* eidx_){
    hipMemsetAsync(cnt_, 0, (size_t)Ndst * 4, stream);
    hipMemsetAsync(cur_, 0, (size_t)Ndst * 4, stream);
    hist_k<<<(E + 255) / 256, 256, 0, stream>>>(edst, cnt_, E);
    exscan_k<<<1, 256, 0, stream>>>(cnt_, off_, Ndst);
    scatter_k<<<(E + 255) / 256, 256, 0, stream>>>(edst, off_, cur_, eidx_, E);
  };

  // GAT layer-1 one edge type: scores -> fused edge-softmax+agg -> per-head GEMM
  auto gat1_type = [&](const float* xsrc, int Nsrc, const float* xdst, int Ndst,
                       const int* esrc, const int* edst, int E,
                       const float* W, const float* as_, const float* ad_,
                       const int* eidx_, const int* off_, const int* cnt_, float* accOut,
                       const float* gbias, int act, int accum){
    gat_proj_k<<<4, 256, 0, stream>>>(W, as_, ad_, Ps, Pd);
    gemm32(xsrc, Ps, ssrc, nullptr, nullptr, Nsrc, 8, 128, 128, 8, 8, 0);
    gemm32(xdst, Pd, sdst, nullptr, nullptr, Ndst, 8, 128, 128, 8, 8, 0);
    hipMemsetAsync(mEnc, 0, (size_t)Ndst * 8 * 4, stream);
    int EH = E * 8;
    edgeA_k<<<(EH + 255) / 256, 256, 0, stream>>>(esrc, edst, ssrc, sdst, wbuf, mEnc, E, 8);
    gat_agg8f_k<<<(Ndst + 3) / 4, 256, 0, stream>>>(eidx_, off_, cnt_, esrc, xsrc, wbuf, mEnc, agg, Ndst);
    gemm(agg, W, accOut, gbias, nullptr, Ndst, 128, 128, 1024, 1024, 1024, act, 8, 128, 128, 128, accum);
  };

  // ---- stage 0: node feature MLPs ----
  gemm(x_author, t1_W, xa, t1_b, nullptr, NA, 128, 334, 334, 128, 128, 1);
  gemm(x_paper,  t2_W, xp, t2_b, nullptr, NPA, 128, 512, 512, 128, 128, 1);
  gemm(x_term,   t3_W, xt, t3_b, nullptr, NT, 128, 128, 128, 128, 128, 1);

  // gat1 biases: paper node gets b[0]+b[3]
  addvec_k<<<4, 256, 0, stream>>>(gat1_b, gat1_b + 3 * 1024, bsum, 1024);

  // ---- GAT layer 1 ----
  build_csr(ap_dst, E_AP, NPA, cnt, offb, cur, eidx);
  gat1_type(xa, NA, xp, NPA, ap_src, ap_dst, E_AP,
            gat1_W + 0 * 131072, gat1_as + 0 * 1024, gat1_ad + 0 * 1024, eidx, offb, cnt,
            accP, nullptr, 0, 0);
  build_csr(tp_dst, E_TP, NPA, cnt, offb, cur, eidx);
  gat1_type(xt, NT, xp, NPA, tp_src, tp_dst, E_TP,
            gat1_W + 3 * 131072, gat1_as + 3 * 1024, gat1_ad + 3 * 1024, eidx, offb, cnt,
            accP, bsum, 1, 1);
  build_csr(pa_dst, E_PA, NA, cntpa, offpa, curpa, eidxpa);
  gat1_type(xp, NPA, xa, NA, pa_src, pa_dst, E_PA,
            gat1_W + 1 * 131072, gat1_as + 1 * 1024, gat1_ad + 1 * 1024, eidxpa, offpa, cntpa,
            accA, gat1_b + 1024, 1, 0);
  // accP == h_p1, accA == h_a1

  // ---- GAT layer 2 (type pa, heads=1, out=128) ----
  gemm(accP, gat2_W + 131072, hs2, nullptr, nullptr, NPA, 128, 1024, 1024, 128, 128, 0);
  gemm(accA, gat2_W + 131072, hd2, nullptr, nullptr, NA, 128, 1024, 1024, 128, 128, 0);
  rowdot_k<<<NPA, 64, 0, stream>>>(hs2, gat2_as + 128, s2s, 128);
  rowdot_k<<<NA, 64, 0, stream>>>(hd2, gat2_ad + 128, s2d, 128);
  hipMemsetAsync(m2Enc, 0, (size_t)NA * 4, stream);
  edgeA_k<<<(E_PA + 255) / 256, 256, 0, stream>>>(pa_src, pa_dst, s2s, s2d, w2, m2Enc, E_PA, 1);
  gat_agg1f_k<<<(NA + 3) / 4, 256, 0, stream>>>(eidxpa, offpa, cntpa, pa_src, hs2, w2, m2Enc, gat2_b + 128, hA2, NA);

  // ---- positional encodings + reconstruction loss ----
  gemm(pe_embed, peWQ, peQ, nullptr, nullptr, NA, 128, 128, 128, 128, 128, 0);
  gemm(pe_embed, peWK, peK, nullptr, nullptr, NA, 128, 128, 128, 128, 128, 0);
  db_k<<<16, 256, 0, stream>>>(deg, dbv);
  hipMemsetAsync(lossAcc, 0, 256, stream);
  loss_mfma_k<<<dim3(64, 32), 256, 0, stream>>>(peQ, peK, original_A, lossAcc);
  finalize_loss_k<<<1, 1, 0, stream>>>(lossAcc, out);

  // ---- graph transformer (2 layers) ----
  const float* x = hA2;
  float* louts[2] = { outs1, outs2 };
  for (int i = 0; i < 2; ++i){
    const float* Wq = gt_Wq + i * 16384; const float* bq = gt_bq + i * 128;
    const float* Wk = gt_Wk + i * 16384; const float* bk = gt_bk + i * 128;
    const float* Wv = gt_Wv + i * 16384; const float* bv = gt_bv + i * 128;
    const float* Wo = gt_Wo + i * 16384; const float* bo = gt_bo + i * 128;
    const float* Wf1 = gt_Wf1 + i * 32768; const float* bf1 = gt_bf1 + i * 256;
    const float* Wf2 = gt_Wf2 + i * 32768; const float* bf2 = gt_bf2 + i * 128;
    gemm(x, Wq, Qb, bq, peQ, NA, 128, 128, 128, 128, 128, 0);
    gemm(x, Wk, Kb, bk, peK, NA, 128, 128, 128, 128, 128, 0);
    gemm(x, Wv, Vb, bv, nullptr, NA, 128, 128, 128, 128, 128, 0);
    attn_mfma_k<<<dim3(NA / 64, 8, ASPLIT), 256, 0, stream>>>(Qb, Kb, Vb, dbv, part);
    attn_comb_k<<<(NA * 8) / 256, 256, 0, stream>>>(part, Ob);
    gemm(Ob, Wo, res1, bo, x, NA, 128, 128, 128, 128, 128, 0);
    ln_k<<<NA, 64, 0, stream>>>(res1, gt_g1 + i * 128, gt_be1 + i * 128, x1b);
    gemm(x1b, Wf1, f1, bf1, nullptr, NA, 256, 128, 128, 256, 256, 1);
    gemm(f1, Wf2, ffres, bf2, x1b, NA, 128, 256, 256, 128, 128, 0);
    ln_k<<<NA, 64, 0, stream>>>(ffres, gt_g2 + i * 128, gt_be2 + i * 128, louts[i]);
    x = louts[i];
  }

  // ---- head ----
  concat3_k<<<((NA * 384) + 255) / 256, 256, 0, stream>>>(hA2, outs1, outs2, catb, NA);
  float* xgt = out + 1 + NA * 4;
  gemm(catb, cat_W, xgt, cat_b, nullptr, NA, 128, 384, 384, 128, 128, 1);
  gemm(xgt, mlp_W1, l1, mlp_b1, nullptr, NA, 256, 128, 128, 256, 256, 1);
  gemm32(l1, mlp_W2, logits, mlp_b2, nullptr, NA, 4, 256, 256, 4, 4, 0);
  softmax4_k<<<(NA + 255) / 256, 256, 0, stream>>>(logits, out + 1);
}

// Round 5
// 1108.136 us; speedup vs baseline: 2.5954x; 1.3330x over previous
//
#include <hip/hip_runtime.h>
#include <math.h>

// Problem constants
#define NA   4096
#define NPA  8192
#define NT   4096
#define E_AP 80000
#define E_PA 80000
#define E_TP 160000
#define E_TOT (E_AP + E_TP + E_PA)
#define NSLOT (NPA + NPA + NA)     // 20480 global CSR slots: [ap->paper | tp->paper | pa->author]
#define ASPLIT 4                   // attention key-splits

typedef __attribute__((ext_vector_type(4))) float f32x4;
typedef __attribute__((ext_vector_type(8))) short s16x8;
typedef __attribute__((ext_vector_type(8))) unsigned short u16x8;

__device__ __forceinline__ unsigned fenc(float f){
  unsigned u = __float_as_uint(f);
  return (u & 0x80000000u) ? ~u : (u | 0x80000000u);
}
__device__ __forceinline__ float fdec(unsigned u){
  return (u & 0x80000000u) ? __uint_as_float(u & 0x7fffffffu) : __uint_as_float(~u);
}
__device__ __forceinline__ unsigned short f2bf(float f){
  unsigned u = __float_as_uint(f);
  unsigned r = u + 0x7fffu + ((u >> 16) & 1u);   // RNE
  return (unsigned short)(r >> 16);
}

// ---------------------------------------------------------------- f32 GEMM (mlp2 only, ACT=2 -> row softmax over N=4)
template<int ACT>
__global__ __launch_bounds__(256) void gemm_k(
    const float* __restrict__ A, const float* __restrict__ B, float* __restrict__ C,
    const float* __restrict__ bias,
    int M, int N, int K, int lda, int ldb, int ldc)
{
  __shared__ float As[16][68];
  __shared__ float Bs[16][68];
  int bm = blockIdx.x * 64, bn = blockIdx.y * 64;
  int tid = threadIdx.x;
  int tr = tid >> 4, tc = tid & 15;
  float acc[4][4] = {{0.f}};
  for (int k0 = 0; k0 < K; k0 += 16) {
#pragma unroll
    for (int i = 0; i < 4; ++i) {
      int idx = tid + i * 256;
      int r  = idx >> 4, kk = idx & 15;
      int gr = bm + r, gk = k0 + kk;
      As[kk][r] = (gr < M && gk < K) ? A[(size_t)gr * lda + gk] : 0.f;
      int c  = idx & 63, k2 = idx >> 6;
      int gc = bn + c, gk2 = k0 + k2;
      Bs[k2][c] = (gk2 < K && gc < N) ? B[(size_t)gk2 * ldb + gc] : 0.f;
    }
    __syncthreads();
#pragma unroll
    for (int kk = 0; kk < 16; ++kk) {
      float a0[4], b0[4];
#pragma unroll
      for (int i = 0; i < 4; ++i) a0[i] = As[kk][tr * 4 + i];
#pragma unroll
      for (int j = 0; j < 4; ++j) b0[j] = Bs[kk][tc * 4 + j];
#pragma unroll
      for (int i = 0; i < 4; ++i)
#pragma unroll
        for (int j = 0; j < 4; ++j) acc[i][j] = fmaf(a0[i], b0[j], acc[i][j]);
    }
    __syncthreads();
  }
  if (ACT == 2) {
    // row softmax over the first 4 cols; only tc==0 threads own cols 0..3
    if (tc != 0) return;
#pragma unroll
    for (int i = 0; i < 4; ++i) {
      int r = bm + tr * 4 + i;
      if (r >= M) continue;
      float l0 = acc[i][0] + bias[0], l1 = acc[i][1] + bias[1];
      float l2 = acc[i][2] + bias[2], l3 = acc[i][3] + bias[3];
      float mx = fmaxf(fmaxf(l0, l1), fmaxf(l2, l3));
      float e0 = __expf(l0 - mx), e1 = __expf(l1 - mx), e2 = __expf(l2 - mx), e3 = __expf(l3 - mx);
      float inv = 1.f / (e0 + e1 + e2 + e3);
      C[(size_t)r * ldc + 0] = e0 * inv;
      C[(size_t)r * ldc + 1] = e1 * inv;
      C[(size_t)r * ldc + 2] = e2 * inv;
      C[(size_t)r * ldc + 3] = e3 * inv;
    }
  } else {
#pragma unroll
    for (int i = 0; i < 4; ++i) {
      int r = bm + tr * 4 + i;
      if (r >= M) continue;
#pragma unroll
      for (int j = 0; j < 4; ++j) {
        int c = bn + tc * 4 + j;
        if (c >= N) continue;
        float v = acc[i][j];
        if (bias) v += bias[c];
        if (ACT == 1) v = fmaxf(v, 0.f);
        C[(size_t)r * ldc + c] = v;
      }
    }
  }
}

// ---------------------------------------------------------------- bf16 MFMA GEMM
// Tile 64x128xBK32, 4 waves (2x2). Requires M%64==0, N%128==0.
// ACT: 0 none, 1 relu, 2 LayerNorm over full row (requires N==128, grid.y==1).
// Optional concatenated A (A2/A3): virtual A = [A|A2|A3], each 128 cols, lda=128.
// addmat: v += (c < addCols) ? addmat[r*addLd + c] : 0.
template<int ACT>
__global__ __launch_bounds__(256) void gemm_mfma_k(
    const float* __restrict__ A, const float* __restrict__ A2, const float* __restrict__ A3,
    const float* __restrict__ B, float* __restrict__ C,
    const float* __restrict__ bias,
    const float* __restrict__ addmat, int addCols, int addLd,
    const float* __restrict__ lng, const float* __restrict__ lnb,
    int M, int N, int K, int lda, int ldb, int ldc,
    int aOffZ, int bOffZ, int cOffZ, int accumulate)
{
  A += (size_t)blockIdx.z * aOffZ;
  B += (size_t)blockIdx.z * bOffZ;
  C += (size_t)blockIdx.z * cOffZ;
  __shared__ __align__(16) unsigned short As[64][40];
  __shared__ __align__(16) unsigned short Bs[128][40];
  int bm = blockIdx.x * 64, bn = blockIdx.y * 128;
  int tid = threadIdx.x;
  int w = tid >> 6, lane = tid & 63, lg = lane >> 4, lid = lane & 15;
  int wm = (w & 1) * 32, wn = (w >> 1) * 64;
  f32x4 acc[2][4];
#pragma unroll
  for (int i = 0; i < 2; ++i)
#pragma unroll
    for (int j = 0; j < 4; ++j) acc[i][j] = (f32x4){0.f, 0.f, 0.f, 0.f};

  for (int k0 = 0; k0 < K; k0 += 32) {
    {
      int r = tid >> 2, ks = (tid & 3) * 8;
      int kcol = k0 + ks;
      const float* Ab = A;
      if (A2) { int seg = kcol >> 7; Ab = (seg == 0) ? A : ((seg == 1) ? A2 : A3); kcol &= 127; }
      const float* ap = Ab + (size_t)(bm + r) * lda + kcol;
      u16x8 v;
#pragma unroll
      for (int j = 0; j < 8; ++j) {
        int gk = k0 + ks + j;
        float fv = (gk < K) ? ap[j] : 0.f;
        v[j] = f2bf(fv);
      }
      *(u16x8*)&As[r][ks] = v;
    }
    {
      int n = tid >> 1, ks = (tid & 1) * 16;
      unsigned short tmp[16];
#pragma unroll
      for (int j = 0; j < 16; ++j) {
        int gk = k0 + ks + j;
        float fv = (gk < K) ? B[(size_t)gk * ldb + bn + n] : 0.f;
        tmp[j] = f2bf(fv);
      }
      u16x8 v0, v1;
#pragma unroll
      for (int j = 0; j < 8; ++j) { v0[j] = tmp[j]; v1[j] = tmp[8 + j]; }
      *(u16x8*)&Bs[n][ks] = v0;
      *(u16x8*)&Bs[n][ks + 8] = v1;
    }
    __syncthreads();
    s16x8 a_frag[2], b_frag[4];
#pragma unroll
    for (int i = 0; i < 2; ++i) a_frag[i] = *(s16x8*)&As[wm + i * 16 + lid][lg * 8];
#pragma unroll
    for (int j = 0; j < 4; ++j) b_frag[j] = *(s16x8*)&Bs[wn + j * 16 + lid][lg * 8];
#pragma unroll
    for (int i = 0; i < 2; ++i)
#pragma unroll
      for (int j = 0; j < 4; ++j)
        acc[i][j] = __builtin_amdgcn_mfma_f32_16x16x32_bf16(a_frag[i], b_frag[j], acc[i][j], 0, 0, 0);
    __syncthreads();
  }
  if (ACT == 2) {
    // fused LayerNorm: requires N==128, grid.y==1 (bn==0), ldc==128
    __shared__ float Ct[64][132];
#pragma unroll
    for (int i = 0; i < 2; ++i) {
#pragma unroll
      for (int j = 0; j < 4; ++j) {
        int coll = wn + j * 16 + lid;
#pragma unroll
        for (int rr = 0; rr < 4; ++rr) {
          int rowl = wm + i * 16 + lg * 4 + rr;
          float v = acc[i][j][rr];
          if (bias) v += bias[coll];
          if (addmat && coll < addCols) v += addmat[(size_t)(bm + rowl) * addLd + coll];
          Ct[rowl][coll] = v;
        }
      }
    }
    __syncthreads();
    int row = tid >> 2, part = tid & 3;
    float s = 0.f, q = 0.f;
#pragma unroll
    for (int c2 = 0; c2 < 32; ++c2) {
      float v = Ct[row][part * 32 + c2];
      s += v; q += v * v;
    }
    s += __shfl_xor(s, 1); q += __shfl_xor(q, 1);
    s += __shfl_xor(s, 2); q += __shfl_xor(q, 2);
    float mean = s * (1.f / 128.f);
    float var = q * (1.f / 128.f) - mean * mean;
    float inv = rsqrtf(var + 1e-5f);
    int r = bm + row;
#pragma unroll
    for (int c2 = 0; c2 < 32; ++c2) {
      int c = part * 32 + c2;
      C[(size_t)r * ldc + c] = (Ct[row][c] - mean) * inv * lng[c] + lnb[c];
    }
  } else {
#pragma unroll
    for (int i = 0; i < 2; ++i) {
#pragma unroll
      for (int j = 0; j < 4; ++j) {
        int c = bn + wn + j * 16 + lid;
#pragma unroll
        for (int rr = 0; rr < 4; ++rr) {
          int r = bm + wm + i * 16 + lg * 4 + rr;
          float v = acc[i][j][rr];
          if (bias)   v += bias[c];
          if (addmat && c < addCols) v += addmat[(size_t)r * addLd + c];
          if (accumulate) v += C[(size_t)r * ldc + c];
          if (ACT == 1) v = fmaxf(v, 0.f);
          C[(size_t)r * ldc + c] = v;
        }
      }
    }
  }
}

// ---------------------------------------------------------------- prep: pack weights/biases
// [0,1024): bsum = gat1_b[0]+gat1_b[3]
// then Wqkv[2][128][384], bqkv[2][384], peW[128][256]
__global__ void prep_k(const float* __restrict__ gat1_b,
                       const float* __restrict__ Wq, const float* __restrict__ bq,
                       const float* __restrict__ Wk, const float* __restrict__ bk,
                       const float* __restrict__ Wv, const float* __restrict__ bv,
                       const float* __restrict__ peWQ, const float* __restrict__ peWK,
                       float* __restrict__ bsum, float* __restrict__ Wqkv,
                       float* __restrict__ bqkv, float* __restrict__ peW)
{
  int idx = blockIdx.x * blockDim.x + threadIdx.x;
  if (idx < 1024) { bsum[idx] = gat1_b[idx] + gat1_b[3 * 1024 + idx]; return; }
  idx -= 1024;
  if (idx < 2 * 128 * 384) {
    int l = idx / 49152, rem = idx % 49152;
    int k = rem / 384, c = rem % 384;
    float v;
    if (c < 128)      v = Wq[(size_t)l * 16384 + k * 128 + c];
    else if (c < 256) v = Wk[(size_t)l * 16384 + k * 128 + c - 128];
    else              v = Wv[(size_t)l * 16384 + k * 128 + c - 256];
    Wqkv[(size_t)l * 49152 + k * 384 + c] = v;
    return;
  }
  idx -= 2 * 128 * 384;
  if (idx < 2 * 384) {
    int l = idx / 384, c = idx % 384;
    float v;
    if (c < 128)      v = bq[l * 128 + c];
    else if (c < 256) v = bk[l * 128 + c - 128];
    else              v = bv[l * 128 + c - 256];
    bqkv[l * 384 + c] = v;
    return;
  }
  idx -= 2 * 384;
  if (idx < 128 * 256) {
    int k = idx / 256, c = idx % 256;
    peW[k * 256 + c] = (c < 128) ? peWQ[k * 128 + c] : peWK[k * 128 + c - 128];
  }
}

// ---------------------------------------------------------------- fused CSR build (3 edge types)
__global__ void histf_k(const int* __restrict__ ap_dst, const int* __restrict__ tp_dst,
                        const int* __restrict__ pa_dst, int* __restrict__ cnt){
  int i = blockIdx.x * blockDim.x + threadIdx.x;
  if (i >= E_TOT) return;
  int slot;
  if (i < E_AP)             slot = ap_dst[i];
  else if (i < E_AP + E_TP) slot = NPA + tp_dst[i - E_AP];
  else                      slot = 2 * NPA + pa_dst[i - E_AP - E_TP];
  atomicAdd(&cnt[slot], 1);
}

__global__ void scatterf_k(const int* __restrict__ ap_dst, const int* __restrict__ tp_dst,
                           const int* __restrict__ pa_dst, const int* __restrict__ off,
                           int* __restrict__ cur, int* __restrict__ eidx){
  int i = blockIdx.x * blockDim.x + threadIdx.x;
  if (i >= E_TOT) return;
  int slot, local;
  if (i < E_AP)             { local = i;                 slot = ap_dst[local]; }
  else if (i < E_AP + E_TP) { local = i - E_AP;          slot = NPA + tp_dst[local]; }
  else                      { local = i - E_AP - E_TP;   slot = 2 * NPA + pa_dst[local]; }
  int p = atomicAdd(&cur[slot], 1);
  eidx[off[slot] + p] = local;
}

// shuffle-based exclusive scan, 1 block
__global__ void exscan_k(const int* __restrict__ in, int* __restrict__ out, int n){
  __shared__ int wsum[4];
  __shared__ int carrySh;
  int t = threadIdx.x, w = t >> 6, lane = t & 63;
  if (t == 0) carrySh = 0;
  __syncthreads();
  for (int base = 0; base < n; base += 256){
    int carry = carrySh;
    int v = (base + t < n) ? in[base + t] : 0;
    int sc = v;
#pragma unroll
    for (int o2 = 1; o2 < 64; o2 <<= 1){
      int u = __shfl_up(sc, o2);
      if (lane >= o2) sc += u;
    }
    if (lane == 63) wsum[w] = sc;
    __syncthreads();
    int wadd = 0;
#pragma unroll
    for (int i = 0; i < 3; ++i) if (i < w) wadd += wsum[i];
    if (base + t < n) out[base + t] = carry + wadd + sc - v;
    if (t == 255) carrySh = carry + wadd + sc;
    __syncthreads();
  }
}

// ---------------------------------------------------------------- GAT batched pieces
// Ps/Pd for 3 types (W index order ap=0, tp=3, pa=1)
__global__ void proj3_k(const float* __restrict__ W, const float* __restrict__ as_,
                        const float* __restrict__ ad_, float* __restrict__ Ps,
                        float* __restrict__ Pd){
  int t = blockIdx.x * blockDim.x + threadIdx.x;
  if (t >= 3 * 1024) return;
  const int wsel[3] = {0, 3, 1};
  int type = t / 1024, rem = t % 1024;
  int k = rem >> 3, h = rem & 7;
  const float* wr = W + (size_t)wsel[type] * 131072 + (size_t)k * 1024 + h * 128;
  const float* a1 = as_ + wsel[type] * 1024 + h * 128;
  const float* a2 = ad_ + wsel[type] * 1024 + h * 128;
  float s1 = 0.f, s2 = 0.f;
  for (int c = 0; c < 128; ++c){ float wv = wr[c]; s1 = fmaf(wv, a1[c], s1); s2 = fmaf(wv, a2[c], s2); }
  Ps[(size_t)type * 1024 + k * 8 + h] = s1;
  Pd[(size_t)type * 1024 + k * 8 + h] = s2;
}

// batched row-dot scores: 6 segments -> scores[36864][8]
// [0,4096)=ss_ap(xa,Ps0) [4096,12288)=sd_ap(xp,Pd0) [12288,16384)=ss_tp(xt,Ps1)
// [16384,24576)=sd_tp(xp,Pd1) [24576,32768)=ss_pa(xp,Ps2) [32768,36864)=sd_pa(xa,Pd2)
__global__ __launch_bounds__(256) void scorev_k(
    const float* __restrict__ xa, const float* __restrict__ xp, const float* __restrict__ xt,
    const float* __restrict__ Ps, const float* __restrict__ Pd, float* __restrict__ scores)
{
  int r = blockIdx.x * 4 + (threadIdx.x >> 6);
  int lane = threadIdx.x & 63;
  const float* x; const float* P; int row;
  if (r < 4096)       { x = xa; P = Ps;        row = r; }
  else if (r < 12288) { x = xp; P = Pd;        row = r - 4096; }
  else if (r < 16384) { x = xt; P = Ps + 1024; row = r - 12288; }
  else if (r < 24576) { x = xp; P = Pd + 1024; row = r - 16384; }
  else if (r < 32768) { x = xp; P = Ps + 2048; row = r - 24576; }
  else                { x = xa; P = Pd + 2048; row = r - 32768; }
  float x0 = x[(size_t)row * 128 + lane];
  float x1 = x[(size_t)row * 128 + 64 + lane];
  float res[8];
#pragma unroll
  for (int h = 0; h < 8; ++h) {
    float s = x0 * P[lane * 8 + h] + x1 * P[(64 + lane) * 8 + h];
#pragma unroll
    for (int o = 32; o; o >>= 1) s += __shfl_down(s, o);
    res[h] = s;
  }
  if (lane == 0) {
#pragma unroll
    for (int h = 0; h < 8; ++h) scores[(size_t)r * 8 + h] = res[h];
  }
}

// fused edge scores+max for all 3 types (H=8)
__global__ void edgeAf_k(
    const int* __restrict__ ap_src, const int* __restrict__ ap_dst,
    const int* __restrict__ tp_src, const int* __restrict__ tp_dst,
    const int* __restrict__ pa_src, const int* __restrict__ pa_dst,
    const float* __restrict__ scores, float* __restrict__ wbuf, unsigned* __restrict__ mEnc)
{
  int i = blockIdx.x * blockDim.x + threadIdx.x;
  if (i >= E_TOT * 8) return;
  int e = i >> 3, h = i & 7;
  const int *src, *dst; const float *ss, *sd; float* tmp; unsigned* mE;
  if (e < E_AP) {
    src = ap_src; dst = ap_dst;
    ss = scores; sd = scores + (size_t)4096 * 8;
    tmp = wbuf; mE = mEnc;
  } else if (e < E_AP + E_TP) {
    e -= E_AP; src = tp_src; dst = tp_dst;
    ss = scores + (size_t)12288 * 8; sd = scores + (size_t)16384 * 8;
    tmp = wbuf + (size_t)E_AP * 8; mE = mEnc + (size_t)NPA * 8;
  } else {
    e -= E_AP + E_TP; src = pa_src; dst = pa_dst;
    ss = scores + (size_t)24576 * 8; sd = scores + (size_t)32768 * 8;
    tmp = wbuf + (size_t)(E_AP + E_TP) * 8; mE = mEnc + (size_t)2 * NPA * 8;
  }
  float v = ss[(size_t)src[e] * 8 + h] + sd[(size_t)dst[e] * 8 + h];
  v = v > 0.f ? v : 0.2f * v;
  tmp[(size_t)e * 8 + h] = v;
  atomicMax(mE + (size_t)dst[e] * 8 + h, fenc(v));
}

// edge scores+max, H=1 (gat2)
__global__ void edgeA1_k(const int* __restrict__ src, const int* __restrict__ dst,
                         const float* __restrict__ ss, const float* __restrict__ sd,
                         float* __restrict__ tmp, unsigned* __restrict__ mEnc, int E){
  int e = blockIdx.x * blockDim.x + threadIdx.x;
  if (e >= E) return;
  float v = ss[src[e]] + sd[dst[e]];
  v = v > 0.f ? v : 0.2f * v;
  tmp[e] = v;
  atomicMax(mEnc + dst[e], fenc(v));
}

// fused edge-softmax + x-space aggregation over all 20480 slots; one wave per slot
__global__ __launch_bounds__(256) void agg8ff_k(
    const int* __restrict__ eidx, const int* __restrict__ off, const int* __restrict__ cnt,
    const int* __restrict__ ap_src, const int* __restrict__ tp_src, const int* __restrict__ pa_src,
    const float* __restrict__ xa, const float* __restrict__ xt, const float* __restrict__ xp,
    const float* __restrict__ wbuf, const unsigned* __restrict__ mEnc, float* __restrict__ agg)
{
  int g = blockIdx.x * 4 + (threadIdx.x >> 6);
  if (g >= NSLOT) return;
  const int* src; const float* x; const float* tmp;
  if (g < NPA)            { src = ap_src; x = xa; tmp = wbuf; }
  else if (g < 2 * NPA)   { src = tp_src; x = xt; tmp = wbuf + (size_t)E_AP * 8; }
  else                    { src = pa_src; x = xp; tmp = wbuf + (size_t)(E_AP + E_TP) * 8; }
  int lane = threadIdx.x & 63;
  int hh = lane & 7;
  float mh = fdec(mEnc[(size_t)g * 8 + hh]);
  float acc0[8], acc1[8];
#pragma unroll
  for (int h2 = 0; h2 < 8; ++h2){ acc0[h2] = 0.f; acc1[h2] = 0.f; }
  float den = 0.f;
  int base = off[g], n = cnt[g];
  int e = (n > 0) ? eidx[base] : 0;
  int s = (n > 0) ? src[e] : 0;
  for (int k = 0; k < n; ++k){
    int en = 0, sn = 0;
    if (k + 1 < n){ en = eidx[base + k + 1]; sn = src[en]; }
    float wv_ = __expf(tmp[(size_t)e * 8 + hh] - mh);
    den += wv_;
    float xv0 = x[(size_t)s * 128 + lane];
    float xv1 = x[(size_t)s * 128 + 64 + lane];
#pragma unroll
    for (int h2 = 0; h2 < 8; ++h2){
      float wh = __shfl(wv_, h2);
      acc0[h2] = fmaf(wh, xv0, acc0[h2]);
      acc1[h2] = fmaf(wh, xv1, acc1[h2]);
    }
    e = en; s = sn;
  }
  float* o = agg + (size_t)g * 1024;
#pragma unroll
  for (int h2 = 0; h2 < 8; ++h2){
    float dh = __shfl(den, h2) + 1e-16f;
    o[h2 * 128 + lane] = acc0[h2] / dh;
    o[h2 * 128 + 64 + lane] = acc1[h2] / dh;
  }
}

// fused H=1 aggregation (gat2): one wave per dst
__global__ __launch_bounds__(256) void gat_agg1f_k(
    const int* __restrict__ eidx, const int* __restrict__ off, const int* __restrict__ cnt,
    const int* __restrict__ src, const float* __restrict__ hs,
    const float* __restrict__ tmp, const unsigned* __restrict__ mEnc,
    const float* __restrict__ bias, float* __restrict__ outp, int Ndst)
{
  int d = blockIdx.x * 4 + (threadIdx.x >> 6);
  if (d >= Ndst) return;
  int lane = threadIdx.x & 63;
  float mh = fdec(mEnc[d]);
  float a0 = 0.f, a1 = 0.f, den = 0.f;
  int base = off[d], n = cnt[d];
  int e = (n > 0) ? eidx[base] : 0;
  int s = (n > 0) ? src[e] : 0;
  for (int k = 0; k < n; ++k){
    int en = 0, sn = 0;
    if (k + 1 < n){ en = eidx[base + k + 1]; sn = src[en]; }
    float w_ = __expf(tmp[e] - mh);
    den += w_;
    a0 = fmaf(w_, hs[(size_t)s * 128 + lane], a0);
    a1 = fmaf(w_, hs[(size_t)s * 128 + 64 + lane], a1);
    e = en; s = sn;
  }
  float inv = 1.f / (den + 1e-16f);
  outp[(size_t)d * 128 + lane]      = a0 * inv + bias[lane];
  outp[(size_t)d * 128 + 64 + lane] = a1 * inv + bias[64 + lane];
}

// batched rowdots for gat2: rows [0,8192)=hs2 with va, [8192,12288)=hd2 with vb
__global__ __launch_bounds__(256) void rowdot2_k(const float* __restrict__ X,
    const float* __restrict__ va, const float* __restrict__ vb, float* __restrict__ out){
  int r = blockIdx.x * 4 + (threadIdx.x >> 6);
  int lane = threadIdx.x & 63;
  const float* v = (r < 8192) ? va : vb;
  float s = X[(size_t)r * 128 + lane] * v[lane];
  s = fmaf(X[(size_t)r * 128 + 64 + lane], v[64 + lane], s);
#pragma unroll
  for (int o = 32; o; o >>= 1) s += __shfl_down(s, o);
  if (lane == 0) out[r] = s;
}

// ---------------------------------------------------------------- PE loss (MFMA), peQ/peK packed ld=256
__global__ __launch_bounds__(256) void loss_mfma_k(const float* __restrict__ peQ,
    const float* __restrict__ peK, const float* __restrict__ A4, float* __restrict__ lossAcc)
{
  __shared__ __align__(16) unsigned short As[64][40];
  __shared__ __align__(16) unsigned short Bs[128][40];
  __shared__ float red[256];
  int br = blockIdx.x * 64, bc = blockIdx.y * 128;
  int tid = threadIdx.x;
  int w = tid >> 6, lane = tid & 63, lg = lane >> 4, lid = lane & 15;
  int wm = (w & 1) * 32, wn = (w >> 1) * 64;
  f32x4 acc[2][4];
#pragma unroll
  for (int i = 0; i < 2; ++i)
#pragma unroll
    for (int j = 0; j < 4; ++j) acc[i][j] = (f32x4){0.f, 0.f, 0.f, 0.f};

  for (int k0 = 0; k0 < 128; k0 += 32) {
    {
      int r = tid >> 2, ks = (tid & 3) * 8;
      const float* ap = peQ + (size_t)(br + r) * 256 + k0 + ks;
      u16x8 v;
#pragma unroll
      for (int j = 0; j < 8; ++j) v[j] = f2bf(ap[j]);
      *(u16x8*)&As[r][ks] = v;
    }
    {
      int n = tid >> 1, ks = (tid & 1) * 16;
      const float* bp = peK + (size_t)(bc + n) * 256 + k0 + ks;
      u16x8 v0, v1;
#pragma unroll
      for (int j = 0; j < 8; ++j) { v0[j] = f2bf(bp[j]); v1[j] = f2bf(bp[8 + j]); }
      *(u16x8*)&Bs[n][ks] = v0;
      *(u16x8*)&Bs[n][ks + 8] = v1;
    }
    __syncthreads();
    s16x8 a_frag[2], b_frag[4];
#pragma unroll
    for (int i = 0; i < 2; ++i) a_frag[i] = *(s16x8*)&As[wm + i * 16 + lid][lg * 8];
#pragma unroll
    for (int j = 0; j < 4; ++j) b_frag[j] = *(s16x8*)&Bs[wn + j * 16 + lid][lg * 8];
#pragma unroll
    for (int i = 0; i < 2; ++i)
#pragma unroll
      for (int j = 0; j < 4; ++j)
        acc[i][j] = __builtin_amdgcn_mfma_f32_16x16x32_bf16(a_frag[i], b_frag[j], acc[i][j], 0, 0, 0);
    __syncthreads();
  }
  float err = 0.f;
#pragma unroll
  for (int i = 0; i < 2; ++i) {
#pragma unroll
    for (int rr = 0; rr < 4; ++rr) {
      int r = br + wm + i * 16 + lg * 4 + rr;
#pragma unroll
      for (int j = 0; j < 4; ++j) {
        int c = bc + wn + j * 16 + lid;
        float s = 1.f / (1.f + __expf(-acc[i][j][rr]));
        size_t o = (size_t)r * 4096 + c;
#pragma unroll
        for (int q = 0; q < 4; ++q) {
          float d = s - A4[(size_t)q * 16777216 + o];
          err += d * d;
        }
      }
    }
  }
  red[tid] = err;
  __syncthreads();
  for (int o = 128; o; o >>= 1){
    if (tid < o) red[tid] += red[tid + o];
    __syncthreads();
  }
  if (tid == 0) atomicAdd(lossAcc, red[0]);
}

__global__ void finalize_loss_k(const float* __restrict__ acc, float* __restrict__ out){
  out[0] = acc[0] * (1.0f / 67108864.0f);
}

__global__ void db_k(const int* __restrict__ deg, float* __restrict__ dbv){
  int i = blockIdx.x * blockDim.x + threadIdx.x;
  if (i >= NA) return;
  dbv[i] = logf(fmaxf((float)deg[i], 1.f));
}

// ---------------------------------------------------------------- MFMA flash attention (packed QKV, ld=384)
__global__ __launch_bounds__(256) void attn_mfma_k(
    const float* __restrict__ Q, const float* __restrict__ K, const float* __restrict__ V,
    const float* __restrict__ dbv, float* __restrict__ part)
{
  const int ld = 384;
  int h = blockIdx.y, sp = blockIdx.z;
  int qbase = blockIdx.x * 64;
  int tid = threadIdx.x;
  int w = tid >> 6, lane = tid & 63, lid = lane & 15, lg = lane >> 4;
  __shared__ __align__(16) unsigned short Vt[16][72];
  __shared__ __align__(16) unsigned short Pl[4][16][72];
  __shared__ float dbs[64];

  s16x8 qf;
  if (lg < 2) {
    const float* qp = Q + (size_t)(qbase + 16 * w + lid) * ld + h * 16 + 8 * lg;
    u16x8 v;
#pragma unroll
    for (int j = 0; j < 8; ++j) v[j] = f2bf(qp[j] * 0.25f);
    qf = (s16x8)v;
  } else {
    qf = (s16x8){0,0,0,0,0,0,0,0};
  }

  float m = -1e30f, l = 0.f;
  f32x4 o = {0.f, 0.f, 0.f, 0.f};

  int kb0 = sp * (4096 / ASPLIT);
  for (int kt = 0; kt < 4096 / ASPLIT; kt += 64) {
    int kb = kb0 + kt;
    __syncthreads();
    {
      int key = tid >> 2, ds_ = (tid & 3) * 4;
      const float* vp = V + (size_t)(kb + key) * ld + h * 16 + ds_;
#pragma unroll
      for (int j = 0; j < 4; ++j) Vt[ds_ + j][key] = f2bf(vp[j]);
      if (tid < 64) dbs[tid] = dbv[kb + tid];
    }
    __syncthreads();

    f32x4 s[4];
#pragma unroll
    for (int g = 0; g < 4; ++g) {
      s16x8 kf;
      if (lg < 2) {
        const float* kp = K + (size_t)(kb + 16 * g + lid) * ld + h * 16 + 8 * lg;
        u16x8 v;
#pragma unroll
        for (int j = 0; j < 8; ++j) v[j] = f2bf(kp[j]);
        kf = (s16x8)v;
      } else kf = (s16x8){0,0,0,0,0,0,0,0};
      s[g] = __builtin_amdgcn_mfma_f32_16x16x32_bf16(kf, qf, (f32x4){0.f,0.f,0.f,0.f}, 0, 0, 0);
    }
#pragma unroll
    for (int g = 0; g < 4; ++g)
#pragma unroll
      for (int r = 0; r < 4; ++r) s[g][r] += dbs[16 * g + 4 * lg + r];

    float tmax = -1e30f;
#pragma unroll
    for (int g = 0; g < 4; ++g)
#pragma unroll
      for (int r = 0; r < 4; ++r) tmax = fmaxf(tmax, s[g][r]);
    tmax = fmaxf(tmax, __shfl_xor(tmax, 16));
    tmax = fmaxf(tmax, __shfl_xor(tmax, 32));
    float mn = fmaxf(m, tmax);
    float scale = __expf(m - mn);
    float psum = 0.f;
    float p[4][4];
#pragma unroll
    for (int g = 0; g < 4; ++g)
#pragma unroll
      for (int r = 0; r < 4; ++r) { p[g][r] = __expf(s[g][r] - mn); psum += p[g][r]; }
    psum += __shfl_xor(psum, 16);
    psum += __shfl_xor(psum, 32);
    l = l * scale + psum;
    m = mn;

#pragma unroll
    for (int g = 0; g < 4; ++g) {
#pragma unroll
      for (int rp = 0; rp < 4; rp += 2) {
        unsigned pack = (unsigned)f2bf(p[g][rp]) | ((unsigned)f2bf(p[g][rp + 1]) << 16);
        *(unsigned*)&Pl[w][lid][16 * g + 4 * lg + rp] = pack;
      }
    }
#pragma unroll
    for (int r = 0; r < 4; ++r) o[r] *= __shfl(scale, 4 * lg + r);
#pragma unroll
    for (int kc = 0; kc < 2; ++kc) {
      s16x8 pa = *(s16x8*)&Pl[w][lid][32 * kc + 8 * lg];
      s16x8 vb = *(s16x8*)&Vt[lid][32 * kc + 8 * lg];
      o = __builtin_amdgcn_mfma_f32_16x16x32_bf16(pa, vb, o, 0, 0, 0);
    }
  }
  float* pb = part + ((size_t)(sp * 8 + h) * NA) * 18;
#pragma unroll
  for (int r = 0; r < 4; ++r) {
    int qq = qbase + 16 * w + 4 * lg + r;
    pb[(size_t)qq * 18 + lid] = o[r];
  }
  if (lg == 0) {
    int qq = qbase + 16 * w + lid;
    pb[(size_t)qq * 18 + 16] = m;
    pb[(size_t)qq * 18 + 17] = l;
  }
}

__global__ __launch_bounds__(256) void attn_comb_k(const float* __restrict__ part,
                                                   float* __restrict__ O){
  int t = blockIdx.x * 256 + threadIdx.x;
  int r = t >> 3, h = t & 7;
  float m = -1e30f;
#pragma unroll
  for (int sp = 0; sp < ASPLIT; ++sp)
    m = fmaxf(m, part[((size_t)(sp * 8 + h) * NA + r) * 18 + 16]);
  float l = 0.f, acc[16];
#pragma unroll
  for (int j = 0; j < 16; ++j) acc[j] = 0.f;
  for (int sp = 0; sp < ASPLIT; ++sp){
    const float* pp = part + ((size_t)(sp * 8 + h) * NA + r) * 18;
    float w = __expf(pp[16] - m);
    l += pp[17] * w;
#pragma unroll
    for (int j = 0; j < 16; ++j) acc[j] = fmaf(pp[j], w, acc[j]);
  }
  float inv = 1.f / l;
#pragma unroll
  for (int j = 0; j < 16; ++j) O[(size_t)r * 128 + h * 16 + j] = acc[j] * inv;
}

__global__ void setval_k(float* p, float v){ p[0] = v; }

// ---------------------------------------------------------------- host
extern "C" void kernel_launch(void* const* d_in, const int* in_sizes, int n_in,
                              void* d_out, int out_size, void* d_ws, size_t ws_size,
                              hipStream_t stream)
{
  (void)in_sizes; (void)n_in; (void)out_size;
  const float* x_author = (const float*)d_in[0];
  const float* x_paper  = (const float*)d_in[1];
  const float* x_term   = (const float*)d_in[2];
  const int* ap_src = (const int*)d_in[3];
  const int* ap_dst = (const int*)d_in[4];
  const int* pa_src = (const int*)d_in[5];
  const int* pa_dst = (const int*)d_in[6];
  const int* tp_src = (const int*)d_in[9];
  const int* tp_dst = (const int*)d_in[10];
  const float* original_A = (const float*)d_in[11];
  const int* deg = (const int*)d_in[12];
  const float* t1_W = (const float*)d_in[13]; const float* t1_b = (const float*)d_in[14];
  const float* t2_W = (const float*)d_in[15]; const float* t2_b = (const float*)d_in[16];
  const float* t3_W = (const float*)d_in[17]; const float* t3_b = (const float*)d_in[18];
  const float* gat1_W  = (const float*)d_in[19];
  const float* gat1_as = (const float*)d_in[20];
  const float* gat1_ad = (const float*)d_in[21];
  const float* gat1_b  = (const float*)d_in[22];
  const float* gat2_W  = (const float*)d_in[23];
  const float* gat2_as = (const float*)d_in[24];
  const float* gat2_ad = (const float*)d_in[25];
  const float* gat2_b  = (const float*)d_in[26];
  const float* pe_embed = (const float*)d_in[27];
  const float* peWQ = (const float*)d_in[28];
  const float* peWK = (const float*)d_in[29];
  const float* gt_Wq = (const float*)d_in[30]; const float* gt_bq = (const float*)d_in[31];
  const float* gt_Wk = (const float*)d_in[32]; const float* gt_bk = (const float*)d_in[33];
  const float* gt_Wv = (const float*)d_in[34]; const float* gt_bv = (const float*)d_in[35];
  const float* gt_Wo = (const float*)d_in[36]; const float* gt_bo = (const float*)d_in[37];
  const float* gt_g1 = (const float*)d_in[38]; const float* gt_be1 = (const float*)d_in[39];
  const float* gt_Wf1 = (const float*)d_in[40]; const float* gt_bf1 = (const float*)d_in[41];
  const float* gt_Wf2 = (const float*)d_in[42]; const float* gt_bf2 = (const float*)d_in[43];
  const float* gt_g2 = (const float*)d_in[44]; const float* gt_be2 = (const float*)d_in[45];
  const float* cat_W = (const float*)d_in[46]; const float* cat_b = (const float*)d_in[47];
  const float* mlp_W1 = (const float*)d_in[48]; const float* mlp_b1 = (const float*)d_in[49];
  const float* mlp_W2 = (const float*)d_in[50]; const float* mlp_b2 = (const float*)d_in[51];
  float* out = (float*)d_out;

  // ---- workspace layout ----
  char* base = (char*)d_ws;
  size_t off = 0;
  auto alloc = [&](size_t nbytes) -> void* {
    void* p = base + off;
    off += (nbytes + 255) & ~(size_t)255;
    return p;
  };
  float* xa   = (float*)alloc((size_t)NA * 128 * 4);
  float* xp   = (float*)alloc((size_t)NPA * 128 * 4);
  float* xt   = (float*)alloc((size_t)NT * 128 * 4);
  float* accP = (float*)alloc((size_t)NPA * 1024 * 4);   // + accA contiguous; reused as attn partials
  float* accA = (float*)alloc((size_t)NA * 1024 * 4);
  float* agg  = (float*)alloc((size_t)NSLOT * 1024 * 4); // 80 MB
  float* wbuf = (float*)alloc((size_t)E_TOT * 8 * 4);
  float* scores = (float*)alloc((size_t)36864 * 8 * 4);
  float* Ps   = (float*)alloc(3 * 1024 * 4);
  float* Pd   = (float*)alloc(3 * 1024 * 4);
  float* hs2  = (float*)alloc((size_t)NPA * 128 * 4);    // + hd2 contiguous
  float* hd2  = (float*)alloc((size_t)NA * 128 * 4);
  float* s2sd = (float*)alloc((size_t)(NPA + NA) * 4);   // s2s | s2d
  float* w2   = (float*)alloc((size_t)E_PA * 4);
  float* hA2  = (float*)alloc((size_t)NA * 128 * 4);
  float* peQK = (float*)alloc((size_t)NA * 256 * 4);
  float* dbv  = (float*)alloc((size_t)NA * 4);
  float* bsum = (float*)alloc(1024 * 4);
  float* Wqkv = (float*)alloc((size_t)2 * 128 * 384 * 4);
  float* bqkv = (float*)alloc((size_t)2 * 384 * 4);
  float* peW  = (float*)alloc((size_t)128 * 256 * 4);
  float* QKVb = (float*)alloc((size_t)NA * 384 * 4);
  float* Ob   = (float*)alloc((size_t)NA * 128 * 4);
  float* x1b  = (float*)alloc((size_t)NA * 128 * 4);
  float* f1   = (float*)alloc((size_t)NA * 256 * 4);
  float* outs1= (float*)alloc((size_t)NA * 128 * 4);
  float* outs2= (float*)alloc((size_t)NA * 128 * 4);
  float* l1   = (float*)alloc((size_t)NA * 256 * 4);
  int*   offb = (int*)alloc((size_t)NSLOT * 4);
  int*   eidx = (int*)alloc((size_t)E_TOT * 4);
  // ---- zero-init region (single memset): cnt, cur, mEnc, m2Enc, lossAcc ----
  size_t zstart = off;
  int*      cnt   = (int*)alloc((size_t)NSLOT * 4);
  int*      cur   = (int*)alloc((size_t)NSLOT * 4);
  unsigned* mEnc  = (unsigned*)alloc((size_t)NSLOT * 8 * 4);
  unsigned* m2Enc = (unsigned*)alloc((size_t)NA * 4);
  float*    lossAcc = (float*)alloc(256);
  size_t zlen = off - zstart;

  float* part = accP;  // attn partials alias (9.4 MB, accP dead by transformer)

  if (off > ws_size){
    setval_k<<<1, 1, 0, stream>>>(out, -12345.0f);
    return;
  }

  // MFMA GEMM dispatcher
  auto gemmx = [&](int act, const float* A, const float* B, float* C, const float* bias,
                   const float* addmat, int addCols, int addLd,
                   const float* lng, const float* lnb,
                   const float* A2, const float* A3,
                   int M, int N, int K, int lda, int ldb, int ldc,
                   int Z, int aOffZ, int bOffZ, int cOffZ, int accum){
    dim3 g(M / 64, N / 128, Z);
    if (act == 0)      gemm_mfma_k<0><<<g, 256, 0, stream>>>(A, A2, A3, B, C, bias, addmat, addCols, addLd, lng, lnb, M, N, K, lda, ldb, ldc, aOffZ, bOffZ, cOffZ, accum);
    else if (act == 1) gemm_mfma_k<1><<<g, 256, 0, stream>>>(A, A2, A3, B, C, bias, addmat, addCols, addLd, lng, lnb, M, N, K, lda, ldb, ldc, aOffZ, bOffZ, cOffZ, accum);
    else               gemm_mfma_k<2><<<g, 256, 0, stream>>>(A, A2, A3, B, C, bias, addmat, addCols, addLd, lng, lnb, M, N, K, lda, ldb, ldc, aOffZ, bOffZ, cOffZ, accum);
  };
  auto gemm = [&](const float* A, const float* B, float* C, const float* bias,
                  int M, int N, int K, int lda, int ldb, int ldc, int act){
    gemmx(act, A, B, C, bias, nullptr, 0, 0, nullptr, nullptr, nullptr, nullptr,
          M, N, K, lda, ldb, ldc, 1, 0, 0, 0, 0);
  };

  // 1. zero-init
  hipMemsetAsync(base + zstart, 0, zlen, stream);
  // 2. prep packs
  prep_k<<<(132864 + 255) / 256, 256, 0, stream>>>(gat1_b, gt_Wq, gt_bq, gt_Wk, gt_bk, gt_Wv, gt_bv,
                                                   peWQ, peWK, bsum, Wqkv, bqkv, peW);
  // 3. stage 0 feature MLPs
  gemm(x_author, t1_W, xa, t1_b, NA, 128, 334, 334, 128, 128, 1);
  gemm(x_paper,  t2_W, xp, t2_b, NPA, 128, 512, 512, 128, 128, 1);
  gemm(x_term,   t3_W, xt, t3_b, NT, 128, 128, 128, 128, 128, 1);
  // 4-6. fused CSR build (all 3 edge types)
  histf_k<<<(E_TOT + 255) / 256, 256, 0, stream>>>(ap_dst, tp_dst, pa_dst, cnt);
  exscan_k<<<1, 256, 0, stream>>>(cnt, offb, NSLOT);
  scatterf_k<<<(E_TOT + 255) / 256, 256, 0, stream>>>(ap_dst, tp_dst, pa_dst, offb, cur, eidx);
  // 7-10. GAT1 batched: proj, scores, edge, aggregate
  proj3_k<<<12, 256, 0, stream>>>(gat1_W, gat1_as, gat1_ad, Ps, Pd);
  scorev_k<<<9216, 256, 0, stream>>>(xa, xp, xt, Ps, Pd, scores);
  edgeAf_k<<<(E_TOT * 8 + 255) / 256, 256, 0, stream>>>(ap_src, ap_dst, tp_src, tp_dst, pa_src, pa_dst,
                                                        scores, wbuf, mEnc);
  agg8ff_k<<<NSLOT / 4, 256, 0, stream>>>(eidx, offb, cnt, ap_src, tp_src, pa_src,
                                          xa, xt, xp, wbuf, mEnc, agg);
  // 11. per-head transform GEMMs (z=8)
  gemmx(0, agg, gat1_W + 0 * 131072, accP, nullptr, nullptr, 0, 0, nullptr, nullptr, nullptr, nullptr,
        NPA, 128, 128, 1024, 1024, 1024, 8, 128, 128, 128, 0);
  gemmx(1, agg + (size_t)NPA * 1024, gat1_W + 3 * 131072, accP, bsum, nullptr, 0, 0, nullptr, nullptr, nullptr, nullptr,
        NPA, 128, 128, 1024, 1024, 1024, 8, 128, 128, 128, 1);
  gemmx(1, agg + (size_t)2 * NPA * 1024, gat1_W + 1 * 131072, accA, gat1_b + 1024, nullptr, 0, 0, nullptr, nullptr, nullptr, nullptr,
        NA, 128, 128, 1024, 1024, 1024, 8, 128, 128, 128, 0);
  // 12-15. GAT2
  gemm(accP, gat2_W + 131072, hs2, nullptr, NPA + NA, 128, 1024, 1024, 128, 128, 0); // hs2|hd2 (A=accP|accA contiguous)
  rowdot2_k<<<(NPA + NA) / 4, 256, 0, stream>>>(hs2, gat2_as + 128, gat2_ad + 128, s2sd);
  edgeA1_k<<<(E_PA + 255) / 256, 256, 0, stream>>>(pa_src, pa_dst, s2sd, s2sd + NPA, w2, m2Enc, E_PA);
  gat_agg1f_k<<<NA / 4, 256, 0, stream>>>(eidx, offb + 2 * NPA, cnt + 2 * NPA, pa_src, hs2, w2, m2Enc,
                                          gat2_b + 128, hA2, NA);
  // 16-19. PE + loss
  gemm(pe_embed, peW, peQK, nullptr, NA, 256, 128, 128, 256, 256, 0);
  db_k<<<16, 256, 0, stream>>>(deg, dbv);
  loss_mfma_k<<<dim3(64, 32), 256, 0, stream>>>(peQK, peQK + 128, original_A, lossAcc);
  finalize_loss_k<<<1, 1, 0, stream>>>(lossAcc, out);
  // 20. graph transformer (2 layers), 6 dispatches each
  const float* x = hA2;
  float* louts[2] = { outs1, outs2 };
  for (int i = 0; i < 2; ++i){
    const float* Wo = gt_Wo + i * 16384; const float* bo = gt_bo + i * 128;
    const float* Wf1 = gt_Wf1 + i * 32768; const float* bf1 = gt_bf1 + i * 256;
    const float* Wf2 = gt_Wf2 + i * 32768; const float* bf2 = gt_bf2 + i * 128;
    // QKV fused: C=[Q|K|V], addmat = peQK for cols<256
    gemmx(0, x, Wqkv + (size_t)i * 49152, QKVb, bqkv + i * 384, peQK, 256, 256,
          nullptr, nullptr, nullptr, nullptr, NA, 384, 128, 128, 384, 384, 1, 0, 0, 0, 0);
    attn_mfma_k<<<dim3(NA / 64, 8, ASPLIT), 256, 0, stream>>>(QKVb, QKVb + 128, QKVb + 256, dbv, part);
    attn_comb_k<<<(NA * 8) / 256, 256, 0, stream>>>(part, Ob);
    // Wo GEMM + residual + LN fused
    gemmx(2, Ob, Wo, x1b, bo, x, 128, 128, gt_g1 + i * 128, gt_be1 + i * 128, nullptr, nullptr,
          NA, 128, 128, 128, 128, 128, 1, 0, 0, 0, 0);
    gemm(x1b, Wf1, f1, bf1, NA, 256, 128, 128, 256, 256, 1);
    // FF2 + residual + LN fused
    gemmx(2, f1, Wf2, louts[i], bf2, x1b, 128, 128, gt_g2 + i * 128, gt_be2 + i * 128, nullptr, nullptr,
          NA, 128, 256, 256, 128, 128, 1, 0, 0, 0, 0);
    x = louts[i];
  }
  // 21-23. head: concat folded into GEMM A-staging; softmax folded into mlp2
  float* xgt = out + 1 + NA * 4;
  gemmx(1, hA2, cat_W, xgt, cat_b, nullptr, 0, 0, nullptr, nullptr, outs1, outs2,
        NA, 128, 384, 128, 128, 128, 1, 0, 0, 0, 0);
  gemm(xgt, mlp_W1, l1, mlp_b1, NA, 256, 128, 128, 256, 256, 1);
  gemm_k<2><<<dim3(64, 1), 256, 0, stream>>>(l1, mlp_W2, out + 1, mlp_b2, NA, 4, 256, 256, 4, 4);
}

// Round 6
// 953.210 us; speedup vs baseline: 3.0172x; 1.1625x over previous
//
#include <hip/hip_runtime.h>
#include <math.h>

// Problem constants
#define NA   4096
#define NPA  8192
#define NT   4096
#define E_AP 80000
#define E_PA 80000
#define E_TP 160000
#define E_TOT (E_AP + E_TP + E_PA)
#define NSLOT (NPA + NPA + NA)     // 20480 global CSR slots: [ap->paper | tp->paper | pa->author]
#define ASPLIT 4                   // attention key-splits

typedef __attribute__((ext_vector_type(4))) float f32x4;
typedef __attribute__((ext_vector_type(8))) short s16x8;
typedef __attribute__((ext_vector_type(8))) unsigned short u16x8;
typedef unsigned short ushort_t;

__device__ __forceinline__ unsigned fenc(float f){
  unsigned u = __float_as_uint(f);
  return (u & 0x80000000u) ? ~u : (u | 0x80000000u);
}
__device__ __forceinline__ float fdec(unsigned u){
  return (u & 0x80000000u) ? __uint_as_float(u & 0x7fffffffu) : __uint_as_float(~u);
}
__device__ __forceinline__ ushort_t f2bf(float f){
  unsigned u = __float_as_uint(f);
  unsigned r = u + 0x7fffu + ((u >> 16) & 1u);   // RNE
  return (ushort_t)(r >> 16);
}
__device__ __forceinline__ float bf2f(ushort_t u){
  return __uint_as_float(((unsigned)u) << 16);
}

// ---------------------------------------------------------------- f32 GEMM (mlp2 only; ACT=2 -> row softmax over N=4)
template<int ACT>
__global__ __launch_bounds__(256) void gemm_k(
    const float* __restrict__ A, const float* __restrict__ B, float* __restrict__ C,
    const float* __restrict__ bias,
    int M, int N, int K, int lda, int ldb, int ldc)
{
  __shared__ float As[16][68];
  __shared__ float Bs[16][68];
  int bm = blockIdx.x * 64, bn = blockIdx.y * 64;
  int tid = threadIdx.x;
  int tr = tid >> 4, tc = tid & 15;
  float acc[4][4] = {{0.f}};
  for (int k0 = 0; k0 < K; k0 += 16) {
#pragma unroll
    for (int i = 0; i < 4; ++i) {
      int idx = tid + i * 256;
      int r  = idx >> 4, kk = idx & 15;
      int gr = bm + r, gk = k0 + kk;
      As[kk][r] = (gr < M && gk < K) ? A[(size_t)gr * lda + gk] : 0.f;
      int c  = idx & 63, k2 = idx >> 6;
      int gc = bn + c, gk2 = k0 + k2;
      Bs[k2][c] = (gk2 < K && gc < N) ? B[(size_t)gk2 * ldb + gc] : 0.f;
    }
    __syncthreads();
#pragma unroll
    for (int kk = 0; kk < 16; ++kk) {
      float a0[4], b0[4];
#pragma unroll
      for (int i = 0; i < 4; ++i) a0[i] = As[kk][tr * 4 + i];
#pragma unroll
      for (int j = 0; j < 4; ++j) b0[j] = Bs[kk][tc * 4 + j];
#pragma unroll
      for (int i = 0; i < 4; ++i)
#pragma unroll
        for (int j = 0; j < 4; ++j) acc[i][j] = fmaf(a0[i], b0[j], acc[i][j]);
    }
    __syncthreads();
  }
  if (ACT == 2) {
    if (tc != 0) return;
#pragma unroll
    for (int i = 0; i < 4; ++i) {
      int r = bm + tr * 4 + i;
      if (r >= M) continue;
      float l0 = acc[i][0] + bias[0], l1 = acc[i][1] + bias[1];
      float l2 = acc[i][2] + bias[2], l3 = acc[i][3] + bias[3];
      float mx = fmaxf(fmaxf(l0, l1), fmaxf(l2, l3));
      float e0 = __expf(l0 - mx), e1 = __expf(l1 - mx), e2 = __expf(l2 - mx), e3 = __expf(l3 - mx);
      float inv = 1.f / (e0 + e1 + e2 + e3);
      C[(size_t)r * ldc + 0] = e0 * inv;
      C[(size_t)r * ldc + 1] = e1 * inv;
      C[(size_t)r * ldc + 2] = e2 * inv;
      C[(size_t)r * ldc + 3] = e3 * inv;
    }
  } else {
#pragma unroll
    for (int i = 0; i < 4; ++i) {
      int r = bm + tr * 4 + i;
      if (r >= M) continue;
#pragma unroll
      for (int j = 0; j < 4; ++j) {
        int c = bn + tc * 4 + j;
        if (c >= N) continue;
        float v = acc[i][j];
        if (bias) v += bias[c];
        if (ACT == 1) v = fmaxf(v, 0.f);
        C[(size_t)r * ldc + c] = v;
      }
    }
  }
}

// ---------------------------------------------------------------- bf16 MFMA GEMM
// Tile 64x128xBK32, 4 waves (2x2). Requires M%64==0, N%128==0.
// aBf16: A (and A2/A3) stored bf16 (requires K%32==0); cBf16: C written bf16.
// ACT: 0 none, 1 relu, 2 LayerNorm over full row (requires N==128, grid.y==1, C f32).
// A2/A3: virtual A = [A|A2|A3], segments of 128 cols, shared lda.
// addmat(f32): v += (c < addCols) ? addmat[r*addLd+c] : 0.  bias z-offset = cOffZ.
template<int ACT>
__global__ __launch_bounds__(256) void gemm_mfma_k(
    const void* __restrict__ Ain, const void* __restrict__ A2in, const void* __restrict__ A3in,
    int aBf16,
    const float* __restrict__ B, void* __restrict__ Cout, int cBf16,
    const float* __restrict__ bias,
    const float* __restrict__ addmat, int addCols, int addLd,
    const float* __restrict__ lng, const float* __restrict__ lnb,
    int M, int N, int K, int lda, int ldb, int ldc,
    int aOffZ, int bOffZ, int cOffZ)
{
  int asz = aBf16 ? 2 : 4;
  const char* A  = (const char*)Ain  + (size_t)blockIdx.z * aOffZ * asz;
  const char* A2 = A2in ? (const char*)A2in + (size_t)blockIdx.z * aOffZ * asz : nullptr;
  const char* A3 = A3in ? (const char*)A3in + (size_t)blockIdx.z * aOffZ * asz : nullptr;
  B += (size_t)blockIdx.z * bOffZ;
  char* C = (char*)Cout + (size_t)blockIdx.z * cOffZ * (cBf16 ? 2 : 4);
  if (bias) bias += (size_t)blockIdx.z * cOffZ;

  __shared__ __align__(16) ushort_t As[64][40];
  __shared__ __align__(16) ushort_t Bs[128][40];
  int bm = blockIdx.x * 64, bn = blockIdx.y * 128;
  int tid = threadIdx.x;
  int w = tid >> 6, lane = tid & 63, lg = lane >> 4, lid = lane & 15;
  int wm = (w & 1) * 32, wn = (w >> 1) * 64;
  f32x4 acc[2][4];
#pragma unroll
  for (int i = 0; i < 2; ++i)
#pragma unroll
    for (int j = 0; j < 4; ++j) acc[i][j] = (f32x4){0.f, 0.f, 0.f, 0.f};

  for (int k0 = 0; k0 < K; k0 += 32) {
    {
      int r = tid >> 2, ks = (tid & 3) * 8;
      int kcol = k0 + ks;
      const char* Ab = A;
      if (A2) { int seg = kcol >> 7; Ab = (seg == 0) ? A : ((seg == 1) ? A2 : A3); kcol &= 127; }
      u16x8 v;
      if (aBf16) {
        v = *(const u16x8*)((const ushort_t*)Ab + (size_t)(bm + r) * lda + kcol);
      } else {
        const float* ap = (const float*)Ab + (size_t)(bm + r) * lda + kcol;
#pragma unroll
        for (int j = 0; j < 8; ++j) {
          int gk = k0 + ks + j;
          float fv = (gk < K) ? ap[j] : 0.f;
          v[j] = f2bf(fv);
        }
      }
      *(u16x8*)&As[r][ks] = v;
    }
    {
      int n = tid >> 1, ks = (tid & 1) * 16;
      ushort_t tmp[16];
#pragma unroll
      for (int j = 0; j < 16; ++j) {
        int gk = k0 + ks + j;
        float fv = (gk < K) ? B[(size_t)gk * ldb + bn + n] : 0.f;
        tmp[j] = f2bf(fv);
      }
      u16x8 v0, v1;
#pragma unroll
      for (int j = 0; j < 8; ++j) { v0[j] = tmp[j]; v1[j] = tmp[8 + j]; }
      *(u16x8*)&Bs[n][ks] = v0;
      *(u16x8*)&Bs[n][ks + 8] = v1;
    }
    __syncthreads();
    s16x8 a_frag[2], b_frag[4];
#pragma unroll
    for (int i = 0; i < 2; ++i) a_frag[i] = *(s16x8*)&As[wm + i * 16 + lid][lg * 8];
#pragma unroll
    for (int j = 0; j < 4; ++j) b_frag[j] = *(s16x8*)&Bs[wn + j * 16 + lid][lg * 8];
#pragma unroll
    for (int i = 0; i < 2; ++i)
#pragma unroll
      for (int j = 0; j < 4; ++j)
        acc[i][j] = __builtin_amdgcn_mfma_f32_16x16x32_bf16(a_frag[i], b_frag[j], acc[i][j], 0, 0, 0);
    __syncthreads();
  }
  if (ACT == 2) {
    // fused LayerNorm: N==128, grid.y==1, C f32
    __shared__ float Ct[64][132];
#pragma unroll
    for (int i = 0; i < 2; ++i) {
#pragma unroll
      for (int j = 0; j < 4; ++j) {
        int coll = wn + j * 16 + lid;
#pragma unroll
        for (int rr = 0; rr < 4; ++rr) {
          int rowl = wm + i * 16 + lg * 4 + rr;
          float v = acc[i][j][rr];
          if (bias) v += bias[coll];
          if (addmat && coll < addCols) v += addmat[(size_t)(bm + rowl) * addLd + coll];
          Ct[rowl][coll] = v;
        }
      }
    }
    __syncthreads();
    int row = tid >> 2, part = tid & 3;
    float s = 0.f, q = 0.f;
#pragma unroll
    for (int c2 = 0; c2 < 32; ++c2) {
      float v = Ct[row][part * 32 + c2];
      s += v; q += v * v;
    }
    s += __shfl_xor(s, 1); q += __shfl_xor(q, 1);
    s += __shfl_xor(s, 2); q += __shfl_xor(q, 2);
    float mean = s * (1.f / 128.f);
    float var = q * (1.f / 128.f) - mean * mean;
    float inv = rsqrtf(var + 1e-5f);
    int r = bm + row;
    float* Cf = (float*)C;
#pragma unroll
    for (int c2 = 0; c2 < 32; ++c2) {
      int c = part * 32 + c2;
      Cf[(size_t)r * ldc + c] = (Ct[row][c] - mean) * inv * lng[c] + lnb[c];
    }
  } else {
#pragma unroll
    for (int i = 0; i < 2; ++i) {
#pragma unroll
      for (int j = 0; j < 4; ++j) {
        int c = bn + wn + j * 16 + lid;
#pragma unroll
        for (int rr = 0; rr < 4; ++rr) {
          int r = bm + wm + i * 16 + lg * 4 + rr;
          float v = acc[i][j][rr];
          if (bias)   v += bias[c];
          if (addmat && c < addCols) v += addmat[(size_t)r * addLd + c];
          if (ACT == 1) v = fmaxf(v, 0.f);
          if (cBf16) ((ushort_t*)C)[(size_t)r * ldc + c] = f2bf(v);
          else       ((float*)C)[(size_t)r * ldc + c] = v;
        }
      }
    }
  }
}

// ---------------------------------------------------------------- prep: pack weights/biases + db
// sections: bsum[1024] | Wqkv[2*128*384] | bqkv[2*384] | peW[128*256] | Bstack[256*1024] | dbv[4096]
__global__ void prep_k(const float* __restrict__ gat1_b, const float* __restrict__ gat1_W,
                       const float* __restrict__ Wq, const float* __restrict__ bq,
                       const float* __restrict__ Wk, const float* __restrict__ bk,
                       const float* __restrict__ Wv, const float* __restrict__ bv,
                       const float* __restrict__ peWQ, const float* __restrict__ peWK,
                       const int* __restrict__ deg,
                       float* __restrict__ bsum, float* __restrict__ Wqkv,
                       float* __restrict__ bqkv, float* __restrict__ peW,
                       float* __restrict__ Bstack, float* __restrict__ dbv)
{
  int idx = blockIdx.x * blockDim.x + threadIdx.x;
  if (idx < 1024) { bsum[idx] = gat1_b[idx] + gat1_b[3 * 1024 + idx]; return; }
  idx -= 1024;
  if (idx < 2 * 128 * 384) {
    int l = idx / 49152, rem = idx % 49152;
    int k = rem / 384, c = rem % 384;
    float v;
    if (c < 128)      v = Wq[(size_t)l * 16384 + k * 128 + c];
    else if (c < 256) v = Wk[(size_t)l * 16384 + k * 128 + c - 128];
    else              v = Wv[(size_t)l * 16384 + k * 128 + c - 256];
    Wqkv[(size_t)l * 49152 + k * 384 + c] = v;
    return;
  }
  idx -= 2 * 128 * 384;
  if (idx < 2 * 384) {
    int l = idx / 384, c = idx % 384;
    float v;
    if (c < 128)      v = bq[l * 128 + c];
    else if (c < 256) v = bk[l * 128 + c - 128];
    else              v = bv[l * 128 + c - 256];
    bqkv[l * 384 + c] = v;
    return;
  }
  idx -= 2 * 384;
  if (idx < 128 * 256) {
    int k = idx / 256, c = idx % 256;
    peW[k * 256 + c] = (c < 128) ? peWQ[k * 128 + c] : peWK[k * 128 + c - 128];
    return;
  }
  idx -= 128 * 256;
  if (idx < 256 * 1024) {
    int k = idx / 1024, c = idx % 1024;
    Bstack[idx] = (k < 128) ? gat1_W[(size_t)k * 1024 + c]
                            : gat1_W[(size_t)3 * 131072 + (size_t)(k - 128) * 1024 + c];
    return;
  }
  idx -= 256 * 1024;
  if (idx < NA) dbv[idx] = logf(fmaxf((float)deg[idx], 1.f));
}

// ---------------------------------------------------------------- fused CSR build (3 edge types)
__global__ void histf_k(const int* __restrict__ ap_dst, const int* __restrict__ tp_dst,
                        const int* __restrict__ pa_dst, int* __restrict__ cnt){
  int i = blockIdx.x * blockDim.x + threadIdx.x;
  if (i >= E_TOT) return;
  int slot;
  if (i < E_AP)             slot = ap_dst[i];
  else if (i < E_AP + E_TP) slot = NPA + tp_dst[i - E_AP];
  else                      slot = 2 * NPA + pa_dst[i - E_AP - E_TP];
  atomicAdd(&cnt[slot], 1);
}

__global__ void scatterf_k(const int* __restrict__ ap_dst, const int* __restrict__ tp_dst,
                           const int* __restrict__ pa_dst, const int* __restrict__ off,
                           int* __restrict__ cur, int* __restrict__ eidx){
  int i = blockIdx.x * blockDim.x + threadIdx.x;
  if (i >= E_TOT) return;
  int slot, local;
  if (i < E_AP)             { local = i;                 slot = ap_dst[local]; }
  else if (i < E_AP + E_TP) { local = i - E_AP;          slot = NPA + tp_dst[local]; }
  else                      { local = i - E_AP - E_TP;   slot = 2 * NPA + pa_dst[local]; }
  int p = atomicAdd(&cur[slot], 1);
  eidx[off[slot] + p] = local;
}

// shuffle-based exclusive scan, 1 block of 1024 threads
__global__ __launch_bounds__(1024) void exscan_k(const int* __restrict__ in, int* __restrict__ out, int n){
  __shared__ int wsum[16];
  __shared__ int carrySh;
  int t = threadIdx.x, w = t >> 6, lane = t & 63;
  if (t == 0) carrySh = 0;
  __syncthreads();
  for (int base = 0; base < n; base += 1024){
    int carry = carrySh;
    int v = (base + t < n) ? in[base + t] : 0;
    int sc = v;
#pragma unroll
    for (int o2 = 1; o2 < 64; o2 <<= 1){
      int u = __shfl_up(sc, o2);
      if (lane >= o2) sc += u;
    }
    if (lane == 63) wsum[w] = sc;
    __syncthreads();
    int wadd = 0;
#pragma unroll
    for (int i = 0; i < 15; ++i) if (i < w) wadd += wsum[i];
    if (base + t < n) out[base + t] = carry + wadd + sc - v;
    if (t == 1023) carrySh = carry + wadd + sc;
    __syncthreads();
  }
}

// ---------------------------------------------------------------- GAT batched pieces
// Ps/Pd for 3 types (W index order ap=0, tp=3, pa=1)
__global__ void proj3_k(const float* __restrict__ W, const float* __restrict__ as_,
                        const float* __restrict__ ad_, float* __restrict__ Ps,
                        float* __restrict__ Pd){
  int t = blockIdx.x * blockDim.x + threadIdx.x;
  if (t >= 3 * 1024) return;
  const int wsel[3] = {0, 3, 1};
  int type = t / 1024, rem = t % 1024;
  int k = rem >> 3, h = rem & 7;
  const float* wr = W + (size_t)wsel[type] * 131072 + (size_t)k * 1024 + h * 128;
  const float* a1 = as_ + wsel[type] * 1024 + h * 128;
  const float* a2 = ad_ + wsel[type] * 1024 + h * 128;
  float s1 = 0.f, s2 = 0.f;
  for (int c = 0; c < 128; ++c){ float wv = wr[c]; s1 = fmaf(wv, a1[c], s1); s2 = fmaf(wv, a2[c], s2); }
  Ps[(size_t)type * 1024 + k * 8 + h] = s1;
  Pd[(size_t)type * 1024 + k * 8 + h] = s2;
}

// batched row-dot scores (x bf16): 6 segments -> scores[36864][8]
__global__ __launch_bounds__(256) void scorev_k(
    const ushort_t* __restrict__ xa, const ushort_t* __restrict__ xp, const ushort_t* __restrict__ xt,
    const float* __restrict__ Ps, const float* __restrict__ Pd, float* __restrict__ scores)
{
  int r = blockIdx.x * 4 + (threadIdx.x >> 6);
  int lane = threadIdx.x & 63;
  const ushort_t* x; const float* P; int row;
  if (r < 4096)       { x = xa; P = Ps;        row = r; }
  else if (r < 12288) { x = xp; P = Pd;        row = r - 4096; }
  else if (r < 16384) { x = xt; P = Ps + 1024; row = r - 12288; }
  else if (r < 24576) { x = xp; P = Pd + 1024; row = r - 16384; }
  else if (r < 32768) { x = xp; P = Ps + 2048; row = r - 24576; }
  else                { x = xa; P = Pd + 2048; row = r - 32768; }
  unsigned u = *(const unsigned*)(x + (size_t)row * 128 + 2 * lane);
  float x0 = bf2f((ushort_t)(u & 0xffff));
  float x1 = bf2f((ushort_t)(u >> 16));
  float res[8];
#pragma unroll
  for (int h = 0; h < 8; ++h) {
    float s = x0 * P[(2 * lane) * 8 + h] + x1 * P[(2 * lane + 1) * 8 + h];
#pragma unroll
    for (int o = 32; o; o >>= 1) s += __shfl_down(s, o);
    res[h] = s;
  }
  if (lane == 0) {
#pragma unroll
    for (int h = 0; h < 8; ++h) scores[(size_t)r * 8 + h] = res[h];
  }
}

// fused edge scores+max for all 3 types (H=8)
__global__ void edgeAf_k(
    const int* __restrict__ ap_src, const int* __restrict__ ap_dst,
    const int* __restrict__ tp_src, const int* __restrict__ tp_dst,
    const int* __restrict__ pa_src, const int* __restrict__ pa_dst,
    const float* __restrict__ scores, float* __restrict__ wbuf, unsigned* __restrict__ mEnc)
{
  int i = blockIdx.x * blockDim.x + threadIdx.x;
  if (i >= E_TOT * 8) return;
  int e = i >> 3, h = i & 7;
  const int *src, *dst; const float *ss, *sd; float* tmp; unsigned* mE;
  if (e < E_AP) {
    src = ap_src; dst = ap_dst;
    ss = scores; sd = scores + (size_t)4096 * 8;
    tmp = wbuf; mE = mEnc;
  } else if (e < E_AP + E_TP) {
    e -= E_AP; src = tp_src; dst = tp_dst;
    ss = scores + (size_t)12288 * 8; sd = scores + (size_t)16384 * 8;
    tmp = wbuf + (size_t)E_AP * 8; mE = mEnc + (size_t)NPA * 8;
  } else {
    e -= E_AP + E_TP; src = pa_src; dst = pa_dst;
    ss = scores + (size_t)24576 * 8; sd = scores + (size_t)32768 * 8;
    tmp = wbuf + (size_t)(E_AP + E_TP) * 8; mE = mEnc + (size_t)2 * NPA * 8;
  }
  float v = ss[(size_t)src[e] * 8 + h] + sd[(size_t)dst[e] * 8 + h];
  v = v > 0.f ? v : 0.2f * v;
  tmp[(size_t)e * 8 + h] = v;
  atomicMax(mE + (size_t)dst[e] * 8 + h, fenc(v));
}

// edge scores+max, H=1 (gat2)
__global__ void edgeA1_k(const int* __restrict__ src, const int* __restrict__ dst,
                         const float* __restrict__ ss, const float* __restrict__ sd,
                         float* __restrict__ tmp, unsigned* __restrict__ mEnc, int E){
  int e = blockIdx.x * blockDim.x + threadIdx.x;
  if (e >= E) return;
  float v = ss[src[e]] + sd[dst[e]];
  v = v > 0.f ? v : 0.2f * v;
  tmp[e] = v;
  atomicMax(mEnc + dst[e], fenc(v));
}

// fused edge-softmax + x-space aggregation (x bf16, agg bf16); one wave per slot
__global__ __launch_bounds__(256) void agg8ff_k(
    const int* __restrict__ eidx, const int* __restrict__ off, const int* __restrict__ cnt,
    const int* __restrict__ ap_src, const int* __restrict__ tp_src, const int* __restrict__ pa_src,
    const ushort_t* __restrict__ xa, const ushort_t* __restrict__ xt, const ushort_t* __restrict__ xp,
    const float* __restrict__ wbuf, const unsigned* __restrict__ mEnc, ushort_t* __restrict__ agg)
{
  int g = blockIdx.x * 4 + (threadIdx.x >> 6);
  if (g >= NSLOT) return;
  const int* src; const ushort_t* x; const float* tmp;
  if (g < NPA)            { src = ap_src; x = xa; tmp = wbuf; }
  else if (g < 2 * NPA)   { src = tp_src; x = xt; tmp = wbuf + (size_t)E_AP * 8; }
  else                    { src = pa_src; x = xp; tmp = wbuf + (size_t)(E_AP + E_TP) * 8; }
  int lane = threadIdx.x & 63;
  int hh = lane & 7;
  float mh = fdec(mEnc[(size_t)g * 8 + hh]);
  float acc0[8], acc1[8];
#pragma unroll
  for (int h2 = 0; h2 < 8; ++h2){ acc0[h2] = 0.f; acc1[h2] = 0.f; }
  float den = 0.f;
  int base = off[g], n = cnt[g];
  int e = (n > 0) ? eidx[base] : 0;
  int s = (n > 0) ? src[e] : 0;
  for (int k = 0; k < n; ++k){
    int en = 0, sn = 0;
    if (k + 1 < n){ en = eidx[base + k + 1]; sn = src[en]; }
    float wv_ = __expf(tmp[(size_t)e * 8 + hh] - mh);
    den += wv_;
    unsigned u = *(const unsigned*)(x + (size_t)s * 128 + 2 * lane);
    float xv0 = bf2f((ushort_t)(u & 0xffff));
    float xv1 = bf2f((ushort_t)(u >> 16));
#pragma unroll
    for (int h2 = 0; h2 < 8; ++h2){
      float wh = __shfl(wv_, h2);
      acc0[h2] = fmaf(wh, xv0, acc0[h2]);
      acc1[h2] = fmaf(wh, xv1, acc1[h2]);
    }
    e = en; s = sn;
  }
  ushort_t* o = agg + (size_t)g * 1024;
#pragma unroll
  for (int h2 = 0; h2 < 8; ++h2){
    float dh = __shfl(den, h2) + 1e-16f;
    unsigned pk = (unsigned)f2bf(acc0[h2] / dh) | ((unsigned)f2bf(acc1[h2] / dh) << 16);
    *(unsigned*)(o + h2 * 128 + 2 * lane) = pk;
  }
}

// fused H=1 aggregation (gat2), hs bf16 -> out f32; one wave per dst
__global__ __launch_bounds__(256) void gat_agg1f_k(
    const int* __restrict__ eidx, const int* __restrict__ off, const int* __restrict__ cnt,
    const int* __restrict__ src, const ushort_t* __restrict__ hs,
    const float* __restrict__ tmp, const unsigned* __restrict__ mEnc,
    const float* __restrict__ bias, float* __restrict__ outp, int Ndst)
{
  int d = blockIdx.x * 4 + (threadIdx.x >> 6);
  if (d >= Ndst) return;
  int lane = threadIdx.x & 63;
  float mh = fdec(mEnc[d]);
  float a0 = 0.f, a1 = 0.f, den = 0.f;
  int base = off[d], n = cnt[d];
  int e = (n > 0) ? eidx[base] : 0;
  int s = (n > 0) ? src[e] : 0;
  for (int k = 0; k < n; ++k){
    int en = 0, sn = 0;
    if (k + 1 < n){ en = eidx[base + k + 1]; sn = src[en]; }
    float w_ = __expf(tmp[e] - mh);
    den += w_;
    unsigned u = *(const unsigned*)(hs + (size_t)s * 128 + 2 * lane);
    a0 = fmaf(w_, bf2f((ushort_t)(u & 0xffff)), a0);
    a1 = fmaf(w_, bf2f((ushort_t)(u >> 16)), a1);
    e = en; s = sn;
  }
  float inv = 1.f / (den + 1e-16f);
  outp[(size_t)d * 128 + 2 * lane]     = a0 * inv + bias[2 * lane];
  outp[(size_t)d * 128 + 2 * lane + 1] = a1 * inv + bias[2 * lane + 1];
}

// batched rowdots for gat2 (X bf16): rows [0,8192)=hs2 w/ va, [8192,12288)=hd2 w/ vb
__global__ __launch_bounds__(256) void rowdot2_k(const ushort_t* __restrict__ X,
    const float* __restrict__ va, const float* __restrict__ vb, float* __restrict__ out){
  int r = blockIdx.x * 4 + (threadIdx.x >> 6);
  int lane = threadIdx.x & 63;
  const float* v = (r < 8192) ? va : vb;
  unsigned u = *(const unsigned*)(X + (size_t)r * 128 + 2 * lane);
  float s = bf2f((ushort_t)(u & 0xffff)) * v[2 * lane]
          + bf2f((ushort_t)(u >> 16)) * v[2 * lane + 1];
#pragma unroll
  for (int o = 32; o; o >>= 1) s += __shfl_down(s, o);
  if (lane == 0) out[r] = s;
}

// ---------------------------------------------------------------- PE loss (MFMA), peQ/peK packed f32 ld=256
__global__ __launch_bounds__(256) void loss_mfma_k(const float* __restrict__ peQ,
    const float* __restrict__ peK, const float* __restrict__ A4, float* __restrict__ lossAcc)
{
  __shared__ __align__(16) ushort_t As[64][40];
  __shared__ __align__(16) ushort_t Bs[128][40];
  __shared__ float red[256];
  int br = blockIdx.x * 64, bc = blockIdx.y * 128;
  int tid = threadIdx.x;
  int w = tid >> 6, lane = tid & 63, lg = lane >> 4, lid = lane & 15;
  int wm = (w & 1) * 32, wn = (w >> 1) * 64;
  f32x4 acc[2][4];
#pragma unroll
  for (int i = 0; i < 2; ++i)
#pragma unroll
    for (int j = 0; j < 4; ++j) acc[i][j] = (f32x4){0.f, 0.f, 0.f, 0.f};

  for (int k0 = 0; k0 < 128; k0 += 32) {
    {
      int r = tid >> 2, ks = (tid & 3) * 8;
      const float* ap = peQ + (size_t)(br + r) * 256 + k0 + ks;
      u16x8 v;
#pragma unroll
      for (int j = 0; j < 8; ++j) v[j] = f2bf(ap[j]);
      *(u16x8*)&As[r][ks] = v;
    }
    {
      int n = tid >> 1, ks = (tid & 1) * 16;
      const float* bp = peK + (size_t)(bc + n) * 256 + k0 + ks;
      u16x8 v0, v1;
#pragma unroll
      for (int j = 0; j < 8; ++j) { v0[j] = f2bf(bp[j]); v1[j] = f2bf(bp[8 + j]); }
      *(u16x8*)&Bs[n][ks] = v0;
      *(u16x8*)&Bs[n][ks + 8] = v1;
    }
    __syncthreads();
    s16x8 a_frag[2], b_frag[4];
#pragma unroll
    for (int i = 0; i < 2; ++i) a_frag[i] = *(s16x8*)&As[wm + i * 16 + lid][lg * 8];
#pragma unroll
    for (int j = 0; j < 4; ++j) b_frag[j] = *(s16x8*)&Bs[wn + j * 16 + lid][lg * 8];
#pragma unroll
    for (int i = 0; i < 2; ++i)
#pragma unroll
      for (int j = 0; j < 4; ++j)
        acc[i][j] = __builtin_amdgcn_mfma_f32_16x16x32_bf16(a_frag[i], b_frag[j], acc[i][j], 0, 0, 0);
    __syncthreads();
  }
  float err = 0.f;
#pragma unroll
  for (int i = 0; i < 2; ++i) {
#pragma unroll
    for (int rr = 0; rr < 4; ++rr) {
      int r = br + wm + i * 16 + lg * 4 + rr;
#pragma unroll
      for (int j = 0; j < 4; ++j) {
        int c = bc + wn + j * 16 + lid;
        float s = 1.f / (1.f + __expf(-acc[i][j][rr]));
        size_t o = (size_t)r * 4096 + c;
#pragma unroll
        for (int q = 0; q < 4; ++q) {
          float d = s - A4[(size_t)q * 16777216 + o];
          err += d * d;
        }
      }
    }
  }
  red[tid] = err;
  __syncthreads();
  for (int o = 128; o; o >>= 1){
    if (tid < o) red[tid] += red[tid + o];
    __syncthreads();
  }
  if (tid == 0) atomicAdd(lossAcc, red[0]);
}

__global__ void finalize_loss_k(const float* __restrict__ acc, float* __restrict__ out){
  out[0] = acc[0] * (1.0f / 67108864.0f);
}

// ---------------------------------------------------------------- MFMA flash attention (bf16 QKV packed, ld=384)
__global__ __launch_bounds__(256) void attn_mfma_k(
    const ushort_t* __restrict__ Q, const ushort_t* __restrict__ K, const ushort_t* __restrict__ V,
    const float* __restrict__ dbv, float* __restrict__ part)
{
  const int ld = 384;
  int h = blockIdx.y, sp = blockIdx.z;
  int qbase = blockIdx.x * 64;
  int tid = threadIdx.x;
  int w = tid >> 6, lane = tid & 63, lid = lane & 15, lg = lane >> 4;
  __shared__ __align__(16) ushort_t Vt[16][72];
  __shared__ __align__(16) ushort_t Pl[4][16][72];
  __shared__ float dbs[64];

  s16x8 qf;
  if (lg < 2) {
    u16x8 v = *(const u16x8*)(Q + (size_t)(qbase + 16 * w + lid) * ld + h * 16 + 8 * lg);
#pragma unroll
    for (int j = 0; j < 8; ++j) v[j] = f2bf(bf2f(v[j]) * 0.25f);  // exact pow2 scale
    qf = (s16x8)v;
  } else {
    qf = (s16x8){0,0,0,0,0,0,0,0};
  }

  float m = -1e30f, l = 0.f;
  f32x4 o = {0.f, 0.f, 0.f, 0.f};

  int kb0 = sp * (4096 / ASPLIT);
  for (int kt = 0; kt < 4096 / ASPLIT; kt += 64) {
    int kb = kb0 + kt;
    __syncthreads();
    {
      int key = tid >> 2, ds_ = (tid & 3) * 4;
      const ushort_t* vp = V + (size_t)(kb + key) * ld + h * 16 + ds_;
#pragma unroll
      for (int j = 0; j < 4; ++j) Vt[ds_ + j][key] = vp[j];
      if (tid < 64) dbs[tid] = dbv[kb + tid];
    }
    __syncthreads();

    f32x4 s[4];
#pragma unroll
    for (int g = 0; g < 4; ++g) {
      s16x8 kf;
      if (lg < 2) {
        kf = (s16x8)(*(const u16x8*)(K + (size_t)(kb + 16 * g + lid) * ld + h * 16 + 8 * lg));
      } else kf = (s16x8){0,0,0,0,0,0,0,0};
      s[g] = __builtin_amdgcn_mfma_f32_16x16x32_bf16(kf, qf, (f32x4){0.f,0.f,0.f,0.f}, 0, 0, 0);
    }
#pragma unroll
    for (int g = 0; g < 4; ++g)
#pragma unroll
      for (int r = 0; r < 4; ++r) s[g][r] += dbs[16 * g + 4 * lg + r];

    float tmax = -1e30f;
#pragma unroll
    for (int g = 0; g < 4; ++g)
#pragma unroll
      for (int r = 0; r < 4; ++r) tmax = fmaxf(tmax, s[g][r]);
    tmax = fmaxf(tmax, __shfl_xor(tmax, 16));
    tmax = fmaxf(tmax, __shfl_xor(tmax, 32));
    float mn = fmaxf(m, tmax);
    float scale = __expf(m - mn);
    float psum = 0.f;
    float p[4][4];
#pragma unroll
    for (int g = 0; g < 4; ++g)
#pragma unroll
      for (int r = 0; r < 4; ++r) { p[g][r] = __expf(s[g][r] - mn); psum += p[g][r]; }
    psum += __shfl_xor(psum, 16);
    psum += __shfl_xor(psum, 32);
    l = l * scale + psum;
    m = mn;

#pragma unroll
    for (int g = 0; g < 4; ++g) {
#pragma unroll
      for (int rp = 0; rp < 4; rp += 2) {
        unsigned pack = (unsigned)f2bf(p[g][rp]) | ((unsigned)f2bf(p[g][rp + 1]) << 16);
        *(unsigned*)&Pl[w][lid][16 * g + 4 * lg + rp] = pack;
      }
    }
#pragma unroll
    for (int r = 0; r < 4; ++r) o[r] *= __shfl(scale, 4 * lg + r);
#pragma unroll
    for (int kc = 0; kc < 2; ++kc) {
      s16x8 pa = *(s16x8*)&Pl[w][lid][32 * kc + 8 * lg];
      s16x8 vb = *(s16x8*)&Vt[lid][32 * kc + 8 * lg];
      o = __builtin_amdgcn_mfma_f32_16x16x32_bf16(pa, vb, o, 0, 0, 0);
    }
  }
  float* pb = part + ((size_t)(sp * 8 + h) * NA) * 18;
#pragma unroll
  for (int r = 0; r < 4; ++r) {
    int qq = qbase + 16 * w + 4 * lg + r;
    pb[(size_t)qq * 18 + lid] = o[r];
  }
  if (lg == 0) {
    int qq = qbase + 16 * w + lid;
    pb[(size_t)qq * 18 + 16] = m;
    pb[(size_t)qq * 18 + 17] = l;
  }
}

__global__ __launch_bounds__(256) void attn_comb_k(const float* __restrict__ part,
                                                   float* __restrict__ O){
  int t = blockIdx.x * 256 + threadIdx.x;
  int r = t >> 3, h = t & 7;
  float m = -1e30f;
#pragma unroll
  for (int sp = 0; sp < ASPLIT; ++sp)
    m = fmaxf(m, part[((size_t)(sp * 8 + h) * NA + r) * 18 + 16]);
  float l = 0.f, acc[16];
#pragma unroll
  for (int j = 0; j < 16; ++j) acc[j] = 0.f;
  for (int sp = 0; sp < ASPLIT; ++sp){
    const float* pp = part + ((size_t)(sp * 8 + h) * NA + r) * 18;
    float w = __expf(pp[16] - m);
    l += pp[17] * w;
#pragma unroll
    for (int j = 0; j < 16; ++j) acc[j] = fmaf(pp[j], w, acc[j]);
  }
  float inv = 1.f / l;
#pragma unroll
  for (int j = 0; j < 16; ++j) O[(size_t)r * 128 + h * 16 + j] = acc[j] * inv;
}

__global__ void setval_k(float* p, float v){ p[0] = v; }

// ---------------------------------------------------------------- host
extern "C" void kernel_launch(void* const* d_in, const int* in_sizes, int n_in,
                              void* d_out, int out_size, void* d_ws, size_t ws_size,
                              hipStream_t stream)
{
  (void)in_sizes; (void)n_in; (void)out_size;
  const float* x_author = (const float*)d_in[0];
  const float* x_paper  = (const float*)d_in[1];
  const float* x_term   = (const float*)d_in[2];
  const int* ap_src = (const int*)d_in[3];
  const int* ap_dst = (const int*)d_in[4];
  const int* pa_src = (const int*)d_in[5];
  const int* pa_dst = (const int*)d_in[6];
  const int* tp_src = (const int*)d_in[9];
  const int* tp_dst = (const int*)d_in[10];
  const float* original_A = (const float*)d_in[11];
  const int* deg = (const int*)d_in[12];
  const float* t1_W = (const float*)d_in[13]; const float* t1_b = (const float*)d_in[14];
  const float* t2_W = (const float*)d_in[15]; const float* t2_b = (const float*)d_in[16];
  const float* t3_W = (const float*)d_in[17]; const float* t3_b = (const float*)d_in[18];
  const float* gat1_W  = (const float*)d_in[19];
  const float* gat1_as = (const float*)d_in[20];
  const float* gat1_ad = (const float*)d_in[21];
  const float* gat1_b  = (const float*)d_in[22];
  const float* gat2_W  = (const float*)d_in[23];
  const float* gat2_as = (const float*)d_in[24];
  const float* gat2_ad = (const float*)d_in[25];
  const float* gat2_b  = (const float*)d_in[26];
  const float* pe_embed = (const float*)d_in[27];
  const float* peWQ = (const float*)d_in[28];
  const float* peWK = (const float*)d_in[29];
  const float* gt_Wq = (const float*)d_in[30]; const float* gt_bq = (const float*)d_in[31];
  const float* gt_Wk = (const float*)d_in[32]; const float* gt_bk = (const float*)d_in[33];
  const float* gt_Wv = (const float*)d_in[34]; const float* gt_bv = (const float*)d_in[35];
  const float* gt_Wo = (const float*)d_in[36]; const float* gt_bo = (const float*)d_in[37];
  const float* gt_g1 = (const float*)d_in[38]; const float* gt_be1 = (const float*)d_in[39];
  const float* gt_Wf1 = (const float*)d_in[40]; const float* gt_bf1 = (const float*)d_in[41];
  const float* gt_Wf2 = (const float*)d_in[42]; const float* gt_bf2 = (const float*)d_in[43];
  const float* gt_g2 = (const float*)d_in[44]; const float* gt_be2 = (const float*)d_in[45];
  const float* cat_W = (const float*)d_in[46]; const float* cat_b = (const float*)d_in[47];
  const float* mlp_W1 = (const float*)d_in[48]; const float* mlp_b1 = (const float*)d_in[49];
  const float* mlp_W2 = (const float*)d_in[50]; const float* mlp_b2 = (const float*)d_in[51];
  float* out = (float*)d_out;

  // ---- workspace layout ----
  char* base = (char*)d_ws;
  size_t off = 0;
  auto alloc = [&](size_t nbytes) -> void* {
    void* p = base + off;
    off += (nbytes + 255) & ~(size_t)255;
    return p;
  };
  ushort_t* xa  = (ushort_t*)alloc((size_t)NA * 128 * 2);    // bf16
  ushort_t* xp  = (ushort_t*)alloc((size_t)NPA * 128 * 2);
  ushort_t* xt  = (ushort_t*)alloc((size_t)NT * 128 * 2);
  ushort_t* accP = (ushort_t*)alloc((size_t)NPA * 1024 * 2); // bf16; +accA contiguous; aliased as attn part
  ushort_t* accA = (ushort_t*)alloc((size_t)NA * 1024 * 2);
  ushort_t* agg  = (ushort_t*)alloc((size_t)NSLOT * 1024 * 2); // bf16
  float* wbuf = (float*)alloc((size_t)E_TOT * 8 * 4);
  float* scores = (float*)alloc((size_t)36864 * 8 * 4);
  float* Ps   = (float*)alloc(3 * 1024 * 4);
  float* Pd   = (float*)alloc(3 * 1024 * 4);
  ushort_t* hs2 = (ushort_t*)alloc((size_t)NPA * 128 * 2);   // bf16; +hd2 contiguous
  ushort_t* hd2 = (ushort_t*)alloc((size_t)NA * 128 * 2);
  float* s2sd = (float*)alloc((size_t)(NPA + NA) * 4);
  float* w2   = (float*)alloc((size_t)E_PA * 4);
  float* hA2  = (float*)alloc((size_t)NA * 128 * 4);
  float* peQK = (float*)alloc((size_t)NA * 256 * 4);
  float* dbv  = (float*)alloc((size_t)NA * 4);
  float* bsum = (float*)alloc(1024 * 4);
  float* Wqkv = (float*)alloc((size_t)2 * 128 * 384 * 4);
  float* bqkv = (float*)alloc((size_t)2 * 384 * 4);
  float* peW  = (float*)alloc((size_t)128 * 256 * 4);
  float* Bstack = (float*)alloc((size_t)256 * 1024 * 4);
  ushort_t* QKVb = (ushort_t*)alloc((size_t)NA * 384 * 2);   // bf16
  float* Ob   = (float*)alloc((size_t)NA * 128 * 4);
  float* x1b  = (float*)alloc((size_t)NA * 128 * 4);
  ushort_t* f1 = (ushort_t*)alloc((size_t)NA * 256 * 2);     // bf16
  float* outs1= (float*)alloc((size_t)NA * 128 * 4);
  float* outs2= (float*)alloc((size_t)NA * 128 * 4);
  float* l1   = (float*)alloc((size_t)NA * 256 * 4);
  int*   offb = (int*)alloc((size_t)NSLOT * 4);
  int*   eidx = (int*)alloc((size_t)E_TOT * 4);
  // ---- zero-init region (single memset) ----
  size_t zstart = off;
  int*      cnt   = (int*)alloc((size_t)NSLOT * 4);
  int*      cur   = (int*)alloc((size_t)NSLOT * 4);
  unsigned* mEnc  = (unsigned*)alloc((size_t)NSLOT * 8 * 4);
  unsigned* m2Enc = (unsigned*)alloc((size_t)NA * 4);
  float*    lossAcc = (float*)alloc(256);
  size_t zlen = off - zstart;

  float* part = (float*)accP;  // 9.4 MB f32 partials alias onto 16.7 MB accP (dead by transformer)

  if (off > ws_size){
    setval_k<<<1, 1, 0, stream>>>(out, -12345.0f);
    return;
  }

  auto gemmx = [&](int act, const void* A, const void* A2, const void* A3, int aBf16,
                   const float* B, void* C, int cBf16, const float* bias,
                   const float* addmat, int addCols, int addLd,
                   const float* lng, const float* lnb,
                   int M, int N, int K, int lda, int ldb, int ldc,
                   int Z, int aOffZ, int bOffZ, int cOffZ){
    dim3 g(M / 64, N / 128, Z);
    if (act == 0)      gemm_mfma_k<0><<<g, 256, 0, stream>>>(A, A2, A3, aBf16, B, C, cBf16, bias, addmat, addCols, addLd, lng, lnb, M, N, K, lda, ldb, ldc, aOffZ, bOffZ, cOffZ);
    else if (act == 1) gemm_mfma_k<1><<<g, 256, 0, stream>>>(A, A2, A3, aBf16, B, C, cBf16, bias, addmat, addCols, addLd, lng, lnb, M, N, K, lda, ldb, ldc, aOffZ, bOffZ, cOffZ);
    else               gemm_mfma_k<2><<<g, 256, 0, stream>>>(A, A2, A3, aBf16, B, C, cBf16, bias, addmat, addCols, addLd, lng, lnb, M, N, K, lda, ldb, ldc, aOffZ, bOffZ, cOffZ);
  };

  // 1. zero-init
  hipMemsetAsync(base + zstart, 0, zlen, stream);
  // 2. prep (packs + db)
  prep_k<<<1560, 256, 0, stream>>>(gat1_b, gat1_W, gt_Wq, gt_bq, gt_Wk, gt_bk, gt_Wv, gt_bv,
                                   peWQ, peWK, deg, bsum, Wqkv, bqkv, peW, Bstack, dbv);
  // 3-5. stage-0 feature MLPs (bf16 outputs)
  gemmx(1, x_author, 0, 0, 0, t1_W, xa, 1, t1_b, 0, 0, 0, 0, 0, NA, 128, 334, 334, 128, 128, 1, 0, 0, 0);
  gemmx(1, x_paper,  0, 0, 0, t2_W, xp, 1, t2_b, 0, 0, 0, 0, 0, NPA, 128, 512, 512, 128, 128, 1, 0, 0, 0);
  gemmx(1, x_term,   0, 0, 0, t3_W, xt, 1, t3_b, 0, 0, 0, 0, 0, NT, 128, 128, 128, 128, 128, 1, 0, 0, 0);
  // 6-8. fused CSR build
  histf_k<<<(E_TOT + 255) / 256, 256, 0, stream>>>(ap_dst, tp_dst, pa_dst, cnt);
  exscan_k<<<1, 1024, 0, stream>>>(cnt, offb, NSLOT);
  scatterf_k<<<(E_TOT + 255) / 256, 256, 0, stream>>>(ap_dst, tp_dst, pa_dst, offb, cur, eidx);
  // 9-12. GAT1: proj, scores, edge, aggregate
  proj3_k<<<12, 256, 0, stream>>>(gat1_W, gat1_as, gat1_ad, Ps, Pd);
  scorev_k<<<9216, 256, 0, stream>>>(xa, xp, xt, Ps, Pd, scores);
  edgeAf_k<<<(E_TOT * 8 + 255) / 256, 256, 0, stream>>>(ap_src, ap_dst, tp_src, tp_dst, pa_src, pa_dst,
                                                        scores, wbuf, mEnc);
  agg8ff_k<<<NSLOT / 4, 256, 0, stream>>>(eidx, offb, cnt, ap_src, tp_src, pa_src,
                                          xa, xt, xp, wbuf, mEnc, agg);
  // 13-14. per-head transform GEMMs: paper via K=256 stacked [W_ap; W_tp], author K=128
  gemmx(1, agg, agg + (size_t)NPA * 1024, 0, 1, Bstack, accP, 1, bsum, 0, 0, 0, 0, 0,
        NPA, 128, 256, 1024, 1024, 1024, 8, 128, 128, 128);
  gemmx(1, agg + (size_t)2 * NPA * 1024, 0, 0, 1, gat1_W + 131072, accA, 1, gat1_b + 1024,
        0, 0, 0, 0, 0, NA, 128, 128, 1024, 1024, 1024, 8, 128, 128, 128);
  // 15-18. GAT2
  gemmx(0, accP, 0, 0, 1, gat2_W + 131072, hs2, 1, 0, 0, 0, 0, 0, 0,
        NPA + NA, 128, 1024, 1024, 128, 128, 1, 0, 0, 0);
  rowdot2_k<<<(NPA + NA) / 4, 256, 0, stream>>>(hs2, gat2_as + 128, gat2_ad + 128, s2sd);
  edgeA1_k<<<(E_PA + 255) / 256, 256, 0, stream>>>(pa_src, pa_dst, s2sd, s2sd + NPA, w2, m2Enc, E_PA);
  gat_agg1f_k<<<NA / 4, 256, 0, stream>>>(eidx, offb + 2 * NPA, cnt + 2 * NPA, pa_src, hs2, w2, m2Enc,
                                          gat2_b + 128, hA2, NA);
  // 19-21. PE + loss
  gemmx(0, pe_embed, 0, 0, 0, peW, peQK, 0, 0, 0, 0, 0, 0, 0, NA, 256, 128, 128, 256, 256, 1, 0, 0, 0);
  loss_mfma_k<<<dim3(64, 32), 256, 0, stream>>>(peQK, peQK + 128, original_A, lossAcc);
  finalize_loss_k<<<1, 1, 0, stream>>>(lossAcc, out);
  // 22-33. graph transformer (2 layers)
  const float* x = hA2;
  float* louts[2] = { outs1, outs2 };
  for (int i = 0; i < 2; ++i){
    const float* Wo = gt_Wo + i * 16384; const float* bo = gt_bo + i * 128;
    const float* Wf1 = gt_Wf1 + i * 32768; const float* bf1 = gt_bf1 + i * 256;
    const float* Wf2 = gt_Wf2 + i * 32768; const float* bf2 = gt_bf2 + i * 128;
    // QKV fused (bf16 out): C=[Q|K|V], addmat=peQK for cols<256
    gemmx(0, x, 0, 0, 0, Wqkv + (size_t)i * 49152, QKVb, 1, bqkv + i * 384, peQK, 256, 256,
          0, 0, NA, 384, 128, 128, 384, 384, 1, 0, 0, 0);
    attn_mfma_k<<<dim3(NA / 64, 8, ASPLIT), 256, 0, stream>>>(QKVb, QKVb + 128, QKVb + 256, dbv, part);
    attn_comb_k<<<(NA * 8) / 256, 256, 0, stream>>>(part, Ob);
    // Wo GEMM + residual + LN fused
    gemmx(2, Ob, 0, 0, 0, Wo, x1b, 0, bo, x, 128, 128, gt_g1 + i * 128, gt_be1 + i * 128,
          NA, 128, 128, 128, 128, 128, 1, 0, 0, 0);
    gemmx(1, x1b, 0, 0, 0, Wf1, f1, 1, bf1, 0, 0, 0, 0, 0, NA, 256, 128, 128, 256, 256, 1, 0, 0, 0);
    // FF2 + residual + LN fused (A=f1 bf16)
    gemmx(2, f1, 0, 0, 1, Wf2, louts[i], 0, bf2, x1b, 128, 128, gt_g2 + i * 128, gt_be2 + i * 128,
          NA, 128, 256, 256, 128, 128, 1, 0, 0, 0);
    x = louts[i];
  }
  // 34-36. head
  float* xgt = out + 1 + NA * 4;
  gemmx(1, hA2, outs1, outs2, 0, cat_W, xgt, 0, cat_b, 0, 0, 0, 0, 0,
        NA, 128, 384, 128, 128, 128, 1, 0, 0, 0);
  gemmx(1, xgt, 0, 0, 0, mlp_W1, l1, 0, mlp_b1, 0, 0, 0, 0, 0, NA, 256, 128, 128, 256, 256, 1, 0, 0, 0);
  gemm_k<2><<<dim3(64, 1), 256, 0, stream>>>(l1, mlp_W2, out + 1, mlp_b2, NA, 4, 256, 256, 4, 4);
}

// Round 7
// 875.342 us; speedup vs baseline: 3.2856x; 1.0890x over previous
//
#include <hip/hip_runtime.h>
#include <math.h>

// Problem constants
#define NA   4096
#define NPA  8192
#define NT   4096
#define E_AP 80000
#define E_PA 80000
#define E_TP 160000
#define E_TOT (E_AP + E_TP + E_PA)
#define NSLOT (NPA + NPA + NA)     // 20480 global CSR slots: [ap->paper | tp->paper | pa->author]
#define ASPLIT 4                   // attention key-splits

typedef __attribute__((ext_vector_type(4))) float f32x4;
typedef __attribute__((ext_vector_type(8))) short s16x8;
typedef __attribute__((ext_vector_type(8))) unsigned short u16x8;
typedef unsigned short ushort_t;

__device__ __forceinline__ ushort_t f2bf(float f){
  unsigned u = __float_as_uint(f);
  unsigned r = u + 0x7fffu + ((u >> 16) & 1u);   // RNE
  return (ushort_t)(r >> 16);
}
__device__ __forceinline__ float bf2f(ushort_t u){
  return __uint_as_float(((unsigned)u) << 16);
}

// ---------------------------------------------------------------- f32 GEMM (mlp2 only; ACT=2 -> row softmax over N=4)
template<int ACT>
__global__ __launch_bounds__(256) void gemm_k(
    const float* __restrict__ A, const float* __restrict__ B, float* __restrict__ C,
    const float* __restrict__ bias,
    int M, int N, int K, int lda, int ldb, int ldc)
{
  __shared__ float As[16][68];
  __shared__ float Bs[16][68];
  int bm = blockIdx.x * 64, bn = blockIdx.y * 64;
  int tid = threadIdx.x;
  int tr = tid >> 4, tc = tid & 15;
  float acc[4][4] = {{0.f}};
  for (int k0 = 0; k0 < K; k0 += 16) {
#pragma unroll
    for (int i = 0; i < 4; ++i) {
      int idx = tid + i * 256;
      int r  = idx >> 4, kk = idx & 15;
      int gr = bm + r, gk = k0 + kk;
      As[kk][r] = (gr < M && gk < K) ? A[(size_t)gr * lda + gk] : 0.f;
      int c  = idx & 63, k2 = idx >> 6;
      int gc = bn + c, gk2 = k0 + k2;
      Bs[k2][c] = (gk2 < K && gc < N) ? B[(size_t)gk2 * ldb + gc] : 0.f;
    }
    __syncthreads();
#pragma unroll
    for (int kk = 0; kk < 16; ++kk) {
      float a0[4], b0[4];
#pragma unroll
      for (int i = 0; i < 4; ++i) a0[i] = As[kk][tr * 4 + i];
#pragma unroll
      for (int j = 0; j < 4; ++j) b0[j] = Bs[kk][tc * 4 + j];
#pragma unroll
      for (int i = 0; i < 4; ++i)
#pragma unroll
        for (int j = 0; j < 4; ++j) acc[i][j] = fmaf(a0[i], b0[j], acc[i][j]);
    }
    __syncthreads();
  }
  if (ACT == 2) {
    if (tc != 0) return;
#pragma unroll
    for (int i = 0; i < 4; ++i) {
      int r = bm + tr * 4 + i;
      if (r >= M) continue;
      float l0 = acc[i][0] + bias[0], l1 = acc[i][1] + bias[1];
      float l2 = acc[i][2] + bias[2], l3 = acc[i][3] + bias[3];
      float mx = fmaxf(fmaxf(l0, l1), fmaxf(l2, l3));
      float e0 = __expf(l0 - mx), e1 = __expf(l1 - mx), e2 = __expf(l2 - mx), e3 = __expf(l3 - mx);
      float inv = 1.f / (e0 + e1 + e2 + e3);
      C[(size_t)r * ldc + 0] = e0 * inv;
      C[(size_t)r * ldc + 1] = e1 * inv;
      C[(size_t)r * ldc + 2] = e2 * inv;
      C[(size_t)r * ldc + 3] = e3 * inv;
    }
  } else {
#pragma unroll
    for (int i = 0; i < 4; ++i) {
      int r = bm + tr * 4 + i;
      if (r >= M) continue;
#pragma unroll
      for (int j = 0; j < 4; ++j) {
        int c = bn + tc * 4 + j;
        if (c >= N) continue;
        float v = acc[i][j];
        if (bias) v += bias[c];
        if (ACT == 1) v = fmaxf(v, 0.f);
        C[(size_t)r * ldc + c] = v;
      }
    }
  }
}

// ---------------------------------------------------------------- bf16 MFMA GEMM
// Tile 64 x TN x BK32, 4 waves (2x2); TN in {64,128}. Requires M%64==0, N%TN==0.
// aBf16: A (and A2/A3) stored bf16 (K%32==0); cBf16: C written bf16.
// ACT: 0 none, 1 relu, 2 LayerNorm over full row (TN==128, grid.y==1, C f32).
// A2/A3: virtual A = [A|A2|A3], segments of 128 cols, shared lda.
// addmat(f32): v += (c < addCols) ? addmat[r*addLd+c] : 0.  bias z-offset = cOffZ.
template<int ACT, int TN>
__global__ __launch_bounds__(256) void gemm_mfma_k(
    const void* __restrict__ Ain, const void* __restrict__ A2in, const void* __restrict__ A3in,
    int aBf16,
    const float* __restrict__ B, void* __restrict__ Cout, int cBf16,
    const float* __restrict__ bias,
    const float* __restrict__ addmat, int addCols, int addLd,
    const float* __restrict__ lng, const float* __restrict__ lnb,
    int M, int N, int K, int lda, int ldb, int ldc,
    int aOffZ, int bOffZ, int cOffZ)
{
  int asz = aBf16 ? 2 : 4;
  const char* A  = (const char*)Ain  + (size_t)blockIdx.z * aOffZ * asz;
  const char* A2 = A2in ? (const char*)A2in + (size_t)blockIdx.z * aOffZ * asz : nullptr;
  const char* A3 = A3in ? (const char*)A3in + (size_t)blockIdx.z * aOffZ * asz : nullptr;
  B += (size_t)blockIdx.z * bOffZ;
  char* C = (char*)Cout + (size_t)blockIdx.z * cOffZ * (cBf16 ? 2 : 4);
  if (bias) bias += (size_t)blockIdx.z * cOffZ;

  __shared__ __align__(16) ushort_t As[64][40];
  __shared__ __align__(16) ushort_t Bs[TN][40];
  constexpr int NJ = TN / 32;
  int bm = blockIdx.x * 64, bn = blockIdx.y * TN;
  int tid = threadIdx.x;
  int w = tid >> 6, lane = tid & 63, lg = lane >> 4, lid = lane & 15;
  int wm = (w & 1) * 32, wn = (w >> 1) * (TN / 2);
  f32x4 acc[2][NJ];
#pragma unroll
  for (int i = 0; i < 2; ++i)
#pragma unroll
    for (int j = 0; j < NJ; ++j) acc[i][j] = (f32x4){0.f, 0.f, 0.f, 0.f};

  for (int k0 = 0; k0 < K; k0 += 32) {
    {
      int r = tid >> 2, ks = (tid & 3) * 8;
      int kcol = k0 + ks;
      const char* Ab = A;
      if (A2) { int seg = kcol >> 7; Ab = (seg == 0) ? A : ((seg == 1) ? A2 : A3); kcol &= 127; }
      u16x8 v;
      if (aBf16) {
        v = *(const u16x8*)((const ushort_t*)Ab + (size_t)(bm + r) * lda + kcol);
      } else {
        const float* ap = (const float*)Ab + (size_t)(bm + r) * lda + kcol;
#pragma unroll
        for (int j = 0; j < 8; ++j) {
          int gk = k0 + ks + j;
          float fv = (gk < K) ? ap[j] : 0.f;
          v[j] = f2bf(fv);
        }
      }
      *(u16x8*)&As[r][ks] = v;
    }
    if (TN == 128) {
      int n = tid >> 1, ks = (tid & 1) * 16;
      ushort_t tmp[16];
#pragma unroll
      for (int j = 0; j < 16; ++j) {
        int gk = k0 + ks + j;
        float fv = (gk < K) ? B[(size_t)gk * ldb + bn + n] : 0.f;
        tmp[j] = f2bf(fv);
      }
      u16x8 v0, v1;
#pragma unroll
      for (int j = 0; j < 8; ++j) { v0[j] = tmp[j]; v1[j] = tmp[8 + j]; }
      *(u16x8*)&Bs[n][ks] = v0;
      *(u16x8*)&Bs[n][ks + 8] = v1;
    } else {
      int n = tid >> 2, ks = (tid & 3) * 8;
      u16x8 v;
#pragma unroll
      for (int j = 0; j < 8; ++j) {
        int gk = k0 + ks + j;
        float fv = (gk < K) ? B[(size_t)gk * ldb + bn + n] : 0.f;
        v[j] = f2bf(fv);
      }
      *(u16x8*)&Bs[n][ks] = v;
    }
    __syncthreads();
    s16x8 a_frag[2], b_frag[NJ];
#pragma unroll
    for (int i = 0; i < 2; ++i) a_frag[i] = *(s16x8*)&As[wm + i * 16 + lid][lg * 8];
#pragma unroll
    for (int j = 0; j < NJ; ++j) b_frag[j] = *(s16x8*)&Bs[wn + j * 16 + lid][lg * 8];
#pragma unroll
    for (int i = 0; i < 2; ++i)
#pragma unroll
      for (int j = 0; j < NJ; ++j)
        acc[i][j] = __builtin_amdgcn_mfma_f32_16x16x32_bf16(a_frag[i], b_frag[j], acc[i][j], 0, 0, 0);
    __syncthreads();
  }
  if (ACT == 2) {
    // fused LayerNorm: TN==128, grid.y==1, C f32
    __shared__ float Ct[64][132];
#pragma unroll
    for (int i = 0; i < 2; ++i) {
#pragma unroll
      for (int j = 0; j < NJ; ++j) {
        int coll = wn + j * 16 + lid;
#pragma unroll
        for (int rr = 0; rr < 4; ++rr) {
          int rowl = wm + i * 16 + lg * 4 + rr;
          float v = acc[i][j][rr];
          if (bias) v += bias[coll];
          if (addmat && coll < addCols) v += addmat[(size_t)(bm + rowl) * addLd + coll];
          Ct[rowl][coll] = v;
        }
      }
    }
    __syncthreads();
    int row = tid >> 2, part = tid & 3;
    float s = 0.f, q = 0.f;
#pragma unroll
    for (int c2 = 0; c2 < 32; ++c2) {
      float v = Ct[row][part * 32 + c2];
      s += v; q += v * v;
    }
    s += __shfl_xor(s, 1); q += __shfl_xor(q, 1);
    s += __shfl_xor(s, 2); q += __shfl_xor(q, 2);
    float mean = s * (1.f / 128.f);
    float var = q * (1.f / 128.f) - mean * mean;
    float inv = rsqrtf(var + 1e-5f);
    int r = bm + row;
    float* Cf = (float*)C;
#pragma unroll
    for (int c2 = 0; c2 < 32; ++c2) {
      int c = part * 32 + c2;
      Cf[(size_t)r * ldc + c] = (Ct[row][c] - mean) * inv * lng[c] + lnb[c];
    }
  } else {
#pragma unroll
    for (int i = 0; i < 2; ++i) {
#pragma unroll
      for (int j = 0; j < NJ; ++j) {
        int c = bn + wn + j * 16 + lid;
#pragma unroll
        for (int rr = 0; rr < 4; ++rr) {
          int r = bm + wm + i * 16 + lg * 4 + rr;
          float v = acc[i][j][rr];
          if (bias)   v += bias[c];
          if (addmat && c < addCols) v += addmat[(size_t)r * addLd + c];
          if (ACT == 1) v = fmaxf(v, 0.f);
          if (cBf16) ((ushort_t*)C)[(size_t)r * ldc + c] = f2bf(v);
          else       ((float*)C)[(size_t)r * ldc + c] = v;
        }
      }
    }
  }
}

// ---------------------------------------------------------------- prep: pack weights/biases + db
__global__ void prep_k(const float* __restrict__ gat1_b, const float* __restrict__ gat1_W,
                       const float* __restrict__ Wq, const float* __restrict__ bq,
                       const float* __restrict__ Wk, const float* __restrict__ bk,
                       const float* __restrict__ Wv, const float* __restrict__ bv,
                       const float* __restrict__ peWQ, const float* __restrict__ peWK,
                       const int* __restrict__ deg,
                       float* __restrict__ bsum, float* __restrict__ Wqkv,
                       float* __restrict__ bqkv, float* __restrict__ peW,
                       float* __restrict__ Bstack, float* __restrict__ dbv)
{
  int idx = blockIdx.x * blockDim.x + threadIdx.x;
  if (idx < 1024) { bsum[idx] = gat1_b[idx] + gat1_b[3 * 1024 + idx]; return; }
  idx -= 1024;
  if (idx < 2 * 128 * 384) {
    int l = idx / 49152, rem = idx % 49152;
    int k = rem / 384, c = rem % 384;
    float v;
    if (c < 128)      v = Wq[(size_t)l * 16384 + k * 128 + c];
    else if (c < 256) v = Wk[(size_t)l * 16384 + k * 128 + c - 128];
    else              v = Wv[(size_t)l * 16384 + k * 128 + c - 256];
    Wqkv[(size_t)l * 49152 + k * 384 + c] = v;
    return;
  }
  idx -= 2 * 128 * 384;
  if (idx < 2 * 384) {
    int l = idx / 384, c = idx % 384;
    float v;
    if (c < 128)      v = bq[l * 128 + c];
    else if (c < 256) v = bk[l * 128 + c - 128];
    else              v = bv[l * 128 + c - 256];
    bqkv[l * 384 + c] = v;
    return;
  }
  idx -= 2 * 384;
  if (idx < 128 * 256) {
    int k = idx / 256, c = idx % 256;
    peW[k * 256 + c] = (c < 128) ? peWQ[k * 128 + c] : peWK[k * 128 + c - 128];
    return;
  }
  idx -= 128 * 256;
  if (idx < 256 * 1024) {
    int k = idx / 1024, c = idx % 1024;
    Bstack[idx] = (k < 128) ? gat1_W[(size_t)k * 1024 + c]
                            : gat1_W[(size_t)3 * 131072 + (size_t)(k - 128) * 1024 + c];
    return;
  }
  idx -= 256 * 1024;
  if (idx < NA) dbv[idx] = logf(fmaxf((float)deg[idx], 1.f));
}

// ---------------------------------------------------------------- fused CSR build (3 edge types)
__global__ void histf_k(const int* __restrict__ ap_dst, const int* __restrict__ tp_dst,
                        const int* __restrict__ pa_dst, int* __restrict__ cnt){
  int i = blockIdx.x * blockDim.x + threadIdx.x;
  if (i >= E_TOT) return;
  int slot;
  if (i < E_AP)             slot = ap_dst[i];
  else if (i < E_AP + E_TP) slot = NPA + tp_dst[i - E_AP];
  else                      slot = 2 * NPA + pa_dst[i - E_AP - E_TP];
  atomicAdd(&cnt[slot], 1);
}

__global__ void scatterf_k(const int* __restrict__ ap_dst, const int* __restrict__ tp_dst,
                           const int* __restrict__ pa_dst, const int* __restrict__ off,
                           int* __restrict__ cur, int* __restrict__ eidx){
  int i = blockIdx.x * blockDim.x + threadIdx.x;
  if (i >= E_TOT) return;
  int slot, local;
  if (i < E_AP)             { local = i;                 slot = ap_dst[local]; }
  else if (i < E_AP + E_TP) { local = i - E_AP;          slot = NPA + tp_dst[local]; }
  else                      { local = i - E_AP - E_TP;   slot = 2 * NPA + pa_dst[local]; }
  int p = atomicAdd(&cur[slot], 1);
  eidx[off[slot] + p] = local;
}

// shuffle-based exclusive scan, 1 block of 1024 threads
__global__ __launch_bounds__(1024) void exscan_k(const int* __restrict__ in, int* __restrict__ out, int n){
  __shared__ int wsum[16];
  __shared__ int carrySh;
  int t = threadIdx.x, w = t >> 6, lane = t & 63;
  if (t == 0) carrySh = 0;
  __syncthreads();
  for (int base = 0; base < n; base += 1024){
    int carry = carrySh;
    int v = (base + t < n) ? in[base + t] : 0;
    int sc = v;
#pragma unroll
    for (int o2 = 1; o2 < 64; o2 <<= 1){
      int u = __shfl_up(sc, o2);
      if (lane >= o2) sc += u;
    }
    if (lane == 63) wsum[w] = sc;
    __syncthreads();
    int wadd = 0;
#pragma unroll
    for (int i = 0; i < 15; ++i) if (i < w) wadd += wsum[i];
    if (base + t < n) out[base + t] = carry + wadd + sc - v;
    if (t == 1023) carrySh = carry + wadd + sc;
    __syncthreads();
  }
}

// ---------------------------------------------------------------- GAT batched pieces
// Ps/Pd for 3 types (W index order ap=0, tp=3, pa=1)
__global__ void proj3_k(const float* __restrict__ W, const float* __restrict__ as_,
                        const float* __restrict__ ad_, float* __restrict__ Ps,
                        float* __restrict__ Pd){
  int t = blockIdx.x * blockDim.x + threadIdx.x;
  if (t >= 3 * 1024) return;
  const int wsel[3] = {0, 3, 1};
  int type = t / 1024, rem = t % 1024;
  int k = rem >> 3, h = rem & 7;
  const float* wr = W + (size_t)wsel[type] * 131072 + (size_t)k * 1024 + h * 128;
  const float* a1 = as_ + wsel[type] * 1024 + h * 128;
  const float* a2 = ad_ + wsel[type] * 1024 + h * 128;
  float s1 = 0.f, s2 = 0.f;
  for (int c = 0; c < 128; ++c){ float wv = wr[c]; s1 = fmaf(wv, a1[c], s1); s2 = fmaf(wv, a2[c], s2); }
  Ps[(size_t)type * 1024 + k * 8 + h] = s1;
  Pd[(size_t)type * 1024 + k * 8 + h] = s2;
}

// batched row-dot scores (x bf16): 6 segments -> scores[36864][8]
// [0,4096)=ss_ap(xa,Ps0) [4096,12288)=sd_ap(xp,Pd0) [12288,16384)=ss_tp(xt,Ps1)
// [16384,24576)=sd_tp(xp,Pd1) [24576,32768)=ss_pa(xp,Ps2) [32768,36864)=sd_pa(xa,Pd2)
__global__ __launch_bounds__(256) void scorev_k(
    const ushort_t* __restrict__ xa, const ushort_t* __restrict__ xp, const ushort_t* __restrict__ xt,
    const float* __restrict__ Ps, const float* __restrict__ Pd, float* __restrict__ scores)
{
  int r = blockIdx.x * 4 + (threadIdx.x >> 6);
  int lane = threadIdx.x & 63;
  const ushort_t* x; const float* P; int row;
  if (r < 4096)       { x = xa; P = Ps;        row = r; }
  else if (r < 12288) { x = xp; P = Pd;        row = r - 4096; }
  else if (r < 16384) { x = xt; P = Ps + 1024; row = r - 12288; }
  else if (r < 24576) { x = xp; P = Pd + 1024; row = r - 16384; }
  else if (r < 32768) { x = xp; P = Ps + 2048; row = r - 24576; }
  else                { x = xa; P = Pd + 2048; row = r - 32768; }
  unsigned u = *(const unsigned*)(x + (size_t)row * 128 + 2 * lane);
  float x0 = bf2f((ushort_t)(u & 0xffff));
  float x1 = bf2f((ushort_t)(u >> 16));
  float res[8];
#pragma unroll
  for (int h = 0; h < 8; ++h) {
    float s = x0 * P[(2 * lane) * 8 + h] + x1 * P[(2 * lane + 1) * 8 + h];
#pragma unroll
    for (int o = 32; o; o >>= 1) s += __shfl_down(s, o);
    res[h] = s;
  }
  if (lane == 0) {
#pragma unroll
    for (int h = 0; h < 8; ++h) scores[(size_t)r * 8 + h] = res[h];
  }
}

// fused edge-softmax (scores computed inline, two-pass) + x-space aggregation;
// one wave per slot; x bf16, agg bf16. scores array is L2-resident (1.2 MB).
__global__ __launch_bounds__(256) void agg8ff_k(
    const int* __restrict__ eidx, const int* __restrict__ off, const int* __restrict__ cnt,
    const int* __restrict__ ap_src, const int* __restrict__ tp_src, const int* __restrict__ pa_src,
    const ushort_t* __restrict__ xa, const ushort_t* __restrict__ xt, const ushort_t* __restrict__ xp,
    const float* __restrict__ scores, ushort_t* __restrict__ agg)
{
  int g = blockIdx.x * 4 + (threadIdx.x >> 6);
  if (g >= NSLOT) return;
  const int* src; const ushort_t* x; const float* ssb; const float* sdb; int d;
  if (g < NPA)          { src = ap_src; x = xa; ssb = scores;                    sdb = scores + (size_t)4096 * 8;  d = g; }
  else if (g < 2 * NPA) { src = tp_src; x = xt; ssb = scores + (size_t)12288 * 8; sdb = scores + (size_t)16384 * 8; d = g - NPA; }
  else                  { src = pa_src; x = xp; ssb = scores + (size_t)24576 * 8; sdb = scores + (size_t)32768 * 8; d = g - 2 * NPA; }
  int lane = threadIdx.x & 63;
  int hh = lane & 7;
  float sdv = sdb[(size_t)d * 8 + hh];
  int base = off[g], n = cnt[g];
  // pass 1: per-head max over incoming edges
  float mh = -1e30f;
  {
    int e = (n > 0) ? eidx[base] : 0;
    int s = (n > 0) ? src[e] : 0;
    for (int k = 0; k < n; ++k){
      int en = 0, sn = 0;
      if (k + 1 < n){ en = eidx[base + k + 1]; sn = src[en]; }
      float v = ssb[(size_t)s * 8 + hh] + sdv;
      v = v > 0.f ? v : 0.2f * v;
      mh = fmaxf(mh, v);
      e = en; s = sn;
    }
  }
  // pass 2: exp + weighted gather
  float acc0[8], acc1[8];
#pragma unroll
  for (int h2 = 0; h2 < 8; ++h2){ acc0[h2] = 0.f; acc1[h2] = 0.f; }
  float den = 0.f;
  int e = (n > 0) ? eidx[base] : 0;
  int s = (n > 0) ? src[e] : 0;
  for (int k = 0; k < n; ++k){
    int en = 0, sn = 0;
    if (k + 1 < n){ en = eidx[base + k + 1]; sn = src[en]; }
    float v = ssb[(size_t)s * 8 + hh] + sdv;
    v = v > 0.f ? v : 0.2f * v;
    float wv_ = __expf(v - mh);
    den += wv_;
    unsigned u = *(const unsigned*)(x + (size_t)s * 128 + 2 * lane);
    float xv0 = bf2f((ushort_t)(u & 0xffff));
    float xv1 = bf2f((ushort_t)(u >> 16));
#pragma unroll
    for (int h2 = 0; h2 < 8; ++h2){
      float wh = __shfl(wv_, h2);
      acc0[h2] = fmaf(wh, xv0, acc0[h2]);
      acc1[h2] = fmaf(wh, xv1, acc1[h2]);
    }
    e = en; s = sn;
  }
  ushort_t* o = agg + (size_t)g * 1024;
#pragma unroll
  for (int h2 = 0; h2 < 8; ++h2){
    float dh = __shfl(den, h2) + 1e-16f;
    unsigned pk = (unsigned)f2bf(acc0[h2] / dh) | ((unsigned)f2bf(acc1[h2] / dh) << 16);
    *(unsigned*)(o + h2 * 128 + 2 * lane) = pk;
  }
}

// fused H=1 softmax+aggregation (gat2), scores inline two-pass; hs bf16 -> out f32
// sArr: [0,8192)=paper(src) scores, [8192,12288)=author(dst) scores
__global__ __launch_bounds__(256) void gat_agg1f_k(
    const int* __restrict__ eidx, const int* __restrict__ off, const int* __restrict__ cnt,
    const int* __restrict__ src, const ushort_t* __restrict__ hs,
    const float* __restrict__ sArr,
    const float* __restrict__ bias, float* __restrict__ outp, int Ndst)
{
  int d = blockIdx.x * 4 + (threadIdx.x >> 6);
  if (d >= Ndst) return;
  int lane = threadIdx.x & 63;
  float sdv = sArr[8192 + d];
  int base = off[d], n = cnt[d];
  float mh = -1e30f;
  {
    int e = (n > 0) ? eidx[base] : 0;
    int s = (n > 0) ? src[e] : 0;
    for (int k = 0; k < n; ++k){
      int en = 0, sn = 0;
      if (k + 1 < n){ en = eidx[base + k + 1]; sn = src[en]; }
      float v = sArr[s] + sdv;
      v = v > 0.f ? v : 0.2f * v;
      mh = fmaxf(mh, v);
      e = en; s = sn;
    }
  }
  float a0 = 0.f, a1 = 0.f, den = 0.f;
  int e = (n > 0) ? eidx[base] : 0;
  int s = (n > 0) ? src[e] : 0;
  for (int k = 0; k < n; ++k){
    int en = 0, sn = 0;
    if (k + 1 < n){ en = eidx[base + k + 1]; sn = src[en]; }
    float v = sArr[s] + sdv;
    v = v > 0.f ? v : 0.2f * v;
    float w_ = __expf(v - mh);
    den += w_;
    unsigned u = *(const unsigned*)(hs + (size_t)s * 128 + 2 * lane);
    a0 = fmaf(w_, bf2f((ushort_t)(u & 0xffff)), a0);
    a1 = fmaf(w_, bf2f((ushort_t)(u >> 16)), a1);
    e = en; s = sn;
  }
  float inv = 1.f / (den + 1e-16f);
  outp[(size_t)d * 128 + 2 * lane]     = a0 * inv + bias[2 * lane];
  outp[(size_t)d * 128 + 2 * lane + 1] = a1 * inv + bias[2 * lane + 1];
}

// batched rowdots for gat2 (X bf16): rows [0,8192)=hs2 w/ va, [8192,12288)=hd2 w/ vb
__global__ __launch_bounds__(256) void rowdot2_k(const ushort_t* __restrict__ X,
    const float* __restrict__ va, const float* __restrict__ vb, float* __restrict__ out){
  int r = blockIdx.x * 4 + (threadIdx.x >> 6);
  int lane = threadIdx.x & 63;
  const float* v = (r < 8192) ? va : vb;
  unsigned u = *(const unsigned*)(X + (size_t)r * 128 + 2 * lane);
  float s = bf2f((ushort_t)(u & 0xffff)) * v[2 * lane]
          + bf2f((ushort_t)(u >> 16)) * v[2 * lane + 1];
#pragma unroll
  for (int o = 32; o; o >>= 1) s += __shfl_down(s, o);
  if (lane == 0) out[r] = s;
}

// ---------------------------------------------------------------- PE loss (MFMA), peQ/peK packed f32 ld=256
__global__ __launch_bounds__(256) void loss_mfma_k(const float* __restrict__ peQ,
    const float* __restrict__ peK, const float* __restrict__ A4, float* __restrict__ lossAcc)
{
  __shared__ __align__(16) ushort_t As[64][40];
  __shared__ __align__(16) ushort_t Bs[128][40];
  __shared__ float red[256];
  int br = blockIdx.x * 64, bc = blockIdx.y * 128;
  int tid = threadIdx.x;
  int w = tid >> 6, lane = tid & 63, lg = lane >> 4, lid = lane & 15;
  int wm = (w & 1) * 32, wn = (w >> 1) * 64;
  f32x4 acc[2][4];
#pragma unroll
  for (int i = 0; i < 2; ++i)
#pragma unroll
    for (int j = 0; j < 4; ++j) acc[i][j] = (f32x4){0.f, 0.f, 0.f, 0.f};

  for (int k0 = 0; k0 < 128; k0 += 32) {
    {
      int r = tid >> 2, ks = (tid & 3) * 8;
      const float* ap = peQ + (size_t)(br + r) * 256 + k0 + ks;
      u16x8 v;
#pragma unroll
      for (int j = 0; j < 8; ++j) v[j] = f2bf(ap[j]);
      *(u16x8*)&As[r][ks] = v;
    }
    {
      int n = tid >> 1, ks = (tid & 1) * 16;
      const float* bp = peK + (size_t)(bc + n) * 256 + k0 + ks;
      u16x8 v0, v1;
#pragma unroll
      for (int j = 0; j < 8; ++j) { v0[j] = f2bf(bp[j]); v1[j] = f2bf(bp[8 + j]); }
      *(u16x8*)&Bs[n][ks] = v0;
      *(u16x8*)&Bs[n][ks + 8] = v1;
    }
    __syncthreads();
    s16x8 a_frag[2], b_frag[4];
#pragma unroll
    for (int i = 0; i < 2; ++i) a_frag[i] = *(s16x8*)&As[wm + i * 16 + lid][lg * 8];
#pragma unroll
    for (int j = 0; j < 4; ++j) b_frag[j] = *(s16x8*)&Bs[wn + j * 16 + lid][lg * 8];
#pragma unroll
    for (int i = 0; i < 2; ++i)
#pragma unroll
      for (int j = 0; j < 4; ++j)
        acc[i][j] = __builtin_amdgcn_mfma_f32_16x16x32_bf16(a_frag[i], b_frag[j], acc[i][j], 0, 0, 0);
    __syncthreads();
  }
  float err = 0.f;
#pragma unroll
  for (int i = 0; i < 2; ++i) {
#pragma unroll
    for (int rr = 0; rr < 4; ++rr) {
      int r = br + wm + i * 16 + lg * 4 + rr;
#pragma unroll
      for (int j = 0; j < 4; ++j) {
        int c = bc + wn + j * 16 + lid;
        float s = 1.f / (1.f + __expf(-acc[i][j][rr]));
        size_t o = (size_t)r * 4096 + c;
#pragma unroll
        for (int q = 0; q < 4; ++q) {
          float d = s - A4[(size_t)q * 16777216 + o];
          err += d * d;
        }
      }
    }
  }
  red[tid] = err;
  __syncthreads();
  for (int o = 128; o; o >>= 1){
    if (tid < o) red[tid] += red[tid + o];
    __syncthreads();
  }
  if (tid == 0) atomicAdd(lossAcc, red[0]);
}

__global__ void finalize_loss_k(const float* __restrict__ acc, float* __restrict__ out){
  out[0] = acc[0] * (1.0f / 67108864.0f);
}

// ---------------------------------------------------------------- MFMA flash attention (bf16 QKV packed, ld=384)
__global__ __launch_bounds__(256) void attn_mfma_k(
    const ushort_t* __restrict__ Q, const ushort_t* __restrict__ K, const ushort_t* __restrict__ V,
    const float* __restrict__ dbv, float* __restrict__ part)
{
  const int ld = 384;
  int h = blockIdx.y, sp = blockIdx.z;
  int qbase = blockIdx.x * 64;
  int tid = threadIdx.x;
  int w = tid >> 6, lane = tid & 63, lid = lane & 15, lg = lane >> 4;
  __shared__ __align__(16) ushort_t Vt[16][72];
  __shared__ __align__(16) ushort_t Pl[4][16][72];
  __shared__ float dbs[64];

  s16x8 qf;
  if (lg < 2) {
    u16x8 v = *(const u16x8*)(Q + (size_t)(qbase + 16 * w + lid) * ld + h * 16 + 8 * lg);
#pragma unroll
    for (int j = 0; j < 8; ++j) v[j] = f2bf(bf2f(v[j]) * 0.25f);  // exact pow2 scale
    qf = (s16x8)v;
  } else {
    qf = (s16x8){0,0,0,0,0,0,0,0};
  }

  float m = -1e30f, l = 0.f;
  f32x4 o = {0.f, 0.f, 0.f, 0.f};

  int kb0 = sp * (4096 / ASPLIT);
  for (int kt = 0; kt < 4096 / ASPLIT; kt += 64) {
    int kb = kb0 + kt;
    __syncthreads();
    {
      int key = tid >> 2, ds_ = (tid & 3) * 4;
      const ushort_t* vp = V + (size_t)(kb + key) * ld + h * 16 + ds_;
#pragma unroll
      for (int j = 0; j < 4; ++j) Vt[ds_ + j][key] = vp[j];
      if (tid < 64) dbs[tid] = dbv[kb + tid];
    }
    __syncthreads();

    f32x4 s[4];
#pragma unroll
    for (int g = 0; g < 4; ++g) {
      s16x8 kf;
      if (lg < 2) {
        kf = (s16x8)(*(const u16x8*)(K + (size_t)(kb + 16 * g + lid) * ld + h * 16 + 8 * lg));
      } else kf = (s16x8){0,0,0,0,0,0,0,0};
      s[g] = __builtin_amdgcn_mfma_f32_16x16x32_bf16(kf, qf, (f32x4){0.f,0.f,0.f,0.f}, 0, 0, 0);
    }
#pragma unroll
    for (int g = 0; g < 4; ++g)
#pragma unroll
      for (int r = 0; r < 4; ++r) s[g][r] += dbs[16 * g + 4 * lg + r];

    float tmax = -1e30f;
#pragma unroll
    for (int g = 0; g < 4; ++g)
#pragma unroll
      for (int r = 0; r < 4; ++r) tmax = fmaxf(tmax, s[g][r]);
    tmax = fmaxf(tmax, __shfl_xor(tmax, 16));
    tmax = fmaxf(tmax, __shfl_xor(tmax, 32));
    float mn = fmaxf(m, tmax);
    float scale = __expf(m - mn);
    float psum = 0.f;
    float p[4][4];
#pragma unroll
    for (int g = 0; g < 4; ++g)
#pragma unroll
      for (int r = 0; r < 4; ++r) { p[g][r] = __expf(s[g][r] - mn); psum += p[g][r]; }
    psum += __shfl_xor(psum, 16);
    psum += __shfl_xor(psum, 32);
    l = l * scale + psum;
    m = mn;

#pragma unroll
    for (int g = 0; g < 4; ++g) {
#pragma unroll
      for (int rp = 0; rp < 4; rp += 2) {
        unsigned pack = (unsigned)f2bf(p[g][rp]) | ((unsigned)f2bf(p[g][rp + 1]) << 16);
        *(unsigned*)&Pl[w][lid][16 * g + 4 * lg + rp] = pack;
      }
    }
#pragma unroll
    for (int r = 0; r < 4; ++r) o[r] *= __shfl(scale, 4 * lg + r);
#pragma unroll
    for (int kc = 0; kc < 2; ++kc) {
      s16x8 pa = *(s16x8*)&Pl[w][lid][32 * kc + 8 * lg];
      s16x8 vb = *(s16x8*)&Vt[lid][32 * kc + 8 * lg];
      o = __builtin_amdgcn_mfma_f32_16x16x32_bf16(pa, vb, o, 0, 0, 0);
    }
  }
  float* pb = part + ((size_t)(sp * 8 + h) * NA) * 18;
#pragma unroll
  for (int r = 0; r < 4; ++r) {
    int qq = qbase + 16 * w + 4 * lg + r;
    pb[(size_t)qq * 18 + lid] = o[r];
  }
  if (lg == 0) {
    int qq = qbase + 16 * w + lid;
    pb[(size_t)qq * 18 + 16] = m;
    pb[(size_t)qq * 18 + 17] = l;
  }
}

// combine -> bf16 O
__global__ __launch_bounds__(256) void attn_comb_k(const float* __restrict__ part,
                                                   ushort_t* __restrict__ O){
  int t = blockIdx.x * 256 + threadIdx.x;
  int r = t >> 3, h = t & 7;
  float m = -1e30f;
#pragma unroll
  for (int sp = 0; sp < ASPLIT; ++sp)
    m = fmaxf(m, part[((size_t)(sp * 8 + h) * NA + r) * 18 + 16]);
  float l = 0.f, acc[16];
#pragma unroll
  for (int j = 0; j < 16; ++j) acc[j] = 0.f;
  for (int sp = 0; sp < ASPLIT; ++sp){
    const float* pp = part + ((size_t)(sp * 8 + h) * NA + r) * 18;
    float w = __expf(pp[16] - m);
    l += pp[17] * w;
#pragma unroll
    for (int j = 0; j < 16; ++j) acc[j] = fmaf(pp[j], w, acc[j]);
  }
  float inv = 1.f / l;
#pragma unroll
  for (int j = 0; j < 16; ++j) O[(size_t)r * 128 + h * 16 + j] = f2bf(acc[j] * inv);
}

__global__ void setval_k(float* p, float v){ p[0] = v; }

// ---------------------------------------------------------------- host
extern "C" void kernel_launch(void* const* d_in, const int* in_sizes, int n_in,
                              void* d_out, int out_size, void* d_ws, size_t ws_size,
                              hipStream_t stream)
{
  (void)in_sizes; (void)n_in; (void)out_size;
  const float* x_author = (const float*)d_in[0];
  const float* x_paper  = (const float*)d_in[1];
  const float* x_term   = (const float*)d_in[2];
  const int* ap_src = (const int*)d_in[3];
  const int* ap_dst = (const int*)d_in[4];
  const int* pa_src = (const int*)d_in[5];
  const int* pa_dst = (const int*)d_in[6];
  const int* tp_src = (const int*)d_in[9];
  const int* tp_dst = (const int*)d_in[10];
  const float* original_A = (const float*)d_in[11];
  const int* deg = (const int*)d_in[12];
  const float* t1_W = (const float*)d_in[13]; const float* t1_b = (const float*)d_in[14];
  const float* t2_W = (const float*)d_in[15]; const float* t2_b = (const float*)d_in[16];
  const float* t3_W = (const float*)d_in[17]; const float* t3_b = (const float*)d_in[18];
  const float* gat1_W  = (const float*)d_in[19];
  const float* gat1_as = (const float*)d_in[20];
  const float* gat1_ad = (const float*)d_in[21];
  const float* gat1_b  = (const float*)d_in[22];
  const float* gat2_W  = (const float*)d_in[23];
  const float* gat2_as = (const float*)d_in[24];
  const float* gat2_ad = (const float*)d_in[25];
  const float* gat2_b  = (const float*)d_in[26];
  const float* pe_embed = (const float*)d_in[27];
  const float* peWQ = (const float*)d_in[28];
  const float* peWK = (const float*)d_in[29];
  const float* gt_Wq = (const float*)d_in[30]; const float* gt_bq = (const float*)d_in[31];
  const float* gt_Wk = (const float*)d_in[32]; const float* gt_bk = (const float*)d_in[33];
  const float* gt_Wv = (const float*)d_in[34]; const float* gt_bv = (const float*)d_in[35];
  const float* gt_Wo = (const float*)d_in[36]; const float* gt_bo = (const float*)d_in[37];
  const float* gt_g1 = (const float*)d_in[38]; const float* gt_be1 = (const float*)d_in[39];
  const float* gt_Wf1 = (const float*)d_in[40]; const float* gt_bf1 = (const float*)d_in[41];
  const float* gt_Wf2 = (const float*)d_in[42]; const float* gt_bf2 = (const float*)d_in[43];
  const float* gt_g2 = (const float*)d_in[44]; const float* gt_be2 = (const float*)d_in[45];
  const float* cat_W = (const float*)d_in[46]; const float* cat_b = (const float*)d_in[47];
  const float* mlp_W1 = (const float*)d_in[48]; const float* mlp_b1 = (const float*)d_in[49];
  const float* mlp_W2 = (const float*)d_in[50]; const float* mlp_b2 = (const float*)d_in[51];
  float* out = (float*)d_out;

  // ---- workspace layout ----
  char* base = (char*)d_ws;
  size_t off = 0;
  auto alloc = [&](size_t nbytes) -> void* {
    void* p = base + off;
    off += (nbytes + 255) & ~(size_t)255;
    return p;
  };
  ushort_t* xa  = (ushort_t*)alloc((size_t)NA * 128 * 2);    // bf16
  ushort_t* xp  = (ushort_t*)alloc((size_t)NPA * 128 * 2);
  ushort_t* xt  = (ushort_t*)alloc((size_t)NT * 128 * 2);
  ushort_t* accP = (ushort_t*)alloc((size_t)NPA * 1024 * 2); // bf16; +accA contiguous; aliased as attn part
  ushort_t* accA = (ushort_t*)alloc((size_t)NA * 1024 * 2);
  ushort_t* agg  = (ushort_t*)alloc((size_t)NSLOT * 1024 * 2); // bf16
  float* scores = (float*)alloc((size_t)36864 * 8 * 4);
  float* Ps   = (float*)alloc(3 * 1024 * 4);
  float* Pd   = (float*)alloc(3 * 1024 * 4);
  ushort_t* hs2 = (ushort_t*)alloc((size_t)NPA * 128 * 2);   // bf16; +hd2 contiguous
  ushort_t* hd2 = (ushort_t*)alloc((size_t)NA * 128 * 2);
  float* s2sd = (float*)alloc((size_t)(NPA + NA) * 4);
  float* hA2  = (float*)alloc((size_t)NA * 128 * 4);
  float* peQK = (float*)alloc((size_t)NA * 256 * 4);
  float* dbv  = (float*)alloc((size_t)NA * 4);
  float* bsum = (float*)alloc(1024 * 4);
  float* Wqkv = (float*)alloc((size_t)2 * 128 * 384 * 4);
  float* bqkv = (float*)alloc((size_t)2 * 384 * 4);
  float* peW  = (float*)alloc((size_t)128 * 256 * 4);
  float* Bstack = (float*)alloc((size_t)256 * 1024 * 4);
  ushort_t* QKVb = (ushort_t*)alloc((size_t)NA * 384 * 2);   // bf16
  ushort_t* Ob  = (ushort_t*)alloc((size_t)NA * 128 * 2);    // bf16
  float* x1b  = (float*)alloc((size_t)NA * 128 * 4);
  ushort_t* f1 = (ushort_t*)alloc((size_t)NA * 256 * 2);     // bf16
  float* outs1= (float*)alloc((size_t)NA * 128 * 4);
  float* outs2= (float*)alloc((size_t)NA * 128 * 4);
  float* l1   = (float*)alloc((size_t)NA * 256 * 4);
  int*   offb = (int*)alloc((size_t)NSLOT * 4);
  int*   eidx = (int*)alloc((size_t)E_TOT * 4);
  // ---- zero-init region (single small memset): cnt, cur, lossAcc ----
  size_t zstart = off;
  int*      cnt   = (int*)alloc((size_t)NSLOT * 4);
  int*      cur   = (int*)alloc((size_t)NSLOT * 4);
  float*    lossAcc = (float*)alloc(256);
  size_t zlen = off - zstart;

  float* part = (float*)accP;  // 9.4 MB f32 partials alias onto 16.7 MB accP (dead by transformer)

  if (off > ws_size){
    setval_k<<<1, 1, 0, stream>>>(out, -12345.0f);
    return;
  }

  auto gemmx = [&](int act, int tn, const void* A, const void* A2, const void* A3, int aBf16,
                   const float* B, void* C, int cBf16, const float* bias,
                   const float* addmat, int addCols, int addLd,
                   const float* lng, const float* lnb,
                   int M, int N, int K, int lda, int ldb, int ldc,
                   int Z, int aOffZ, int bOffZ, int cOffZ){
    dim3 g(M / 64, N / tn, Z);
    if (tn == 128) {
      if (act == 0)      gemm_mfma_k<0,128><<<g, 256, 0, stream>>>(A, A2, A3, aBf16, B, C, cBf16, bias, addmat, addCols, addLd, lng, lnb, M, N, K, lda, ldb, ldc, aOffZ, bOffZ, cOffZ);
      else if (act == 1) gemm_mfma_k<1,128><<<g, 256, 0, stream>>>(A, A2, A3, aBf16, B, C, cBf16, bias, addmat, addCols, addLd, lng, lnb, M, N, K, lda, ldb, ldc, aOffZ, bOffZ, cOffZ);
      else               gemm_mfma_k<2,128><<<g, 256, 0, stream>>>(A, A2, A3, aBf16, B, C, cBf16, bias, addmat, addCols, addLd, lng, lnb, M, N, K, lda, ldb, ldc, aOffZ, bOffZ, cOffZ);
    } else {
      if (act == 0)      gemm_mfma_k<0,64><<<g, 256, 0, stream>>>(A, A2, A3, aBf16, B, C, cBf16, bias, addmat, addCols, addLd, lng, lnb, M, N, K, lda, ldb, ldc, aOffZ, bOffZ, cOffZ);
      else               gemm_mfma_k<1,64><<<g, 256, 0, stream>>>(A, A2, A3, aBf16, B, C, cBf16, bias, addmat, addCols, addLd, lng, lnb, M, N, K, lda, ldb, ldc, aOffZ, bOffZ, cOffZ);
    }
  };

  // 1. zero-init (tiny)
  hipMemsetAsync(base + zstart, 0, zlen, stream);
  // 2. prep (packs + db)
  prep_k<<<1560, 256, 0, stream>>>(gat1_b, gat1_W, gt_Wq, gt_bq, gt_Wk, gt_bk, gt_Wv, gt_bv,
                                   peWQ, peWK, deg, bsum, Wqkv, bqkv, peW, Bstack, dbv);
  // 3-5. stage-0 feature MLPs (bf16 outputs, TN=64 for grid)
  gemmx(1, 64, x_author, 0, 0, 0, t1_W, xa, 1, t1_b, 0, 0, 0, 0, 0, NA, 128, 334, 334, 128, 128, 1, 0, 0, 0);
  gemmx(1, 64, x_paper,  0, 0, 0, t2_W, xp, 1, t2_b, 0, 0, 0, 0, 0, NPA, 128, 512, 512, 128, 128, 1, 0, 0, 0);
  gemmx(1, 64, x_term,   0, 0, 0, t3_W, xt, 1, t3_b, 0, 0, 0, 0, 0, NT, 128, 128, 128, 128, 128, 1, 0, 0, 0);
  // 6-8. fused CSR build
  histf_k<<<(E_TOT + 255) / 256, 256, 0, stream>>>(ap_dst, tp_dst, pa_dst, cnt);
  exscan_k<<<1, 1024, 0, stream>>>(cnt, offb, NSLOT);
  scatterf_k<<<(E_TOT + 255) / 256, 256, 0, stream>>>(ap_dst, tp_dst, pa_dst, offb, cur, eidx);
  // 9-11. GAT1: proj, scores, fused softmax+aggregate
  proj3_k<<<12, 256, 0, stream>>>(gat1_W, gat1_as, gat1_ad, Ps, Pd);
  scorev_k<<<9216, 256, 0, stream>>>(xa, xp, xt, Ps, Pd, scores);
  agg8ff_k<<<NSLOT / 4, 256, 0, stream>>>(eidx, offb, cnt, ap_src, tp_src, pa_src,
                                          xa, xt, xp, scores, agg);
  // 12-13. per-head transform GEMMs: paper via K=256 stacked [W_ap; W_tp], author K=128
  gemmx(1, 128, agg, agg + (size_t)NPA * 1024, 0, 1, Bstack, accP, 1, bsum, 0, 0, 0, 0, 0,
        NPA, 128, 256, 1024, 1024, 1024, 8, 128, 128, 128);
  gemmx(1, 128, agg + (size_t)2 * NPA * 1024, 0, 0, 1, gat1_W + 131072, accA, 1, gat1_b + 1024,
        0, 0, 0, 0, 0, NA, 128, 128, 1024, 1024, 1024, 8, 128, 128, 128);
  // 14-16. GAT2
  gemmx(0, 64, accP, 0, 0, 1, gat2_W + 131072, hs2, 1, 0, 0, 0, 0, 0, 0,
        NPA + NA, 128, 1024, 1024, 128, 128, 1, 0, 0, 0);
  rowdot2_k<<<(NPA + NA) / 4, 256, 0, stream>>>(hs2, gat2_as + 128, gat2_ad + 128, s2sd);
  gat_agg1f_k<<<NA / 4, 256, 0, stream>>>(eidx, offb + 2 * NPA, cnt + 2 * NPA, pa_src, hs2, s2sd,
                                          gat2_b + 128, hA2, NA);
  // 17-19. PE + loss
  gemmx(0, 64, pe_embed, 0, 0, 0, peW, peQK, 0, 0, 0, 0, 0, 0, 0, NA, 256, 128, 128, 256, 256, 1, 0, 0, 0);
  loss_mfma_k<<<dim3(64, 32), 256, 0, stream>>>(peQK, peQK + 128, original_A, lossAcc);
  finalize_loss_k<<<1, 1, 0, stream>>>(lossAcc, out);
  // 20-31. graph transformer (2 layers)
  const float* x = hA2;
  float* louts[2] = { outs1, outs2 };
  for (int i = 0; i < 2; ++i){
    const float* Wo = gt_Wo + i * 16384; const float* bo = gt_bo + i * 128;
    const float* Wf1 = gt_Wf1 + i * 32768; const float* bf1 = gt_bf1 + i * 256;
    const float* Wf2 = gt_Wf2 + i * 32768; const float* bf2 = gt_bf2 + i * 128;
    // QKV fused (bf16 out): C=[Q|K|V], addmat=peQK for cols<256
    gemmx(0, 64, x, 0, 0, 0, Wqkv + (size_t)i * 49152, QKVb, 1, bqkv + i * 384, peQK, 256, 256,
          0, 0, NA, 384, 128, 128, 384, 384, 1, 0, 0, 0);
    attn_mfma_k<<<dim3(NA / 64, 8, ASPLIT), 256, 0, stream>>>(QKVb, QKVb + 128, QKVb + 256, dbv, part);
    attn_comb_k<<<(NA * 8) / 256, 256, 0, stream>>>(part, Ob);
    // Wo GEMM (A=Ob bf16) + residual + LN fused
    gemmx(2, 128, Ob, 0, 0, 1, Wo, x1b, 0, bo, x, 128, 128, gt_g1 + i * 128, gt_be1 + i * 128,
          NA, 128, 128, 128, 128, 128, 1, 0, 0, 0);
    gemmx(1, 64, x1b, 0, 0, 0, Wf1, f1, 1, bf1, 0, 0, 0, 0, 0, NA, 256, 128, 128, 256, 256, 1, 0, 0, 0);
    // FF2 + residual + LN fused (A=f1 bf16)
    gemmx(2, 128, f1, 0, 0, 1, Wf2, louts[i], 0, bf2, x1b, 128, 128, gt_g2 + i * 128, gt_be2 + i * 128,
          NA, 128, 256, 256, 128, 128, 1, 0, 0, 0);
    x = louts[i];
  }
  // 32-34. head
  float* xgt = out + 1 + NA * 4;
  gemmx(1, 64, hA2, outs1, outs2, 0, cat_W, xgt, 0, cat_b, 0, 0, 0, 0, 0,
        NA, 128, 384, 128, 128, 128, 1, 0, 0, 0);
  gemmx(1, 64, xgt, 0, 0, 0, mlp_W1, l1, 0, mlp_b1, 0, 0, 0, 0, 0, NA, 256, 128, 128, 256, 256, 1, 0, 0, 0);
  gemm_k<2><<<dim3(64, 1), 256, 0, stream>>>(l1, mlp_W2, out + 1, mlp_b2, NA, 4, 256, 256, 4, 4);
}

// Round 8
// 777.417 us; speedup vs baseline: 3.6994x; 1.1260x over previous
//
#include <hip/hip_runtime.h>
#include <math.h>

// Problem constants
#define NA   4096
#define NPA  8192
#define NT   4096
#define E_AP 80000
#define E_PA 80000
#define E_TP 160000
#define E_TOT (E_AP + E_TP + E_PA)
#define NSLOT (NPA + NPA + NA)     // 20480 global CSR slots: [ap->paper | tp->paper | pa->author]
#define ASPLIT 4                   // attention key-splits

typedef __attribute__((ext_vector_type(4))) float f32x4;
typedef __attribute__((ext_vector_type(8))) short s16x8;
typedef __attribute__((ext_vector_type(8))) unsigned short u16x8;
typedef unsigned short ushort_t;

__device__ __forceinline__ ushort_t f2bf(float f){
  unsigned u = __float_as_uint(f);
  unsigned r = u + 0x7fffu + ((u >> 16) & 1u);   // RNE
  return (ushort_t)(r >> 16);
}
__device__ __forceinline__ float bf2f(ushort_t u){
  return __uint_as_float(((unsigned)u) << 16);
}

// ---------------------------------------------------------------- f32 GEMM (mlp2 only; row softmax over N=4 + loss finalize)
__global__ __launch_bounds__(256) void gemm_sm4_k(
    const float* __restrict__ A, const float* __restrict__ B, float* __restrict__ C,
    const float* __restrict__ bias, const float* __restrict__ lossAcc, float* __restrict__ lossOut,
    int M, int N, int K, int lda, int ldb, int ldc)
{
  if (blockIdx.x == 0 && threadIdx.x == 0)
    lossOut[0] = lossAcc[0] * (1.0f / 67108864.0f);
  __shared__ float As[16][68];
  __shared__ float Bs[16][68];
  int bm = blockIdx.x * 64, bn = 0;
  int tid = threadIdx.x;
  int tr = tid >> 4, tc = tid & 15;
  float acc[4][4] = {{0.f}};
  for (int k0 = 0; k0 < K; k0 += 16) {
#pragma unroll
    for (int i = 0; i < 4; ++i) {
      int idx = tid + i * 256;
      int r  = idx >> 4, kk = idx & 15;
      int gr = bm + r, gk = k0 + kk;
      As[kk][r] = (gr < M && gk < K) ? A[(size_t)gr * lda + gk] : 0.f;
      int c  = idx & 63, k2 = idx >> 6;
      int gc = bn + c, gk2 = k0 + k2;
      Bs[k2][c] = (gk2 < K && gc < N) ? B[(size_t)gk2 * ldb + gc] : 0.f;
    }
    __syncthreads();
#pragma unroll
    for (int kk = 0; kk < 16; ++kk) {
      float a0[4], b0[4];
#pragma unroll
      for (int i = 0; i < 4; ++i) a0[i] = As[kk][tr * 4 + i];
#pragma unroll
      for (int j = 0; j < 4; ++j) b0[j] = Bs[kk][tc * 4 + j];
#pragma unroll
      for (int i = 0; i < 4; ++i)
#pragma unroll
        for (int j = 0; j < 4; ++j) acc[i][j] = fmaf(a0[i], b0[j], acc[i][j]);
    }
    __syncthreads();
  }
  if (tc != 0) return;
#pragma unroll
  for (int i = 0; i < 4; ++i) {
    int r = bm + tr * 4 + i;
    if (r >= M) continue;
    float l0 = acc[i][0] + bias[0], l1 = acc[i][1] + bias[1];
    float l2 = acc[i][2] + bias[2], l3 = acc[i][3] + bias[3];
    float mx = fmaxf(fmaxf(l0, l1), fmaxf(l2, l3));
    float e0 = __expf(l0 - mx), e1 = __expf(l1 - mx), e2 = __expf(l2 - mx), e3 = __expf(l3 - mx);
    float inv = 1.f / (e0 + e1 + e2 + e3);
    C[(size_t)r * ldc + 0] = e0 * inv;
    C[(size_t)r * ldc + 1] = e1 * inv;
    C[(size_t)r * ldc + 2] = e2 * inv;
    C[(size_t)r * ldc + 3] = e3 * inv;
  }
}

// ---------------------------------------------------------------- bf16 MFMA GEMM (templated)
// Tile 64 x TN x BK32, 4 waves (2x2); TN in {64,128}. Requires M%64==0, N%TN==0.
// ACT: 0 none, 1 relu, 2 LayerNorm over full row (TN==128, grid.y==1, C f32).
// partIn: A-staging computes split-attention combine from partials (K==128, M rows of NA).
template<int ACT, int TN>
__global__ __launch_bounds__(256) void gemm_mfma_k(
    const void* __restrict__ Ain, const void* __restrict__ A2in, const void* __restrict__ A3in,
    int aBf16,
    const float* __restrict__ B, void* __restrict__ Cout, int cBf16,
    const float* __restrict__ bias,
    const float* __restrict__ addmat, int addCols, int addLd,
    const float* __restrict__ lng, const float* __restrict__ lnb,
    const float* __restrict__ partIn,
    int M, int N, int K, int lda, int ldb, int ldc)
{
  const char* A  = (const char*)Ain;
  const char* A2 = (const char*)A2in;
  const char* A3 = (const char*)A3in;
  char* C = (char*)Cout;

  __shared__ __align__(16) ushort_t As[64][40];
  __shared__ __align__(16) ushort_t Bs[TN][40];
  constexpr int NJ = TN / 32;
  int bm = blockIdx.x * 64, bn = blockIdx.y * TN;
  int tid = threadIdx.x;
  int w = tid >> 6, lane = tid & 63, lg = lane >> 4, lid = lane & 15;
  int wm = (w & 1) * 32, wn = (w >> 1) * (TN / 2);
  f32x4 acc[2][NJ];
#pragma unroll
  for (int i = 0; i < 2; ++i)
#pragma unroll
    for (int j = 0; j < NJ; ++j) acc[i][j] = (f32x4){0.f, 0.f, 0.f, 0.f};

  for (int k0 = 0; k0 < K; k0 += 32) {
    {
      int r = tid >> 2, ks = (tid & 3) * 8;
      u16x8 v;
      if (partIn) {
        // split-attention combine: row bm+r, dims kcol..kcol+8 within head kcol>>4
        int row = bm + r;
        int kcol = k0 + ks;
        int h = kcol >> 4, d0 = kcol & 15;
        float mm = -1e30f;
#pragma unroll
        for (int sp = 0; sp < ASPLIT; ++sp)
          mm = fmaxf(mm, partIn[((size_t)(sp * 8 + h) * NA + row) * 18 + 16]);
        float ll = 0.f;
        float a[8];
#pragma unroll
        for (int j = 0; j < 8; ++j) a[j] = 0.f;
#pragma unroll
        for (int sp = 0; sp < ASPLIT; ++sp) {
          const float* pp = partIn + ((size_t)(sp * 8 + h) * NA + row) * 18;
          float wq = __expf(pp[16] - mm);
          ll += pp[17] * wq;
#pragma unroll
          for (int j = 0; j < 8; ++j) a[j] = fmaf(pp[d0 + j], wq, a[j]);
        }
        float inv = 1.f / ll;
#pragma unroll
        for (int j = 0; j < 8; ++j) v[j] = f2bf(a[j] * inv);
      } else {
        int kcol = k0 + ks;
        const char* Ab = A;
        if (A2) { int seg = kcol >> 7; Ab = (seg == 0) ? A : ((seg == 1) ? A2 : A3); kcol &= 127; }
        if (aBf16) {
          v = *(const u16x8*)((const ushort_t*)Ab + (size_t)(bm + (tid >> 2)) * lda + kcol);
        } else {
          const float* ap = (const float*)Ab + (size_t)(bm + (tid >> 2)) * lda + kcol;
#pragma unroll
          for (int j = 0; j < 8; ++j) {
            int gk = k0 + ks + j;
            float fv = (gk < K) ? ap[j] : 0.f;
            v[j] = f2bf(fv);
          }
        }
      }
      *(u16x8*)&As[tid >> 2][ks] = v;
    }
    if (TN == 128) {
      int n = tid >> 1, ks = (tid & 1) * 16;
      ushort_t tmp[16];
#pragma unroll
      for (int j = 0; j < 16; ++j) {
        int gk = k0 + ks + j;
        float fv = (gk < K) ? B[(size_t)gk * ldb + bn + n] : 0.f;
        tmp[j] = f2bf(fv);
      }
      u16x8 v0, v1;
#pragma unroll
      for (int j = 0; j < 8; ++j) { v0[j] = tmp[j]; v1[j] = tmp[8 + j]; }
      *(u16x8*)&Bs[n][ks] = v0;
      *(u16x8*)&Bs[n][ks + 8] = v1;
    } else {
      int n = tid >> 2, ks = (tid & 3) * 8;
      u16x8 v;
#pragma unroll
      for (int j = 0; j < 8; ++j) {
        int gk = k0 + ks + j;
        float fv = (gk < K) ? B[(size_t)gk * ldb + bn + n] : 0.f;
        v[j] = f2bf(fv);
      }
      *(u16x8*)&Bs[n][ks] = v;
    }
    __syncthreads();
    s16x8 a_frag[2], b_frag[NJ];
#pragma unroll
    for (int i = 0; i < 2; ++i) a_frag[i] = *(s16x8*)&As[wm + i * 16 + lid][lg * 8];
#pragma unroll
    for (int j = 0; j < NJ; ++j) b_frag[j] = *(s16x8*)&Bs[wn + j * 16 + lid][lg * 8];
#pragma unroll
    for (int i = 0; i < 2; ++i)
#pragma unroll
      for (int j = 0; j < NJ; ++j)
        acc[i][j] = __builtin_amdgcn_mfma_f32_16x16x32_bf16(a_frag[i], b_frag[j], acc[i][j], 0, 0, 0);
    __syncthreads();
  }
  if (ACT == 2) {
    // fused LayerNorm: TN==128, grid.y==1, C f32
    __shared__ float Ct[64][132];
#pragma unroll
    for (int i = 0; i < 2; ++i) {
#pragma unroll
      for (int j = 0; j < NJ; ++j) {
        int coll = wn + j * 16 + lid;
#pragma unroll
        for (int rr = 0; rr < 4; ++rr) {
          int rowl = wm + i * 16 + lg * 4 + rr;
          float v = acc[i][j][rr];
          if (bias) v += bias[coll];
          if (addmat && coll < addCols) v += addmat[(size_t)(bm + rowl) * addLd + coll];
          Ct[rowl][coll] = v;
        }
      }
    }
    __syncthreads();
    int row = tid >> 2, part = tid & 3;
    float s = 0.f, q = 0.f;
#pragma unroll
    for (int c2 = 0; c2 < 32; ++c2) {
      float v = Ct[row][part * 32 + c2];
      s += v; q += v * v;
    }
    s += __shfl_xor(s, 1); q += __shfl_xor(q, 1);
    s += __shfl_xor(s, 2); q += __shfl_xor(q, 2);
    float mean = s * (1.f / 128.f);
    float var = q * (1.f / 128.f) - mean * mean;
    float inv = rsqrtf(var + 1e-5f);
    int r = bm + row;
    float* Cf = (float*)C;
#pragma unroll
    for (int c2 = 0; c2 < 32; ++c2) {
      int c = part * 32 + c2;
      Cf[(size_t)r * ldc + c] = (Ct[row][c] - mean) * inv * lng[c] + lnb[c];
    }
  } else {
#pragma unroll
    for (int i = 0; i < 2; ++i) {
#pragma unroll
      for (int j = 0; j < NJ; ++j) {
        int c = bn + wn + j * 16 + lid;
#pragma unroll
        for (int rr = 0; rr < 4; ++rr) {
          int r = bm + wm + i * 16 + lg * 4 + rr;
          float v = acc[i][j][rr];
          if (bias)   v += bias[c];
          if (addmat && c < addCols) v += addmat[(size_t)r * addLd + c];
          if (ACT == 1) v = fmaxf(v, 0.f);
          if (cBf16) ((ushort_t*)C)[(size_t)r * ldc + c] = f2bf(v);
          else       ((float*)C)[(size_t)r * ldc + c] = v;
        }
      }
    }
  }
}

// ---------------------------------------------------------------- descriptor multi-GEMM (TN=64, runtime params)
struct GDesc {
  const void* A; const void* A2;
  const float* B; void* C;
  const float* bias;
  int aBf16, cBf16, act;
  int M, N, K, lda, ldb, ldc;
  int nz, aOffZ, bOffZ, cOffZ;
  int tileStart;
};
struct GDescArr { GDesc d[4]; int nd; };

__global__ __launch_bounds__(256) void gemm_multi_k(GDescArr da){
  int t = blockIdx.x;
  int di = 0;
#pragma unroll
  for (int i = 1; i < 4; ++i) if (i < da.nd && t >= da.d[i].tileStart) di = i;
  const int aBf16 = da.d[di].aBf16, cBf16 = da.d[di].cBf16, act = da.d[di].act;
  const int M = da.d[di].M, N = da.d[di].N, K = da.d[di].K;
  const int lda = da.d[di].lda, ldb = da.d[di].ldb, ldc = da.d[di].ldc;
  int local = t - da.d[di].tileStart;
  int tM = M >> 6;
  int perZ = tM * (N >> 6);
  int z = local / perZ, rem = local - z * perZ;
  int bm = (rem % tM) * 64, bn = (rem / tM) * 64;
  int asz = aBf16 ? 2 : 4;
  const char* A  = (const char*)da.d[di].A  + (size_t)z * da.d[di].aOffZ * asz;
  const char* A2 = da.d[di].A2 ? (const char*)da.d[di].A2 + (size_t)z * da.d[di].aOffZ * asz : nullptr;
  const float* B = da.d[di].B + (size_t)z * da.d[di].bOffZ;
  char* C = (char*)da.d[di].C + (size_t)z * da.d[di].cOffZ * (cBf16 ? 2 : 4);
  const float* bias = da.d[di].bias ? da.d[di].bias + (size_t)z * da.d[di].cOffZ : nullptr;

  __shared__ __align__(16) ushort_t As[64][40];
  __shared__ __align__(16) ushort_t Bs[64][40];
  int tid = threadIdx.x;
  int w = tid >> 6, lane = tid & 63, lg = lane >> 4, lid = lane & 15;
  int wm = (w & 1) * 32, wn = (w >> 1) * 32;
  f32x4 acc[2][2];
#pragma unroll
  for (int i = 0; i < 2; ++i)
#pragma unroll
    for (int j = 0; j < 2; ++j) acc[i][j] = (f32x4){0.f, 0.f, 0.f, 0.f};

  for (int k0 = 0; k0 < K; k0 += 32) {
    {
      int r = tid >> 2, ks = (tid & 3) * 8;
      int kcol = k0 + ks;
      const char* Ab = A;
      if (A2) { int seg = kcol >> 7; Ab = seg ? A2 : A; kcol &= 127; }
      u16x8 v;
      if (aBf16) {
        v = *(const u16x8*)((const ushort_t*)Ab + (size_t)(bm + r) * lda + kcol);
      } else {
        const float* ap = (const float*)Ab + (size_t)(bm + r) * lda + kcol;
#pragma unroll
        for (int j = 0; j < 8; ++j) {
          int gk = k0 + ks + j;
          float fv = (gk < K) ? ap[j] : 0.f;
          v[j] = f2bf(fv);
        }
      }
      *(u16x8*)&As[r][ks] = v;
    }
    {
      int n = tid >> 2, ks = (tid & 3) * 8;
      u16x8 v;
#pragma unroll
      for (int j = 0; j < 8; ++j) {
        int gk = k0 + ks + j;
        float fv = (gk < K) ? B[(size_t)gk * ldb + bn + n] : 0.f;
        v[j] = f2bf(fv);
      }
      *(u16x8*)&Bs[n][ks] = v;
    }
    __syncthreads();
    s16x8 a_frag[2], b_frag[2];
#pragma unroll
    for (int i = 0; i < 2; ++i) a_frag[i] = *(s16x8*)&As[wm + i * 16 + lid][lg * 8];
#pragma unroll
    for (int j = 0; j < 2; ++j) b_frag[j] = *(s16x8*)&Bs[wn + j * 16 + lid][lg * 8];
#pragma unroll
    for (int i = 0; i < 2; ++i)
#pragma unroll
      for (int j = 0; j < 2; ++j)
        acc[i][j] = __builtin_amdgcn_mfma_f32_16x16x32_bf16(a_frag[i], b_frag[j], acc[i][j], 0, 0, 0);
    __syncthreads();
  }
#pragma unroll
  for (int i = 0; i < 2; ++i) {
#pragma unroll
    for (int j = 0; j < 2; ++j) {
      int c = bn + wn + j * 16 + lid;
#pragma unroll
      for (int rr = 0; rr < 4; ++rr) {
        int r = bm + wm + i * 16 + lg * 4 + rr;
        float v = acc[i][j][rr];
        if (bias) v += bias[c];
        if (act == 1) v = fmaxf(v, 0.f);
        if (cBf16) ((ushort_t*)C)[(size_t)r * ldc + c] = f2bf(v);
        else       ((float*)C)[(size_t)r * ldc + c] = v;
      }
    }
  }
}

// ---------------------------------------------------------------- prep: packs + proj3 + db + histogram
// sections: bsum[1024] | Wqkv[2*128*384] | bqkv[2*384] | peW[128*256] | Bstack[256*1024]
//         | dbv[4096] | proj3[3072] | hist[E_TOT]
__global__ void prep_k(const float* __restrict__ gat1_b, const float* __restrict__ gat1_W,
                       const float* __restrict__ Wq, const float* __restrict__ bq,
                       const float* __restrict__ Wk, const float* __restrict__ bk,
                       const float* __restrict__ Wv, const float* __restrict__ bv,
                       const float* __restrict__ peWQ, const float* __restrict__ peWK,
                       const int* __restrict__ deg,
                       const float* __restrict__ gat1_as, const float* __restrict__ gat1_ad,
                       const int* __restrict__ ap_dst, const int* __restrict__ tp_dst,
                       const int* __restrict__ pa_dst,
                       float* __restrict__ bsum, float* __restrict__ Wqkv,
                       float* __restrict__ bqkv, float* __restrict__ peW,
                       float* __restrict__ Bstack, float* __restrict__ dbv,
                       float* __restrict__ Ps, float* __restrict__ Pd,
                       int* __restrict__ cnt)
{
  int idx = blockIdx.x * blockDim.x + threadIdx.x;
  if (idx < 1024) { bsum[idx] = gat1_b[idx] + gat1_b[3 * 1024 + idx]; return; }
  idx -= 1024;
  if (idx < 2 * 128 * 384) {
    int l = idx / 49152, rem = idx % 49152;
    int k = rem / 384, c = rem % 384;
    float v;
    if (c < 128)      v = Wq[(size_t)l * 16384 + k * 128 + c];
    else if (c < 256) v = Wk[(size_t)l * 16384 + k * 128 + c - 128];
    else              v = Wv[(size_t)l * 16384 + k * 128 + c - 256];
    Wqkv[(size_t)l * 49152 + k * 384 + c] = v;
    return;
  }
  idx -= 2 * 128 * 384;
  if (idx < 2 * 384) {
    int l = idx / 384, c = idx % 384;
    float v;
    if (c < 128)      v = bq[l * 128 + c];
    else if (c < 256) v = bk[l * 128 + c - 128];
    else              v = bv[l * 128 + c - 256];
    bqkv[l * 384 + c] = v;
    return;
  }
  idx -= 2 * 384;
  if (idx < 128 * 256) {
    int k = idx / 256, c = idx % 256;
    peW[k * 256 + c] = (c < 128) ? peWQ[k * 128 + c] : peWK[k * 128 + c - 128];
    return;
  }
  idx -= 128 * 256;
  if (idx < 256 * 1024) {
    int k = idx / 1024, c = idx % 1024;
    Bstack[idx] = (k < 128) ? gat1_W[(size_t)k * 1024 + c]
                            : gat1_W[(size_t)3 * 131072 + (size_t)(k - 128) * 1024 + c];
    return;
  }
  idx -= 256 * 1024;
  if (idx < NA) { dbv[idx] = logf(fmaxf((float)deg[idx], 1.f)); return; }
  idx -= NA;
  if (idx < 3 * 1024) {
    const int wsel[3] = {0, 3, 1};
    int type = idx / 1024, rem = idx % 1024;
    int k = rem >> 3, h = rem & 7;
    const float* wr = gat1_W + (size_t)wsel[type] * 131072 + (size_t)k * 1024 + h * 128;
    const float* a1 = gat1_as + wsel[type] * 1024 + h * 128;
    const float* a2 = gat1_ad + wsel[type] * 1024 + h * 128;
    float s1 = 0.f, s2 = 0.f;
    for (int c = 0; c < 128; ++c){ float wv = wr[c]; s1 = fmaf(wv, a1[c], s1); s2 = fmaf(wv, a2[c], s2); }
    Ps[(size_t)type * 1024 + k * 8 + h] = s1;
    Pd[(size_t)type * 1024 + k * 8 + h] = s2;
    return;
  }
  idx -= 3 * 1024;
  if (idx < E_TOT) {
    int slot;
    if (idx < E_AP)             slot = ap_dst[idx];
    else if (idx < E_AP + E_TP) slot = NPA + tp_dst[idx - E_AP];
    else                        slot = 2 * NPA + pa_dst[idx - E_AP - E_TP];
    atomicAdd(&cnt[slot], 1);
  }
}

// ---------------------------------------------------------------- CSR build pieces
__global__ void scatterf_k(const int* __restrict__ ap_dst, const int* __restrict__ tp_dst,
                           const int* __restrict__ pa_dst, const int* __restrict__ off,
                           int* __restrict__ cur, int* __restrict__ eidx){
  int i = blockIdx.x * blockDim.x + threadIdx.x;
  if (i >= E_TOT) return;
  int slot, local;
  if (i < E_AP)             { local = i;                 slot = ap_dst[local]; }
  else if (i < E_AP + E_TP) { local = i - E_AP;          slot = NPA + tp_dst[local]; }
  else                      { local = i - E_AP - E_TP;   slot = 2 * NPA + pa_dst[local]; }
  int p = atomicAdd(&cur[slot], 1);
  eidx[off[slot] + p] = local;
}

__global__ __launch_bounds__(1024) void exscan_k(const int* __restrict__ in, int* __restrict__ out, int n){
  __shared__ int wsum[16];
  __shared__ int carrySh;
  int t = threadIdx.x, w = t >> 6, lane = t & 63;
  if (t == 0) carrySh = 0;
  __syncthreads();
  for (int base = 0; base < n; base += 1024){
    int carry = carrySh;
    int v = (base + t < n) ? in[base + t] : 0;
    int sc = v;
#pragma unroll
    for (int o2 = 1; o2 < 64; o2 <<= 1){
      int u = __shfl_up(sc, o2);
      if (lane >= o2) sc += u;
    }
    if (lane == 63) wsum[w] = sc;
    __syncthreads();
    int wadd = 0;
#pragma unroll
    for (int i = 0; i < 15; ++i) if (i < w) wadd += wsum[i];
    if (base + t < n) out[base + t] = carry + wadd + sc - v;
    if (t == 1023) carrySh = carry + wadd + sc;
    __syncthreads();
  }
}

// ---------------------------------------------------------------- GAT pieces
// batched row-dot scores (x bf16): 6 segments -> scores[36864][8]
__global__ __launch_bounds__(256) void scorev_k(
    const ushort_t* __restrict__ xa, const ushort_t* __restrict__ xp, const ushort_t* __restrict__ xt,
    const float* __restrict__ Ps, const float* __restrict__ Pd, float* __restrict__ scores)
{
  int r = blockIdx.x * 4 + (threadIdx.x >> 6);
  int lane = threadIdx.x & 63;
  const ushort_t* x; const float* P; int row;
  if (r < 4096)       { x = xa; P = Ps;        row = r; }
  else if (r < 12288) { x = xp; P = Pd;        row = r - 4096; }
  else if (r < 16384) { x = xt; P = Ps + 1024; row = r - 12288; }
  else if (r < 24576) { x = xp; P = Pd + 1024; row = r - 16384; }
  else if (r < 32768) { x = xp; P = Ps + 2048; row = r - 24576; }
  else                { x = xa; P = Pd + 2048; row = r - 32768; }
  unsigned u = *(const unsigned*)(x + (size_t)row * 128 + 2 * lane);
  float x0 = bf2f((ushort_t)(u & 0xffff));
  float x1 = bf2f((ushort_t)(u >> 16));
  float res[8];
#pragma unroll
  for (int h = 0; h < 8; ++h) {
    float s = x0 * P[(2 * lane) * 8 + h] + x1 * P[(2 * lane + 1) * 8 + h];
#pragma unroll
    for (int o = 32; o; o >>= 1) s += __shfl_down(s, o);
    res[h] = s;
  }
  if (lane == 0) {
#pragma unroll
    for (int h = 0; h < 8; ++h) scores[(size_t)r * 8 + h] = res[h];
  }
}

// fused online edge-softmax + x-space aggregation; one wave per slot; single pass
__global__ __launch_bounds__(256) void agg8ff_k(
    const int* __restrict__ eidx, const int* __restrict__ off, const int* __restrict__ cnt,
    const int* __restrict__ ap_src, const int* __restrict__ tp_src, const int* __restrict__ pa_src,
    const ushort_t* __restrict__ xa, const ushort_t* __restrict__ xt, const ushort_t* __restrict__ xp,
    const float* __restrict__ scores, ushort_t* __restrict__ agg)
{
  int g = blockIdx.x * 4 + (threadIdx.x >> 6);
  if (g >= NSLOT) return;
  const int* src; const ushort_t* x; const float* ssb; const float* sdb; int d;
  if (g < NPA)          { src = ap_src; x = xa; ssb = scores;                     sdb = scores + (size_t)4096 * 8;  d = g; }
  else if (g < 2 * NPA) { src = tp_src; x = xt; ssb = scores + (size_t)12288 * 8; sdb = scores + (size_t)16384 * 8; d = g - NPA; }
  else                  { src = pa_src; x = xp; ssb = scores + (size_t)24576 * 8; sdb = scores + (size_t)32768 * 8; d = g - 2 * NPA; }
  int lane = threadIdx.x & 63;
  int hh = lane & 7;
  float sdv = sdb[(size_t)d * 8 + hh];
  int base = off[g], n = cnt[g];
  float mh = -1e30f, den = 0.f;
  float acc0[8], acc1[8];
#pragma unroll
  for (int h2 = 0; h2 < 8; ++h2){ acc0[h2] = 0.f; acc1[h2] = 0.f; }
  int e = (n > 0) ? eidx[base] : 0;
  int s = (n > 0) ? src[e] : 0;
  for (int k = 0; k < n; ++k){
    int en = 0, sn = 0;
    if (k + 1 < n){ en = eidx[base + k + 1]; sn = src[en]; }
    float v = ssb[(size_t)s * 8 + hh] + sdv;
    v = v > 0.f ? v : 0.2f * v;
    float mn = fmaxf(mh, v);
    float sc = __expf(mh - mn);
    float wv_ = __expf(v - mn);
    den = den * sc + wv_;
    mh = mn;
    unsigned u = *(const unsigned*)(x + (size_t)s * 128 + 2 * lane);
    float xv0 = bf2f((ushort_t)(u & 0xffff));
    float xv1 = bf2f((ushort_t)(u >> 16));
#pragma unroll
    for (int h2 = 0; h2 < 8; ++h2){
      float sch = __shfl(sc, h2);
      float wh = __shfl(wv_, h2);
      acc0[h2] = fmaf(wh, xv0, acc0[h2] * sch);
      acc1[h2] = fmaf(wh, xv1, acc1[h2] * sch);
    }
    e = en; s = sn;
  }
  ushort_t* o = agg + (size_t)g * 1024;
#pragma unroll
  for (int h2 = 0; h2 < 8; ++h2){
    float dh = __shfl(den, h2) + 1e-16f;
    unsigned pk = (unsigned)f2bf(acc0[h2] / dh) | ((unsigned)f2bf(acc1[h2] / dh) << 16);
    *(unsigned*)(o + h2 * 128 + 2 * lane) = pk;
  }
}

// fused online H=1 softmax+aggregation (gat2); hs bf16 -> out f32
// sArr: [0,8192)=paper(src) scores, [8192,12288)=author(dst) scores
__global__ __launch_bounds__(256) void gat_agg1f_k(
    const int* __restrict__ eidx, const int* __restrict__ off, const int* __restrict__ cnt,
    const int* __restrict__ src, const ushort_t* __restrict__ hs,
    const float* __restrict__ sArr,
    const float* __restrict__ bias, float* __restrict__ outp, int Ndst)
{
  int d = blockIdx.x * 4 + (threadIdx.x >> 6);
  if (d >= Ndst) return;
  int lane = threadIdx.x & 63;
  float sdv = sArr[8192 + d];
  int base = off[d], n = cnt[d];
  float mh = -1e30f, den = 0.f, a0 = 0.f, a1 = 0.f;
  int e = (n > 0) ? eidx[base] : 0;
  int s = (n > 0) ? src[e] : 0;
  for (int k = 0; k < n; ++k){
    int en = 0, sn = 0;
    if (k + 1 < n){ en = eidx[base + k + 1]; sn = src[en]; }
    float v = sArr[s] + sdv;
    v = v > 0.f ? v : 0.2f * v;
    float mn = fmaxf(mh, v);
    float sc = __expf(mh - mn);
    float w_ = __expf(v - mn);
    den = den * sc + w_;
    mh = mn;
    unsigned u = *(const unsigned*)(hs + (size_t)s * 128 + 2 * lane);
    a0 = fmaf(w_, bf2f((ushort_t)(u & 0xffff)), a0 * sc);
    a1 = fmaf(w_, bf2f((ushort_t)(u >> 16)), a1 * sc);
    e = en; s = sn;
  }
  float inv = 1.f / (den + 1e-16f);
  outp[(size_t)d * 128 + 2 * lane]     = a0 * inv + bias[2 * lane];
  outp[(size_t)d * 128 + 2 * lane + 1] = a1 * inv + bias[2 * lane + 1];
}

// batched rowdots for gat2 (X bf16): rows [0,8192)=hs2 w/ va, [8192,12288)=hd2 w/ vb
__global__ __launch_bounds__(256) void rowdot2_k(const ushort_t* __restrict__ X,
    const float* __restrict__ va, const float* __restrict__ vb, float* __restrict__ out){
  int r = blockIdx.x * 4 + (threadIdx.x >> 6);
  int lane = threadIdx.x & 63;
  const float* v = (r < 8192) ? va : vb;
  unsigned u = *(const unsigned*)(X + (size_t)r * 128 + 2 * lane);
  float s = bf2f((ushort_t)(u & 0xffff)) * v[2 * lane]
          + bf2f((ushort_t)(u >> 16)) * v[2 * lane + 1];
#pragma unroll
  for (int o = 32; o; o >>= 1) s += __shfl_down(s, o);
  if (lane == 0) out[r] = s;
}

// ---------------------------------------------------------------- PE loss (MFMA + LDS-staged sigmoid + coalesced A4 sweep)
__global__ __launch_bounds__(256) void loss_mfma_k(const float* __restrict__ peQ,
    const float* __restrict__ peK, const float* __restrict__ A4, float* __restrict__ lossAcc)
{
  __shared__ __align__(16) ushort_t As[64][40];
  __shared__ __align__(16) ushort_t Bs[128][40];
  __shared__ float sig[64][128];
  __shared__ float red[256];
  int br = blockIdx.x * 64, bc = blockIdx.y * 128;
  int tid = threadIdx.x;
  int w = tid >> 6, lane = tid & 63, lg = lane >> 4, lid = lane & 15;
  int wm = (w & 1) * 32, wn = (w >> 1) * 64;
  f32x4 acc[2][4];
#pragma unroll
  for (int i = 0; i < 2; ++i)
#pragma unroll
    for (int j = 0; j < 4; ++j) acc[i][j] = (f32x4){0.f, 0.f, 0.f, 0.f};

  for (int k0 = 0; k0 < 128; k0 += 32) {
    {
      int r = tid >> 2, ks = (tid & 3) * 8;
      const float* ap = peQ + (size_t)(br + r) * 256 + k0 + ks;
      u16x8 v;
#pragma unroll
      for (int j = 0; j < 8; ++j) v[j] = f2bf(ap[j]);
      *(u16x8*)&As[r][ks] = v;
    }
    {
      int n = tid >> 1, ks = (tid & 1) * 16;
      const float* bp = peK + (size_t)(bc + n) * 256 + k0 + ks;
      u16x8 v0, v1;
#pragma unroll
      for (int j = 0; j < 8; ++j) { v0[j] = f2bf(bp[j]); v1[j] = f2bf(bp[8 + j]); }
      *(u16x8*)&Bs[n][ks] = v0;
      *(u16x8*)&Bs[n][ks + 8] = v1;
    }
    __syncthreads();
    s16x8 a_frag[2], b_frag[4];
#pragma unroll
    for (int i = 0; i < 2; ++i) a_frag[i] = *(s16x8*)&As[wm + i * 16 + lid][lg * 8];
#pragma unroll
    for (int j = 0; j < 4; ++j) b_frag[j] = *(s16x8*)&Bs[wn + j * 16 + lid][lg * 8];
#pragma unroll
    for (int i = 0; i < 2; ++i)
#pragma unroll
      for (int j = 0; j < 4; ++j)
        acc[i][j] = __builtin_amdgcn_mfma_f32_16x16x32_bf16(a_frag[i], b_frag[j], acc[i][j], 0, 0, 0);
    __syncthreads();
  }
  // stage sigmoid(S) into LDS
#pragma unroll
  for (int i = 0; i < 2; ++i) {
#pragma unroll
    for (int rr = 0; rr < 4; ++rr) {
      int row = wm + i * 16 + lg * 4 + rr;
#pragma unroll
      for (int j = 0; j < 4; ++j) {
        int col = wn + j * 16 + lid;
        sig[row][col] = 1.f / (1.f + __expf(-acc[i][j][rr]));
      }
    }
  }
  __syncthreads();
  // coalesced float4 sweep over 4 adjacency planes
  float err = 0.f;
#pragma unroll
  for (int it = 0; it < 8; ++it) {
    int idx = tid + it * 256;          // 0..2047
    int rr = idx >> 5, c4 = idx & 31;
    float4 s4 = *(const float4*)&sig[rr][c4 * 4];
    size_t o = (size_t)(br + rr) * 4096 + bc + c4 * 4;
#pragma unroll
    for (int q = 0; q < 4; ++q) {
      float4 a = *(const float4*)&A4[(size_t)q * 16777216 + o];
      float d0 = s4.x - a.x, d1 = s4.y - a.y, d2 = s4.z - a.z, d3 = s4.w - a.w;
      err += d0 * d0 + d1 * d1 + d2 * d2 + d3 * d3;
    }
  }
  red[tid] = err;
  __syncthreads();
  for (int o = 128; o; o >>= 1){
    if (tid < o) red[tid] += red[tid + o];
    __syncthreads();
  }
  if (tid == 0) atomicAdd(lossAcc, red[0]);
}

// ---------------------------------------------------------------- MFMA flash attention (bf16 QKV packed, ld=384)
__global__ __launch_bounds__(256) void attn_mfma_k(
    const ushort_t* __restrict__ Q, const ushort_t* __restrict__ K, const ushort_t* __restrict__ V,
    const float* __restrict__ dbv, float* __restrict__ part)
{
  const int ld = 384;
  int h = blockIdx.y, sp = blockIdx.z;
  int qbase = blockIdx.x * 64;
  int tid = threadIdx.x;
  int w = tid >> 6, lane = tid & 63, lid = lane & 15, lg = lane >> 4;
  __shared__ __align__(16) ushort_t Vt[16][72];
  __shared__ __align__(16) ushort_t Pl[4][16][72];
  __shared__ float dbs[64];

  s16x8 qf;
  if (lg < 2) {
    u16x8 v = *(const u16x8*)(Q + (size_t)(qbase + 16 * w + lid) * ld + h * 16 + 8 * lg);
#pragma unroll
    for (int j = 0; j < 8; ++j) v[j] = f2bf(bf2f(v[j]) * 0.25f);  // exact pow2 scale
    qf = (s16x8)v;
  } else {
    qf = (s16x8){0,0,0,0,0,0,0,0};
  }

  float m = -1e30f, l = 0.f;
  f32x4 o = {0.f, 0.f, 0.f, 0.f};

  int kb0 = sp * (4096 / ASPLIT);
  for (int kt = 0; kt < 4096 / ASPLIT; kt += 64) {
    int kb = kb0 + kt;
    __syncthreads();
    {
      int key = tid >> 2, ds_ = (tid & 3) * 4;
      const ushort_t* vp = V + (size_t)(kb + key) * ld + h * 16 + ds_;
#pragma unroll
      for (int j = 0; j < 4; ++j) Vt[ds_ + j][key] = vp[j];
      if (tid < 64) dbs[tid] = dbv[kb + tid];
    }
    __syncthreads();

    f32x4 s[4];
#pragma unroll
    for (int g = 0; g < 4; ++g) {
      s16x8 kf;
      if (lg < 2) {
        kf = (s16x8)(*(const u16x8*)(K + (size_t)(kb + 16 * g + lid) * ld + h * 16 + 8 * lg));
      } else kf = (s16x8){0,0,0,0,0,0,0,0};
      s[g] = __builtin_amdgcn_mfma_f32_16x16x32_bf16(kf, qf, (f32x4){0.f,0.f,0.f,0.f}, 0, 0, 0);
    }
#pragma unroll
    for (int g = 0; g < 4; ++g)
#pragma unroll
      for (int r = 0; r < 4; ++r) s[g][r] += dbs[16 * g + 4 * lg + r];

    float tmax = -1e30f;
#pragma unroll
    for (int g = 0; g < 4; ++g)
#pragma unroll
      for (int r = 0; r < 4; ++r) tmax = fmaxf(tmax, s[g][r]);
    tmax = fmaxf(tmax, __shfl_xor(tmax, 16));
    tmax = fmaxf(tmax, __shfl_xor(tmax, 32));
    float mn = fmaxf(m, tmax);
    float scale = __expf(m - mn);
    float psum = 0.f;
    float p[4][4];
#pragma unroll
    for (int g = 0; g < 4; ++g)
#pragma unroll
      for (int r = 0; r < 4; ++r) { p[g][r] = __expf(s[g][r] - mn); psum += p[g][r]; }
    psum += __shfl_xor(psum, 16);
    psum += __shfl_xor(psum, 32);
    l = l * scale + psum;
    m = mn;

#pragma unroll
    for (int g = 0; g < 4; ++g) {
#pragma unroll
      for (int rp = 0; rp < 4; rp += 2) {
        unsigned pack = (unsigned)f2bf(p[g][rp]) | ((unsigned)f2bf(p[g][rp + 1]) << 16);
        *(unsigned*)&Pl[w][lid][16 * g + 4 * lg + rp] = pack;
      }
    }
#pragma unroll
    for (int r = 0; r < 4; ++r) o[r] *= __shfl(scale, 4 * lg + r);
#pragma unroll
    for (int kc = 0; kc < 2; ++kc) {
      s16x8 pa = *(s16x8*)&Pl[w][lid][32 * kc + 8 * lg];
      s16x8 vb = *(s16x8*)&Vt[lid][32 * kc + 8 * lg];
      o = __builtin_amdgcn_mfma_f32_16x16x32_bf16(pa, vb, o, 0, 0, 0);
    }
  }
  float* pb = part + ((size_t)(sp * 8 + h) * NA) * 18;
#pragma unroll
  for (int r = 0; r < 4; ++r) {
    int qq = qbase + 16 * w + 4 * lg + r;
    pb[(size_t)qq * 18 + lid] = o[r];
  }
  if (lg == 0) {
    int qq = qbase + 16 * w + lid;
    pb[(size_t)qq * 18 + 16] = m;
    pb[(size_t)qq * 18 + 17] = l;
  }
}

__global__ void setval_k(float* p, float v){ p[0] = v; }

// ---------------------------------------------------------------- host
extern "C" void kernel_launch(void* const* d_in, const int* in_sizes, int n_in,
                              void* d_out, int out_size, void* d_ws, size_t ws_size,
                              hipStream_t stream)
{
  (void)in_sizes; (void)n_in; (void)out_size;
  const float* x_author = (const float*)d_in[0];
  const float* x_paper  = (const float*)d_in[1];
  const float* x_term   = (const float*)d_in[2];
  const int* ap_src = (const int*)d_in[3];
  const int* ap_dst = (const int*)d_in[4];
  const int* pa_src = (const int*)d_in[5];
  const int* pa_dst = (const int*)d_in[6];
  const int* tp_src = (const int*)d_in[9];
  const int* tp_dst = (const int*)d_in[10];
  const float* original_A = (const float*)d_in[11];
  const int* deg = (const int*)d_in[12];
  const float* t1_W = (const float*)d_in[13]; const float* t1_b = (const float*)d_in[14];
  const float* t2_W = (const float*)d_in[15]; const float* t2_b = (const float*)d_in[16];
  const float* t3_W = (const float*)d_in[17]; const float* t3_b = (const float*)d_in[18];
  const float* gat1_W  = (const float*)d_in[19];
  const float* gat1_as = (const float*)d_in[20];
  const float* gat1_ad = (const float*)d_in[21];
  const float* gat1_b  = (const float*)d_in[22];
  const float* gat2_W  = (const float*)d_in[23];
  const float* gat2_as = (const float*)d_in[24];
  const float* gat2_ad = (const float*)d_in[25];
  const float* gat2_b  = (const float*)d_in[26];
  const float* pe_embed = (const float*)d_in[27];
  const float* peWQ = (const float*)d_in[28];
  const float* peWK = (const float*)d_in[29];
  const float* gt_Wq = (const float*)d_in[30]; const float* gt_bq = (const float*)d_in[31];
  const float* gt_Wk = (const float*)d_in[32]; const float* gt_bk = (const float*)d_in[33];
  const float* gt_Wv = (const float*)d_in[34]; const float* gt_bv = (const float*)d_in[35];
  const float* gt_Wo = (const float*)d_in[36]; const float* gt_bo = (const float*)d_in[37];
  const float* gt_g1 = (const float*)d_in[38]; const float* gt_be1 = (const float*)d_in[39];
  const float* gt_Wf1 = (const float*)d_in[40]; const float* gt_bf1 = (const float*)d_in[41];
  const float* gt_Wf2 = (const float*)d_in[42]; const float* gt_bf2 = (const float*)d_in[43];
  const float* gt_g2 = (const float*)d_in[44]; const float* gt_be2 = (const float*)d_in[45];
  const float* cat_W = (const float*)d_in[46]; const float* cat_b = (const float*)d_in[47];
  const float* mlp_W1 = (const float*)d_in[48]; const float* mlp_b1 = (const float*)d_in[49];
  const float* mlp_W2 = (const float*)d_in[50]; const float* mlp_b2 = (const float*)d_in[51];
  float* out = (float*)d_out;

  // ---- workspace layout ----
  char* base = (char*)d_ws;
  size_t off = 0;
  auto alloc = [&](size_t nbytes) -> void* {
    void* p = base + off;
    off += (nbytes + 255) & ~(size_t)255;
    return p;
  };
  ushort_t* xa  = (ushort_t*)alloc((size_t)NA * 128 * 2);    // bf16
  ushort_t* xp  = (ushort_t*)alloc((size_t)NPA * 128 * 2);
  ushort_t* xt  = (ushort_t*)alloc((size_t)NT * 128 * 2);
  ushort_t* accP = (ushort_t*)alloc((size_t)NPA * 1024 * 2); // bf16; +accA contiguous; aliased as attn part
  ushort_t* accA = (ushort_t*)alloc((size_t)NA * 1024 * 2);
  ushort_t* agg  = (ushort_t*)alloc((size_t)NSLOT * 1024 * 2); // bf16
  float* scores = (float*)alloc((size_t)36864 * 8 * 4);
  float* Ps   = (float*)alloc(3 * 1024 * 4);
  float* Pd   = (float*)alloc(3 * 1024 * 4);
  ushort_t* hs2 = (ushort_t*)alloc((size_t)NPA * 128 * 2);   // bf16; +hd2 contiguous
  ushort_t* hd2 = (ushort_t*)alloc((size_t)NA * 128 * 2);
  float* s2sd = (float*)alloc((size_t)(NPA + NA) * 4);
  float* hA2  = (float*)alloc((size_t)NA * 128 * 4);
  float* peQK = (float*)alloc((size_t)NA * 256 * 4);
  float* dbv  = (float*)alloc((size_t)NA * 4);
  float* bsum = (float*)alloc(1024 * 4);
  float* Wqkv = (float*)alloc((size_t)2 * 128 * 384 * 4);
  float* bqkv = (float*)alloc((size_t)2 * 384 * 4);
  float* peW  = (float*)alloc((size_t)128 * 256 * 4);
  float* Bstack = (float*)alloc((size_t)256 * 1024 * 4);
  ushort_t* QKVb = (ushort_t*)alloc((size_t)NA * 384 * 2);   // bf16
  float* x1b  = (float*)alloc((size_t)NA * 128 * 4);
  ushort_t* f1 = (ushort_t*)alloc((size_t)NA * 256 * 2);     // bf16
  float* outs1= (float*)alloc((size_t)NA * 128 * 4);
  float* outs2= (float*)alloc((size_t)NA * 128 * 4);
  float* l1   = (float*)alloc((size_t)NA * 256 * 4);
  int*   offb = (int*)alloc((size_t)NSLOT * 4);
  int*   eidx = (int*)alloc((size_t)E_TOT * 4);
  // ---- zero-init region (single small memset): cnt, cur, lossAcc ----
  size_t zstart = off;
  int*      cnt   = (int*)alloc((size_t)NSLOT * 4);
  int*      cur   = (int*)alloc((size_t)NSLOT * 4);
  float*    lossAcc = (float*)alloc(256);
  size_t zlen = off - zstart;

  float* part = (float*)accP;  // 9.4 MB f32 partials alias onto accP+accA (dead by transformer)

  if (off > ws_size){
    setval_k<<<1, 1, 0, stream>>>(out, -12345.0f);
    return;
  }

  auto gemmx = [&](int act, int tn, const void* A, const void* A2, const void* A3, int aBf16,
                   const float* B, void* C, int cBf16, const float* bias,
                   const float* addmat, int addCols, int addLd,
                   const float* lng, const float* lnb, const float* partIn,
                   int M, int N, int K, int lda, int ldb, int ldc){
    dim3 g(M / 64, N / tn, 1);
    if (tn == 128) {
      if (act == 0)      gemm_mfma_k<0,128><<<g, 256, 0, stream>>>(A, A2, A3, aBf16, B, C, cBf16, bias, addmat, addCols, addLd, lng, lnb, partIn, M, N, K, lda, ldb, ldc);
      else if (act == 1) gemm_mfma_k<1,128><<<g, 256, 0, stream>>>(A, A2, A3, aBf16, B, C, cBf16, bias, addmat, addCols, addLd, lng, lnb, partIn, M, N, K, lda, ldb, ldc);
      else               gemm_mfma_k<2,128><<<g, 256, 0, stream>>>(A, A2, A3, aBf16, B, C, cBf16, bias, addmat, addCols, addLd, lng, lnb, partIn, M, N, K, lda, ldb, ldc);
    } else {
      if (act == 0)      gemm_mfma_k<0,64><<<g, 256, 0, stream>>>(A, A2, A3, aBf16, B, C, cBf16, bias, addmat, addCols, addLd, lng, lnb, partIn, M, N, K, lda, ldb, ldc);
      else               gemm_mfma_k<1,64><<<g, 256, 0, stream>>>(A, A2, A3, aBf16, B, C, cBf16, bias, addmat, addCols, addLd, lng, lnb, partIn, M, N, K, lda, ldb, ldc);
    }
  };

  // 1. zero-init (tiny)
  hipMemsetAsync(base + zstart, 0, zlen, stream);
  // 2. prep: packs + db + proj3 + histogram
  prep_k<<<2822, 256, 0, stream>>>(gat1_b, gat1_W, gt_Wq, gt_bq, gt_Wk, gt_bk, gt_Wv, gt_bv,
                                   peWQ, peWK, deg, gat1_as, gat1_ad, ap_dst, tp_dst, pa_dst,
                                   bsum, Wqkv, bqkv, peW, Bstack, dbv, Ps, Pd, cnt);
  // 3. D1 mega-GEMM: 3 stage-0 MLPs + peQK (768 tiles)
  {
    GDescArr da; da.nd = 4;
    da.d[0] = { x_author, nullptr, t1_W, xa, t1_b, 0, 1, 1, NA, 128, 334, 334, 128, 128, 1, 0, 0, 0, 0 };
    da.d[1] = { x_paper,  nullptr, t2_W, xp, t2_b, 0, 1, 1, NPA, 128, 512, 512, 128, 128, 1, 0, 0, 0, 128 };
    da.d[2] = { x_term,   nullptr, t3_W, xt, t3_b, 0, 1, 1, NT, 128, 128, 128, 128, 128, 1, 0, 0, 0, 384 };
    da.d[3] = { pe_embed, nullptr, peW, peQK, nullptr, 0, 0, 0, NA, 256, 128, 128, 256, 256, 1, 0, 0, 0, 512 };
    gemm_multi_k<<<768, 256, 0, stream>>>(da);
  }
  // 4-5. CSR scan + scatter
  exscan_k<<<1, 1024, 0, stream>>>(cnt, offb, NSLOT);
  scatterf_k<<<(E_TOT + 255) / 256, 256, 0, stream>>>(ap_dst, tp_dst, pa_dst, offb, cur, eidx);
  // 6-7. GAT1: scores, fused online softmax+aggregate
  scorev_k<<<9216, 256, 0, stream>>>(xa, xp, xt, Ps, Pd, scores);
  agg8ff_k<<<NSLOT / 4, 256, 0, stream>>>(eidx, offb, cnt, ap_src, tp_src, pa_src,
                                          xa, xt, xp, scores, agg);
  // 8. D2 mega-GEMM: GAT1 per-head transforms (paper K=256 stacked, author K=128) — 3072 tiles
  {
    GDescArr da; da.nd = 2;
    da.d[0] = { agg, agg + (size_t)NPA * 1024, Bstack, accP, bsum, 1, 1, 1,
                NPA, 128, 256, 1024, 1024, 1024, 8, 128, 128, 128, 0 };
    da.d[1] = { agg + (size_t)2 * NPA * 1024, nullptr, gat1_W + 131072, accA, gat1_b + 1024, 1, 1, 1,
                NA, 128, 128, 1024, 1024, 1024, 8, 128, 128, 128, 2048 };
    gemm_multi_k<<<3072, 256, 0, stream>>>(da);
  }
  // 9-11. GAT2
  gemmx(0, 64, accP, 0, 0, 1, gat2_W + 131072, hs2, 1, 0, 0, 0, 0, 0, 0, 0,
        NPA + NA, 128, 1024, 1024, 128, 128);
  rowdot2_k<<<(NPA + NA) / 4, 256, 0, stream>>>(hs2, gat2_as + 128, gat2_ad + 128, s2sd);
  gat_agg1f_k<<<NA / 4, 256, 0, stream>>>(eidx, offb + 2 * NPA, cnt + 2 * NPA, pa_src, hs2, s2sd,
                                          gat2_b + 128, hA2, NA);
  // 12. PE reconstruction loss
  loss_mfma_k<<<dim3(64, 32), 256, 0, stream>>>(peQK, peQK + 128, original_A, lossAcc);
  // 13-22. graph transformer (2 layers x 5 dispatches)
  const float* x = hA2;
  float* louts[2] = { outs1, outs2 };
  for (int i = 0; i < 2; ++i){
    const float* Wo = gt_Wo + i * 16384; const float* bo = gt_bo + i * 128;
    const float* Wf1 = gt_Wf1 + i * 32768; const float* bf1 = gt_bf1 + i * 256;
    const float* Wf2 = gt_Wf2 + i * 32768; const float* bf2 = gt_bf2 + i * 128;
    // QKV fused (bf16 out): C=[Q|K|V], addmat=peQK for cols<256
    gemmx(0, 64, x, 0, 0, 0, Wqkv + (size_t)i * 49152, QKVb, 1, bqkv + i * 384, peQK, 256, 256,
          0, 0, 0, NA, 384, 128, 128, 384, 384);
    attn_mfma_k<<<dim3(NA / 64, 8, ASPLIT), 256, 0, stream>>>(QKVb, QKVb + 128, QKVb + 256, dbv, part);
    // Wo GEMM with fused split-combine A-staging + residual + LN
    gemmx(2, 128, nullptr, 0, 0, 0, Wo, x1b, 0, bo, x, 128, 128, gt_g1 + i * 128, gt_be1 + i * 128,
          part, NA, 128, 128, 128, 128, 128);
    gemmx(1, 64, x1b, 0, 0, 0, Wf1, f1, 1, bf1, 0, 0, 0, 0, 0, 0, NA, 256, 128, 128, 256, 256);
    // FF2 + residual + LN fused (A=f1 bf16)
    gemmx(2, 128, f1, 0, 0, 1, Wf2, louts[i], 0, bf2, x1b, 128, 128, gt_g2 + i * 128, gt_be2 + i * 128,
          0, NA, 128, 256, 256, 128, 128);
    x = louts[i];
  }
  // 23-25. head (concat folded into A-staging; softmax + loss-finalize folded into mlp2)
  float* xgt = out + 1 + NA * 4;
  gemmx(1, 64, hA2, outs1, outs2, 0, cat_W, xgt, 0, cat_b, 0, 0, 0, 0, 0, 0,
        NA, 128, 384, 128, 128, 128);
  gemmx(1, 64, xgt, 0, 0, 0, mlp_W1, l1, 0, mlp_b1, 0, 0, 0, 0, 0, 0, NA, 256, 128, 128, 256, 256);
  gemm_sm4_k<<<64, 256, 0, stream>>>(l1, mlp_W2, out + 1, mlp_b2, lossAcc, out, NA, 4, 256, 256, 4, 4);
}

// Round 9
// 646.173 us; speedup vs baseline: 4.4508x; 1.2031x over previous
//
#include <hip/hip_runtime.h>
#include <math.h>

// Problem constants
#define NA   4096
#define NPA  8192
#define NT   4096
#define E_AP 80000
#define E_PA 80000
#define E_TP 160000
#define E_TOT (E_AP + E_TP + E_PA)
#define NSLOT (NPA + NPA + NA)     // 20480 global CSR slots: [ap->paper | tp->paper | pa->author]
#define ASPLIT 4                   // attention key-splits

typedef __attribute__((ext_vector_type(4))) float f32x4;
typedef __attribute__((ext_vector_type(8))) short s16x8;
typedef __attribute__((ext_vector_type(8))) unsigned short u16x8;
typedef unsigned short ushort_t;

__device__ __forceinline__ ushort_t f2bf(float f){
  unsigned u = __float_as_uint(f);
  unsigned r = u + 0x7fffu + ((u >> 16) & 1u);   // RNE
  return (ushort_t)(r >> 16);
}
__device__ __forceinline__ float bf2f(ushort_t u){
  return __uint_as_float(((unsigned)u) << 16);
}

// ---------------------------------------------------------------- bf16 MFMA GEMM (templated)
// Tile 64 x TN x BK32, 4 waves (2x2); TN in {64,128}. Requires M%64==0, N%TN==0.
// ACT: 0 none, 1 relu, 2 LayerNorm full row (TN==128, grid.y==1, C f32),
//      3 bf16-C + per-row dot with lng (rows<8192) / lnb into rdOut (TN==128, grid.y==1).
template<int ACT, int TN>
__global__ __launch_bounds__(256) void gemm_mfma_k(
    const void* __restrict__ Ain, const void* __restrict__ A2in, const void* __restrict__ A3in,
    int aBf16,
    const float* __restrict__ B, void* __restrict__ Cout, int cBf16,
    const float* __restrict__ bias,
    const float* __restrict__ addmat, int addCols, int addLd,
    const float* __restrict__ lng, const float* __restrict__ lnb,
    float* __restrict__ rdOut,
    int M, int N, int K, int lda, int ldb, int ldc)
{
  const char* A  = (const char*)Ain;
  const char* A2 = (const char*)A2in;
  const char* A3 = (const char*)A3in;
  char* C = (char*)Cout;

  __shared__ __align__(16) ushort_t As[64][40];
  __shared__ __align__(16) ushort_t Bs[TN][40];
  constexpr int NJ = TN / 32;
  int bm = blockIdx.x * 64, bn = blockIdx.y * TN;
  int tid = threadIdx.x;
  int w = tid >> 6, lane = tid & 63, lg = lane >> 4, lid = lane & 15;
  int wm = (w & 1) * 32, wn = (w >> 1) * (TN / 2);
  f32x4 acc[2][NJ];
#pragma unroll
  for (int i = 0; i < 2; ++i)
#pragma unroll
    for (int j = 0; j < NJ; ++j) acc[i][j] = (f32x4){0.f, 0.f, 0.f, 0.f};

  for (int k0 = 0; k0 < K; k0 += 32) {
    {
      int r = tid >> 2, ks = (tid & 3) * 8;
      int kcol = k0 + ks;
      const char* Ab = A;
      if (A2) { int seg = kcol >> 7; Ab = (seg == 0) ? A : ((seg == 1) ? A2 : A3); kcol &= 127; }
      u16x8 v;
      if (aBf16) {
        v = *(const u16x8*)((const ushort_t*)Ab + (size_t)(bm + r) * lda + kcol);
      } else {
        const float* ap = (const float*)Ab + (size_t)(bm + r) * lda + kcol;
#pragma unroll
        for (int j = 0; j < 8; ++j) {
          int gk = k0 + ks + j;
          float fv = (gk < K) ? ap[j] : 0.f;
          v[j] = f2bf(fv);
        }
      }
      *(u16x8*)&As[r][ks] = v;
    }
    if (TN == 128) {
      int n = tid >> 1, ks = (tid & 1) * 16;
      ushort_t tmp[16];
#pragma unroll
      for (int j = 0; j < 16; ++j) {
        int gk = k0 + ks + j;
        float fv = (gk < K) ? B[(size_t)gk * ldb + bn + n] : 0.f;
        tmp[j] = f2bf(fv);
      }
      u16x8 v0, v1;
#pragma unroll
      for (int j = 0; j < 8; ++j) { v0[j] = tmp[j]; v1[j] = tmp[8 + j]; }
      *(u16x8*)&Bs[n][ks] = v0;
      *(u16x8*)&Bs[n][ks + 8] = v1;
    } else {
      int n = tid >> 2, ks = (tid & 3) * 8;
      u16x8 v;
#pragma unroll
      for (int j = 0; j < 8; ++j) {
        int gk = k0 + ks + j;
        float fv = (gk < K) ? B[(size_t)gk * ldb + bn + n] : 0.f;
        v[j] = f2bf(fv);
      }
      *(u16x8*)&Bs[n][ks] = v;
    }
    __syncthreads();
    s16x8 a_frag[2], b_frag[NJ];
#pragma unroll
    for (int i = 0; i < 2; ++i) a_frag[i] = *(s16x8*)&As[wm + i * 16 + lid][lg * 8];
#pragma unroll
    for (int j = 0; j < NJ; ++j) b_frag[j] = *(s16x8*)&Bs[wn + j * 16 + lid][lg * 8];
#pragma unroll
    for (int i = 0; i < 2; ++i)
#pragma unroll
      for (int j = 0; j < NJ; ++j)
        acc[i][j] = __builtin_amdgcn_mfma_f32_16x16x32_bf16(a_frag[i], b_frag[j], acc[i][j], 0, 0, 0);
    __syncthreads();
  }
  if constexpr (ACT == 2) {
    // fused LayerNorm: TN==128, grid.y==1, C f32
    __shared__ float Ct[64][132];
#pragma unroll
    for (int i = 0; i < 2; ++i) {
#pragma unroll
      for (int j = 0; j < NJ; ++j) {
        int coll = wn + j * 16 + lid;
#pragma unroll
        for (int rr = 0; rr < 4; ++rr) {
          int rowl = wm + i * 16 + lg * 4 + rr;
          float v = acc[i][j][rr];
          if (bias) v += bias[coll];
          if (addmat && coll < addCols) v += addmat[(size_t)(bm + rowl) * addLd + coll];
          Ct[rowl][coll] = v;
        }
      }
    }
    __syncthreads();
    int row = tid >> 2, part = tid & 3;
    float s = 0.f, q = 0.f;
#pragma unroll
    for (int c2 = 0; c2 < 32; ++c2) {
      float v = Ct[row][part * 32 + c2];
      s += v; q += v * v;
    }
    s += __shfl_xor(s, 1); q += __shfl_xor(q, 1);
    s += __shfl_xor(s, 2); q += __shfl_xor(q, 2);
    float mean = s * (1.f / 128.f);
    float var = q * (1.f / 128.f) - mean * mean;
    float inv = rsqrtf(var + 1e-5f);
    int r = bm + row;
    float* Cf = (float*)C;
#pragma unroll
    for (int c2 = 0; c2 < 32; ++c2) {
      int c = part * 32 + c2;
      Cf[(size_t)r * ldc + c] = (Ct[row][c] - mean) * inv * lng[c] + lnb[c];
    }
  } else if constexpr (ACT == 3) {
    // bf16 C + per-row dot: TN==128, grid.y==1
    __shared__ float Ct[64][132];
#pragma unroll
    for (int i = 0; i < 2; ++i) {
#pragma unroll
      for (int j = 0; j < NJ; ++j) {
        int coll = wn + j * 16 + lid;
#pragma unroll
        for (int rr = 0; rr < 4; ++rr) {
          int rowl = wm + i * 16 + lg * 4 + rr;
          Ct[rowl][coll] = acc[i][j][rr];
        }
      }
    }
    __syncthreads();
    int row = tid >> 2, part = tid & 3;
    const float* vsel = (bm + row < 8192) ? lng : lnb;
    float rd = 0.f;
    ushort_t* Cu = (ushort_t*)C;
#pragma unroll
    for (int c2 = 0; c2 < 32; ++c2) {
      int c = part * 32 + c2;
      float f = Ct[row][c];
      rd = fmaf(f, vsel[c], rd);
      Cu[(size_t)(bm + row) * ldc + c] = f2bf(f);
    }
    rd += __shfl_xor(rd, 1);
    rd += __shfl_xor(rd, 2);
    if (part == 0) rdOut[bm + row] = rd;
  } else {
#pragma unroll
    for (int i = 0; i < 2; ++i) {
#pragma unroll
      for (int j = 0; j < NJ; ++j) {
        int c = bn + wn + j * 16 + lid;
#pragma unroll
        for (int rr = 0; rr < 4; ++rr) {
          int r = bm + wm + i * 16 + lg * 4 + rr;
          float v = acc[i][j][rr];
          if (bias)   v += bias[c];
          if (addmat && c < addCols) v += addmat[(size_t)r * addLd + c];
          if (ACT == 1) v = fmaxf(v, 0.f);
          if (cBf16) ((ushort_t*)C)[(size_t)r * ldc + c] = f2bf(v);
          else       ((float*)C)[(size_t)r * ldc + c] = v;
        }
      }
    }
  }
}

// ---------------------------------------------------------------- descriptor multi-GEMM (TN=64, runtime params)
struct GDesc {
  const void* A; const void* A2;
  const float* B; void* C;
  const float* bias;
  int aBf16, cBf16, act;
  int M, N, K, lda, ldb, ldc;
  int nz, aOffZ, bOffZ, cOffZ;
  int tileStart;
};
struct GDescArr { GDesc d[4]; int nd; };

__global__ __launch_bounds__(256) void gemm_multi_k(GDescArr da){
  int t = blockIdx.x;
  int di = 0;
#pragma unroll
  for (int i = 1; i < 4; ++i) if (i < da.nd && t >= da.d[i].tileStart) di = i;
  const int aBf16 = da.d[di].aBf16, cBf16 = da.d[di].cBf16, act = da.d[di].act;
  const int M = da.d[di].M, N = da.d[di].N, K = da.d[di].K;
  const int lda = da.d[di].lda, ldb = da.d[di].ldb, ldc = da.d[di].ldc;
  int local = t - da.d[di].tileStart;
  int tM = M >> 6;
  int perZ = tM * (N >> 6);
  int z = local / perZ, rem = local - z * perZ;
  int bm = (rem % tM) * 64, bn = (rem / tM) * 64;
  int asz = aBf16 ? 2 : 4;
  const char* A  = (const char*)da.d[di].A  + (size_t)z * da.d[di].aOffZ * asz;
  const char* A2 = da.d[di].A2 ? (const char*)da.d[di].A2 + (size_t)z * da.d[di].aOffZ * asz : nullptr;
  const float* B = da.d[di].B + (size_t)z * da.d[di].bOffZ;
  char* C = (char*)da.d[di].C + (size_t)z * da.d[di].cOffZ * (cBf16 ? 2 : 4);
  const float* bias = da.d[di].bias ? da.d[di].bias + (size_t)z * da.d[di].cOffZ : nullptr;

  __shared__ __align__(16) ushort_t As[64][40];
  __shared__ __align__(16) ushort_t Bs[64][40];
  int tid = threadIdx.x;
  int w = tid >> 6, lane = tid & 63, lg = lane >> 4, lid = lane & 15;
  int wm = (w & 1) * 32, wn = (w >> 1) * 32;
  f32x4 acc[2][2];
#pragma unroll
  for (int i = 0; i < 2; ++i)
#pragma unroll
    for (int j = 0; j < 2; ++j) acc[i][j] = (f32x4){0.f, 0.f, 0.f, 0.f};

  for (int k0 = 0; k0 < K; k0 += 32) {
    {
      int r = tid >> 2, ks = (tid & 3) * 8;
      int kcol = k0 + ks;
      const char* Ab = A;
      if (A2) { int seg = kcol >> 7; Ab = seg ? A2 : A; kcol &= 127; }
      u16x8 v;
      if (aBf16) {
        v = *(const u16x8*)((const ushort_t*)Ab + (size_t)(bm + r) * lda + kcol);
      } else {
        const float* ap = (const float*)Ab + (size_t)(bm + r) * lda + kcol;
#pragma unroll
        for (int j = 0; j < 8; ++j) {
          int gk = k0 + ks + j;
          float fv = (gk < K) ? ap[j] : 0.f;
          v[j] = f2bf(fv);
        }
      }
      *(u16x8*)&As[r][ks] = v;
    }
    {
      int n = tid >> 2, ks = (tid & 3) * 8;
      u16x8 v;
#pragma unroll
      for (int j = 0; j < 8; ++j) {
        int gk = k0 + ks + j;
        float fv = (gk < K) ? B[(size_t)gk * ldb + bn + n] : 0.f;
        v[j] = f2bf(fv);
      }
      *(u16x8*)&Bs[n][ks] = v;
    }
    __syncthreads();
    s16x8 a_frag[2], b_frag[2];
#pragma unroll
    for (int i = 0; i < 2; ++i) a_frag[i] = *(s16x8*)&As[wm + i * 16 + lid][lg * 8];
#pragma unroll
    for (int j = 0; j < 2; ++j) b_frag[j] = *(s16x8*)&Bs[wn + j * 16 + lid][lg * 8];
#pragma unroll
    for (int i = 0; i < 2; ++i)
#pragma unroll
      for (int j = 0; j < 2; ++j)
        acc[i][j] = __builtin_amdgcn_mfma_f32_16x16x32_bf16(a_frag[i], b_frag[j], acc[i][j], 0, 0, 0);
    __syncthreads();
  }
#pragma unroll
  for (int i = 0; i < 2; ++i) {
#pragma unroll
    for (int j = 0; j < 2; ++j) {
      int c = bn + wn + j * 16 + lid;
#pragma unroll
      for (int rr = 0; rr < 4; ++rr) {
        int r = bm + wm + i * 16 + lg * 4 + rr;
        float v = acc[i][j][rr];
        if (bias) v += bias[c];
        if (act == 1) v = fmaxf(v, 0.f);
        if (cBf16) ((ushort_t*)C)[(size_t)r * ldc + c] = f2bf(v);
        else       ((float*)C)[(size_t)r * ldc + c] = v;
      }
    }
  }
}

// ---------------------------------------------------------------- prep: packs + proj3 + db + histogram + transposed bf16 weights
// sections: bsum[1024] | Wqkv[98304] | bqkv[768] | peW[32768] | Bstack[262144]
//         | dbv[4096] | proj3[3072] | hist[E_TOT]
//         | Wot[32768] | Wf1t[65536] | Wf2t[65536] | catt[49152] | mlp1t[32768]
__global__ void prep_k(const float* __restrict__ gat1_b, const float* __restrict__ gat1_W,
                       const float* __restrict__ Wq, const float* __restrict__ bq,
                       const float* __restrict__ Wk, const float* __restrict__ bk,
                       const float* __restrict__ Wv, const float* __restrict__ bv,
                       const float* __restrict__ peWQ, const float* __restrict__ peWK,
                       const int* __restrict__ deg,
                       const float* __restrict__ gat1_as, const float* __restrict__ gat1_ad,
                       const int* __restrict__ ap_dst, const int* __restrict__ tp_dst,
                       const int* __restrict__ pa_dst,
                       const float* __restrict__ gt_Wo, const float* __restrict__ gt_Wf1,
                       const float* __restrict__ gt_Wf2, const float* __restrict__ cat_W,
                       const float* __restrict__ mlp_W1,
                       float* __restrict__ bsum, float* __restrict__ Wqkv,
                       float* __restrict__ bqkv, float* __restrict__ peW,
                       float* __restrict__ Bstack, float* __restrict__ dbv,
                       float* __restrict__ Ps, float* __restrict__ Pd,
                       int* __restrict__ cnt,
                       ushort_t* __restrict__ Wot, ushort_t* __restrict__ Wf1t,
                       ushort_t* __restrict__ Wf2t, ushort_t* __restrict__ catt,
                       ushort_t* __restrict__ mlp1t)
{
  int idx = blockIdx.x * blockDim.x + threadIdx.x;
  if (idx < 1024) { bsum[idx] = gat1_b[idx] + gat1_b[3 * 1024 + idx]; return; }
  idx -= 1024;
  if (idx < 2 * 128 * 384) {
    int l = idx / 49152, rem = idx % 49152;
    int k = rem / 384, c = rem % 384;
    float v;
    if (c < 128)      v = Wq[(size_t)l * 16384 + k * 128 + c];
    else if (c < 256) v = Wk[(size_t)l * 16384 + k * 128 + c - 128];
    else              v = Wv[(size_t)l * 16384 + k * 128 + c - 256];
    Wqkv[(size_t)l * 49152 + k * 384 + c] = v;
    return;
  }
  idx -= 2 * 128 * 384;
  if (idx < 2 * 384) {
    int l = idx / 384, c = idx % 384;
    float v;
    if (c < 128)      v = bq[l * 128 + c];
    else if (c < 256) v = bk[l * 128 + c - 128];
    else              v = bv[l * 128 + c - 256];
    bqkv[l * 384 + c] = v;
    return;
  }
  idx -= 2 * 384;
  if (idx < 128 * 256) {
    int k = idx / 256, c = idx % 256;
    peW[k * 256 + c] = (c < 128) ? peWQ[k * 128 + c] : peWK[k * 128 + c - 128];
    return;
  }
  idx -= 128 * 256;
  if (idx < 256 * 1024) {
    int k = idx / 1024, c = idx % 1024;
    Bstack[idx] = (k < 128) ? gat1_W[(size_t)k * 1024 + c]
                            : gat1_W[(size_t)3 * 131072 + (size_t)(k - 128) * 1024 + c];
    return;
  }
  idx -= 256 * 1024;
  if (idx < NA) { dbv[idx] = logf(fmaxf((float)deg[idx], 1.f)); return; }
  idx -= NA;
  if (idx < 3 * 1024) {
    const int wsel[3] = {0, 3, 1};
    int type = idx / 1024, rem = idx % 1024;
    int k = rem >> 3, h = rem & 7;
    const float* wr = gat1_W + (size_t)wsel[type] * 131072 + (size_t)k * 1024 + h * 128;
    const float* a1 = gat1_as + wsel[type] * 1024 + h * 128;
    const float* a2 = gat1_ad + wsel[type] * 1024 + h * 128;
    float s1 = 0.f, s2 = 0.f;
    for (int c = 0; c < 128; ++c){ float wv = wr[c]; s1 = fmaf(wv, a1[c], s1); s2 = fmaf(wv, a2[c], s2); }
    Ps[(size_t)type * 1024 + k * 8 + h] = s1;
    Pd[(size_t)type * 1024 + k * 8 + h] = s2;
    return;
  }
  idx -= 3 * 1024;
  if (idx < E_TOT) {
    int slot;
    if (idx < E_AP)             slot = ap_dst[idx];
    else if (idx < E_AP + E_TP) slot = NPA + tp_dst[idx - E_AP];
    else                        slot = 2 * NPA + pa_dst[idx - E_AP - E_TP];
    atomicAdd(&cnt[slot], 1);
    return;
  }
  idx -= E_TOT;
  if (idx < 2 * 128 * 128) {  // Wot[l][n][k] = Wo[l][k][n]
    int l = idx / 16384, rem = idx % 16384;
    int n = rem / 128, k = rem % 128;
    Wot[idx] = f2bf(gt_Wo[(size_t)l * 16384 + k * 128 + n]);
    return;
  }
  idx -= 2 * 128 * 128;
  if (idx < 2 * 256 * 128) {  // Wf1t[l][n][k] = Wf1[l][k][n], n<256,k<128
    int l = idx / 32768, rem = idx % 32768;
    int n = rem / 128, k = rem % 128;
    Wf1t[idx] = f2bf(gt_Wf1[(size_t)l * 32768 + k * 256 + n]);
    return;
  }
  idx -= 2 * 256 * 128;
  if (idx < 2 * 128 * 256) {  // Wf2t[l][n][k] = Wf2[l][k][n], n<128,k<256
    int l = idx / 32768, rem = idx % 32768;
    int n = rem / 256, k = rem % 256;
    Wf2t[idx] = f2bf(gt_Wf2[(size_t)l * 32768 + k * 128 + n]);
    return;
  }
  idx -= 2 * 128 * 256;
  if (idx < 128 * 384) {      // catt[n][k] = cat_W[k][n], n<128,k<384
    int n = idx / 384, k = idx % 384;
    catt[idx] = f2bf(cat_W[(size_t)k * 128 + n]);
    return;
  }
  idx -= 128 * 384;
  if (idx < 256 * 128) {      // mlp1t[n][k] = mlp_W1[k][n], n<256,k<128
    int n = idx / 128, k = idx % 128;
    mlp1t[idx] = f2bf(mlp_W1[(size_t)k * 256 + n]);
  }
}

// ---------------------------------------------------------------- CSR build pieces
__global__ void scatterf_k(const int* __restrict__ ap_dst, const int* __restrict__ tp_dst,
                           const int* __restrict__ pa_dst, const int* __restrict__ off,
                           int* __restrict__ cur, int* __restrict__ eidx){
  int i = blockIdx.x * blockDim.x + threadIdx.x;
  if (i >= E_TOT) return;
  int slot, local;
  if (i < E_AP)             { local = i;                 slot = ap_dst[local]; }
  else if (i < E_AP + E_TP) { local = i - E_AP;          slot = NPA + tp_dst[local]; }
  else                      { local = i - E_AP - E_TP;   slot = 2 * NPA + pa_dst[local]; }
  int p = atomicAdd(&cur[slot], 1);
  eidx[off[slot] + p] = local;
}

__global__ __launch_bounds__(1024) void exscan_k(const int* __restrict__ in, int* __restrict__ out, int n){
  __shared__ int wsum[16];
  __shared__ int carrySh;
  int t = threadIdx.x, w = t >> 6, lane = t & 63;
  if (t == 0) carrySh = 0;
  __syncthreads();
  for (int base = 0; base < n; base += 1024){
    int carry = carrySh;
    int v = (base + t < n) ? in[base + t] : 0;
    int sc = v;
#pragma unroll
    for (int o2 = 1; o2 < 64; o2 <<= 1){
      int u = __shfl_up(sc, o2);
      if (lane >= o2) sc += u;
    }
    if (lane == 63) wsum[w] = sc;
    __syncthreads();
    int wadd = 0;
#pragma unroll
    for (int i = 0; i < 15; ++i) if (i < w) wadd += wsum[i];
    if (base + t < n) out[base + t] = carry + wadd + sc - v;
    if (t == 1023) carrySh = carry + wadd + sc;
    __syncthreads();
  }
}

// ---------------------------------------------------------------- GAT pieces
__global__ __launch_bounds__(256) void scorev_k(
    const ushort_t* __restrict__ xa, const ushort_t* __restrict__ xp, const ushort_t* __restrict__ xt,
    const float* __restrict__ Ps, const float* __restrict__ Pd, float* __restrict__ scores)
{
  int r = blockIdx.x * 4 + (threadIdx.x >> 6);
  int lane = threadIdx.x & 63;
  const ushort_t* x; const float* P; int row;
  if (r < 4096)       { x = xa; P = Ps;        row = r; }
  else if (r < 12288) { x = xp; P = Pd;        row = r - 4096; }
  else if (r < 16384) { x = xt; P = Ps + 1024; row = r - 12288; }
  else if (r < 24576) { x = xp; P = Pd + 1024; row = r - 16384; }
  else if (r < 32768) { x = xp; P = Ps + 2048; row = r - 24576; }
  else                { x = xa; P = Pd + 2048; row = r - 32768; }
  unsigned u = *(const unsigned*)(x + (size_t)row * 128 + 2 * lane);
  float x0 = bf2f((ushort_t)(u & 0xffff));
  float x1 = bf2f((ushort_t)(u >> 16));
  float res[8];
#pragma unroll
  for (int h = 0; h < 8; ++h) {
    float s = x0 * P[(2 * lane) * 8 + h] + x1 * P[(2 * lane + 1) * 8 + h];
#pragma unroll
    for (int o = 32; o; o >>= 1) s += __shfl_down(s, o);
    res[h] = s;
  }
  if (lane == 0) {
#pragma unroll
    for (int h = 0; h < 8; ++h) scores[(size_t)r * 8 + h] = res[h];
  }
}

// fused online edge-softmax + x-space aggregation; one wave per slot; single pass
__global__ __launch_bounds__(256) void agg8ff_k(
    const int* __restrict__ eidx, const int* __restrict__ off, const int* __restrict__ cnt,
    const int* __restrict__ ap_src, const int* __restrict__ tp_src, const int* __restrict__ pa_src,
    const ushort_t* __restrict__ xa, const ushort_t* __restrict__ xt, const ushort_t* __restrict__ xp,
    const float* __restrict__ scores, ushort_t* __restrict__ agg)
{
  int g = blockIdx.x * 4 + (threadIdx.x >> 6);
  if (g >= NSLOT) return;
  const int* src; const ushort_t* x; const float* ssb; const float* sdb; int d;
  if (g < NPA)          { src = ap_src; x = xa; ssb = scores;                     sdb = scores + (size_t)4096 * 8;  d = g; }
  else if (g < 2 * NPA) { src = tp_src; x = xt; ssb = scores + (size_t)12288 * 8; sdb = scores + (size_t)16384 * 8; d = g - NPA; }
  else                  { src = pa_src; x = xp; ssb = scores + (size_t)24576 * 8; sdb = scores + (size_t)32768 * 8; d = g - 2 * NPA; }
  int lane = threadIdx.x & 63;
  int hh = lane & 7;
  float sdv = sdb[(size_t)d * 8 + hh];
  int base = off[g], n = cnt[g];
  float mh = -1e30f, den = 0.f;
  float acc0[8], acc1[8];
#pragma unroll
  for (int h2 = 0; h2 < 8; ++h2){ acc0[h2] = 0.f; acc1[h2] = 0.f; }
  int e = (n > 0) ? eidx[base] : 0;
  int s = (n > 0) ? src[e] : 0;
  for (int k = 0; k < n; ++k){
    int en = 0, sn = 0;
    if (k + 1 < n){ en = eidx[base + k + 1]; sn = src[en]; }
    float v = ssb[(size_t)s * 8 + hh] + sdv;
    v = v > 0.f ? v : 0.2f * v;
    float mn = fmaxf(mh, v);
    float sc = __expf(mh - mn);
    float wv_ = __expf(v - mn);
    den = den * sc + wv_;
    mh = mn;
    unsigned u = *(const unsigned*)(x + (size_t)s * 128 + 2 * lane);
    float xv0 = bf2f((ushort_t)(u & 0xffff));
    float xv1 = bf2f((ushort_t)(u >> 16));
#pragma unroll
    for (int h2 = 0; h2 < 8; ++h2){
      float sch = __shfl(sc, h2);
      float wh = __shfl(wv_, h2);
      acc0[h2] = fmaf(wh, xv0, acc0[h2] * sch);
      acc1[h2] = fmaf(wh, xv1, acc1[h2] * sch);
    }
    e = en; s = sn;
  }
  ushort_t* o = agg + (size_t)g * 1024;
#pragma unroll
  for (int h2 = 0; h2 < 8; ++h2){
    float dh = __shfl(den, h2) + 1e-16f;
    unsigned pk = (unsigned)f2bf(acc0[h2] / dh) | ((unsigned)f2bf(acc1[h2] / dh) << 16);
    *(unsigned*)(o + h2 * 128 + 2 * lane) = pk;
  }
}

// fused online H=1 softmax+aggregation (gat2); hs bf16 -> out f32
__global__ __launch_bounds__(256) void gat_agg1f_k(
    const int* __restrict__ eidx, const int* __restrict__ off, const int* __restrict__ cnt,
    const int* __restrict__ src, const ushort_t* __restrict__ hs,
    const float* __restrict__ sArr,
    const float* __restrict__ bias, float* __restrict__ outp, int Ndst)
{
  int d = blockIdx.x * 4 + (threadIdx.x >> 6);
  if (d >= Ndst) return;
  int lane = threadIdx.x & 63;
  float sdv = sArr[8192 + d];
  int base = off[d], n = cnt[d];
  float mh = -1e30f, den = 0.f, a0 = 0.f, a1 = 0.f;
  int e = (n > 0) ? eidx[base] : 0;
  int s = (n > 0) ? src[e] : 0;
  for (int k = 0; k < n; ++k){
    int en = 0, sn = 0;
    if (k + 1 < n){ en = eidx[base + k + 1]; sn = src[en]; }
    float v = sArr[s] + sdv;
    v = v > 0.f ? v : 0.2f * v;
    float mn = fmaxf(mh, v);
    float sc = __expf(mh - mn);
    float w_ = __expf(v - mn);
    den = den * sc + w_;
    mh = mn;
    unsigned u = *(const unsigned*)(hs + (size_t)s * 128 + 2 * lane);
    a0 = fmaf(w_, bf2f((ushort_t)(u & 0xffff)), a0 * sc);
    a1 = fmaf(w_, bf2f((ushort_t)(u >> 16)), a1 * sc);
    e = en; s = sn;
  }
  float inv = 1.f / (den + 1e-16f);
  outp[(size_t)d * 128 + 2 * lane]     = a0 * inv + bias[2 * lane];
  outp[(size_t)d * 128 + 2 * lane + 1] = a1 * inv + bias[2 * lane + 1];
}

// ---------------------------------------------------------------- PE loss (MFMA + LDS sigmoid + coalesced A4 sweep)
__global__ __launch_bounds__(256) void loss_mfma_k(const float* __restrict__ peQ,
    const float* __restrict__ peK, const float* __restrict__ A4, float* __restrict__ lossAcc)
{
  __shared__ __align__(16) ushort_t As[64][40];
  __shared__ __align__(16) ushort_t Bs[128][40];
  __shared__ float sig[64][128];
  __shared__ float red[256];
  int br = blockIdx.x * 64, bc = blockIdx.y * 128;
  int tid = threadIdx.x;
  int w = tid >> 6, lane = tid & 63, lg = lane >> 4, lid = lane & 15;
  int wm = (w & 1) * 32, wn = (w >> 1) * 64;
  f32x4 acc[2][4];
#pragma unroll
  for (int i = 0; i < 2; ++i)
#pragma unroll
    for (int j = 0; j < 4; ++j) acc[i][j] = (f32x4){0.f, 0.f, 0.f, 0.f};

  for (int k0 = 0; k0 < 128; k0 += 32) {
    {
      int r = tid >> 2, ks = (tid & 3) * 8;
      const float* ap = peQ + (size_t)(br + r) * 256 + k0 + ks;
      u16x8 v;
#pragma unroll
      for (int j = 0; j < 8; ++j) v[j] = f2bf(ap[j]);
      *(u16x8*)&As[r][ks] = v;
    }
    {
      int n = tid >> 1, ks = (tid & 1) * 16;
      const float* bp = peK + (size_t)(bc + n) * 256 + k0 + ks;
      u16x8 v0, v1;
#pragma unroll
      for (int j = 0; j < 8; ++j) { v0[j] = f2bf(bp[j]); v1[j] = f2bf(bp[8 + j]); }
      *(u16x8*)&Bs[n][ks] = v0;
      *(u16x8*)&Bs[n][ks + 8] = v1;
    }
    __syncthreads();
    s16x8 a_frag[2], b_frag[4];
#pragma unroll
    for (int i = 0; i < 2; ++i) a_frag[i] = *(s16x8*)&As[wm + i * 16 + lid][lg * 8];
#pragma unroll
    for (int j = 0; j < 4; ++j) b_frag[j] = *(s16x8*)&Bs[wn + j * 16 + lid][lg * 8];
#pragma unroll
    for (int i = 0; i < 2; ++i)
#pragma unroll
      for (int j = 0; j < 4; ++j)
        acc[i][j] = __builtin_amdgcn_mfma_f32_16x16x32_bf16(a_frag[i], b_frag[j], acc[i][j], 0, 0, 0);
    __syncthreads();
  }
#pragma unroll
  for (int i = 0; i < 2; ++i) {
#pragma unroll
    for (int rr = 0; rr < 4; ++rr) {
      int row = wm + i * 16 + lg * 4 + rr;
#pragma unroll
      for (int j = 0; j < 4; ++j) {
        int col = wn + j * 16 + lid;
        sig[row][col] = 1.f / (1.f + __expf(-acc[i][j][rr]));
      }
    }
  }
  __syncthreads();
  float err = 0.f;
#pragma unroll
  for (int it = 0; it < 8; ++it) {
    int idx = tid + it * 256;
    int rr = idx >> 5, c4 = idx & 31;
    float4 s4 = *(const float4*)&sig[rr][c4 * 4];
    size_t o = (size_t)(br + rr) * 4096 + bc + c4 * 4;
#pragma unroll
    for (int q = 0; q < 4; ++q) {
      float4 a = *(const float4*)&A4[(size_t)q * 16777216 + o];
      float d0 = s4.x - a.x, d1 = s4.y - a.y, d2 = s4.z - a.z, d3 = s4.w - a.w;
      err += d0 * d0 + d1 * d1 + d2 * d2 + d3 * d3;
    }
  }
  red[tid] = err;
  __syncthreads();
  for (int o = 128; o; o >>= 1){
    if (tid < o) red[tid] += red[tid + o];
    __syncthreads();
  }
  if (tid == 0) atomicAdd(lossAcc, red[0]);
}

// ---------------------------------------------------------------- MFMA flash attention (bf16 QKV packed, ld=384)
__global__ __launch_bounds__(256) void attn_mfma_k(
    const ushort_t* __restrict__ Q, const ushort_t* __restrict__ K, const ushort_t* __restrict__ V,
    const float* __restrict__ dbv, float* __restrict__ part)
{
  const int ld = 384;
  int h = blockIdx.y, sp = blockIdx.z;
  int qbase = blockIdx.x * 64;
  int tid = threadIdx.x;
  int w = tid >> 6, lane = tid & 63, lid = lane & 15, lg = lane >> 4;
  __shared__ __align__(16) ushort_t Vt[16][72];
  __shared__ __align__(16) ushort_t Pl[4][16][72];
  __shared__ float dbs[64];

  s16x8 qf;
  if (lg < 2) {
    u16x8 v = *(const u16x8*)(Q + (size_t)(qbase + 16 * w + lid) * ld + h * 16 + 8 * lg);
#pragma unroll
    for (int j = 0; j < 8; ++j) v[j] = f2bf(bf2f(v[j]) * 0.25f);
    qf = (s16x8)v;
  } else {
    qf = (s16x8){0,0,0,0,0,0,0,0};
  }

  float m = -1e30f, l = 0.f;
  f32x4 o = {0.f, 0.f, 0.f, 0.f};

  int kb0 = sp * (4096 / ASPLIT);
  for (int kt = 0; kt < 4096 / ASPLIT; kt += 64) {
    int kb = kb0 + kt;
    __syncthreads();
    {
      int key = tid >> 2, ds_ = (tid & 3) * 4;
      const ushort_t* vp = V + (size_t)(kb + key) * ld + h * 16 + ds_;
#pragma unroll
      for (int j = 0; j < 4; ++j) Vt[ds_ + j][key] = vp[j];
      if (tid < 64) dbs[tid] = dbv[kb + tid];
    }
    __syncthreads();

    f32x4 s[4];
#pragma unroll
    for (int g = 0; g < 4; ++g) {
      s16x8 kf;
      if (lg < 2) {
        kf = (s16x8)(*(const u16x8*)(K + (size_t)(kb + 16 * g + lid) * ld + h * 16 + 8 * lg));
      } else kf = (s16x8){0,0,0,0,0,0,0,0};
      s[g] = __builtin_amdgcn_mfma_f32_16x16x32_bf16(kf, qf, (f32x4){0.f,0.f,0.f,0.f}, 0, 0, 0);
    }
#pragma unroll
    for (int g = 0; g < 4; ++g)
#pragma unroll
      for (int r = 0; r < 4; ++r) s[g][r] += dbs[16 * g + 4 * lg + r];

    float tmax = -1e30f;
#pragma unroll
    for (int g = 0; g < 4; ++g)
#pragma unroll
      for (int r = 0; r < 4; ++r) tmax = fmaxf(tmax, s[g][r]);
    tmax = fmaxf(tmax, __shfl_xor(tmax, 16));
    tmax = fmaxf(tmax, __shfl_xor(tmax, 32));
    float mn = fmaxf(m, tmax);
    float scale = __expf(m - mn);
    float psum = 0.f;
    float p[4][4];
#pragma unroll
    for (int g = 0; g < 4; ++g)
#pragma unroll
      for (int r = 0; r < 4; ++r) { p[g][r] = __expf(s[g][r] - mn); psum += p[g][r]; }
    psum += __shfl_xor(psum, 16);
    psum += __shfl_xor(psum, 32);
    l = l * scale + psum;
    m = mn;

#pragma unroll
    for (int g = 0; g < 4; ++g) {
#pragma unroll
      for (int rp = 0; rp < 4; rp += 2) {
        unsigned pack = (unsigned)f2bf(p[g][rp]) | ((unsigned)f2bf(p[g][rp + 1]) << 16);
        *(unsigned*)&Pl[w][lid][16 * g + 4 * lg + rp] = pack;
      }
    }
#pragma unroll
    for (int r = 0; r < 4; ++r) o[r] *= __shfl(scale, 4 * lg + r);
#pragma unroll
    for (int kc = 0; kc < 2; ++kc) {
      s16x8 pa = *(s16x8*)&Pl[w][lid][32 * kc + 8 * lg];
      s16x8 vb = *(s16x8*)&Vt[lid][32 * kc + 8 * lg];
      o = __builtin_amdgcn_mfma_f32_16x16x32_bf16(pa, vb, o, 0, 0, 0);
    }
  }
  float* pb = part + ((size_t)(sp * 8 + h) * NA) * 18;
#pragma unroll
  for (int r = 0; r < 4; ++r) {
    int qq = qbase + 16 * w + 4 * lg + r;
    pb[(size_t)qq * 18 + lid] = o[r];
  }
  if (lg == 0) {
    int qq = qbase + 16 * w + lid;
    pb[(size_t)qq * 18 + 16] = m;
    pb[(size_t)qq * 18 + 17] = l;
  }
}

// ---------------------------------------------------------------- fused transformer tail:
// combine(part) -> @Wo + bo + xin -> LN1 -> @Wf1 + bf1, relu -> @Wf2 + bf2 + x1 -> LN2 -> outX
// grid: NA/16 blocks x 256 threads. Weights pre-transposed bf16 [n][k].
__global__ __launch_bounds__(256) void gt_tail_k(
    const float* __restrict__ part,
    const ushort_t* __restrict__ Wot, const float* __restrict__ bo,
    const float* __restrict__ xin,
    const float* __restrict__ g1, const float* __restrict__ be1,
    const ushort_t* __restrict__ Wf1t, const float* __restrict__ bf1,
    const ushort_t* __restrict__ Wf2t, const float* __restrict__ bf2,
    const float* __restrict__ g2, const float* __restrict__ be2,
    float* __restrict__ outX)
{
  __shared__ __align__(16) ushort_t Aly[16][136];
  __shared__ __align__(16) ushort_t Bs[256][40];
  __shared__ __align__(16) ushort_t F1b[16][264];
  __shared__ float X1[16][132];
  int bm = blockIdx.x * 16;
  int tid = threadIdx.x;
  int w = tid >> 6, lane = tid & 63, lg = lane >> 4, lid = lane & 15;

  // phase 0: split-attention combine -> O bf16 (16 x 128)
  {
    int row = bm + (tid >> 4);
    int seg = tid & 15;
    int kcol = seg * 8;
    int h = kcol >> 4, d0 = kcol & 15;
    float mm = -1e30f;
#pragma unroll
    for (int sp = 0; sp < ASPLIT; ++sp)
      mm = fmaxf(mm, part[((size_t)(sp * 8 + h) * NA + row) * 18 + 16]);
    float ll = 0.f, a[8];
#pragma unroll
    for (int j = 0; j < 8; ++j) a[j] = 0.f;
#pragma unroll
    for (int sp = 0; sp < ASPLIT; ++sp){
      const float* pp = part + ((size_t)(sp * 8 + h) * NA + row) * 18;
      float wq = __expf(pp[16] - mm);
      ll += pp[17] * wq;
#pragma unroll
      for (int j = 0; j < 8; ++j) a[j] = fmaf(pp[d0 + j], wq, a[j]);
    }
    float inv = 1.f / ll;
    u16x8 v;
#pragma unroll
    for (int j = 0; j < 8; ++j) v[j] = f2bf(a[j] * inv);
    *(u16x8*)&Aly[tid >> 4][kcol] = v;
  }
  __syncthreads();

  // phase 1: O @ Wo + bo + xin -> X1, LN1 -> Aly(bf16) + X1(f32)
  f32x4 acc1[2];
  acc1[0] = (f32x4){0.f,0.f,0.f,0.f};
  acc1[1] = (f32x4){0.f,0.f,0.f,0.f};
  for (int k0 = 0; k0 < 128; k0 += 32){
    int n = tid >> 1, ks = (tid & 1) * 16;
    *(u16x8*)&Bs[n][ks]     = *(const u16x8*)(Wot + (size_t)n * 128 + k0 + ks);
    *(u16x8*)&Bs[n][ks + 8] = *(const u16x8*)(Wot + (size_t)n * 128 + k0 + ks + 8);
    __syncthreads();
    s16x8 af = *(s16x8*)&Aly[lid][k0 + lg * 8];
#pragma unroll
    for (int j = 0; j < 2; ++j){
      s16x8 bf = *(s16x8*)&Bs[w * 32 + j * 16 + lid][lg * 8];
      acc1[j] = __builtin_amdgcn_mfma_f32_16x16x32_bf16(af, bf, acc1[j], 0, 0, 0);
    }
    __syncthreads();
  }
#pragma unroll
  for (int j = 0; j < 2; ++j)
#pragma unroll
    for (int rr = 0; rr < 4; ++rr){
      int r = lg * 4 + rr, c = w * 32 + j * 16 + lid;
      X1[r][c] = acc1[j][rr] + bo[c] + xin[(size_t)(bm + r) * 128 + c];
    }
  __syncthreads();
  {
    int r = tid >> 4, p = tid & 15;
    float s = 0.f, q = 0.f;
#pragma unroll
    for (int j = 0; j < 8; ++j){ float v = X1[r][p * 8 + j]; s += v; q += v * v; }
#pragma unroll
    for (int mk = 1; mk < 16; mk <<= 1){ s += __shfl_xor(s, mk); q += __shfl_xor(q, mk); }
    float mean = s * (1.f / 128.f), var = q * (1.f / 128.f) - mean * mean;
    float inv = rsqrtf(var + 1e-5f);
    u16x8 v;
#pragma unroll
    for (int j = 0; j < 8; ++j){
      int c = p * 8 + j;
      float f = (X1[r][c] - mean) * inv * g1[c] + be1[c];
      X1[r][c] = f;
      v[j] = f2bf(f);
    }
    *(u16x8*)&Aly[r][p * 8] = v;
  }
  __syncthreads();

  // phase 2: x1 @ Wf1 + bf1, relu -> F1b (16 x 256)
  f32x4 acc2[4];
#pragma unroll
  for (int j = 0; j < 4; ++j) acc2[j] = (f32x4){0.f,0.f,0.f,0.f};
  for (int k0 = 0; k0 < 128; k0 += 32){
#pragma unroll
    for (int q4 = 0; q4 < 4; ++q4)
      *(u16x8*)&Bs[tid][q4 * 8] = *(const u16x8*)(Wf1t + (size_t)tid * 128 + k0 + q4 * 8);
    __syncthreads();
    s16x8 af = *(s16x8*)&Aly[lid][k0 + lg * 8];
#pragma unroll
    for (int j = 0; j < 4; ++j){
      s16x8 bf = *(s16x8*)&Bs[w * 64 + j * 16 + lid][lg * 8];
      acc2[j] = __builtin_amdgcn_mfma_f32_16x16x32_bf16(af, bf, acc2[j], 0, 0, 0);
    }
    __syncthreads();
  }
#pragma unroll
  for (int j = 0; j < 4; ++j)
#pragma unroll
    for (int rr = 0; rr < 4; ++rr){
      int r = lg * 4 + rr, c = w * 64 + j * 16 + lid;
      F1b[r][c] = f2bf(fmaxf(acc2[j][rr] + bf1[c], 0.f));
    }
  __syncthreads();

  // phase 3: f1 @ Wf2 + bf2 + X1 -> LN2 -> outX
  f32x4 acc3[2];
  acc3[0] = (f32x4){0.f,0.f,0.f,0.f};
  acc3[1] = (f32x4){0.f,0.f,0.f,0.f};
  for (int k0 = 0; k0 < 256; k0 += 32){
    int n = tid >> 1, ks = (tid & 1) * 16;
    *(u16x8*)&Bs[n][ks]     = *(const u16x8*)(Wf2t + (size_t)n * 256 + k0 + ks);
    *(u16x8*)&Bs[n][ks + 8] = *(const u16x8*)(Wf2t + (size_t)n * 256 + k0 + ks + 8);
    __syncthreads();
    s16x8 af = *(s16x8*)&F1b[lid][k0 + lg * 8];
#pragma unroll
    for (int j = 0; j < 2; ++j){
      s16x8 bf = *(s16x8*)&Bs[w * 32 + j * 16 + lid][lg * 8];
      acc3[j] = __builtin_amdgcn_mfma_f32_16x16x32_bf16(af, bf, acc3[j], 0, 0, 0);
    }
    __syncthreads();
  }
#pragma unroll
  for (int j = 0; j < 2; ++j)
#pragma unroll
    for (int rr = 0; rr < 4; ++rr){
      int r = lg * 4 + rr, c = w * 32 + j * 16 + lid;
      X1[r][c] = acc3[j][rr] + bf2[c] + X1[r][c];
    }
  __syncthreads();
  {
    int r = tid >> 4, p = tid & 15;
    float s = 0.f, q = 0.f;
#pragma unroll
    for (int j = 0; j < 8; ++j){ float v = X1[r][p * 8 + j]; s += v; q += v * v; }
#pragma unroll
    for (int mk = 1; mk < 16; mk <<= 1){ s += __shfl_xor(s, mk); q += __shfl_xor(q, mk); }
    float mean = s * (1.f / 128.f), var = q * (1.f / 128.f) - mean * mean;
    float inv = rsqrtf(var + 1e-5f);
#pragma unroll
    for (int j = 0; j < 8; ++j){
      int c = p * 8 + j;
      outX[(size_t)(bm + r) * 128 + c] = (X1[r][c] - mean) * inv * g2[c] + be2[c];
    }
  }
}

// ---------------------------------------------------------------- fused head:
// cat(hA2|o1|o2) -> @cat_W relu (writes x_gt) -> @mlp_W1 relu -> @mlp_W2 + softmax -> probs
__global__ __launch_bounds__(256) void head_k(
    const float* __restrict__ hA2, const float* __restrict__ o1, const float* __restrict__ o2,
    const ushort_t* __restrict__ catt, const float* __restrict__ cat_b,
    const ushort_t* __restrict__ mlp1t, const float* __restrict__ mlp_b1,
    const float* __restrict__ mlp_W2, const float* __restrict__ mlp_b2,
    const float* __restrict__ lossAcc, float* __restrict__ out)
{
  __shared__ __align__(16) ushort_t Aly[16][392];
  __shared__ __align__(16) ushort_t Bs[256][40];
  __shared__ __align__(16) ushort_t L1b[16][264];
  __shared__ float LG[16][4];
  int bm = blockIdx.x * 16;
  int tid = threadIdx.x;
  int w = tid >> 6, lane = tid & 63, lg = lane >> 4, lid = lane & 15;
  if (blockIdx.x == 0 && tid == 0) out[0] = lossAcc[0] * (1.0f / 67108864.0f);

  // stage concat A (16 x 384 bf16)
  {
    int r = bm + (tid >> 4), seg = tid & 15;
#pragma unroll
    for (int ch = 0; ch < 3; ++ch){
      int c0 = seg * 24 + ch * 8;
      const float* src; int cc;
      if (c0 < 128)      { src = hA2; cc = c0; }
      else if (c0 < 256) { src = o1;  cc = c0 - 128; }
      else               { src = o2;  cc = c0 - 256; }
      u16x8 v;
#pragma unroll
      for (int j = 0; j < 8; ++j) v[j] = f2bf(src[(size_t)r * 128 + cc + j]);
      *(u16x8*)&Aly[tid >> 4][c0] = v;
    }
  }
  __syncthreads();

  // GEMM1: 384 -> 128, relu; write x_gt, keep bf16 in Aly[.][0..128)
  float* xgt = out + 1 + NA * 4;
  f32x4 acc1[2];
  acc1[0] = (f32x4){0.f,0.f,0.f,0.f};
  acc1[1] = (f32x4){0.f,0.f,0.f,0.f};
  for (int k0 = 0; k0 < 384; k0 += 32){
    int n = tid >> 1, ks = (tid & 1) * 16;
    *(u16x8*)&Bs[n][ks]     = *(const u16x8*)(catt + (size_t)n * 384 + k0 + ks);
    *(u16x8*)&Bs[n][ks + 8] = *(const u16x8*)(catt + (size_t)n * 384 + k0 + ks + 8);
    __syncthreads();
    s16x8 af = *(s16x8*)&Aly[lid][k0 + lg * 8];
#pragma unroll
    for (int j = 0; j < 2; ++j){
      s16x8 bf = *(s16x8*)&Bs[w * 32 + j * 16 + lid][lg * 8];
      acc1[j] = __builtin_amdgcn_mfma_f32_16x16x32_bf16(af, bf, acc1[j], 0, 0, 0);
    }
    __syncthreads();
  }
#pragma unroll
  for (int j = 0; j < 2; ++j)
#pragma unroll
    for (int rr = 0; rr < 4; ++rr){
      int r = lg * 4 + rr, c = w * 32 + j * 16 + lid;
      float f = fmaxf(acc1[j][rr] + cat_b[c], 0.f);
      xgt[(size_t)(bm + r) * 128 + c] = f;
      Aly[r][c] = f2bf(f);
    }
  __syncthreads();

  // GEMM2: 128 -> 256, relu -> L1b
  f32x4 acc2[4];
#pragma unroll
  for (int j = 0; j < 4; ++j) acc2[j] = (f32x4){0.f,0.f,0.f,0.f};
  for (int k0 = 0; k0 < 128; k0 += 32){
#pragma unroll
    for (int q4 = 0; q4 < 4; ++q4)
      *(u16x8*)&Bs[tid][q4 * 8] = *(const u16x8*)(mlp1t + (size_t)tid * 128 + k0 + q4 * 8);
    __syncthreads();
    s16x8 af = *(s16x8*)&Aly[lid][k0 + lg * 8];
#pragma unroll
    for (int j = 0; j < 4; ++j){
      s16x8 bf = *(s16x8*)&Bs[w * 64 + j * 16 + lid][lg * 8];
      acc2[j] = __builtin_amdgcn_mfma_f32_16x16x32_bf16(af, bf, acc2[j], 0, 0, 0);
    }
    __syncthreads();
  }
#pragma unroll
  for (int j = 0; j < 4; ++j)
#pragma unroll
    for (int rr = 0; rr < 4; ++rr){
      int r = lg * 4 + rr, c = w * 64 + j * 16 + lid;
      L1b[r][c] = f2bf(fmaxf(acc2[j][rr] + mlp_b1[c], 0.f));
    }
  __syncthreads();

  // mlp2 (K=256, N=4) + softmax
  {
    int r = tid >> 4, rem = tid & 15, c = rem >> 2, p = rem & 3;
    float s = 0.f;
    for (int k = p * 64; k < p * 64 + 64; ++k)
      s = fmaf(bf2f(L1b[r][k]), mlp_W2[(size_t)k * 4 + c], s);
    s += __shfl_xor(s, 1);
    s += __shfl_xor(s, 2);
    if (p == 0) LG[r][c] = s + mlp_b2[c];
  }
  __syncthreads();
  if (tid < 16){
    int r = tid;
    float l0 = LG[r][0], l1 = LG[r][1], l2 = LG[r][2], l3 = LG[r][3];
    float mx = fmaxf(fmaxf(l0, l1), fmaxf(l2, l3));
    float e0 = __expf(l0 - mx), e1 = __expf(l1 - mx), e2 = __expf(l2 - mx), e3 = __expf(l3 - mx);
    float inv = 1.f / (e0 + e1 + e2 + e3);
    float* o = out + 1 + (size_t)(bm + r) * 4;
    o[0] = e0 * inv; o[1] = e1 * inv; o[2] = e2 * inv; o[3] = e3 * inv;
  }
}

__global__ void setval_k(float* p, float v){ p[0] = v; }

// ---------------------------------------------------------------- host
extern "C" void kernel_launch(void* const* d_in, const int* in_sizes, int n_in,
                              void* d_out, int out_size, void* d_ws, size_t ws_size,
                              hipStream_t stream)
{
  (void)in_sizes; (void)n_in; (void)out_size;
  const float* x_author = (const float*)d_in[0];
  const float* x_paper  = (const float*)d_in[1];
  const float* x_term   = (const float*)d_in[2];
  const int* ap_src = (const int*)d_in[3];
  const int* ap_dst = (const int*)d_in[4];
  const int* pa_src = (const int*)d_in[5];
  const int* pa_dst = (const int*)d_in[6];
  const int* tp_src = (const int*)d_in[9];
  const int* tp_dst = (const int*)d_in[10];
  const float* original_A = (const float*)d_in[11];
  const int* deg = (const int*)d_in[12];
  const float* t1_W = (const float*)d_in[13]; const float* t1_b = (const float*)d_in[14];
  const float* t2_W = (const float*)d_in[15]; const float* t2_b = (const float*)d_in[16];
  const float* t3_W = (const float*)d_in[17]; const float* t3_b = (const float*)d_in[18];
  const float* gat1_W  = (const float*)d_in[19];
  const float* gat1_as = (const float*)d_in[20];
  const float* gat1_ad = (const float*)d_in[21];
  const float* gat1_b  = (const float*)d_in[22];
  const float* gat2_W  = (const float*)d_in[23];
  const float* gat2_as = (const float*)d_in[24];
  const float* gat2_ad = (const float*)d_in[25];
  const float* gat2_b  = (const float*)d_in[26];
  const float* pe_embed = (const float*)d_in[27];
  const float* peWQ = (const float*)d_in[28];
  const float* peWK = (const float*)d_in[29];
  const float* gt_Wq = (const float*)d_in[30]; const float* gt_bq = (const float*)d_in[31];
  const float* gt_Wk = (const float*)d_in[32]; const float* gt_bk = (const float*)d_in[33];
  const float* gt_Wv = (const float*)d_in[34]; const float* gt_bv = (const float*)d_in[35];
  const float* gt_Wo = (const float*)d_in[36]; const float* gt_bo = (const float*)d_in[37];
  const float* gt_g1 = (const float*)d_in[38]; const float* gt_be1 = (const float*)d_in[39];
  const float* gt_Wf1 = (const float*)d_in[40]; const float* gt_bf1 = (const float*)d_in[41];
  const float* gt_Wf2 = (const float*)d_in[42]; const float* gt_bf2 = (const float*)d_in[43];
  const float* gt_g2 = (const float*)d_in[44]; const float* gt_be2 = (const float*)d_in[45];
  const float* cat_W = (const float*)d_in[46]; const float* cat_b = (const float*)d_in[47];
  const float* mlp_W1 = (const float*)d_in[48]; const float* mlp_b1 = (const float*)d_in[49];
  const float* mlp_W2 = (const float*)d_in[50]; const float* mlp_b2 = (const float*)d_in[51];
  float* out = (float*)d_out;

  // ---- workspace layout ----
  char* base = (char*)d_ws;
  size_t off = 0;
  auto alloc = [&](size_t nbytes) -> void* {
    void* p = base + off;
    off += (nbytes + 255) & ~(size_t)255;
    return p;
  };
  ushort_t* xa  = (ushort_t*)alloc((size_t)NA * 128 * 2);
  ushort_t* xp  = (ushort_t*)alloc((size_t)NPA * 128 * 2);
  ushort_t* xt  = (ushort_t*)alloc((size_t)NT * 128 * 2);
  ushort_t* accP = (ushort_t*)alloc((size_t)NPA * 1024 * 2); // +accA contiguous; aliased as attn part
  ushort_t* accA = (ushort_t*)alloc((size_t)NA * 1024 * 2);
  ushort_t* agg  = (ushort_t*)alloc((size_t)NSLOT * 1024 * 2);
  float* scores = (float*)alloc((size_t)36864 * 8 * 4);
  float* Ps   = (float*)alloc(3 * 1024 * 4);
  float* Pd   = (float*)alloc(3 * 1024 * 4);
  ushort_t* hs2 = (ushort_t*)alloc((size_t)NPA * 128 * 2);   // +hd2 contiguous
  ushort_t* hd2 = (ushort_t*)alloc((size_t)NA * 128 * 2);
  float* s2sd = (float*)alloc((size_t)(NPA + NA) * 4);
  float* hA2  = (float*)alloc((size_t)NA * 128 * 4);
  float* peQK = (float*)alloc((size_t)NA * 256 * 4);
  float* dbv  = (float*)alloc((size_t)NA * 4);
  float* bsum = (float*)alloc(1024 * 4);
  float* Wqkv = (float*)alloc((size_t)2 * 128 * 384 * 4);
  float* bqkv = (float*)alloc((size_t)2 * 384 * 4);
  float* peW  = (float*)alloc((size_t)128 * 256 * 4);
  float* Bstack = (float*)alloc((size_t)256 * 1024 * 4);
  ushort_t* Wot   = (ushort_t*)alloc((size_t)2 * 128 * 128 * 2);
  ushort_t* Wf1t  = (ushort_t*)alloc((size_t)2 * 256 * 128 * 2);
  ushort_t* Wf2t  = (ushort_t*)alloc((size_t)2 * 128 * 256 * 2);
  ushort_t* catt  = (ushort_t*)alloc((size_t)128 * 384 * 2);
  ushort_t* mlp1t = (ushort_t*)alloc((size_t)256 * 128 * 2);
  ushort_t* QKVb = (ushort_t*)alloc((size_t)NA * 384 * 2);
  float* outs1= (float*)alloc((size_t)NA * 128 * 4);
  float* outs2= (float*)alloc((size_t)NA * 128 * 4);
  int*   offb = (int*)alloc((size_t)NSLOT * 4);
  int*   eidx = (int*)alloc((size_t)E_TOT * 4);
  // ---- zero-init region (single small memset): cnt, cur, lossAcc ----
  size_t zstart = off;
  int*      cnt   = (int*)alloc((size_t)NSLOT * 4);
  int*      cur   = (int*)alloc((size_t)NSLOT * 4);
  float*    lossAcc = (float*)alloc(256);
  size_t zlen = off - zstart;

  float* part = (float*)accP;  // 9.4 MB f32 partials alias onto accP+accA (dead by transformer)

  if (off > ws_size){
    setval_k<<<1, 1, 0, stream>>>(out, -12345.0f);
    return;
  }

  auto gemmx = [&](int act, int tn, const void* A, const void* A2, const void* A3, int aBf16,
                   const float* B, void* C, int cBf16, const float* bias,
                   const float* addmat, int addCols, int addLd,
                   const float* lng, const float* lnb, float* rdOut,
                   int M, int N, int K, int lda, int ldb, int ldc){
    dim3 g(M / 64, N / tn, 1);
    if (tn == 128) {
      if (act == 0)      gemm_mfma_k<0,128><<<g, 256, 0, stream>>>(A, A2, A3, aBf16, B, C, cBf16, bias, addmat, addCols, addLd, lng, lnb, rdOut, M, N, K, lda, ldb, ldc);
      else if (act == 1) gemm_mfma_k<1,128><<<g, 256, 0, stream>>>(A, A2, A3, aBf16, B, C, cBf16, bias, addmat, addCols, addLd, lng, lnb, rdOut, M, N, K, lda, ldb, ldc);
      else if (act == 2) gemm_mfma_k<2,128><<<g, 256, 0, stream>>>(A, A2, A3, aBf16, B, C, cBf16, bias, addmat, addCols, addLd, lng, lnb, rdOut, M, N, K, lda, ldb, ldc);
      else               gemm_mfma_k<3,128><<<g, 256, 0, stream>>>(A, A2, A3, aBf16, B, C, cBf16, bias, addmat, addCols, addLd, lng, lnb, rdOut, M, N, K, lda, ldb, ldc);
    } else {
      if (act == 0)      gemm_mfma_k<0,64><<<g, 256, 0, stream>>>(A, A2, A3, aBf16, B, C, cBf16, bias, addmat, addCols, addLd, lng, lnb, rdOut, M, N, K, lda, ldb, ldc);
      else               gemm_mfma_k<1,64><<<g, 256, 0, stream>>>(A, A2, A3, aBf16, B, C, cBf16, bias, addmat, addCols, addLd, lng, lnb, rdOut, M, N, K, lda, ldb, ldc);
    }
  };

  // 1. zero-init (tiny)
  hipMemsetAsync(base + zstart, 0, zlen, stream);
  // 2. prep: packs + db + proj3 + histogram + transposed bf16 weights
  prep_k<<<3781, 256, 0, stream>>>(gat1_b, gat1_W, gt_Wq, gt_bq, gt_Wk, gt_bk, gt_Wv, gt_bv,
                                   peWQ, peWK, deg, gat1_as, gat1_ad, ap_dst, tp_dst, pa_dst,
                                   gt_Wo, gt_Wf1, gt_Wf2, cat_W, mlp_W1,
                                   bsum, Wqkv, bqkv, peW, Bstack, dbv, Ps, Pd, cnt,
                                   Wot, Wf1t, Wf2t, catt, mlp1t);
  // 3. D1 mega-GEMM: 3 stage-0 MLPs + peQK (768 tiles)
  {
    GDescArr da; da.nd = 4;
    da.d[0] = { x_author, nullptr, t1_W, xa, t1_b, 0, 1, 1, NA, 128, 334, 334, 128, 128, 1, 0, 0, 0, 0 };
    da.d[1] = { x_paper,  nullptr, t2_W, xp, t2_b, 0, 1, 1, NPA, 128, 512, 512, 128, 128, 1, 0, 0, 0, 128 };
    da.d[2] = { x_term,   nullptr, t3_W, xt, t3_b, 0, 1, 1, NT, 128, 128, 128, 128, 128, 1, 0, 0, 0, 384 };
    da.d[3] = { pe_embed, nullptr, peW, peQK, nullptr, 0, 0, 0, NA, 256, 128, 128, 256, 256, 1, 0, 0, 0, 512 };
    gemm_multi_k<<<768, 256, 0, stream>>>(da);
  }
  // 4-5. CSR scan + scatter
  exscan_k<<<1, 1024, 0, stream>>>(cnt, offb, NSLOT);
  scatterf_k<<<(E_TOT + 255) / 256, 256, 0, stream>>>(ap_dst, tp_dst, pa_dst, offb, cur, eidx);
  // 6-7. GAT1: scores, fused online softmax+aggregate
  scorev_k<<<9216, 256, 0, stream>>>(xa, xp, xt, Ps, Pd, scores);
  agg8ff_k<<<NSLOT / 4, 256, 0, stream>>>(eidx, offb, cnt, ap_src, tp_src, pa_src,
                                          xa, xt, xp, scores, agg);
  // 8. D2 mega-GEMM: GAT1 per-head transforms — 3072 tiles
  {
    GDescArr da; da.nd = 2;
    da.d[0] = { agg, agg + (size_t)NPA * 1024, Bstack, accP, bsum, 1, 1, 1,
                NPA, 128, 256, 1024, 1024, 1024, 8, 128, 128, 128, 0 };
    da.d[1] = { agg + (size_t)2 * NPA * 1024, nullptr, gat1_W + 131072, accA, gat1_b + 1024, 1, 1, 1,
                NA, 128, 128, 1024, 1024, 1024, 8, 128, 128, 128, 2048 };
    gemm_multi_k<<<3072, 256, 0, stream>>>(da);
  }
  // 9-10. GAT2: hs2 GEMM + fused rowdot, then aggregation
  gemmx(3, 128, accP, 0, 0, 1, gat2_W + 131072, hs2, 1, 0, 0, 0, 0,
        gat2_as + 128, gat2_ad + 128, s2sd, NPA + NA, 128, 1024, 1024, 128, 128);
  gat_agg1f_k<<<NA / 4, 256, 0, stream>>>(eidx, offb + 2 * NPA, cnt + 2 * NPA, pa_src, hs2, s2sd,
                                          gat2_b + 128, hA2, NA);
  // 11. PE reconstruction loss
  loss_mfma_k<<<dim3(64, 32), 256, 0, stream>>>(peQK, peQK + 128, original_A, lossAcc);
  // 12-17. graph transformer (2 layers x 3 dispatches)
  const float* x = hA2;
  float* louts[2] = { outs1, outs2 };
  for (int i = 0; i < 2; ++i){
    gemmx(0, 64, x, 0, 0, 0, Wqkv + (size_t)i * 49152, QKVb, 1, bqkv + i * 384, peQK, 256, 256,
          0, 0, 0, NA, 384, 128, 128, 384, 384);
    attn_mfma_k<<<dim3(NA / 64, 8, ASPLIT), 256, 0, stream>>>(QKVb, QKVb + 128, QKVb + 256, dbv, part);
    gt_tail_k<<<NA / 16, 256, 0, stream>>>(part, Wot + (size_t)i * 16384, gt_bo + i * 128, x,
                                           gt_g1 + i * 128, gt_be1 + i * 128,
                                           Wf1t + (size_t)i * 32768, gt_bf1 + i * 256,
                                           Wf2t + (size_t)i * 32768, gt_bf2 + i * 128,
                                           gt_g2 + i * 128, gt_be2 + i * 128, louts[i]);
    x = louts[i];
  }
  // 18. fused head
  head_k<<<NA / 16, 256, 0, stream>>>(hA2, outs1, outs2, catt, cat_b, mlp1t, mlp_b1,
                                      mlp_W2, mlp_b2, lossAcc, out);
}

// Round 10
// 638.859 us; speedup vs baseline: 4.5018x; 1.0114x over previous
//
#include <hip/hip_runtime.h>
#include <math.h>

// Problem constants
#define NA   4096
#define NPA  8192
#define NT   4096
#define E_AP 80000
#define E_PA 80000
#define E_TP 160000
#define E_TOT (E_AP + E_TP + E_PA)
#define NSLOT (NPA + NPA + NA)     // 20480 global CSR slots: [ap->paper | tp->paper | pa->author]
#define ASPLIT 4                   // attention key-splits

typedef __attribute__((ext_vector_type(4))) float f32x4;
typedef __attribute__((ext_vector_type(8))) short s16x8;
typedef __attribute__((ext_vector_type(8))) unsigned short u16x8;
typedef unsigned short ushort_t;

__device__ __forceinline__ ushort_t f2bf(float f){
  unsigned u = __float_as_uint(f);
  unsigned r = u + 0x7fffu + ((u >> 16) & 1u);   // RNE
  return (ushort_t)(r >> 16);
}
__device__ __forceinline__ float bf2f(ushort_t u){
  return __uint_as_float(((unsigned)u) << 16);
}

// ---------------------------------------------------------------- bf16 MFMA GEMM (templated)
// Tile 64 x TN x BK32, 4 waves (2x2); TN in {64,128}. Requires M%64==0, N%TN==0.
// ACT: 0 none, 1 relu, 3 bf16-C + per-row dot with lng (rows<8192) / lnb into rdOut (TN==128, grid.y==1).
template<int ACT, int TN>
__global__ __launch_bounds__(256) void gemm_mfma_k(
    const void* __restrict__ Ain, const void* __restrict__ A2in, const void* __restrict__ A3in,
    int aBf16,
    const float* __restrict__ B, void* __restrict__ Cout, int cBf16,
    const float* __restrict__ bias,
    const float* __restrict__ addmat, int addCols, int addLd,
    const float* __restrict__ lng, const float* __restrict__ lnb,
    float* __restrict__ rdOut,
    int M, int N, int K, int lda, int ldb, int ldc)
{
  const char* A  = (const char*)Ain;
  const char* A2 = (const char*)A2in;
  const char* A3 = (const char*)A3in;
  char* C = (char*)Cout;

  __shared__ __align__(16) ushort_t As[64][40];
  __shared__ __align__(16) ushort_t Bs[TN][40];
  constexpr int NJ = TN / 32;
  int bm = blockIdx.x * 64, bn = blockIdx.y * TN;
  int tid = threadIdx.x;
  int w = tid >> 6, lane = tid & 63, lg = lane >> 4, lid = lane & 15;
  int wm = (w & 1) * 32, wn = (w >> 1) * (TN / 2);
  f32x4 acc[2][NJ];
#pragma unroll
  for (int i = 0; i < 2; ++i)
#pragma unroll
    for (int j = 0; j < NJ; ++j) acc[i][j] = (f32x4){0.f, 0.f, 0.f, 0.f};

  for (int k0 = 0; k0 < K; k0 += 32) {
    {
      int r = tid >> 2, ks = (tid & 3) * 8;
      int kcol = k0 + ks;
      const char* Ab = A;
      if (A2) { int seg = kcol >> 7; Ab = (seg == 0) ? A : ((seg == 1) ? A2 : A3); kcol &= 127; }
      u16x8 v;
      if (aBf16) {
        v = *(const u16x8*)((const ushort_t*)Ab + (size_t)(bm + r) * lda + kcol);
      } else {
        const float* ap = (const float*)Ab + (size_t)(bm + r) * lda + kcol;
#pragma unroll
        for (int j = 0; j < 8; ++j) {
          int gk = k0 + ks + j;
          float fv = (gk < K) ? ap[j] : 0.f;
          v[j] = f2bf(fv);
        }
      }
      *(u16x8*)&As[r][ks] = v;
    }
    if (TN == 128) {
      int n = tid >> 1, ks = (tid & 1) * 16;
      ushort_t tmp[16];
#pragma unroll
      for (int j = 0; j < 16; ++j) {
        int gk = k0 + ks + j;
        float fv = (gk < K) ? B[(size_t)gk * ldb + bn + n] : 0.f;
        tmp[j] = f2bf(fv);
      }
      u16x8 v0, v1;
#pragma unroll
      for (int j = 0; j < 8; ++j) { v0[j] = tmp[j]; v1[j] = tmp[8 + j]; }
      *(u16x8*)&Bs[n][ks] = v0;
      *(u16x8*)&Bs[n][ks + 8] = v1;
    } else {
      int n = tid >> 2, ks = (tid & 3) * 8;
      u16x8 v;
#pragma unroll
      for (int j = 0; j < 8; ++j) {
        int gk = k0 + ks + j;
        float fv = (gk < K) ? B[(size_t)gk * ldb + bn + n] : 0.f;
        v[j] = f2bf(fv);
      }
      *(u16x8*)&Bs[n][ks] = v;
    }
    __syncthreads();
    s16x8 a_frag[2], b_frag[NJ];
#pragma unroll
    for (int i = 0; i < 2; ++i) a_frag[i] = *(s16x8*)&As[wm + i * 16 + lid][lg * 8];
#pragma unroll
    for (int j = 0; j < NJ; ++j) b_frag[j] = *(s16x8*)&Bs[wn + j * 16 + lid][lg * 8];
#pragma unroll
    for (int i = 0; i < 2; ++i)
#pragma unroll
      for (int j = 0; j < NJ; ++j)
        acc[i][j] = __builtin_amdgcn_mfma_f32_16x16x32_bf16(a_frag[i], b_frag[j], acc[i][j], 0, 0, 0);
    __syncthreads();
  }
  if constexpr (ACT == 3) {
    // bf16 C + per-row dot: TN==128, grid.y==1
    __shared__ float Ct[64][132];
#pragma unroll
    for (int i = 0; i < 2; ++i) {
#pragma unroll
      for (int j = 0; j < NJ; ++j) {
        int coll = wn + j * 16 + lid;
#pragma unroll
        for (int rr = 0; rr < 4; ++rr) {
          int rowl = wm + i * 16 + lg * 4 + rr;
          Ct[rowl][coll] = acc[i][j][rr];
        }
      }
    }
    __syncthreads();
    int row = tid >> 2, part = tid & 3;
    const float* vsel = (bm + row < 8192) ? lng : lnb;
    float rd = 0.f;
    ushort_t* Cu = (ushort_t*)C;
#pragma unroll
    for (int c2 = 0; c2 < 32; ++c2) {
      int c = part * 32 + c2;
      float f = Ct[row][c];
      rd = fmaf(f, vsel[c], rd);
      Cu[(size_t)(bm + row) * ldc + c] = f2bf(f);
    }
    rd += __shfl_xor(rd, 1);
    rd += __shfl_xor(rd, 2);
    if (part == 0) rdOut[bm + row] = rd;
  } else {
#pragma unroll
    for (int i = 0; i < 2; ++i) {
#pragma unroll
      for (int j = 0; j < NJ; ++j) {
        int c = bn + wn + j * 16 + lid;
#pragma unroll
        for (int rr = 0; rr < 4; ++rr) {
          int r = bm + wm + i * 16 + lg * 4 + rr;
          float v = acc[i][j][rr];
          if (bias)   v += bias[c];
          if (addmat && c < addCols) v += addmat[(size_t)r * addLd + c];
          if (ACT == 1) v = fmaxf(v, 0.f);
          if (cBf16) ((ushort_t*)C)[(size_t)r * ldc + c] = f2bf(v);
          else       ((float*)C)[(size_t)r * ldc + c] = v;
        }
      }
    }
  }
}

// ---------------------------------------------------------------- descriptor multi-GEMM (TN=64, runtime params)
struct GDesc {
  const void* A; const void* A2;
  const float* B; void* C;
  const float* bias;
  int aBf16, cBf16, act;
  int M, N, K, lda, ldb, ldc;
  int nz, aOffZ, bOffZ, cOffZ;
  int tileStart;
};
struct GDescArr { GDesc d[4]; int nd; };

__global__ __launch_bounds__(256) void gemm_multi_k(GDescArr da){
  int t = blockIdx.x;
  int di = 0;
#pragma unroll
  for (int i = 1; i < 4; ++i) if (i < da.nd && t >= da.d[i].tileStart) di = i;
  const int aBf16 = da.d[di].aBf16, cBf16 = da.d[di].cBf16, act = da.d[di].act;
  const int M = da.d[di].M, N = da.d[di].N, K = da.d[di].K;
  const int lda = da.d[di].lda, ldb = da.d[di].ldb, ldc = da.d[di].ldc;
  int local = t - da.d[di].tileStart;
  int tM = M >> 6;
  int perZ = tM * (N >> 6);
  int z = local / perZ, rem = local - z * perZ;
  int bm = (rem % tM) * 64, bn = (rem / tM) * 64;
  int asz = aBf16 ? 2 : 4;
  const char* A  = (const char*)da.d[di].A  + (size_t)z * da.d[di].aOffZ * asz;
  const char* A2 = da.d[di].A2 ? (const char*)da.d[di].A2 + (size_t)z * da.d[di].aOffZ * asz : nullptr;
  const float* B = da.d[di].B + (size_t)z * da.d[di].bOffZ;
  char* C = (char*)da.d[di].C + (size_t)z * da.d[di].cOffZ * (cBf16 ? 2 : 4);
  const float* bias = da.d[di].bias ? da.d[di].bias + (size_t)z * da.d[di].cOffZ : nullptr;

  __shared__ __align__(16) ushort_t As[64][40];
  __shared__ __align__(16) ushort_t Bs[64][40];
  int tid = threadIdx.x;
  int w = tid >> 6, lane = tid & 63, lg = lane >> 4, lid = lane & 15;
  int wm = (w & 1) * 32, wn = (w >> 1) * 32;
  f32x4 acc[2][2];
#pragma unroll
  for (int i = 0; i < 2; ++i)
#pragma unroll
    for (int j = 0; j < 2; ++j) acc[i][j] = (f32x4){0.f, 0.f, 0.f, 0.f};

  for (int k0 = 0; k0 < K; k0 += 32) {
    {
      int r = tid >> 2, ks = (tid & 3) * 8;
      int kcol = k0 + ks;
      const char* Ab = A;
      if (A2) { int seg = kcol >> 7; Ab = seg ? A2 : A; kcol &= 127; }
      u16x8 v;
      if (aBf16) {
        v = *(const u16x8*)((const ushort_t*)Ab + (size_t)(bm + r) * lda + kcol);
      } else {
        const float* ap = (const float*)Ab + (size_t)(bm + r) * lda + kcol;
#pragma unroll
        for (int j = 0; j < 8; ++j) {
          int gk = k0 + ks + j;
          float fv = (gk < K) ? ap[j] : 0.f;
          v[j] = f2bf(fv);
        }
      }
      *(u16x8*)&As[r][ks] = v;
    }
    {
      int n = tid >> 2, ks = (tid & 3) * 8;
      u16x8 v;
#pragma unroll
      for (int j = 0; j < 8; ++j) {
        int gk = k0 + ks + j;
        float fv = (gk < K) ? B[(size_t)gk * ldb + bn + n] : 0.f;
        v[j] = f2bf(fv);
      }
      *(u16x8*)&Bs[n][ks] = v;
    }
    __syncthreads();
    s16x8 a_frag[2], b_frag[2];
#pragma unroll
    for (int i = 0; i < 2; ++i) a_frag[i] = *(s16x8*)&As[wm + i * 16 + lid][lg * 8];
#pragma unroll
    for (int j = 0; j < 2; ++j) b_frag[j] = *(s16x8*)&Bs[wn + j * 16 + lid][lg * 8];
#pragma unroll
    for (int i = 0; i < 2; ++i)
#pragma unroll
      for (int j = 0; j < 2; ++j)
        acc[i][j] = __builtin_amdgcn_mfma_f32_16x16x32_bf16(a_frag[i], b_frag[j], acc[i][j], 0, 0, 0);
    __syncthreads();
  }
#pragma unroll
  for (int i = 0; i < 2; ++i) {
#pragma unroll
    for (int j = 0; j < 2; ++j) {
      int c = bn + wn + j * 16 + lid;
#pragma unroll
      for (int rr = 0; rr < 4; ++rr) {
        int r = bm + wm + i * 16 + lg * 4 + rr;
        float v = acc[i][j][rr];
        if (bias) v += bias[c];
        if (act == 1) v = fmaxf(v, 0.f);
        if (cBf16) ((ushort_t*)C)[(size_t)r * ldc + c] = f2bf(v);
        else       ((float*)C)[(size_t)r * ldc + c] = v;
      }
    }
  }
}

// ---------------------------------------------------------------- prep
// sections: bsum[1024] | Wqkv[98304] | bqkv[768] | peW[32768] | Bstack[262144]
//  | dbv[4096] | proj3[3072] | hist[E_TOT] | Wot[32768] | Wf1t[65536] | Wf2t[65536]
//  | catt[49152] | mlp1t[32768] | Wqkvt[98304]
__global__ void prep_k(const float* __restrict__ gat1_b, const float* __restrict__ gat1_W,
                       const float* __restrict__ Wq, const float* __restrict__ bq,
                       const float* __restrict__ Wk, const float* __restrict__ bk,
                       const float* __restrict__ Wv, const float* __restrict__ bv,
                       const float* __restrict__ peWQ, const float* __restrict__ peWK,
                       const int* __restrict__ deg,
                       const float* __restrict__ gat1_as, const float* __restrict__ gat1_ad,
                       const int* __restrict__ ap_dst, const int* __restrict__ tp_dst,
                       const int* __restrict__ pa_dst,
                       const float* __restrict__ gt_Wo, const float* __restrict__ gt_Wf1,
                       const float* __restrict__ gt_Wf2, const float* __restrict__ cat_W,
                       const float* __restrict__ mlp_W1,
                       float* __restrict__ bsum, float* __restrict__ Wqkv,
                       float* __restrict__ bqkv, float* __restrict__ peW,
                       float* __restrict__ Bstack, float* __restrict__ dbv,
                       float* __restrict__ Ps, float* __restrict__ Pd,
                       int* __restrict__ cnt,
                       ushort_t* __restrict__ Wot, ushort_t* __restrict__ Wf1t,
                       ushort_t* __restrict__ Wf2t, ushort_t* __restrict__ catt,
                       ushort_t* __restrict__ mlp1t, ushort_t* __restrict__ Wqkvt)
{
  int idx = blockIdx.x * blockDim.x + threadIdx.x;
  if (idx < 1024) { bsum[idx] = gat1_b[idx] + gat1_b[3 * 1024 + idx]; return; }
  idx -= 1024;
  if (idx < 2 * 128 * 384) {
    int l = idx / 49152, rem = idx % 49152;
    int k = rem / 384, c = rem % 384;
    float v;
    if (c < 128)      v = Wq[(size_t)l * 16384 + k * 128 + c];
    else if (c < 256) v = Wk[(size_t)l * 16384 + k * 128 + c - 128];
    else              v = Wv[(size_t)l * 16384 + k * 128 + c - 256];
    Wqkv[(size_t)l * 49152 + k * 384 + c] = v;
    return;
  }
  idx -= 2 * 128 * 384;
  if (idx < 2 * 384) {
    int l = idx / 384, c = idx % 384;
    float v;
    if (c < 128)      v = bq[l * 128 + c];
    else if (c < 256) v = bk[l * 128 + c - 128];
    else              v = bv[l * 128 + c - 256];
    bqkv[l * 384 + c] = v;
    return;
  }
  idx -= 2 * 384;
  if (idx < 128 * 256) {
    int k = idx / 256, c = idx % 256;
    peW[k * 256 + c] = (c < 128) ? peWQ[k * 128 + c] : peWK[k * 128 + c - 128];
    return;
  }
  idx -= 128 * 256;
  if (idx < 256 * 1024) {
    int k = idx / 1024, c = idx % 1024;
    Bstack[idx] = (k < 128) ? gat1_W[(size_t)k * 1024 + c]
                            : gat1_W[(size_t)3 * 131072 + (size_t)(k - 128) * 1024 + c];
    return;
  }
  idx -= 256 * 1024;
  if (idx < NA) { dbv[idx] = logf(fmaxf((float)deg[idx], 1.f)); return; }
  idx -= NA;
  if (idx < 3 * 1024) {
    const int wsel[3] = {0, 3, 1};
    int type = idx / 1024, rem = idx % 1024;
    int k = rem >> 3, h = rem & 7;
    const float* wr = gat1_W + (size_t)wsel[type] * 131072 + (size_t)k * 1024 + h * 128;
    const float* a1 = gat1_as + wsel[type] * 1024 + h * 128;
    const float* a2 = gat1_ad + wsel[type] * 1024 + h * 128;
    float s1 = 0.f, s2 = 0.f;
    for (int c = 0; c < 128; ++c){ float wv = wr[c]; s1 = fmaf(wv, a1[c], s1); s2 = fmaf(wv, a2[c], s2); }
    Ps[(size_t)type * 1024 + k * 8 + h] = s1;
    Pd[(size_t)type * 1024 + k * 8 + h] = s2;
    return;
  }
  idx -= 3 * 1024;
  if (idx < E_TOT) {
    int slot;
    if (idx < E_AP)             slot = ap_dst[idx];
    else if (idx < E_AP + E_TP) slot = NPA + tp_dst[idx - E_AP];
    else                        slot = 2 * NPA + pa_dst[idx - E_AP - E_TP];
    atomicAdd(&cnt[slot], 1);
    return;
  }
  idx -= E_TOT;
  if (idx < 2 * 128 * 128) {  // Wot[l][n][k] = Wo[l][k][n]
    int l = idx / 16384, rem = idx % 16384;
    int n = rem / 128, k = rem % 128;
    Wot[idx] = f2bf(gt_Wo[(size_t)l * 16384 + k * 128 + n]);
    return;
  }
  idx -= 2 * 128 * 128;
  if (idx < 2 * 256 * 128) {  // Wf1t[l][n][k] = Wf1[l][k][n]
    int l = idx / 32768, rem = idx % 32768;
    int n = rem / 128, k = rem % 128;
    Wf1t[idx] = f2bf(gt_Wf1[(size_t)l * 32768 + k * 256 + n]);
    return;
  }
  idx -= 2 * 256 * 128;
  if (idx < 2 * 128 * 256) {  // Wf2t[l][n][k] = Wf2[l][k][n]
    int l = idx / 32768, rem = idx % 32768;
    int n = rem / 256, k = rem % 256;
    Wf2t[idx] = f2bf(gt_Wf2[(size_t)l * 32768 + k * 128 + n]);
    return;
  }
  idx -= 2 * 128 * 256;
  if (idx < 128 * 384) {      // catt[n][k] = cat_W[k][n]
    int n = idx / 384, k = idx % 384;
    catt[idx] = f2bf(cat_W[(size_t)k * 128 + n]);
    return;
  }
  idx -= 128 * 384;
  if (idx < 256 * 128) {      // mlp1t[n][k] = mlp_W1[k][n]
    int n = idx / 128, k = idx % 128;
    mlp1t[idx] = f2bf(mlp_W1[(size_t)k * 256 + n]);
    return;
  }
  idx -= 256 * 128;
  if (idx < 2 * 384 * 128) {  // Wqkvt[l][n][k]: col n of [Wq|Wk|Wv], input k
    int l = idx / 49152, rem = idx % 49152;
    int n = rem / 128, k = rem % 128;
    float v;
    if (n < 128)      v = Wq[(size_t)l * 16384 + k * 128 + n];
    else if (n < 256) v = Wk[(size_t)l * 16384 + k * 128 + n - 128];
    else              v = Wv[(size_t)l * 16384 + k * 128 + n - 256];
    Wqkvt[idx] = f2bf(v);
  }
}

// ---------------------------------------------------------------- CSR build pieces
__global__ void scatterf_k(const int* __restrict__ ap_dst, const int* __restrict__ tp_dst,
                           const int* __restrict__ pa_dst, const int* __restrict__ off,
                           int* __restrict__ cur, int* __restrict__ eidx){
  int i = blockIdx.x * blockDim.x + threadIdx.x;
  if (i >= E_TOT) return;
  int slot, local;
  if (i < E_AP)             { local = i;                 slot = ap_dst[local]; }
  else if (i < E_AP + E_TP) { local = i - E_AP;          slot = NPA + tp_dst[local]; }
  else                      { local = i - E_AP - E_TP;   slot = 2 * NPA + pa_dst[local]; }
  int p = atomicAdd(&cur[slot], 1);
  eidx[off[slot] + p] = local;
}

__global__ __launch_bounds__(1024) void exscan_k(const int* __restrict__ in, int* __restrict__ out, int n){
  __shared__ int wsum[16];
  __shared__ int carrySh;
  int t = threadIdx.x, w = t >> 6, lane = t & 63;
  if (t == 0) carrySh = 0;
  __syncthreads();
  for (int base = 0; base < n; base += 1024){
    int carry = carrySh;
    int v = (base + t < n) ? in[base + t] : 0;
    int sc = v;
#pragma unroll
    for (int o2 = 1; o2 < 64; o2 <<= 1){
      int u = __shfl_up(sc, o2);
      if (lane >= o2) sc += u;
    }
    if (lane == 63) wsum[w] = sc;
    __syncthreads();
    int wadd = 0;
#pragma unroll
    for (int i = 0; i < 15; ++i) if (i < w) wadd += wsum[i];
    if (base + t < n) out[base + t] = carry + wadd + sc - v;
    if (t == 1023) carrySh = carry + wadd + sc;
    __syncthreads();
  }
}

// ---------------------------------------------------------------- GAT pieces
__global__ __launch_bounds__(256) void scorev_k(
    const ushort_t* __restrict__ xa, const ushort_t* __restrict__ xp, const ushort_t* __restrict__ xt,
    const float* __restrict__ Ps, const float* __restrict__ Pd, float* __restrict__ scores)
{
  int r = blockIdx.x * 4 + (threadIdx.x >> 6);
  int lane = threadIdx.x & 63;
  const ushort_t* x; const float* P; int row;
  if (r < 4096)       { x = xa; P = Ps;        row = r; }
  else if (r < 12288) { x = xp; P = Pd;        row = r - 4096; }
  else if (r < 16384) { x = xt; P = Ps + 1024; row = r - 12288; }
  else if (r < 24576) { x = xp; P = Pd + 1024; row = r - 16384; }
  else if (r < 32768) { x = xp; P = Ps + 2048; row = r - 24576; }
  else                { x = xa; P = Pd + 2048; row = r - 32768; }
  unsigned u = *(const unsigned*)(x + (size_t)row * 128 + 2 * lane);
  float x0 = bf2f((ushort_t)(u & 0xffff));
  float x1 = bf2f((ushort_t)(u >> 16));
  float res[8];
#pragma unroll
  for (int h = 0; h < 8; ++h) {
    float s = x0 * P[(2 * lane) * 8 + h] + x1 * P[(2 * lane + 1) * 8 + h];
#pragma unroll
    for (int o = 32; o; o >>= 1) s += __shfl_down(s, o);
    res[h] = s;
  }
  if (lane == 0) {
#pragma unroll
    for (int h = 0; h < 8; ++h) scores[(size_t)r * 8 + h] = res[h];
  }
}

// fused online edge-softmax + x-space aggregation; one wave per slot; single pass
__global__ __launch_bounds__(256) void agg8ff_k(
    const int* __restrict__ eidx, const int* __restrict__ off, const int* __restrict__ cnt,
    const int* __restrict__ ap_src, const int* __restrict__ tp_src, const int* __restrict__ pa_src,
    const ushort_t* __restrict__ xa, const ushort_t* __restrict__ xt, const ushort_t* __restrict__ xp,
    const float* __restrict__ scores, ushort_t* __restrict__ agg)
{
  int g = blockIdx.x * 4 + (threadIdx.x >> 6);
  if (g >= NSLOT) return;
  const int* src; const ushort_t* x; const float* ssb; const float* sdb; int d;
  if (g < NPA)          { src = ap_src; x = xa; ssb = scores;                     sdb = scores + (size_t)4096 * 8;  d = g; }
  else if (g < 2 * NPA) { src = tp_src; x = xt; ssb = scores + (size_t)12288 * 8; sdb = scores + (size_t)16384 * 8; d = g - NPA; }
  else                  { src = pa_src; x = xp; ssb = scores + (size_t)24576 * 8; sdb = scores + (size_t)32768 * 8; d = g - 2 * NPA; }
  int lane = threadIdx.x & 63;
  int hh = lane & 7;
  float sdv = sdb[(size_t)d * 8 + hh];
  int base = off[g], n = cnt[g];
  float mh = -1e30f, den = 0.f;
  float acc0[8], acc1[8];
#pragma unroll
  for (int h2 = 0; h2 < 8; ++h2){ acc0[h2] = 0.f; acc1[h2] = 0.f; }
  int e = (n > 0) ? eidx[base] : 0;
  int s = (n > 0) ? src[e] : 0;
  for (int k = 0; k < n; ++k){
    int en = 0, sn = 0;
    if (k + 1 < n){ en = eidx[base + k + 1]; sn = src[en]; }
    float v = ssb[(size_t)s * 8 + hh] + sdv;
    v = v > 0.f ? v : 0.2f * v;
    float mn = fmaxf(mh, v);
    float sc = __expf(mh - mn);
    float wv_ = __expf(v - mn);
    den = den * sc + wv_;
    mh = mn;
    unsigned u = *(const unsigned*)(x + (size_t)s * 128 + 2 * lane);
    float xv0 = bf2f((ushort_t)(u & 0xffff));
    float xv1 = bf2f((ushort_t)(u >> 16));
#pragma unroll
    for (int h2 = 0; h2 < 8; ++h2){
      float sch = __shfl(sc, h2);
      float wh = __shfl(wv_, h2);
      acc0[h2] = fmaf(wh, xv0, acc0[h2] * sch);
      acc1[h2] = fmaf(wh, xv1, acc1[h2] * sch);
    }
    e = en; s = sn;
  }
  ushort_t* o = agg + (size_t)g * 1024;
#pragma unroll
  for (int h2 = 0; h2 < 8; ++h2){
    float dh = __shfl(den, h2) + 1e-16f;
    unsigned pk = (unsigned)f2bf(acc0[h2] / dh) | ((unsigned)f2bf(acc1[h2] / dh) << 16);
    *(unsigned*)(o + h2 * 128 + 2 * lane) = pk;
  }
}

// fused online H=1 softmax+aggregation (gat2); hs bf16 -> out f32
__global__ __launch_bounds__(256) void gat_agg1f_k(
    const int* __restrict__ eidx, const int* __restrict__ off, const int* __restrict__ cnt,
    const int* __restrict__ src, const ushort_t* __restrict__ hs,
    const float* __restrict__ sArr,
    const float* __restrict__ bias, float* __restrict__ outp, int Ndst)
{
  int d = blockIdx.x * 4 + (threadIdx.x >> 6);
  if (d >= Ndst) return;
  int lane = threadIdx.x & 63;
  float sdv = sArr[8192 + d];
  int base = off[d], n = cnt[d];
  float mh = -1e30f, den = 0.f, a0 = 0.f, a1 = 0.f;
  int e = (n > 0) ? eidx[base] : 0;
  int s = (n > 0) ? src[e] : 0;
  for (int k = 0; k < n; ++k){
    int en = 0, sn = 0;
    if (k + 1 < n){ en = eidx[base + k + 1]; sn = src[en]; }
    float v = sArr[s] + sdv;
    v = v > 0.f ? v : 0.2f * v;
    float mn = fmaxf(mh, v);
    float sc = __expf(mh - mn);
    float w_ = __expf(v - mn);
    den = den * sc + w_;
    mh = mn;
    unsigned u = *(const unsigned*)(hs + (size_t)s * 128 + 2 * lane);
    a0 = fmaf(w_, bf2f((ushort_t)(u & 0xffff)), a0 * sc);
    a1 = fmaf(w_, bf2f((ushort_t)(u >> 16)), a1 * sc);
    e = en; s = sn;
  }
  float inv = 1.f / (den + 1e-16f);
  outp[(size_t)d * 128 + 2 * lane]     = a0 * inv + bias[2 * lane];
  outp[(size_t)d * 128 + 2 * lane + 1] = a1 * inv + bias[2 * lane + 1];
}

// ---------------------------------------------------------------- PE loss
__global__ __launch_bounds__(256) void loss_mfma_k(const float* __restrict__ peQ,
    const float* __restrict__ peK, const float* __restrict__ A4, float* __restrict__ lossAcc)
{
  __shared__ __align__(16) ushort_t As[64][40];
  __shared__ __align__(16) ushort_t Bs[128][40];
  __shared__ float sig[64][128];
  __shared__ float red[256];
  int br = blockIdx.x * 64, bc = blockIdx.y * 128;
  int tid = threadIdx.x;
  int w = tid >> 6, lane = tid & 63, lg = lane >> 4, lid = lane & 15;
  int wm = (w & 1) * 32, wn = (w >> 1) * 64;
  f32x4 acc[2][4];
#pragma unroll
  for (int i = 0; i < 2; ++i)
#pragma unroll
    for (int j = 0; j < 4; ++j) acc[i][j] = (f32x4){0.f, 0.f, 0.f, 0.f};

  for (int k0 = 0; k0 < 128; k0 += 32) {
    {
      int r = tid >> 2, ks = (tid & 3) * 8;
      const float* ap = peQ + (size_t)(br + r) * 256 + k0 + ks;
      u16x8 v;
#pragma unroll
      for (int j = 0; j < 8; ++j) v[j] = f2bf(ap[j]);
      *(u16x8*)&As[r][ks] = v;
    }
    {
      int n = tid >> 1, ks = (tid & 1) * 16;
      const float* bp = peK + (size_t)(bc + n) * 256 + k0 + ks;
      u16x8 v0, v1;
#pragma unroll
      for (int j = 0; j < 8; ++j) { v0[j] = f2bf(bp[j]); v1[j] = f2bf(bp[8 + j]); }
      *(u16x8*)&Bs[n][ks] = v0;
      *(u16x8*)&Bs[n][ks + 8] = v1;
    }
    __syncthreads();
    s16x8 a_frag[2], b_frag[4];
#pragma unroll
    for (int i = 0; i < 2; ++i) a_frag[i] = *(s16x8*)&As[wm + i * 16 + lid][lg * 8];
#pragma unroll
    for (int j = 0; j < 4; ++j) b_frag[j] = *(s16x8*)&Bs[wn + j * 16 + lid][lg * 8];
#pragma unroll
    for (int i = 0; i < 2; ++i)
#pragma unroll
      for (int j = 0; j < 4; ++j)
        acc[i][j] = __builtin_amdgcn_mfma_f32_16x16x32_bf16(a_frag[i], b_frag[j], acc[i][j], 0, 0, 0);
    __syncthreads();
  }
#pragma unroll
  for (int i = 0; i < 2; ++i) {
#pragma unroll
    for (int rr = 0; rr < 4; ++rr) {
      int row = wm + i * 16 + lg * 4 + rr;
#pragma unroll
      for (int j = 0; j < 4; ++j) {
        int col = wn + j * 16 + lid;
        sig[row][col] = 1.f / (1.f + __expf(-acc[i][j][rr]));
      }
    }
  }
  __syncthreads();
  float err = 0.f;
#pragma unroll
  for (int it = 0; it < 8; ++it) {
    int idx = tid + it * 256;
    int rr = idx >> 5, c4 = idx & 31;
    float4 s4 = *(const float4*)&sig[rr][c4 * 4];
    size_t o = (size_t)(br + rr) * 4096 + bc + c4 * 4;
#pragma unroll
    for (int q = 0; q < 4; ++q) {
      float4 a = *(const float4*)&A4[(size_t)q * 16777216 + o];
      float d0 = s4.x - a.x, d1 = s4.y - a.y, d2 = s4.z - a.z, d3 = s4.w - a.w;
      err += d0 * d0 + d1 * d1 + d2 * d2 + d3 * d3;
    }
  }
  red[tid] = err;
  __syncthreads();
  for (int o = 128; o; o >>= 1){
    if (tid < o) red[tid] += red[tid + o];
    __syncthreads();
  }
  if (tid == 0) atomicAdd(lossAcc, red[0]);
}

// ---------------------------------------------------------------- MFMA flash attention (bf16 QKV packed, ld=384)
__global__ __launch_bounds__(256) void attn_mfma_k(
    const ushort_t* __restrict__ Q, const ushort_t* __restrict__ K, const ushort_t* __restrict__ V,
    const float* __restrict__ dbv, float* __restrict__ part)
{
  const int ld = 384;
  int h = blockIdx.y, sp = blockIdx.z;
  int qbase = blockIdx.x * 64;
  int tid = threadIdx.x;
  int w = tid >> 6, lane = tid & 63, lid = lane & 15, lg = lane >> 4;
  __shared__ __align__(16) ushort_t Vt[16][72];
  __shared__ __align__(16) ushort_t Pl[4][16][72];
  __shared__ float dbs[64];

  s16x8 qf;
  if (lg < 2) {
    u16x8 v = *(const u16x8*)(Q + (size_t)(qbase + 16 * w + lid) * ld + h * 16 + 8 * lg);
#pragma unroll
    for (int j = 0; j < 8; ++j) v[j] = f2bf(bf2f(v[j]) * 0.25f);
    qf = (s16x8)v;
  } else {
    qf = (s16x8){0,0,0,0,0,0,0,0};
  }

  float m = -1e30f, l = 0.f;
  f32x4 o = {0.f, 0.f, 0.f, 0.f};

  int kb0 = sp * (4096 / ASPLIT);
  for (int kt = 0; kt < 4096 / ASPLIT; kt += 64) {
    int kb = kb0 + kt;
    __syncthreads();
    {
      int key = tid >> 2, ds_ = (tid & 3) * 4;
      const ushort_t* vp = V + (size_t)(kb + key) * ld + h * 16 + ds_;
#pragma unroll
      for (int j = 0; j < 4; ++j) Vt[ds_ + j][key] = vp[j];
      if (tid < 64) dbs[tid] = dbv[kb + tid];
    }
    __syncthreads();

    f32x4 s[4];
#pragma unroll
    for (int g = 0; g < 4; ++g) {
      s16x8 kf;
      if (lg < 2) {
        kf = (s16x8)(*(const u16x8*)(K + (size_t)(kb + 16 * g + lid) * ld + h * 16 + 8 * lg));
      } else kf = (s16x8){0,0,0,0,0,0,0,0};
      s[g] = __builtin_amdgcn_mfma_f32_16x16x32_bf16(kf, qf, (f32x4){0.f,0.f,0.f,0.f}, 0, 0, 0);
    }
#pragma unroll
    for (int g = 0; g < 4; ++g)
#pragma unroll
      for (int r = 0; r < 4; ++r) s[g][r] += dbs[16 * g + 4 * lg + r];

    float tmax = -1e30f;
#pragma unroll
    for (int g = 0; g < 4; ++g)
#pragma unroll
      for (int r = 0; r < 4; ++r) tmax = fmaxf(tmax, s[g][r]);
    tmax = fmaxf(tmax, __shfl_xor(tmax, 16));
    tmax = fmaxf(tmax, __shfl_xor(tmax, 32));
    float mn = fmaxf(m, tmax);
    float scale = __expf(m - mn);
    float psum = 0.f;
    float p[4][4];
#pragma unroll
    for (int g = 0; g < 4; ++g)
#pragma unroll
      for (int r = 0; r < 4; ++r) { p[g][r] = __expf(s[g][r] - mn); psum += p[g][r]; }
    psum += __shfl_xor(psum, 16);
    psum += __shfl_xor(psum, 32);
    l = l * scale + psum;
    m = mn;

#pragma unroll
    for (int g = 0; g < 4; ++g) {
#pragma unroll
      for (int rp = 0; rp < 4; rp += 2) {
        unsigned pack = (unsigned)f2bf(p[g][rp]) | ((unsigned)f2bf(p[g][rp + 1]) << 16);
        *(unsigned*)&Pl[w][lid][16 * g + 4 * lg + rp] = pack;
      }
    }
#pragma unroll
    for (int r = 0; r < 4; ++r) o[r] *= __shfl(scale, 4 * lg + r);
#pragma unroll
    for (int kc = 0; kc < 2; ++kc) {
      s16x8 pa = *(s16x8*)&Pl[w][lid][32 * kc + 8 * lg];
      s16x8 vb = *(s16x8*)&Vt[lid][32 * kc + 8 * lg];
      o = __builtin_amdgcn_mfma_f32_16x16x32_bf16(pa, vb, o, 0, 0, 0);
    }
  }
  float* pb = part + ((size_t)(sp * 8 + h) * NA) * 18;
#pragma unroll
  for (int r = 0; r < 4; ++r) {
    int qq = qbase + 16 * w + 4 * lg + r;
    pb[(size_t)qq * 18 + lid] = o[r];
  }
  if (lg == 0) {
    int qq = qbase + 16 * w + lid;
    pb[(size_t)qq * 18 + 16] = m;
    pb[(size_t)qq * 18 + 17] = l;
  }
}

// ---------------------------------------------------------------- fused transformer tail (templated)
// MODE 0: combine->Wo->LN1->FF1->FF2->LN2 -> write outX f32 AND next-layer QKVb (bf16, via Wqkvt)
// MODE 1: same through LN2, then head: concat(hA2|o1|X) -> cat relu (x_gt) -> mlp1 relu -> mlp2+softmax
template<int MODE>
__global__ __launch_bounds__(256) void gt_tail_k(
    const float* __restrict__ part,
    const ushort_t* __restrict__ Wot, const float* __restrict__ bo,
    const float* __restrict__ xin,
    const float* __restrict__ g1, const float* __restrict__ be1,
    const ushort_t* __restrict__ Wf1t, const float* __restrict__ bf1,
    const ushort_t* __restrict__ Wf2t, const float* __restrict__ bf2,
    const float* __restrict__ g2, const float* __restrict__ be2,
    float* __restrict__ outX,
    const ushort_t* __restrict__ Wqkvt, const float* __restrict__ bqkv,
    const float* __restrict__ peQK, ushort_t* __restrict__ QKVb,
    const float* __restrict__ hA2, const float* __restrict__ o1,
    const ushort_t* __restrict__ catt, const float* __restrict__ cat_b,
    const ushort_t* __restrict__ mlp1t, const float* __restrict__ mlp_b1,
    const float* __restrict__ mlp_W2, const float* __restrict__ mlp_b2,
    const float* __restrict__ lossAcc, float* __restrict__ out)
{
  constexpr int AW = (MODE == 1) ? 392 : 136;
  __shared__ __align__(16) ushort_t Aly[16][AW];
  __shared__ __align__(16) ushort_t Bs[256][40];
  __shared__ __align__(16) ushort_t F1b[16][264];
  __shared__ float X1[16][132];
  __shared__ float LG[16][4];
  int bm = blockIdx.x * 16;
  int tid = threadIdx.x;
  int w = tid >> 6, lane = tid & 63, lg = lane >> 4, lid = lane & 15;
  if (MODE == 1 && blockIdx.x == 0 && tid == 0) out[0] = lossAcc[0] * (1.0f / 67108864.0f);

  // phase 0: split-attention combine -> O bf16 (16 x 128)
  {
    int row = bm + (tid >> 4);
    int seg = tid & 15;
    int kcol = seg * 8;
    int h = kcol >> 4, d0 = kcol & 15;
    float mm = -1e30f;
#pragma unroll
    for (int sp = 0; sp < ASPLIT; ++sp)
      mm = fmaxf(mm, part[((size_t)(sp * 8 + h) * NA + row) * 18 + 16]);
    float ll = 0.f, a[8];
#pragma unroll
    for (int j = 0; j < 8; ++j) a[j] = 0.f;
#pragma unroll
    for (int sp = 0; sp < ASPLIT; ++sp){
      const float* pp = part + ((size_t)(sp * 8 + h) * NA + row) * 18;
      float wq = __expf(pp[16] - mm);
      ll += pp[17] * wq;
#pragma unroll
      for (int j = 0; j < 8; ++j) a[j] = fmaf(pp[d0 + j], wq, a[j]);
    }
    float inv = 1.f / ll;
    u16x8 v;
#pragma unroll
    for (int j = 0; j < 8; ++j) v[j] = f2bf(a[j] * inv);
    *(u16x8*)&Aly[tid >> 4][kcol] = v;
  }
  __syncthreads();

  // phase 1: O @ Wo + bo + xin -> X1, LN1 -> Aly bf16 + X1 f32
  f32x4 acc1[2];
  acc1[0] = (f32x4){0.f,0.f,0.f,0.f};
  acc1[1] = (f32x4){0.f,0.f,0.f,0.f};
  for (int k0 = 0; k0 < 128; k0 += 32){
    int n = tid >> 1, ks = (tid & 1) * 16;
    *(u16x8*)&Bs[n][ks]     = *(const u16x8*)(Wot + (size_t)n * 128 + k0 + ks);
    *(u16x8*)&Bs[n][ks + 8] = *(const u16x8*)(Wot + (size_t)n * 128 + k0 + ks + 8);
    __syncthreads();
    s16x8 af = *(s16x8*)&Aly[lid][k0 + lg * 8];
#pragma unroll
    for (int j = 0; j < 2; ++j){
      s16x8 bf = *(s16x8*)&Bs[w * 32 + j * 16 + lid][lg * 8];
      acc1[j] = __builtin_amdgcn_mfma_f32_16x16x32_bf16(af, bf, acc1[j], 0, 0, 0);
    }
    __syncthreads();
  }
#pragma unroll
  for (int j = 0; j < 2; ++j)
#pragma unroll
    for (int rr = 0; rr < 4; ++rr){
      int r = lg * 4 + rr, c = w * 32 + j * 16 + lid;
      X1[r][c] = acc1[j][rr] + bo[c] + xin[(size_t)(bm + r) * 128 + c];
    }
  __syncthreads();
  {
    int r = tid >> 4, p = tid & 15;
    float s = 0.f, q = 0.f;
#pragma unroll
    for (int j = 0; j < 8; ++j){ float v = X1[r][p * 8 + j]; s += v; q += v * v; }
#pragma unroll
    for (int mk = 1; mk < 16; mk <<= 1){ s += __shfl_xor(s, mk); q += __shfl_xor(q, mk); }
    float mean = s * (1.f / 128.f), var = q * (1.f / 128.f) - mean * mean;
    float inv = rsqrtf(var + 1e-5f);
    u16x8 v;
#pragma unroll
    for (int j = 0; j < 8; ++j){
      int c = p * 8 + j;
      float f = (X1[r][c] - mean) * inv * g1[c] + be1[c];
      X1[r][c] = f;
      v[j] = f2bf(f);
    }
    *(u16x8*)&Aly[r][p * 8] = v;
  }
  __syncthreads();

  // phase 2: x1 @ Wf1 + bf1, relu -> F1b (16 x 256)
  f32x4 acc2[4];
#pragma unroll
  for (int j = 0; j < 4; ++j) acc2[j] = (f32x4){0.f,0.f,0.f,0.f};
  for (int k0 = 0; k0 < 128; k0 += 32){
#pragma unroll
    for (int q4 = 0; q4 < 4; ++q4)
      *(u16x8*)&Bs[tid][q4 * 8] = *(const u16x8*)(Wf1t + (size_t)tid * 128 + k0 + q4 * 8);
    __syncthreads();
    s16x8 af = *(s16x8*)&Aly[lid][k0 + lg * 8];
#pragma unroll
    for (int j = 0; j < 4; ++j){
      s16x8 bf = *(s16x8*)&Bs[w * 64 + j * 16 + lid][lg * 8];
      acc2[j] = __builtin_amdgcn_mfma_f32_16x16x32_bf16(af, bf, acc2[j], 0, 0, 0);
    }
    __syncthreads();
  }
#pragma unroll
  for (int j = 0; j < 4; ++j)
#pragma unroll
    for (int rr = 0; rr < 4; ++rr){
      int r = lg * 4 + rr, c = w * 64 + j * 16 + lid;
      F1b[r][c] = f2bf(fmaxf(acc2[j][rr] + bf1[c], 0.f));
    }
  __syncthreads();

  // phase 3: f1 @ Wf2 + bf2 + X1 -> LN2 -> X1 (normalized) [+ outX in MODE 0]
  f32x4 acc3[2];
  acc3[0] = (f32x4){0.f,0.f,0.f,0.f};
  acc3[1] = (f32x4){0.f,0.f,0.f,0.f};
  for (int k0 = 0; k0 < 256; k0 += 32){
    int n = tid >> 1, ks = (tid & 1) * 16;
    *(u16x8*)&Bs[n][ks]     = *(const u16x8*)(Wf2t + (size_t)n * 256 + k0 + ks);
    *(u16x8*)&Bs[n][ks + 8] = *(const u16x8*)(Wf2t + (size_t)n * 256 + k0 + ks + 8);
    __syncthreads();
    s16x8 af = *(s16x8*)&F1b[lid][k0 + lg * 8];
#pragma unroll
    for (int j = 0; j < 2; ++j){
      s16x8 bf = *(s16x8*)&Bs[w * 32 + j * 16 + lid][lg * 8];
      acc3[j] = __builtin_amdgcn_mfma_f32_16x16x32_bf16(af, bf, acc3[j], 0, 0, 0);
    }
    __syncthreads();
  }
#pragma unroll
  for (int j = 0; j < 2; ++j)
#pragma unroll
    for (int rr = 0; rr < 4; ++rr){
      int r = lg * 4 + rr, c = w * 32 + j * 16 + lid;
      X1[r][c] = acc3[j][rr] + bf2[c] + X1[r][c];
    }
  __syncthreads();
  {
    int r = tid >> 4, p = tid & 15;
    float s = 0.f, q = 0.f;
#pragma unroll
    for (int j = 0; j < 8; ++j){ float v = X1[r][p * 8 + j]; s += v; q += v * v; }
#pragma unroll
    for (int mk = 1; mk < 16; mk <<= 1){ s += __shfl_xor(s, mk); q += __shfl_xor(q, mk); }
    float mean = s * (1.f / 128.f), var = q * (1.f / 128.f) - mean * mean;
    float inv = rsqrtf(var + 1e-5f);
    u16x8 v;
#pragma unroll
    for (int j = 0; j < 8; ++j){
      int c = p * 8 + j;
      float f = (X1[r][c] - mean) * inv * g2[c] + be2[c];
      X1[r][c] = f;
      v[j] = f2bf(f);
      if (MODE == 0) outX[(size_t)(bm + r) * 128 + c] = f;
    }
    if (MODE == 0) *(u16x8*)&Aly[r][p * 8] = v;           // X bf16 for QKV
    else           *(u16x8*)&Aly[r][256 + p * 8] = v;     // concat slot 2
  }
  __syncthreads();

  if constexpr (MODE == 0) {
    // phase 4: X @ Wqkvt (N=384) + bqkv + peQK(cols<256) -> QKVb bf16
#pragma unroll
    for (int nb = 0; nb < 2; ++nb) {
      f32x4 acc4[3];
#pragma unroll
      for (int j = 0; j < 3; ++j) acc4[j] = (f32x4){0.f,0.f,0.f,0.f};
      for (int k0 = 0; k0 < 128; k0 += 32){
#pragma unroll
        for (int p = 0; p < 3; ++p){
          int idx = tid + p * 256;   // < 768
          int n = idx >> 2, seg = (idx & 3) * 8;
          *(u16x8*)&Bs[n][seg] = *(const u16x8*)(Wqkvt + (size_t)(nb * 192 + n) * 128 + k0 + seg);
        }
        __syncthreads();
        s16x8 af = *(s16x8*)&Aly[lid][k0 + lg * 8];
#pragma unroll
        for (int j = 0; j < 3; ++j){
          s16x8 bf = *(s16x8*)&Bs[w * 48 + j * 16 + lid][lg * 8];
          acc4[j] = __builtin_amdgcn_mfma_f32_16x16x32_bf16(af, bf, acc4[j], 0, 0, 0);
        }
        __syncthreads();
      }
#pragma unroll
      for (int j = 0; j < 3; ++j)
#pragma unroll
        for (int rr = 0; rr < 4; ++rr){
          int r = lg * 4 + rr, c = nb * 192 + w * 48 + j * 16 + lid;
          float v = acc4[j][rr] + bqkv[c];
          if (c < 256) v += peQK[(size_t)(bm + r) * 256 + c];
          QKVb[(size_t)(bm + r) * 384 + c] = f2bf(v);
        }
    }
  } else {
    // phase 4': head. stage concat cols 0..255 from hA2/o1
    {
      int r = bm + (tid >> 4), seg = tid & 15;
#pragma unroll
      for (int ch = 0; ch < 2; ++ch){
        int c0 = seg * 16 + ch * 8;   // 0..255
        const float* src; int cc;
        if (c0 < 128) { src = hA2; cc = c0; }
        else          { src = o1;  cc = c0 - 128; }
        u16x8 v;
#pragma unroll
        for (int j = 0; j < 8; ++j) v[j] = f2bf(src[(size_t)r * 128 + cc + j]);
        *(u16x8*)&Aly[tid >> 4][c0] = v;
      }
    }
    __syncthreads();
    // GEMM1: 384 -> 128, relu; write x_gt, keep bf16 in Aly[.][0..128)
    float* xgt = out + 1 + NA * 4;
    f32x4 acc1b[2];
    acc1b[0] = (f32x4){0.f,0.f,0.f,0.f};
    acc1b[1] = (f32x4){0.f,0.f,0.f,0.f};
    for (int k0 = 0; k0 < 384; k0 += 32){
      int n = tid >> 1, ks = (tid & 1) * 16;
      *(u16x8*)&Bs[n][ks]     = *(const u16x8*)(catt + (size_t)n * 384 + k0 + ks);
      *(u16x8*)&Bs[n][ks + 8] = *(const u16x8*)(catt + (size_t)n * 384 + k0 + ks + 8);
      __syncthreads();
      s16x8 af = *(s16x8*)&Aly[lid][k0 + lg * 8];
#pragma unroll
      for (int j = 0; j < 2; ++j){
        s16x8 bf = *(s16x8*)&Bs[w * 32 + j * 16 + lid][lg * 8];
        acc1b[j] = __builtin_amdgcn_mfma_f32_16x16x32_bf16(af, bf, acc1b[j], 0, 0, 0);
      }
      __syncthreads();
    }
#pragma unroll
    for (int j = 0; j < 2; ++j)
#pragma unroll
      for (int rr = 0; rr < 4; ++rr){
        int r = lg * 4 + rr, c = w * 32 + j * 16 + lid;
        float f = fmaxf(acc1b[j][rr] + cat_b[c], 0.f);
        xgt[(size_t)(bm + r) * 128 + c] = f;
        Aly[r][c] = f2bf(f);
      }
    __syncthreads();
    // GEMM2: 128 -> 256, relu -> F1b
    f32x4 acc2b[4];
#pragma unroll
    for (int j = 0; j < 4; ++j) acc2b[j] = (f32x4){0.f,0.f,0.f,0.f};
    for (int k0 = 0; k0 < 128; k0 += 32){
#pragma unroll
      for (int q4 = 0; q4 < 4; ++q4)
        *(u16x8*)&Bs[tid][q4 * 8] = *(const u16x8*)(mlp1t + (size_t)tid * 128 + k0 + q4 * 8);
      __syncthreads();
      s16x8 af = *(s16x8*)&Aly[lid][k0 + lg * 8];
#pragma unroll
      for (int j = 0; j < 4; ++j){
        s16x8 bf = *(s16x8*)&Bs[w * 64 + j * 16 + lid][lg * 8];
        acc2b[j] = __builtin_amdgcn_mfma_f32_16x16x32_bf16(af, bf, acc2b[j], 0, 0, 0);
      }
      __syncthreads();
    }
#pragma unroll
    for (int j = 0; j < 4; ++j)
#pragma unroll
      for (int rr = 0; rr < 4; ++rr){
        int r = lg * 4 + rr, c = w * 64 + j * 16 + lid;
        F1b[r][c] = f2bf(fmaxf(acc2b[j][rr] + mlp_b1[c], 0.f));
      }
    __syncthreads();
    // mlp2 (K=256, N=4) + softmax
    {
      int r = tid >> 4, rem = tid & 15, c = rem >> 2, p = rem & 3;
      float s = 0.f;
      for (int k = p * 64; k < p * 64 + 64; ++k)
        s = fmaf(bf2f(F1b[r][k]), mlp_W2[(size_t)k * 4 + c], s);
      s += __shfl_xor(s, 1);
      s += __shfl_xor(s, 2);
      if (p == 0) LG[r][c] = s + mlp_b2[c];
    }
    __syncthreads();
    if (tid < 16){
      int r = tid;
      float l0 = LG[r][0], l1 = LG[r][1], l2 = LG[r][2], l3 = LG[r][3];
      float mx = fmaxf(fmaxf(l0, l1), fmaxf(l2, l3));
      float e0 = __expf(l0 - mx), e1 = __expf(l1 - mx), e2 = __expf(l2 - mx), e3 = __expf(l3 - mx);
      float inv = 1.f / (e0 + e1 + e2 + e3);
      float* o = out + 1 + (size_t)(bm + r) * 4;
      o[0] = e0 * inv; o[1] = e1 * inv; o[2] = e2 * inv; o[3] = e3 * inv;
    }
  }
}

__global__ void setval_k(float* p, float v){ p[0] = v; }

// ---------------------------------------------------------------- host
extern "C" void kernel_launch(void* const* d_in, const int* in_sizes, int n_in,
                              void* d_out, int out_size, void* d_ws, size_t ws_size,
                              hipStream_t stream)
{
  (void)in_sizes; (void)n_in; (void)out_size;
  const float* x_author = (const float*)d_in[0];
  const float* x_paper  = (const float*)d_in[1];
  const float* x_term   = (const float*)d_in[2];
  const int* ap_src = (const int*)d_in[3];
  const int* ap_dst = (const int*)d_in[4];
  const int* pa_src = (const int*)d_in[5];
  const int* pa_dst = (const int*)d_in[6];
  const int* tp_src = (const int*)d_in[9];
  const int* tp_dst = (const int*)d_in[10];
  const float* original_A = (const float*)d_in[11];
  const int* deg = (const int*)d_in[12];
  const float* t1_W = (const float*)d_in[13]; const float* t1_b = (const float*)d_in[14];
  const float* t2_W = (const float*)d_in[15]; const float* t2_b = (const float*)d_in[16];
  const float* t3_W = (const float*)d_in[17]; const float* t3_b = (const float*)d_in[18];
  const float* gat1_W  = (const float*)d_in[19];
  const float* gat1_as = (const float*)d_in[20];
  const float* gat1_ad = (const float*)d_in[21];
  const float* gat1_b  = (const float*)d_in[22];
  const float* gat2_W  = (const float*)d_in[23];
  const float* gat2_as = (const float*)d_in[24];
  const float* gat2_ad = (const float*)d_in[25];
  const float* gat2_b  = (const float*)d_in[26];
  const float* pe_embed = (const float*)d_in[27];
  const float* peWQ = (const float*)d_in[28];
  const float* peWK = (const float*)d_in[29];
  const float* gt_Wq = (const float*)d_in[30]; const float* gt_bq = (const float*)d_in[31];
  const float* gt_Wk = (const float*)d_in[32]; const float* gt_bk = (const float*)d_in[33];
  const float* gt_Wv = (const float*)d_in[34]; const float* gt_bv = (const float*)d_in[35];
  const float* gt_Wo = (const float*)d_in[36]; const float* gt_bo = (const float*)d_in[37];
  const float* gt_g1 = (const float*)d_in[38]; const float* gt_be1 = (const float*)d_in[39];
  const float* gt_Wf1 = (const float*)d_in[40]; const float* gt_bf1 = (const float*)d_in[41];
  const float* gt_Wf2 = (const float*)d_in[42]; const float* gt_bf2 = (const float*)d_in[43];
  const float* gt_g2 = (const float*)d_in[44]; const float* gt_be2 = (const float*)d_in[45];
  const float* cat_W = (const float*)d_in[46]; const float* cat_b = (const float*)d_in[47];
  const float* mlp_W1 = (const float*)d_in[48]; const float* mlp_b1 = (const float*)d_in[49];
  const float* mlp_W2 = (const float*)d_in[50]; const float* mlp_b2 = (const float*)d_in[51];
  float* out = (float*)d_out;

  // ---- workspace layout ----
  char* base = (char*)d_ws;
  size_t off = 0;
  auto alloc = [&](size_t nbytes) -> void* {
    void* p = base + off;
    off += (nbytes + 255) & ~(size_t)255;
    return p;
  };
  ushort_t* xa  = (ushort_t*)alloc((size_t)NA * 128 * 2);
  ushort_t* xp  = (ushort_t*)alloc((size_t)NPA * 128 * 2);
  ushort_t* xt  = (ushort_t*)alloc((size_t)NT * 128 * 2);
  ushort_t* accP = (ushort_t*)alloc((size_t)NPA * 1024 * 2); // +accA contiguous; aliased as attn part
  ushort_t* accA = (ushort_t*)alloc((size_t)NA * 1024 * 2);
  ushort_t* agg  = (ushort_t*)alloc((size_t)NSLOT * 1024 * 2);
  float* scores = (float*)alloc((size_t)36864 * 8 * 4);
  float* Ps   = (float*)alloc(3 * 1024 * 4);
  float* Pd   = (float*)alloc(3 * 1024 * 4);
  ushort_t* hs2 = (ushort_t*)alloc((size_t)NPA * 128 * 2);   // +hd2 contiguous
  ushort_t* hd2 = (ushort_t*)alloc((size_t)NA * 128 * 2);
  float* s2sd = (float*)alloc((size_t)(NPA + NA) * 4);
  float* hA2  = (float*)alloc((size_t)NA * 128 * 4);
  float* peQK = (float*)alloc((size_t)NA * 256 * 4);
  float* dbv  = (float*)alloc((size_t)NA * 4);
  float* bsum = (float*)alloc(1024 * 4);
  float* Wqkv = (float*)alloc((size_t)2 * 128 * 384 * 4);
  float* bqkv = (float*)alloc((size_t)2 * 384 * 4);
  float* peW  = (float*)alloc((size_t)128 * 256 * 4);
  float* Bstack = (float*)alloc((size_t)256 * 1024 * 4);
  ushort_t* Wot   = (ushort_t*)alloc((size_t)2 * 128 * 128 * 2);
  ushort_t* Wf1t  = (ushort_t*)alloc((size_t)2 * 256 * 128 * 2);
  ushort_t* Wf2t  = (ushort_t*)alloc((size_t)2 * 128 * 256 * 2);
  ushort_t* catt  = (ushort_t*)alloc((size_t)128 * 384 * 2);
  ushort_t* mlp1t = (ushort_t*)alloc((size_t)256 * 128 * 2);
  ushort_t* Wqkvt = (ushort_t*)alloc((size_t)2 * 384 * 128 * 2);
  ushort_t* QKVb = (ushort_t*)alloc((size_t)NA * 384 * 2);
  float* outs1= (float*)alloc((size_t)NA * 128 * 4);
  int*   offb = (int*)alloc((size_t)NSLOT * 4);
  int*   eidx = (int*)alloc((size_t)E_TOT * 4);
  // ---- zero-init region (single small memset): cnt, cur, lossAcc ----
  size_t zstart = off;
  int*      cnt   = (int*)alloc((size_t)NSLOT * 4);
  int*      cur   = (int*)alloc((size_t)NSLOT * 4);
  float*    lossAcc = (float*)alloc(256);
  size_t zlen = off - zstart;

  float* part = (float*)accP;  // 9.4 MB f32 partials alias onto accP+accA (dead by transformer)

  if (off > ws_size){
    setval_k<<<1, 1, 0, stream>>>(out, -12345.0f);
    return;
  }

  auto gemmx = [&](int act, int tn, const void* A, const void* A2, const void* A3, int aBf16,
                   const float* B, void* C, int cBf16, const float* bias,
                   const float* addmat, int addCols, int addLd,
                   const float* lng, const float* lnb, float* rdOut,
                   int M, int N, int K, int lda, int ldb, int ldc){
    dim3 g(M / 64, N / tn, 1);
    if (tn == 128) {
      if (act == 0)      gemm_mfma_k<0,128><<<g, 256, 0, stream>>>(A, A2, A3, aBf16, B, C, cBf16, bias, addmat, addCols, addLd, lng, lnb, rdOut, M, N, K, lda, ldb, ldc);
      else if (act == 1) gemm_mfma_k<1,128><<<g, 256, 0, stream>>>(A, A2, A3, aBf16, B, C, cBf16, bias, addmat, addCols, addLd, lng, lnb, rdOut, M, N, K, lda, ldb, ldc);
      else               gemm_mfma_k<3,128><<<g, 256, 0, stream>>>(A, A2, A3, aBf16, B, C, cBf16, bias, addmat, addCols, addLd, lng, lnb, rdOut, M, N, K, lda, ldb, ldc);
    } else {
      if (act == 0)      gemm_mfma_k<0,64><<<g, 256, 0, stream>>>(A, A2, A3, aBf16, B, C, cBf16, bias, addmat, addCols, addLd, lng, lnb, rdOut, M, N, K, lda, ldb, ldc);
      else               gemm_mfma_k<1,64><<<g, 256, 0, stream>>>(A, A2, A3, aBf16, B, C, cBf16, bias, addmat, addCols, addLd, lng, lnb, rdOut, M, N, K, lda, ldb, ldc);
    }
  };

  // 1. zero-init (tiny)
  hipMemsetAsync(base + zstart, 0, zlen, stream);
  // 2. prep
  prep_k<<<4165, 256, 0, stream>>>(gat1_b, gat1_W, gt_Wq, gt_bq, gt_Wk, gt_bk, gt_Wv, gt_bv,
                                   peWQ, peWK, deg, gat1_as, gat1_ad, ap_dst, tp_dst, pa_dst,
                                   gt_Wo, gt_Wf1, gt_Wf2, cat_W, mlp_W1,
                                   bsum, Wqkv, bqkv, peW, Bstack, dbv, Ps, Pd, cnt,
                                   Wot, Wf1t, Wf2t, catt, mlp1t, Wqkvt);
  // 3. D1 mega-GEMM: 3 stage-0 MLPs + peQK (768 tiles)
  {
    GDescArr da; da.nd = 4;
    da.d[0] = { x_author, nullptr, t1_W, xa, t1_b, 0, 1, 1, NA, 128, 334, 334, 128, 128, 1, 0, 0, 0, 0 };
    da.d[1] = { x_paper,  nullptr, t2_W, xp, t2_b, 0, 1, 1, NPA, 128, 512, 512, 128, 128, 1, 0, 0, 0, 128 };
    da.d[2] = { x_term,   nullptr, t3_W, xt, t3_b, 0, 1, 1, NT, 128, 128, 128, 128, 128, 1, 0, 0, 0, 384 };
    da.d[3] = { pe_embed, nullptr, peW, peQK, nullptr, 0, 0, 0, NA, 256, 128, 128, 256, 256, 1, 0, 0, 0, 512 };
    gemm_multi_k<<<768, 256, 0, stream>>>(da);
  }
  // 4-5. CSR scan + scatter
  exscan_k<<<1, 1024, 0, stream>>>(cnt, offb, NSLOT);
  scatterf_k<<<(E_TOT + 255) / 256, 256, 0, stream>>>(ap_dst, tp_dst, pa_dst, offb, cur, eidx);
  // 6-7. GAT1: scores, fused online softmax+aggregate
  scorev_k<<<9216, 256, 0, stream>>>(xa, xp, xt, Ps, Pd, scores);
  agg8ff_k<<<NSLOT / 4, 256, 0, stream>>>(eidx, offb, cnt, ap_src, tp_src, pa_src,
                                          xa, xt, xp, scores, agg);
  // 8. D2 mega-GEMM: GAT1 per-head transforms — 3072 tiles
  {
    GDescArr da; da.nd = 2;
    da.d[0] = { agg, agg + (size_t)NPA * 1024, Bstack, accP, bsum, 1, 1, 1,
                NPA, 128, 256, 1024, 1024, 1024, 8, 128, 128, 128, 0 };
    da.d[1] = { agg + (size_t)2 * NPA * 1024, nullptr, gat1_W + 131072, accA, gat1_b + 1024, 1, 1, 1,
                NA, 128, 128, 1024, 1024, 1024, 8, 128, 128, 128, 2048 };
    gemm_multi_k<<<3072, 256, 0, stream>>>(da);
  }
  // 9-10. GAT2: hs2 GEMM + fused rowdot, then aggregation
  gemmx(3, 128, accP, 0, 0, 1, gat2_W + 131072, hs2, 1, 0, 0, 0, 0,
        gat2_as + 128, gat2_ad + 128, s2sd, NPA + NA, 128, 1024, 1024, 128, 128);
  gat_agg1f_k<<<NA / 4, 256, 0, stream>>>(eidx, offb + 2 * NPA, cnt + 2 * NPA, pa_src, hs2, s2sd,
                                          gat2_b + 128, hA2, NA);
  // 11. PE reconstruction loss
  loss_mfma_k<<<dim3(64, 32), 256, 0, stream>>>(peQK, peQK + 128, original_A, lossAcc);
  // 12. QKV layer 0
  gemmx(0, 64, hA2, 0, 0, 0, Wqkv, QKVb, 1, bqkv, peQK, 256, 256,
        0, 0, 0, NA, 384, 128, 128, 384, 384);
  // 13-14. attention + tail layer 0 (emits outs1 + QKVb for layer 1)
  attn_mfma_k<<<dim3(NA / 64, 8, ASPLIT), 256, 0, stream>>>(QKVb, QKVb + 128, QKVb + 256, dbv, part);
  gt_tail_k<0><<<NA / 16, 256, 0, stream>>>(part, Wot, gt_bo, hA2,
                                            gt_g1, gt_be1, Wf1t, gt_bf1, Wf2t, gt_bf2,
                                            gt_g2, gt_be2, outs1,
                                            Wqkvt + (size_t)49152, bqkv + 384, peQK, QKVb,
                                            nullptr, nullptr, nullptr, nullptr,
                                            nullptr, nullptr, nullptr, nullptr, nullptr, nullptr);
  // 15-16. attention + tail layer 1 (fused head)
  attn_mfma_k<<<dim3(NA / 64, 8, ASPLIT), 256, 0, stream>>>(QKVb, QKVb + 128, QKVb + 256, dbv, part);
  gt_tail_k<1><<<NA / 16, 256, 0, stream>>>(part, Wot + 16384, gt_bo + 128, outs1,
                                            gt_g1 + 128, gt_be1 + 128, Wf1t + 32768, gt_bf1 + 256,
                                            Wf2t + 32768, gt_bf2 + 128,
                                            gt_g2 + 128, gt_be2 + 128, nullptr,
                                            nullptr, nullptr, nullptr, nullptr,
                                            hA2, outs1, catt, cat_b, mlp1t, mlp_b1,
                                            mlp_W2, mlp_b2, lossAcc, out);
}